// Round 4
// baseline (1984.289 us; speedup 1.0000x reference)
//
#include <hip/hip_runtime.h>
#include <hip/hip_bf16.h>
#include <math.h>

#define EPS 1e-5f
#define FL_SPLITS 5
#define FL_KEYS 500

typedef __attribute__((ext_vector_type(8))) short short8;
typedef __attribute__((ext_vector_type(4))) float f4;

__device__ __forceinline__ short f2s(float f) {
    union { float f; unsigned u; } v; v.f = f;
    unsigned r = (v.u + 0x7fffu + ((v.u >> 16) & 1u)) >> 16;  // RNE
    return (short)r;
}
__device__ __forceinline__ unsigned packbf(float a, float b) {
    return (unsigned)(unsigned short)f2s(a) | ((unsigned)(unsigned short)f2s(b) << 16);
}
__device__ __forceinline__ float bflo(unsigned v) { union { unsigned u; float f; } t; t.u = v << 16; return t.f; }
__device__ __forceinline__ float bfhi(unsigned v) { union { unsigned u; float f; } t; t.u = v & 0xffff0000u; return t.f; }

// ---------------- weight preprocessing ----------------
__global__ __launch_bounds__(256) void wcast_k(const float* __restrict__ in, short* __restrict__ out, int n)
{
    int i = blockIdx.x * 256 + threadIdx.x;
    if (i < n) out[i] = f2s(in[i]);
}

// conv weight reorder: (Cout, Cin, 3,3) fp32 -> (Cout, 9, Cin) bf16 (tap-major)
__global__ __launch_bounds__(256) void wreord_k(const float* __restrict__ in, short* __restrict__ out,
                                                int Cin, int n)
{
    int i = blockIdx.x * 256 + threadIdx.x;
    if (i >= n) return;
    int cin9 = Cin * 9;
    int co = i / cin9, rem = i - co * cin9;
    int ci = rem / 9, t = rem - ci * 9;
    out[(long)co * cin9 + t * Cin + ci] = f2s(in[i]);
}

// (K,N) fp32 -> (N,K) bf16 ; blockIdx.z = matrix index, zstride = output stride per matrix
__global__ __launch_bounds__(256) void wtrans_k(const float* __restrict__ in, short* __restrict__ out,
                                                int K, int N, long zstride)
{
    in  += (long)blockIdx.z * K * N;
    out += (long)blockIdx.z * zstride;
    __shared__ float t[64][65];
    int k0 = blockIdx.y * 64, n0 = blockIdx.x * 64;
    int tid = threadIdx.x;
    int cl = tid & 63, rq = tid >> 6;
    #pragma unroll
    for (int i = 0; i < 16; i++) {
        int rl = rq + i * 4;
        int k = k0 + rl, n = n0 + cl;
        t[rl][cl] = (k < K && n < N) ? in[(long)k * N + n] : 0.f;
    }
    __syncthreads();
    #pragma unroll
    for (int i = 0; i < 16; i++) {
        int nl = rq + i * 4;
        int n = n0 + nl, k = k0 + cl;
        if (n < N && k < K) out[(long)n * K + k] = f2s(t[cl][nl]);
    }
}

// pack per-layer bias segments
__global__ __launch_bounds__(256) void packb_k(const float* __restrict__ a, const float* __restrict__ b,
                                               const float* __restrict__ c, float* __restrict__ y,
                                               int na, int nb, int nc)
{
    int l = blockIdx.y;
    int j = blockIdx.x * 256 + threadIdx.x;
    int ntot = na + nb + nc;
    if (j >= ntot) return;
    float v;
    if (j < na) v = a[l * na + j];
    else if (j < na + nb) v = b[l * nb + (j - na)];
    else v = c[l * nc + (j - na - nb)];
    y[(long)l * ntot + j] = v;
}

// ---------------- MFMA GEMM: C[M,N] = A(fp32 MxK) @ Bt(bf16 NxK)^T ----------------
__global__ __launch_bounds__(256) void mgemm_k(const float* __restrict__ A, int lda,
                                               const short* __restrict__ Bt,
                                               const float* __restrict__ bias,
                                               const float* __restrict__ resid,
                                               float* __restrict__ C,
                                               int M, int N, int K, int act)
{
    __shared__ __align__(16) short As[5120];   // 128 rows x 40 (32 used)
    __shared__ __align__(16) short Bs[5120];
    int tid = threadIdx.x;
    int wave = tid >> 6, lane = tid & 63;
    int wm = wave >> 1, wn = wave & 1;
    int quad = lane >> 4, l15 = lane & 15;
    int m0 = blockIdx.y * 128, n0 = blockIdx.x * 128;
    f4 acc[4][4];
    #pragma unroll
    for (int i = 0; i < 4; i++)
        #pragma unroll
        for (int j = 0; j < 4; j++)
            acc[i][j] = (f4){0.f, 0.f, 0.f, 0.f};
    for (int kt = 0; kt < K; kt += 32) {
        #pragma unroll
        for (int i = 0; i < 2; i++) {
            int u = tid + (i << 8);
            int row = u >> 2, kc = (u & 3) << 3;
            int gm = m0 + row;
            short8 pk = {0, 0, 0, 0, 0, 0, 0, 0};
            if (gm < M) {
                const float4* ap = (const float4*)(A + (long)gm * lda + kt + kc);
                float4 v0 = ap[0], v1 = ap[1];
                pk[0] = f2s(v0.x); pk[1] = f2s(v0.y); pk[2] = f2s(v0.z); pk[3] = f2s(v0.w);
                pk[4] = f2s(v1.x); pk[5] = f2s(v1.y); pk[6] = f2s(v1.z); pk[7] = f2s(v1.w);
            }
            *(short8*)&As[row * 40 + kc] = pk;
            int gn = n0 + row;
            short8 pb = {0, 0, 0, 0, 0, 0, 0, 0};
            if (gn < N) pb = *(const short8*)&Bt[(long)gn * K + kt + kc];
            *(short8*)&Bs[row * 40 + kc] = pb;
        }
        __syncthreads();
        short8 af[4], bf[4];
        #pragma unroll
        for (int mi = 0; mi < 4; mi++) af[mi] = *(const short8*)&As[(wm * 64 + mi * 16 + l15) * 40 + (quad << 3)];
        #pragma unroll
        for (int ni = 0; ni < 4; ni++) bf[ni] = *(const short8*)&Bs[(wn * 64 + ni * 16 + l15) * 40 + (quad << 3)];
        #pragma unroll
        for (int mi = 0; mi < 4; mi++)
            #pragma unroll
            for (int ni = 0; ni < 4; ni++)
                acc[mi][ni] = __builtin_amdgcn_mfma_f32_16x16x32_bf16(af[mi], bf[ni], acc[mi][ni], 0, 0, 0);
        __syncthreads();
    }
    #pragma unroll
    for (int mi = 0; mi < 4; mi++) {
        int row = m0 + wm * 64 + mi * 16 + quad * 4;
        #pragma unroll
        for (int ni = 0; ni < 4; ni++) {
            int col = n0 + wn * 64 + ni * 16 + l15;
            if (col >= N) continue;
            float bv = bias[col];
            #pragma unroll
            for (int r = 0; r < 4; r++) {
                int rr = row + r;
                if (rr >= M) continue;
                float v = acc[mi][ni][r] + bv;
                if (act == 2) v = 0.5f * v * (1.f + erff(v * 0.70710678118654752f));
                if (resid) v += resid[(long)rr * N + col];
                C[(long)rr * N + col] = v;
            }
        }
    }
}

// ---------------- MFMA conv 3x3 s2 p1, tap-major K, bf16-pair input ----------------
// mode 1: f32 spatial-major out (ostride floats). mode 2: bf16-pair out (ostride dwords) + GN partial stats.
__global__ __launch_bounds__(256) void mconv_k(const unsigned* __restrict__ in,
                                               const short* __restrict__ wgt,
                                               const float* __restrict__ bias,
                                               float* __restrict__ out,
                                               float2* __restrict__ parts,
                                               int c5m, int Cout, int Hin, int Win,
                                               int mode, int cpg,
                                               long istride, long ostride)
{
    in  += (long)blockIdx.z * istride;
    const int Hout = Hin >> 1, Wout = Win >> 1;
    const int HWo = Hout * Wout;
    const int HW = Hin * Win;
    const int Ktot = 288 << c5m;   // 9*Cin
    const int m5 = (1 << c5m) - 1;
    const int nsteps = 9 << c5m;
    __shared__ __align__(16) short As[2560];   // 64 rows x 40
    __shared__ __align__(16) short Bs[2560];   // 64 cols x 40
    __shared__ float2 sred[16][2];             // [quad-group][wn] = (s, s2)
    int tid = threadIdx.x;
    int wave = tid >> 6, lane = tid & 63;
    int wm = wave >> 1, wn = wave & 1;
    int quad = lane >> 4, l15 = lane & 15;
    int m0 = blockIdx.y * 64, n0 = blockIdx.x * 64;
    int nn = tid & 63;
    int kp0 = tid >> 6;
    int p = n0 + nn;
    int pok = p < HWo;
    int pc = pok ? p : (HWo - 1);
    int ho = pc / Wout, wo = pc - ho * Wout;
    int hb = ho * 2 - 1, wb = wo * 2 - 1;

    f4 acc[2][2];
    #pragma unroll
    for (int i = 0; i < 2; i++) { acc[i][0] = (f4){0.f,0.f,0.f,0.f}; acc[i][1] = (f4){0.f,0.f,0.f,0.f}; }

    short8 aR;
    unsigned bR[4];
    auto loadA = [&](int s) {
        int r = tid >> 2, kc = (tid & 3) << 3;
        aR = *(const short8*)&wgt[(long)(m0 + r) * Ktot + (s << 5) + kc];
    };
    auto loadB = [&](int s) {
        int t = s >> c5m;
        int kh = (t * 11) >> 5;            // t/3 for t in 0..8
        int kw = t - kh * 3;
        int y = hb + kh, x = wb + kw;
        bool okp = pok && ((unsigned)y < (unsigned)Hin) && ((unsigned)x < (unsigned)Win);
        int base = (((s & m5) << 4) + kp0) * HW + y * Win + x;
        #pragma unroll
        for (int i = 0; i < 4; i++) {
            unsigned v = 0;
            if (okp) v = in[base + (i << 2) * HW];
            bR[i] = v;
        }
    };

    loadA(0); loadB(0);
    for (int s = 0; s < nsteps; s++) {
        {
            int r = tid >> 2, kc = (tid & 3) << 3;
            *(short8*)&As[r * 40 + kc] = aR;
        }
        #pragma unroll
        for (int i = 0; i < 4; i++)
            *(unsigned*)&Bs[nn * 40 + ((kp0 + (i << 2)) << 1)] = bR[i];
        __syncthreads();
        if (s + 1 < nsteps) { loadA(s + 1); loadB(s + 1); }
        short8 af[2], bf[2];
        #pragma unroll
        for (int mi = 0; mi < 2; mi++) af[mi] = *(const short8*)&As[(wm * 32 + mi * 16 + l15) * 40 + (quad << 3)];
        #pragma unroll
        for (int ni = 0; ni < 2; ni++) bf[ni] = *(const short8*)&Bs[(wn * 32 + ni * 16 + l15) * 40 + (quad << 3)];
        #pragma unroll
        for (int mi = 0; mi < 2; mi++)
            #pragma unroll
            for (int ni = 0; ni < 2; ni++)
                acc[mi][ni] = __builtin_amdgcn_mfma_f32_16x16x32_bf16(af[mi], bf[ni], acc[mi][ni], 0, 0, 0);
        __syncthreads();
    }

    if (mode == 1) {
        float* outf = out + (long)blockIdx.z * ostride;
        #pragma unroll
        for (int mi = 0; mi < 2; mi++) {
            int mbase = m0 + wm * 32 + mi * 16 + quad * 4;
            #pragma unroll
            for (int ni = 0; ni < 2; ni++) {
                int n = n0 + wn * 32 + ni * 16 + l15;
                if (n >= HWo) continue;
                #pragma unroll
                for (int r = 0; r < 4; r++) {
                    int m = mbase + r;
                    outf[(long)n * Cout + m] = acc[mi][ni][r] + bias[m];
                }
            }
        }
    } else {
        unsigned* outp = (unsigned*)out + (long)blockIdx.z * ostride;
        float ssum[2] = {0.f, 0.f}, qsum[2] = {0.f, 0.f};
        #pragma unroll
        for (int mi = 0; mi < 2; mi++) {
            int mbase = m0 + wm * 32 + mi * 16 + quad * 4;
            float b0 = bias[mbase], b1 = bias[mbase + 1], b2 = bias[mbase + 2], b3 = bias[mbase + 3];
            #pragma unroll
            for (int ni = 0; ni < 2; ni++) {
                int n = n0 + wn * 32 + ni * 16 + l15;
                if (n >= HWo) continue;
                float v0 = acc[mi][ni][0] + b0;
                float v1 = acc[mi][ni][1] + b1;
                float v2 = acc[mi][ni][2] + b2;
                float v3 = acc[mi][ni][3] + b3;
                long cp = (long)(mbase >> 1) * HWo + n;
                outp[cp]       = packbf(v0, v1);
                outp[cp + HWo] = packbf(v2, v3);
                ssum[mi] += v0 + v1 + v2 + v3;
                qsum[mi] += v0 * v0 + v1 * v1 + v2 * v2 + v3 * v3;
            }
        }
        #pragma unroll
        for (int mi = 0; mi < 2; mi++) {
            #pragma unroll
            for (int off = 1; off < 16; off <<= 1) {
                ssum[mi] += __shfl_xor(ssum[mi], off, 16);
                qsum[mi] += __shfl_xor(qsum[mi], off, 16);
            }
        }
        if (l15 == 0) {
            #pragma unroll
            for (int mi = 0; mi < 2; mi++)
                sred[wm * 8 + mi * 4 + quad][wn] = make_float2(ssum[mi], qsum[mi]);
        }
        __syncthreads();
        int ng = 64 / cpg;          // groups covered by this block
        int qpg = cpg >> 2;         // quad-groups per group
        if (tid < ng) {
            float s = 0.f, q = 0.f;
            for (int u = 0; u < qpg; u++) {
                float2 a = sred[(tid * cpg >> 2) + u][0];
                float2 b = sred[(tid * cpg >> 2) + u][1];
                s += a.x + b.x; q += a.y + b.y;
            }
            int gabs = m0 / cpg + tid;
            parts[((long)blockIdx.z * 32 + gabs) * 1400 + blockIdx.x] = make_float2(s, q);
        }
    }
}

// ---------------- conv0: fp32 implicit GEMM (K=27) -> bf16-pair out + GN stats ----------------
// Cout=64 fixed, cpg=2. Grid.x*64 == HWo exactly (448x800 input). blockIdx.z = camera.
__global__ __launch_bounds__(256, 4) void conv_gemm_k(const float* __restrict__ in,
                                                      const float* __restrict__ w,
                                                      const float* __restrict__ bias,
                                                      unsigned* __restrict__ outp,
                                                      float2* __restrict__ parts,
                                                      int Hin, int Win,
                                                      long istride, long ostride)
{
    in   += (long)blockIdx.z * istride;
    outp += (long)blockIdx.z * ostride;
    const int Hout = Hin >> 1, Wout = Win >> 1;
    const int HWo = Hout * Wout;
    const int Ktot = 27;
    __shared__ float As[16][68];
    __shared__ float Bs[16][68];
    int tid = threadIdx.x;
    int tx = tid & 15, ty = tid >> 4;
    int n0 = blockIdx.x * 64;
    int kb = tid >> 4;
    int nb = (tid & 15) * 4;
    int ma = tid >> 2;
    int ka0 = (tid & 3) * 4;
    int hibase[4], wibase[4];
    #pragma unroll
    for (int u = 0; u < 4; u++) {
        int p = n0 + nb + u;
        int ho = p / Wout, wo = p - ho * Wout;
        hibase[u] = ho * 2 - 1;
        wibase[u] = wo * 2 - 1;
    }
    float acc[4][4] = {{0.f}};
    const long wrow = (long)ma * Ktot;
    for (int kt = 0; kt < Ktot; kt += 16) {
        #pragma unroll
        for (int u = 0; u < 4; u++) {
            int k = kt + ka0 + u;
            As[ka0 + u][ma] = (k < Ktot) ? w[wrow + k] : 0.f;
        }
        int k = kt + kb;
        float bvals[4] = {0.f, 0.f, 0.f, 0.f};
        if (k < Ktot) {
            int ci = k / 9, r = k - ci * 9;
            int kh = r / 3, kw = r - kh * 3;
            const float* ip = in + (long)ci * Hin * Win;
            #pragma unroll
            for (int u = 0; u < 4; u++) {
                int hi = hibase[u] + kh;
                int wi = wibase[u] + kw;
                if (hi >= 0 && hi < Hin && wi >= 0 && wi < Win)
                    bvals[u] = ip[(long)hi * Win + wi];
            }
        }
        #pragma unroll
        for (int u = 0; u < 4; u++) Bs[kb][nb + u] = bvals[u];
        __syncthreads();
        #pragma unroll
        for (int kk = 0; kk < 16; kk++) {
            float av[4], bv[4];
            #pragma unroll
            for (int i = 0; i < 4; i++) av[i] = As[kk][ty * 4 + i];
            #pragma unroll
            for (int j = 0; j < 4; j++) bv[j] = Bs[kk][tx * 4 + j];
            #pragma unroll
            for (int i = 0; i < 4; i++)
                #pragma unroll
                for (int j = 0; j < 4; j++)
                    acc[i][j] += av[i] * bv[j];
        }
        __syncthreads();
    }
    // epilogue: bias + bf16-pair pack + per-group (cpg=2) stats, single pass over acc
    int nbase = n0 + tx * 4;
    #pragma unroll
    for (int h = 0; h < 2; h++) {
        float b0 = bias[ty * 4 + 2 * h], b1 = bias[ty * 4 + 2 * h + 1];
        uint4 o;
        float ss = 0.f, qq = 0.f;
        #pragma unroll
        for (int j = 0; j < 4; j++) {
            float a = acc[2 * h][j] + b0;
            float b = acc[2 * h + 1][j] + b1;
            ss += a + b;
            qq += a * a + b * b;
            ((unsigned*)&o)[j] = packbf(a, b);
        }
        *(uint4*)&outp[(long)(ty * 2 + h) * HWo + nbase] = o;
        #pragma unroll
        for (int off = 1; off < 16; off <<= 1) {
            ss += __shfl_xor(ss, off, 16);
            qq += __shfl_xor(qq, off, 16);
        }
        if (tx == 0)
            parts[((long)blockIdx.z * 32 + ty * 2 + h) * 1400 + blockIdx.x] = make_float2(ss, qq);
    }
}

// ---------------- GN finalize: reduce per-block partials -> mean/rstd ----------------
__global__ __launch_bounds__(256) void gnfin_k(const float2* __restrict__ parts,
                                               float* __restrict__ gnstats, int nx, float invN)
{
    int g = blockIdx.x, cam = blockIdx.y;
    const float2* pb = parts + ((long)cam * 32 + g) * 1400;
    float s = 0.f, q = 0.f;
    for (int i = threadIdx.x; i < nx; i += 256) {
        float2 v = pb[i];
        s += v.x; q += v.y;
    }
    __shared__ float rs[256], rq[256];
    rs[threadIdx.x] = s; rq[threadIdx.x] = q;
    __syncthreads();
    for (int o = 128; o > 0; o >>= 1) {
        if (threadIdx.x < o) { rs[threadIdx.x] += rs[threadIdx.x + o]; rq[threadIdx.x] += rq[threadIdx.x + o]; }
        __syncthreads();
    }
    if (threadIdx.x == 0) {
        float mean = rs[0] * invN;
        float var  = rq[0] * invN - mean * mean;
        gnstats[(cam * 32 + g) * 2]     = mean;
        gnstats[(cam * 32 + g) * 2 + 1] = rsqrtf(var + EPS);
    }
}

// ---------------- in-place GN apply + ReLU on bf16-pair buffer ----------------
__global__ __launch_bounds__(256) void pairapply_k(unsigned* __restrict__ x,
                                                   const float* __restrict__ gamma,
                                                   const float* __restrict__ beta,
                                                   const float* __restrict__ gnstats,
                                                   int HW, int cpg, long zstride)
{
    x       += (long)blockIdx.z * zstride;
    gnstats += (long)blockIdx.z * 64;
    int idx4 = (blockIdx.x * 256 + threadIdx.x) * 4;   // HW%4==0 -> all in one pair-row
    int cp = idx4 / HW;
    int c0 = cp * 2;
    int g = c0 / cpg;
    float mean = gnstats[g * 2], rstd = gnstats[g * 2 + 1];
    float sa = rstd * gamma[c0],     ba = beta[c0]     - mean * sa;
    float sb = rstd * gamma[c0 + 1], bb = beta[c0 + 1] - mean * sb;
    uint4 v = *(uint4*)&x[idx4];
    unsigned* vp = (unsigned*)&v;
    #pragma unroll
    for (int j = 0; j < 4; j++) {
        float lo = fmaxf(bflo(vp[j]) * sa + ba, 0.f);
        float hi = fmaxf(bfhi(vp[j]) * sb + bb, 0.f);
        vp[j] = packbf(lo, hi);
    }
    *(uint4*)&x[idx4] = v;
}

// ---------------- GroupNorm for (1400 x 256) spatial-major, batched over cams (grid.y) ----------------
__global__ __launch_bounds__(256) void gn_stats_hwd_k(const float* __restrict__ x, float* __restrict__ stats)
{
    x += (long)blockIdx.y * 358400;
    stats += blockIdx.y * 64;
    int g = blockIdx.x;  // 32 groups
    float s = 0.f, s2 = 0.f;
    for (int i = threadIdx.x; i < 1400 * 8; i += blockDim.x) {
        int p = i >> 3, c = g * 8 + (i & 7);
        float v = x[(long)p * 256 + c];
        s += v; s2 += v * v;
    }
    __shared__ float rs[256], rq[256];
    rs[threadIdx.x] = s; rq[threadIdx.x] = s2;
    __syncthreads();
    for (int o = 128; o > 0; o >>= 1) {
        if (threadIdx.x < o) { rs[threadIdx.x] += rs[threadIdx.x + o]; rq[threadIdx.x] += rq[threadIdx.x + o]; }
        __syncthreads();
    }
    if (threadIdx.x == 0) {
        float mean = rs[0] / 11200.f;
        float var  = rq[0] / 11200.f - mean * mean;
        stats[g * 2]     = mean;
        stats[g * 2 + 1] = rsqrtf(var + EPS);
    }
}

__global__ __launch_bounds__(256) void gn_apply_hwd_k(float* __restrict__ x,
                                                      const float* __restrict__ gamma,
                                                      const float* __restrict__ beta,
                                                      const float* __restrict__ stats,
                                                      int relu)
{
    x += (long)blockIdx.y * 358400;
    stats += blockIdx.y * 64;
    long i4 = ((long)blockIdx.x * 256 + threadIdx.x) * 4;  // grid.x = 350 -> exact
    int c = (int)(i4 & 255);
    int g = c >> 3;
    float4 v  = *(float4*)&x[i4];
    float4 gm = *(const float4*)&gamma[c];
    float4 bt = *(const float4*)&beta[c];
    float m = stats[g * 2], rs = stats[g * 2 + 1];
    v.x = (v.x - m) * rs * gm.x + bt.x;
    v.y = (v.y - m) * rs * gm.y + bt.y;
    v.z = (v.z - m) * rs * gm.z + bt.z;
    v.w = (v.w - m) * rs * gm.w + bt.w;
    if (relu) {
        v.x = fmaxf(v.x, 0.f); v.y = fmaxf(v.y, 0.f);
        v.z = fmaxf(v.z, 0.f); v.w = fmaxf(v.w, 0.f);
    }
    *(float4*)&x[i4] = v;
}

// ---------------- projection of BEV grid ----------------
__global__ __launch_bounds__(256) void project_k(const float* __restrict__ Kin,
                                                 const float* __restrict__ Ein,
                                                 float* __restrict__ refp, int* __restrict__ valid)
{
    int idx = blockIdx.x * blockDim.x + threadIdx.x;
    if (idx >= 2500 * 6) return;
    int c = idx % 6, q = idx / 6;
    int i = q / 50, j = q % 50;
    float px = (i - 24.5f) * 0.5f;
    float py = (j - 24.5f) * 0.5f;
    const float* E = Ein + c * 16;
    float pc[4];
    #pragma unroll
    for (int r = 0; r < 4; r++)
        pc[r] = E[r * 4 + 0] * px + E[r * 4 + 1] * py + E[r * 4 + 3];
    const float* Km = Kin + c * 9;
    float pix[3];
    #pragma unroll
    for (int r = 0; r < 3; r++)
        pix[r] = Km[r * 3 + 0] * pc[0] + Km[r * 3 + 1] * pc[1] + Km[r * 3 + 2] * pc[2];
    float z = fmaxf(pix[2], 1e-5f);
    float u = pix[0] / z, v = pix[1] / z;
    int ok = (pc[2] > 0.f) && (u >= 0.f) && (u < 800.f) && (v >= 0.f) && (v < 448.f);
    refp[(long)idx * 2 + 0] = 2.f * u / 799.f - 1.f;
    refp[(long)idx * 2 + 1] = 2.f * v / 447.f - 1.f;
    valid[idx] = ok;
}

// ---------------- misc elementwise ----------------
__global__ __launch_bounds__(256) void qinit_k(const float* __restrict__ a, const float* __restrict__ b,
                                               float* __restrict__ y)
{
    int i = blockIdx.x * blockDim.x + threadIdx.x;
    if (i >= 2500 * 256) return;
    y[i] = a[i] + b[i];
}

// ---------------- LayerNorm ----------------
__global__ __launch_bounds__(256) void ln_k(const float* __restrict__ x,
                                            const float* __restrict__ g, const float* __restrict__ b,
                                            float* __restrict__ y)
{
    int row  = blockIdx.x * 4 + (threadIdx.x >> 6);
    int lane = threadIdx.x & 63;
    if (row >= 2500) return;
    const float* xp = x + (long)row * 256;
    float v[4];
    #pragma unroll
    for (int i = 0; i < 4; i++) v[i] = xp[lane + 64 * i];
    float s  = v[0] + v[1] + v[2] + v[3];
    float s2 = v[0] * v[0] + v[1] * v[1] + v[2] * v[2] + v[3] * v[3];
    #pragma unroll
    for (int o = 32; o > 0; o >>= 1) { s += __shfl_xor(s, o, 64); s2 += __shfl_xor(s2, o, 64); }
    float mean = s * (1.f / 256.f);
    float var  = s2 * (1.f / 256.f) - mean * mean;
    float rstd = rsqrtf(var + EPS);
    #pragma unroll
    for (int i = 0; i < 4; i++) {
        int cc = lane + 64 * i;
        y[(long)row * 256 + cc] = (v[i] - mean) * rstd * g[cc] + b[cc];
    }
}

// ---------------- MFMA flash-2 MHA with split-K (packed-QKV aware: row stride ld) ----------------
__global__ __launch_bounds__(256) void flash2_k(const float* __restrict__ Q,
                                                const float* __restrict__ K,
                                                const float* __restrict__ V,
                                                int ld,
                                                float* __restrict__ Opart,   // (S,2500,256)
                                                float* __restrict__ MLpart)  // (S,2500,8,2)
{
    const int h  = blockIdx.y;
    const int q0 = blockIdx.x * 64;
    const int sp = blockIdx.z;
    const int kstart = sp * FL_KEYS, kend = kstart + FL_KEYS;
    const int tid = threadIdx.x;
    const int wave = tid >> 6, lane = tid & 63;
    const int quad = lane >> 4, l15 = lane & 15;
    __shared__ __align__(16) short Qs[64 * 40];
    __shared__ __align__(16) short Ks[64 * 40];
    __shared__ __align__(16) short Vt[32 * 72];
    __shared__ __align__(16) short Ps[64 * 72];
    const float scale = 0.17677669529663687f;
    {
        int row = tid >> 2, kc = (tid & 3) << 3;
        int qi = q0 + row;
        short8 pk = {0, 0, 0, 0, 0, 0, 0, 0};
        if (qi < 2500) {
            const float4* qp = (const float4*)(Q + (long)qi * ld + h * 32 + kc);
            float4 v0 = qp[0], v1 = qp[1];
            pk[0] = f2s(v0.x * scale); pk[1] = f2s(v0.y * scale); pk[2] = f2s(v0.z * scale); pk[3] = f2s(v0.w * scale);
            pk[4] = f2s(v1.x * scale); pk[5] = f2s(v1.y * scale); pk[6] = f2s(v1.z * scale); pk[7] = f2s(v1.w * scale);
        }
        *(short8*)&Qs[row * 40 + kc] = pk;
    }
    __syncthreads();
    short8 aq = *(const short8*)&Qs[(wave * 16 + l15) * 40 + (quad << 3)];
    float m[4], l[4];
    f4 oacc[2];
    #pragma unroll
    for (int r = 0; r < 4; r++) { m[r] = -INFINITY; l[r] = 0.f; }
    oacc[0] = (f4){0.f, 0.f, 0.f, 0.f};
    oacc[1] = (f4){0.f, 0.f, 0.f, 0.f};
    for (int kb = kstart; kb < kend; kb += 64) {
        __syncthreads();
        {
            int row = tid >> 2, kc = (tid & 3) << 3;
            int ki = kb + row;
            short8 pk = {0, 0, 0, 0, 0, 0, 0, 0};
            float vv[8] = {0.f, 0.f, 0.f, 0.f, 0.f, 0.f, 0.f, 0.f};
            if (ki < kend) {
                const float4* kp = (const float4*)(K + (long)ki * ld + h * 32 + kc);
                float4 a0 = kp[0], a1 = kp[1];
                pk[0] = f2s(a0.x); pk[1] = f2s(a0.y); pk[2] = f2s(a0.z); pk[3] = f2s(a0.w);
                pk[4] = f2s(a1.x); pk[5] = f2s(a1.y); pk[6] = f2s(a1.z); pk[7] = f2s(a1.w);
                const float4* vp = (const float4*)(V + (long)ki * ld + h * 32 + kc);
                float4 b0 = vp[0], b1 = vp[1];
                vv[0] = b0.x; vv[1] = b0.y; vv[2] = b0.z; vv[3] = b0.w;
                vv[4] = b1.x; vv[5] = b1.y; vv[6] = b1.z; vv[7] = b1.w;
            }
            *(short8*)&Ks[row * 40 + kc] = pk;
            #pragma unroll
            for (int j = 0; j < 8; j++) Vt[(kc + j) * 72 + row] = f2s(vv[j]);
        }
        __syncthreads();
        f4 sa[4];
        #pragma unroll
        for (int ni = 0; ni < 4; ni++) {
            short8 bk = *(const short8*)&Ks[(ni * 16 + l15) * 40 + (quad << 3)];
            sa[ni] = __builtin_amdgcn_mfma_f32_16x16x32_bf16(aq, bk, (f4){0.f, 0.f, 0.f, 0.f}, 0, 0, 0);
        }
        float sv[4][4];
        #pragma unroll
        for (int ni = 0; ni < 4; ni++) {
            bool colok = (kb + ni * 16 + l15) < kend;
            #pragma unroll
            for (int r = 0; r < 4; r++) sv[ni][r] = colok ? sa[ni][r] : -1e30f;
        }
        float p[4][4];
        #pragma unroll
        for (int r = 0; r < 4; r++) {
            float rm = fmaxf(fmaxf(sv[0][r], sv[1][r]), fmaxf(sv[2][r], sv[3][r]));
            #pragma unroll
            for (int off = 1; off < 16; off <<= 1) rm = fmaxf(rm, __shfl_xor(rm, off, 16));
            float mn = fmaxf(m[r], rm);
            float alpha = __expf(m[r] - mn);
            float rs = 0.f;
            #pragma unroll
            for (int ni = 0; ni < 4; ni++) { p[ni][r] = __expf(sv[ni][r] - mn); rs += p[ni][r]; }
            #pragma unroll
            for (int off = 1; off < 16; off <<= 1) rs += __shfl_xor(rs, off, 16);
            l[r] = l[r] * alpha + rs;
            oacc[0][r] *= alpha; oacc[1][r] *= alpha;
            m[r] = mn;
        }
        #pragma unroll
        for (int ni = 0; ni < 4; ni++)
            #pragma unroll
            for (int r = 0; r < 4; r++)
                Ps[(wave * 16 + quad * 4 + r) * 72 + ni * 16 + l15] = f2s(p[ni][r]);
        #pragma unroll
        for (int kh = 0; kh < 2; kh++) {
            short8 ap = *(const short8*)&Ps[(wave * 16 + l15) * 72 + kh * 32 + (quad << 3)];
            #pragma unroll
            for (int ni = 0; ni < 2; ni++) {
                short8 bv = *(const short8*)&Vt[(ni * 16 + l15) * 72 + kh * 32 + (quad << 3)];
                oacc[ni] = __builtin_amdgcn_mfma_f32_16x16x32_bf16(ap, bv, oacc[ni], 0, 0, 0);
            }
        }
    }
    #pragma unroll
    for (int r = 0; r < 4; r++) {
        int qi = q0 + wave * 16 + quad * 4 + r;
        if (qi < 2500) {
            long ob = ((long)sp * 2500 + qi) * 256 + h * 32;
            Opart[ob + l15]      = oacc[0][r];
            Opart[ob + 16 + l15] = oacc[1][r];
            if (l15 == 0) {
                long mb = (((long)sp * 2500 + qi) * 8 + h) * 2;
                MLpart[mb]     = m[r];
                MLpart[mb + 1] = l[r];
            }
        }
    }
}

__global__ __launch_bounds__(256) void flashmerge_k(const float* __restrict__ Opart,
                                                    const float* __restrict__ MLpart,
                                                    float* __restrict__ O)
{
    int q = blockIdx.x, d = threadIdx.x;
    int h = d >> 5;
    float ms[FL_SPLITS], ls[FL_SPLITS];
    float mg = -INFINITY;
    #pragma unroll
    for (int s = 0; s < FL_SPLITS; s++) {
        long mb = (((long)s * 2500 + q) * 8 + h) * 2;
        ms[s] = MLpart[mb];
        ls[s] = MLpart[mb + 1];
        mg = fmaxf(mg, ms[s]);
    }
    float lsum = 0.f, osum = 0.f;
    #pragma unroll
    for (int s = 0; s < FL_SPLITS; s++) {
        float w = __expf(ms[s] - mg);
        lsum += ls[s] * w;
        osum += Opart[((long)s * 2500 + q) * 256 + d] * w;
    }
    O[(long)q * 256 + d] = osum / lsum;
}

// ---------------- masked softmax over 192 deformable-attn logits (row stride ld) ----------------
__global__ __launch_bounds__(64) void scasoftmax_k(float* __restrict__ logits, int ld,
                                                   const int* __restrict__ valid)
{
    int q = blockIdx.x, lane = threadIdx.x;
    float v[3]; int mk[3];
    #pragma unroll
    for (int i = 0; i < 3; i++) {
        int idx = i * 64 + lane;
        int c = idx >> 5;
        mk[i] = valid[q * 6 + c];
        v[i] = mk[i] ? logits[(long)q * ld + idx] : -1e30f;
    }
    float mx = fmaxf(fmaxf(v[0], v[1]), v[2]);
    #pragma unroll
    for (int o = 32; o > 0; o >>= 1) mx = fmaxf(mx, __shfl_xor(mx, o, 64));
    float e[3]; float s = 0.f;
    #pragma unroll
    for (int i = 0; i < 3; i++) { e[i] = expf(v[i] - mx); s += e[i]; }
    #pragma unroll
    for (int o = 32; o > 0; o >>= 1) s += __shfl_xor(s, o, 64);
    float inv = 1.f / s;
    #pragma unroll
    for (int i = 0; i < 3; i++)
        logits[(long)q * ld + i * 64 + lane] = mk[i] ? e[i] * inv : 0.f;
}

// ---------------- deformable sampling (offs/wts with row stride ld) ----------------
__global__ __launch_bounds__(256) void sample_k(const float* __restrict__ vals,
                                                const float* __restrict__ offs, int ld,
                                                const float* __restrict__ wts,
                                                const float* __restrict__ refp,
                                                const int* __restrict__ valid,
                                                float* __restrict__ out)
{
    int q = blockIdx.x, d = threadIdx.x;
    __shared__ float s_cw[32][4];
    __shared__ int   s_idx[32][4];
    float acc = 0.f;
    for (int c = 0; c < 6; c++) {
        if (!valid[q * 6 + c]) continue;
        __syncthreads();
        if (d < 32) {
            float ox = offs[(long)q * ld + (c * 32 + d) * 2 + 0];
            float oy = offs[(long)q * ld + (c * 32 + d) * 2 + 1];
            float px = refp[(q * 6 + c) * 2 + 0] + ox * (2.f / 49.f);
            float py = refp[(q * 6 + c) * 2 + 1] + oy * (2.f / 27.f);
            float gx = (px + 1.f) * 0.5f * 49.f;
            float gy = (py + 1.f) * 0.5f * 27.f;
            float x0f = floorf(gx), y0f = floorf(gy);
            float wx = gx - x0f, wy = gy - y0f;
            int x0 = (int)x0f, y0 = (int)y0f;
            float wgt = wts[(long)q * ld + c * 32 + d];
            float cw[4] = {(1.f - wx) * (1.f - wy), wx * (1.f - wy), (1.f - wx) * wy, wx * wy};
            const int dxs[4] = {0, 1, 0, 1};
            const int dys[4] = {0, 0, 1, 1};
            #pragma unroll
            for (int k2 = 0; k2 < 4; k2++) {
                int xi = x0 + dxs[k2], yi = y0 + dys[k2];
                bool ok = (xi >= 0) && (xi < 50) && (yi >= 0) && (yi < 28);
                s_cw[d][k2]  = ok ? cw[k2] * wgt : 0.f;
                s_idx[d][k2] = ok ? (yi * 50 + xi) * 256 : 0;
            }
        }
        __syncthreads();
        const float* vb = vals + (long)c * 358400 + d;
        for (int pt = 0; pt < 32; pt++) {
            #pragma unroll
            for (int k2 = 0; k2 < 4; k2++) {
                float cwv = s_cw[pt][k2];
                if (cwv != 0.f) acc += cwv * vb[s_idx[pt][k2]];
            }
        }
    }
    out[(long)q * 256 + d] = acc;
}

// =====================================================================================
extern "C" void kernel_launch(void* const* d_in, const int* in_sizes, int n_in,
                              void* d_out, int out_size, void* d_ws, size_t ws_size,
                              hipStream_t stream)
{
    const float* images = (const float*)d_in[0];
    const float* intr   = (const float*)d_in[1];
    const float* e2c    = (const float*)d_in[2];
    const float* bevq   = (const float*)d_in[3];
    const float* bevp   = (const float*)d_in[4];
    const float* bbw[5]    = {(const float*)d_in[5],  (const float*)d_in[9],  (const float*)d_in[13], (const float*)d_in[17], (const float*)d_in[21]};
    const float* bbb[5]    = {(const float*)d_in[6],  (const float*)d_in[10], (const float*)d_in[14], (const float*)d_in[18], (const float*)d_in[22]};
    const float* bbg[5]    = {(const float*)d_in[7],  (const float*)d_in[11], (const float*)d_in[15], (const float*)d_in[19], (const float*)d_in[23]};
    const float* bbbeta[5] = {(const float*)d_in[8],  (const float*)d_in[12], (const float*)d_in[16], (const float*)d_in[20], (const float*)d_in[24]};
    const float* sa_wq = (const float*)d_in[25]; const float* sa_bq = (const float*)d_in[26];
    const float* sa_wk = (const float*)d_in[27]; const float* sa_bk = (const float*)d_in[28];
    const float* sa_wv = (const float*)d_in[29]; const float* sa_bv = (const float*)d_in[30];
    const float* sa_wo = (const float*)d_in[31]; const float* sa_bo = (const float*)d_in[32];
    const float* ln1g = (const float*)d_in[33]; const float* ln1b = (const float*)d_in[34];
    const float* ln2g = (const float*)d_in[35]; const float* ln2b = (const float*)d_in[36];
    const float* ln3g = (const float*)d_in[37]; const float* ln3b = (const float*)d_in[38];
    const float* offw = (const float*)d_in[39]; const float* offb = (const float*)d_in[40];
    const float* wtw  = (const float*)d_in[41]; const float* wtb  = (const float*)d_in[42];
    const float* valw = (const float*)d_in[43]; const float* valb = (const float*)d_in[44];
    const float* outw = (const float*)d_in[45]; const float* outb = (const float*)d_in[46];
    const float* fw1  = (const float*)d_in[47]; const float* fb1  = (const float*)d_in[48];
    const float* fw2  = (const float*)d_in[49]; const float* fb2  = (const float*)d_in[50];

    // ---- pick camera-batch factor from available workspace (formula unchanged) ----
    auto needB = [](long ncb) -> unsigned long long {
        return (unsigned long long)(ncb * 8601600L + 6681600L) * 4ULL + 6307840ULL + (1 << 20);
    };
    int ncb = 1;
    if      ((unsigned long long)ws_size >= needB(6)) ncb = 6;
    else if ((unsigned long long)ws_size >= needB(3)) ncb = 3;
    else if ((unsigned long long)ws_size >= needB(2)) ncb = 2;

    // ---- workspace layout ----
    float* ws = (float*)d_ws;
    float* A     = ws; ws += (long)ncb * 5734400;  // pair-buffer ping; aliases: bQKV, OP, bOW
    float* Bu    = ws; ws += (long)ncb * 2867200;  // pair-buffer pong; aliases: valsb, MLp
    float* f3bH  = ws; ws += 2560000;              // feats3 (backbone) / ffn hidden (transformer)
    float* feats = ws; ws += 2150400;              // (6,1400,256) hwd; also GN parts (early backbone)
    float* qbuf  = ws; ws += 640000;
    float* xq    = ws; ws += 640000;
    float* bO    = ws; ws += 640000;
    float* refp  = ws; ws += 30016;
    int*   validb = (int*)ws; ws += 15040;
    float* stats = ws; ws += 384;
    float* gnst  = ws; ws += 3072;                 // per-group mean/rstd (ncb x 32 x 2)
    float* qkvb  = ws; ws += 1536;
    float* owb   = ws; ws += 1152;
    // bf16 weight buffers
    short* sb = (short*)ws;
    short* cw1b = sb; sb += 73728;                 // tap-major (128, 9*64)
    short* cw2b = sb; sb += 294912;                // tap-major (256, 9*128)
    short* cw3b = sb; sb += 589824;                // tap-major (256, 9*256)
    short* cw4b = sb; sb += 65536;
    short* qkvT = sb; sb += 393216;
    short* owT  = sb; sb += 131072;
    short* valT = sb; sb += 131072;
    short* outT = sb; sb += 131072;
    short* offwtT = sb; sb += 294912;
    short* f1T  = sb; sb += 524288;
    short* f2T  = sb; sb += 524288;
    // aliases
    float*  feats3 = f3bH;
    float*  bH     = f3bH;
    float*  bQKV   = A;
    float*  OP     = A + 1920000;
    float*  bOW    = A + 1920000;
    float*  valsb  = Bu;
    float*  MLp    = Bu + 2150400;
    unsigned* Bbf0 = (unsigned*)A;                 // pair ping (stride varies per stage)
    unsigned* Bbf1 = (unsigned*)Bu;                // pair pong
    float2* partsP = (float2*)feats;               // 6*32*1400 float2 = 2.15 MB (free until conv4)

    auto mgemm = [&](const float* Ain, int lda, const short* Bt, const float* bias, const float* resid,
                     float* C, int M, int N, int K, int act) {
        dim3 g((N + 127) / 128, (M + 127) / 128);
        mgemm_k<<<g, 256, 0, stream>>>(Ain, lda, Bt, bias, resid, C, M, N, K, act);
    };

    // ---- weight preprocessing ----
    wreord_k<<<(73728 + 255) / 256, 256, 0, stream>>>(bbw[1], cw1b, 64, 73728);
    wreord_k<<<(294912 + 255) / 256, 256, 0, stream>>>(bbw[2], cw2b, 128, 294912);
    wreord_k<<<(589824 + 255) / 256, 256, 0, stream>>>(bbw[3], cw3b, 256, 589824);
    wcast_k<<<(65536 + 255) / 256, 256, 0, stream>>>(bbw[4], cw4b, 65536);
    wtrans_k<<<dim3(4, 4, 2), 256, 0, stream>>>(sa_wq, qkvT,          256, 256,  196608);
    wtrans_k<<<dim3(4, 4, 2), 256, 0, stream>>>(sa_wk, qkvT + 65536,  256, 256,  196608);
    wtrans_k<<<dim3(4, 4, 2), 256, 0, stream>>>(sa_wv, qkvT + 131072, 256, 256,  196608);
    wtrans_k<<<dim3(4, 4, 2), 256, 0, stream>>>(sa_wo, owT,  256, 256,  65536);
    wtrans_k<<<dim3(4, 4, 2), 256, 0, stream>>>(valw,  valT, 256, 256,  65536);
    wtrans_k<<<dim3(4, 4, 2), 256, 0, stream>>>(outw,  outT, 256, 256,  65536);
    wtrans_k<<<dim3(6, 4, 2), 256, 0, stream>>>(offw, offwtT,         256, 384,  147456);
    wtrans_k<<<dim3(3, 4, 2), 256, 0, stream>>>(wtw,  offwtT + 98304, 256, 192,  147456);
    wtrans_k<<<dim3(16, 4, 2), 256, 0, stream>>>(fw1, f1T, 256, 1024, 262144);
    wtrans_k<<<dim3(4, 16, 2), 256, 0, stream>>>(fw2, f2T, 1024, 256, 262144);
    packb_k<<<dim3(3, 2), 256, 0, stream>>>(sa_bq, sa_bk, sa_bv, qkvb, 256, 256, 256);
    packb_k<<<dim3(3, 2), 256, 0, stream>>>(offb, wtb, nullptr, owb, 384, 192, 0);

    // ---- projection of BEV grid ----
    project_k<<<(15000 + 255) / 256, 256, 0, stream>>>(intr, e2c, refp, validb);

    // ---- backbone (cam-batched; bf16-pair activations; GN stats fused into convs) ----
    for (int c0 = 0; c0 < 6; c0 += ncb) {
        const float* img = images + (long)c0 * 1075200;
        // conv0 -> pairs + stats
        conv_gemm_k<<<dim3(1400, 1, ncb), 256, 0, stream>>>(img, bbw[0], bbb[0], Bbf0, partsP,
                                                            448, 800, 1075200L, 2867200L);
        gnfin_k<<<dim3(32, ncb), 256, 0, stream>>>(partsP, gnst, 1400, 1.f / 179200.f);
        pairapply_k<<<dim3(2800, 1, ncb), 256, 0, stream>>>(Bbf0, bbg[0], bbbeta[0], gnst, 89600, 2, 2867200L);
        // conv1 -> pairs + stats
        mconv_k<<<dim3(350, 2, ncb), 256, 0, stream>>>(Bbf0, cw1b, bbb[1], (float*)Bbf1, partsP,
                                                       1, 128, 224, 400, 2, 4, 2867200L, 1433600L);
        gnfin_k<<<dim3(32, ncb), 256, 0, stream>>>(partsP, gnst, 350, 1.f / 89600.f);
        pairapply_k<<<dim3(1400, 1, ncb), 256, 0, stream>>>(Bbf1, bbg[1], bbbeta[1], gnst, 22400, 4, 1433600L);
        // conv2 -> pairs + stats
        mconv_k<<<dim3(88, 4, ncb), 256, 0, stream>>>(Bbf1, cw2b, bbb[2], (float*)Bbf0, partsP,
                                                      2, 256, 112, 200, 2, 8, 1433600L, 716800L);
        gnfin_k<<<dim3(32, ncb), 256, 0, stream>>>(partsP, gnst, 88, 1.f / 44800.f);
        pairapply_k<<<dim3(700, 1, ncb), 256, 0, stream>>>(Bbf0, bbg[2], bbbeta[2], gnst, 5600, 8, 716800L);
        // conv3 -> f32 spatial-major feats3[cam]
        mconv_k<<<dim3(22, 4, ncb), 256, 0, stream>>>(Bbf0, cw3b, bbb[3], feats3 + (long)c0 * 358400, nullptr,
                                                      3, 256, 56, 100, 1, 0, 716800L, 358400L);
    }
    // batched conv3-GN (+relu), conv4 as one 8400x256 GEMM, batched conv4-GN
    gn_stats_hwd_k<<<dim3(32, 6), 256, 0, stream>>>(feats3, stats);
    gn_apply_hwd_k<<<dim3(350, 6), 256, 0, stream>>>(feats3, bbg[3], bbbeta[3], stats, 1);
    mgemm(feats3, 256, cw4b, bbb[4], nullptr, feats, 8400, 256, 256, 0);
    gn_stats_hwd_k<<<dim3(32, 6), 256, 0, stream>>>(feats, stats);
    gn_apply_hwd_k<<<dim3(350, 6), 256, 0, stream>>>(feats, bbg[4], bbbeta[4], stats, 0);

    // ---- transformer ----
    qinit_k<<<2500, 256, 0, stream>>>(bevq, bevp, qbuf);

    for (int l = 0; l < 2; l++) {
        long o1 = (long)l * 256;

        // self-attention (fused QKV projection: 2500 x 768)
        ln_k<<<625, 256, 0, stream>>>(qbuf, ln1g + o1, ln1b + o1, xq);
        mgemm(xq, 256, qkvT + l * 196608, qkvb + l * 768, nullptr, bQKV, 2500, 768, 256, 0);
        flash2_k<<<dim3(40, 8, FL_SPLITS), 256, 0, stream>>>(bQKV, bQKV + 256, bQKV + 512, 768, OP, MLp);
        flashmerge_k<<<2500, 256, 0, stream>>>(OP, MLp, bO);
        mgemm(bO, 256, owT + l * 65536, sa_bo + o1, qbuf, qbuf, 2500, 256, 256, 0);

        // spatial cross-attention (fused offsets+logits projection: 2500 x 576)
        ln_k<<<625, 256, 0, stream>>>(qbuf, ln2g + o1, ln2b + o1, xq);
        mgemm(feats, 256, valT + l * 65536, valb + o1, nullptr, valsb, 8400, 256, 256, 0);
        mgemm(xq, 256, offwtT + l * 147456, owb + l * 576, nullptr, bOW, 2500, 576, 256, 0);
        scasoftmax_k<<<2500, 64, 0, stream>>>(bOW + 384, 576, validb);
        sample_k<<<2500, 256, 0, stream>>>(valsb, bOW, 576, bOW + 384, refp, validb, bO);
        mgemm(bO, 256, outT + l * 65536, outb + o1, qbuf, qbuf, 2500, 256, 256, 0);

        // FFN
        ln_k<<<625, 256, 0, stream>>>(qbuf, ln3g + o1, ln3b + o1, xq);
        mgemm(xq, 256, f1T + l * 262144, fb1 + (long)l * 1024, nullptr, bH, 2500, 1024, 256, 2);
        mgemm(bH, 1024, f2T + l * 262144, fb2 + o1, qbuf,
              (l == 1) ? (float*)d_out : qbuf, 2500, 256, 1024, 0);
    }
}

// Round 5
// 1459.399 us; speedup vs baseline: 1.3597x; 1.3597x over previous
//
#include <hip/hip_runtime.h>
#include <hip/hip_bf16.h>
#include <math.h>

#define EPS 1e-5f
#define FL_SPLITS 5
#define FL_KEYS 500

typedef __attribute__((ext_vector_type(8))) short short8;
typedef __attribute__((ext_vector_type(4))) float f4;

__device__ __forceinline__ short f2s(float f) {
    union { float f; unsigned u; } v; v.f = f;
    unsigned r = (v.u + 0x7fffu + ((v.u >> 16) & 1u)) >> 16;  // RNE
    return (short)r;
}
__device__ __forceinline__ unsigned packbf(float a, float b) {
    return (unsigned)(unsigned short)f2s(a) | ((unsigned)(unsigned short)f2s(b) << 16);
}
__device__ __forceinline__ float bflo(unsigned v) { union { unsigned u; float f; } t; t.u = v << 16; return t.f; }
__device__ __forceinline__ float bfhi(unsigned v) { union { unsigned u; float f; } t; t.u = v & 0xffff0000u; return t.f; }

// ---------------- weight preprocessing ----------------
__global__ __launch_bounds__(256) void wcast_k(const float* __restrict__ in, short* __restrict__ out, int n)
{
    int i = blockIdx.x * 256 + threadIdx.x;
    if (i < n) out[i] = f2s(in[i]);
}

// conv weight reorder: (Cout, Cin, 3,3) fp32 -> (Cout, 9, Cin) bf16 (tap-major)
__global__ __launch_bounds__(256) void wreord_k(const float* __restrict__ in, short* __restrict__ out,
                                                int Cin, int n)
{
    int i = blockIdx.x * 256 + threadIdx.x;
    if (i >= n) return;
    int cin9 = Cin * 9;
    int co = i / cin9, rem = i - co * cin9;
    int ci = rem / 9, t = rem - ci * 9;
    out[(long)co * cin9 + t * Cin + ci] = f2s(in[i]);
}

// (K,N) fp32 -> (N,K) bf16 ; blockIdx.z = matrix index, zstride = output stride per matrix
__global__ __launch_bounds__(256) void wtrans_k(const float* __restrict__ in, short* __restrict__ out,
                                                int K, int N, long zstride)
{
    in  += (long)blockIdx.z * K * N;
    out += (long)blockIdx.z * zstride;
    __shared__ float t[64][65];
    int k0 = blockIdx.y * 64, n0 = blockIdx.x * 64;
    int tid = threadIdx.x;
    int cl = tid & 63, rq = tid >> 6;
    #pragma unroll
    for (int i = 0; i < 16; i++) {
        int rl = rq + i * 4;
        int k = k0 + rl, n = n0 + cl;
        t[rl][cl] = (k < K && n < N) ? in[(long)k * N + n] : 0.f;
    }
    __syncthreads();
    #pragma unroll
    for (int i = 0; i < 16; i++) {
        int nl = rq + i * 4;
        int n = n0 + nl, k = k0 + cl;
        if (n < N && k < K) out[(long)n * K + k] = f2s(t[cl][nl]);
    }
}

// pack per-layer bias segments
__global__ __launch_bounds__(256) void packb_k(const float* __restrict__ a, const float* __restrict__ b,
                                               const float* __restrict__ c, float* __restrict__ y,
                                               int na, int nb, int nc)
{
    int l = blockIdx.y;
    int j = blockIdx.x * 256 + threadIdx.x;
    int ntot = na + nb + nc;
    if (j >= ntot) return;
    float v;
    if (j < na) v = a[l * na + j];
    else if (j < na + nb) v = b[l * nb + (j - na)];
    else v = c[l * nc + (j - na - nb)];
    y[(long)l * ntot + j] = v;
}

// ---------------- MFMA GEMM: C[M,N] = A(fp32 MxK) @ Bt(bf16 NxK)^T ----------------
__global__ __launch_bounds__(256) void mgemm_k(const float* __restrict__ A, int lda,
                                               const short* __restrict__ Bt,
                                               const float* __restrict__ bias,
                                               const float* __restrict__ resid,
                                               float* __restrict__ C,
                                               int M, int N, int K, int act)
{
    __shared__ __align__(16) short As[5120];   // 128 rows x 40 (32 used)
    __shared__ __align__(16) short Bs[5120];
    int tid = threadIdx.x;
    int wave = tid >> 6, lane = tid & 63;
    int wm = wave >> 1, wn = wave & 1;
    int quad = lane >> 4, l15 = lane & 15;
    int m0 = blockIdx.y * 128, n0 = blockIdx.x * 128;
    f4 acc[4][4];
    #pragma unroll
    for (int i = 0; i < 4; i++)
        #pragma unroll
        for (int j = 0; j < 4; j++)
            acc[i][j] = (f4){0.f, 0.f, 0.f, 0.f};
    for (int kt = 0; kt < K; kt += 32) {
        #pragma unroll
        for (int i = 0; i < 2; i++) {
            int u = tid + (i << 8);
            int row = u >> 2, kc = (u & 3) << 3;
            int gm = m0 + row;
            short8 pk = {0, 0, 0, 0, 0, 0, 0, 0};
            if (gm < M) {
                const float4* ap = (const float4*)(A + (long)gm * lda + kt + kc);
                float4 v0 = ap[0], v1 = ap[1];
                pk[0] = f2s(v0.x); pk[1] = f2s(v0.y); pk[2] = f2s(v0.z); pk[3] = f2s(v0.w);
                pk[4] = f2s(v1.x); pk[5] = f2s(v1.y); pk[6] = f2s(v1.z); pk[7] = f2s(v1.w);
            }
            *(short8*)&As[row * 40 + kc] = pk;
            int gn = n0 + row;
            short8 pb = {0, 0, 0, 0, 0, 0, 0, 0};
            if (gn < N) pb = *(const short8*)&Bt[(long)gn * K + kt + kc];
            *(short8*)&Bs[row * 40 + kc] = pb;
        }
        __syncthreads();
        short8 af[4], bf[4];
        #pragma unroll
        for (int mi = 0; mi < 4; mi++) af[mi] = *(const short8*)&As[(wm * 64 + mi * 16 + l15) * 40 + (quad << 3)];
        #pragma unroll
        for (int ni = 0; ni < 4; ni++) bf[ni] = *(const short8*)&Bs[(wn * 64 + ni * 16 + l15) * 40 + (quad << 3)];
        #pragma unroll
        for (int mi = 0; mi < 4; mi++)
            #pragma unroll
            for (int ni = 0; ni < 4; ni++)
                acc[mi][ni] = __builtin_amdgcn_mfma_f32_16x16x32_bf16(af[mi], bf[ni], acc[mi][ni], 0, 0, 0);
        __syncthreads();
    }
    #pragma unroll
    for (int mi = 0; mi < 4; mi++) {
        int row = m0 + wm * 64 + mi * 16 + quad * 4;
        #pragma unroll
        for (int ni = 0; ni < 4; ni++) {
            int col = n0 + wn * 64 + ni * 16 + l15;
            if (col >= N) continue;
            float bv = bias[col];
            #pragma unroll
            for (int r = 0; r < 4; r++) {
                int rr = row + r;
                if (rr >= M) continue;
                float v = acc[mi][ni][r] + bv;
                if (act == 2) v = 0.5f * v * (1.f + erff(v * 0.70710678118654752f));
                if (resid) v += resid[(long)rr * N + col];
                C[(long)rr * N + col] = v;
            }
        }
    }
}

// ---------------- MFMA conv 3x3 s2 p1, tap-major K, bf16-pair input ----------------
// mode 1: f32 spatial-major out (ostride floats). mode 2: bf16-pair out (ostride dwords) + GN partial stats.
__global__ __launch_bounds__(256) void mconv_k(const unsigned* __restrict__ in,
                                               const short* __restrict__ wgt,
                                               const float* __restrict__ bias,
                                               float* __restrict__ out,
                                               float2* __restrict__ parts,
                                               int c5m, int Cout, int Hin, int Win,
                                               int mode, int cpg,
                                               long istride, long ostride)
{
    in  += (long)blockIdx.z * istride;
    const int Hout = Hin >> 1, Wout = Win >> 1;
    const int HWo = Hout * Wout;
    const int HW = Hin * Win;
    const int Ktot = 288 << c5m;   // 9*Cin
    const int m5 = (1 << c5m) - 1;
    const int nsteps = 9 << c5m;
    __shared__ __align__(16) short As[2560];   // 64 rows x 40
    __shared__ __align__(16) short Bs[2560];   // 64 cols x 40
    __shared__ float2 sred[16][2];             // [quad-group][wn] = (s, s2)
    int tid = threadIdx.x;
    int wave = tid >> 6, lane = tid & 63;
    int wm = wave >> 1, wn = wave & 1;
    int quad = lane >> 4, l15 = lane & 15;
    int m0 = blockIdx.y * 64, n0 = blockIdx.x * 64;
    int nn = tid & 63;
    int kp0 = tid >> 6;
    int p = n0 + nn;
    int pok = p < HWo;
    int pc = pok ? p : (HWo - 1);
    int ho = pc / Wout, wo = pc - ho * Wout;
    int hb = ho * 2 - 1, wb = wo * 2 - 1;

    f4 acc[2][2];
    #pragma unroll
    for (int i = 0; i < 2; i++) { acc[i][0] = (f4){0.f,0.f,0.f,0.f}; acc[i][1] = (f4){0.f,0.f,0.f,0.f}; }

    short8 aR;
    unsigned bR[4];
    auto loadA = [&](int s) {
        int r = tid >> 2, kc = (tid & 3) << 3;
        aR = *(const short8*)&wgt[(long)(m0 + r) * Ktot + (s << 5) + kc];
    };
    auto loadB = [&](int s) {
        int t = s >> c5m;
        int kh = (t * 11) >> 5;            // t/3 for t in 0..8
        int kw = t - kh * 3;
        int y = hb + kh, x = wb + kw;
        bool okp = pok && ((unsigned)y < (unsigned)Hin) && ((unsigned)x < (unsigned)Win);
        int base = (((s & m5) << 4) + kp0) * HW + y * Win + x;
        #pragma unroll
        for (int i = 0; i < 4; i++) {
            unsigned v = 0;
            if (okp) v = in[base + (i << 2) * HW];
            bR[i] = v;
        }
    };

    loadA(0); loadB(0);
    for (int s = 0; s < nsteps; s++) {
        {
            int r = tid >> 2, kc = (tid & 3) << 3;
            *(short8*)&As[r * 40 + kc] = aR;
        }
        #pragma unroll
        for (int i = 0; i < 4; i++)
            *(unsigned*)&Bs[nn * 40 + ((kp0 + (i << 2)) << 1)] = bR[i];
        __syncthreads();
        if (s + 1 < nsteps) { loadA(s + 1); loadB(s + 1); }
        short8 af[2], bf[2];
        #pragma unroll
        for (int mi = 0; mi < 2; mi++) af[mi] = *(const short8*)&As[(wm * 32 + mi * 16 + l15) * 40 + (quad << 3)];
        #pragma unroll
        for (int ni = 0; ni < 2; ni++) bf[ni] = *(const short8*)&Bs[(wn * 32 + ni * 16 + l15) * 40 + (quad << 3)];
        #pragma unroll
        for (int mi = 0; mi < 2; mi++)
            #pragma unroll
            for (int ni = 0; ni < 2; ni++)
                acc[mi][ni] = __builtin_amdgcn_mfma_f32_16x16x32_bf16(af[mi], bf[ni], acc[mi][ni], 0, 0, 0);
        __syncthreads();
    }

    if (mode == 1) {
        float* outf = out + (long)blockIdx.z * ostride;
        #pragma unroll
        for (int mi = 0; mi < 2; mi++) {
            int mbase = m0 + wm * 32 + mi * 16 + quad * 4;
            #pragma unroll
            for (int ni = 0; ni < 2; ni++) {
                int n = n0 + wn * 32 + ni * 16 + l15;
                if (n >= HWo) continue;
                #pragma unroll
                for (int r = 0; r < 4; r++) {
                    int m = mbase + r;
                    outf[(long)n * Cout + m] = acc[mi][ni][r] + bias[m];
                }
            }
        }
    } else {
        unsigned* outp = (unsigned*)out + (long)blockIdx.z * ostride;
        float ssum[2] = {0.f, 0.f}, qsum[2] = {0.f, 0.f};
        #pragma unroll
        for (int mi = 0; mi < 2; mi++) {
            int mbase = m0 + wm * 32 + mi * 16 + quad * 4;
            float b0 = bias[mbase], b1 = bias[mbase + 1], b2 = bias[mbase + 2], b3 = bias[mbase + 3];
            #pragma unroll
            for (int ni = 0; ni < 2; ni++) {
                int n = n0 + wn * 32 + ni * 16 + l15;
                if (n >= HWo) continue;
                float v0 = acc[mi][ni][0] + b0;
                float v1 = acc[mi][ni][1] + b1;
                float v2 = acc[mi][ni][2] + b2;
                float v3 = acc[mi][ni][3] + b3;
                long cp = (long)(mbase >> 1) * HWo + n;
                outp[cp]       = packbf(v0, v1);
                outp[cp + HWo] = packbf(v2, v3);
                ssum[mi] += v0 + v1 + v2 + v3;
                qsum[mi] += v0 * v0 + v1 * v1 + v2 * v2 + v3 * v3;
            }
        }
        #pragma unroll
        for (int mi = 0; mi < 2; mi++) {
            #pragma unroll
            for (int off = 1; off < 16; off <<= 1) {
                ssum[mi] += __shfl_xor(ssum[mi], off, 16);
                qsum[mi] += __shfl_xor(qsum[mi], off, 16);
            }
        }
        if (l15 == 0) {
            #pragma unroll
            for (int mi = 0; mi < 2; mi++)
                sred[wm * 8 + mi * 4 + quad][wn] = make_float2(ssum[mi], qsum[mi]);
        }
        __syncthreads();
        int ng = 64 / cpg;          // groups covered by this block
        int qpg = cpg >> 2;         // quad-groups per group
        if (tid < ng) {
            float s = 0.f, q = 0.f;
            for (int u = 0; u < qpg; u++) {
                float2 a = sred[(tid * cpg >> 2) + u][0];
                float2 b = sred[(tid * cpg >> 2) + u][1];
                s += a.x + b.x; q += a.y + b.y;
            }
            int gabs = m0 / cpg + tid;
            parts[((long)blockIdx.z * 32 + gabs) * 1400 + blockIdx.x] = make_float2(s, q);
        }
    }
}

// ---------------- conv0: fp32 implicit GEMM (K=27) -> bf16-pair out (lean epilogue, no stats) ----------
// Cout=64 fixed, grid.x*64 == HWo exactly. blockIdx.z = camera.
__global__ __launch_bounds__(256) void conv_gemm_k(const float* __restrict__ in,
                                                   const float* __restrict__ w,
                                                   const float* __restrict__ bias,
                                                   unsigned* __restrict__ outp,
                                                   int Hin, int Win,
                                                   long istride, long ostride)
{
    in   += (long)blockIdx.z * istride;
    outp += (long)blockIdx.z * ostride;
    const int Hout = Hin >> 1, Wout = Win >> 1;
    const int HWo = Hout * Wout;
    const int Ktot = 27;
    __shared__ float As[16][68];
    __shared__ float Bs[16][68];
    int tid = threadIdx.x;
    int tx = tid & 15, ty = tid >> 4;
    int n0 = blockIdx.x * 64;
    int kb = tid >> 4;
    int nb = (tid & 15) * 4;
    int ma = tid >> 2;
    int ka0 = (tid & 3) * 4;
    int hibase[4], wibase[4];
    #pragma unroll
    for (int u = 0; u < 4; u++) {
        int p = n0 + nb + u;
        int ho = p / Wout, wo = p - ho * Wout;
        hibase[u] = ho * 2 - 1;
        wibase[u] = wo * 2 - 1;
    }
    float acc[4][4] = {{0.f}};
    const long wrow = (long)ma * Ktot;
    for (int kt = 0; kt < Ktot; kt += 16) {
        #pragma unroll
        for (int u = 0; u < 4; u++) {
            int k = kt + ka0 + u;
            As[ka0 + u][ma] = (k < Ktot) ? w[wrow + k] : 0.f;
        }
        int k = kt + kb;
        float bvals[4] = {0.f, 0.f, 0.f, 0.f};
        if (k < Ktot) {
            int ci = k / 9, r = k - ci * 9;
            int kh = r / 3, kw = r - kh * 3;
            const float* ip = in + (long)ci * Hin * Win;
            #pragma unroll
            for (int u = 0; u < 4; u++) {
                int hi = hibase[u] + kh;
                int wi = wibase[u] + kw;
                if (hi >= 0 && hi < Hin && wi >= 0 && wi < Win)
                    bvals[u] = ip[(long)hi * Win + wi];
            }
        }
        #pragma unroll
        for (int u = 0; u < 4; u++) Bs[kb][nb + u] = bvals[u];
        __syncthreads();
        #pragma unroll
        for (int kk = 0; kk < 16; kk++) {
            float av[4], bv[4];
            #pragma unroll
            for (int i = 0; i < 4; i++) av[i] = As[kk][ty * 4 + i];
            #pragma unroll
            for (int j = 0; j < 4; j++) bv[j] = Bs[kk][tx * 4 + j];
            #pragma unroll
            for (int i = 0; i < 4; i++)
                #pragma unroll
                for (int j = 0; j < 4; j++)
                    acc[i][j] += av[i] * bv[j];
        }
        __syncthreads();
    }
    // lean epilogue: bias + bf16-pair pack + store only
    int nbase = n0 + tx * 4;
    #pragma unroll
    for (int h = 0; h < 2; h++) {
        float b0 = bias[ty * 4 + 2 * h], b1 = bias[ty * 4 + 2 * h + 1];
        uint4 o;
        #pragma unroll
        for (int j = 0; j < 4; j++)
            ((unsigned*)&o)[j] = packbf(acc[2 * h][j] + b0, acc[2 * h + 1][j] + b1);
        *(uint4*)&outp[(long)(ty * 2 + h) * HWo + nbase] = o;
    }
}

// ---------------- stats over bf16-pair buffer: one group (= pair-rows) per block ----------------
// cpg==2 layout: group g == channel-pair g, contiguous HWdw dwords.
__global__ __launch_bounds__(256) void pairstats_k(const unsigned* __restrict__ x,
                                                   float* __restrict__ gnstats,
                                                   int HWdw, float invN, long zstride)
{
    x       += (long)blockIdx.z * zstride + (long)blockIdx.x * HWdw;
    gnstats += (long)blockIdx.z * 64;
    float s = 0.f, q = 0.f;
    int n4 = HWdw >> 2;
    for (int i = threadIdx.x; i < n4; i += 256) {
        uint4 v = *(const uint4*)&x[i << 2];
        #pragma unroll
        for (int j = 0; j < 4; j++) {
            unsigned u = ((const unsigned*)&v)[j];
            float lo = bflo(u), hi = bfhi(u);
            s += lo + hi;
            q += lo * lo + hi * hi;
        }
    }
    __shared__ float rs[256], rq[256];
    rs[threadIdx.x] = s; rq[threadIdx.x] = q;
    __syncthreads();
    for (int o = 128; o > 0; o >>= 1) {
        if (threadIdx.x < o) { rs[threadIdx.x] += rs[threadIdx.x + o]; rq[threadIdx.x] += rq[threadIdx.x + o]; }
        __syncthreads();
    }
    if (threadIdx.x == 0) {
        float mean = rs[0] * invN;
        float var  = rq[0] * invN - mean * mean;
        gnstats[blockIdx.x * 2]     = mean;
        gnstats[blockIdx.x * 2 + 1] = rsqrtf(var + EPS);
    }
}

// ---------------- GN finalize: reduce per-block partials -> mean/rstd ----------------
__global__ __launch_bounds__(256) void gnfin_k(const float2* __restrict__ parts,
                                               float* __restrict__ gnstats, int nx, float invN)
{
    int g = blockIdx.x, cam = blockIdx.y;
    const float2* pb = parts + ((long)cam * 32 + g) * 1400;
    float s = 0.f, q = 0.f;
    for (int i = threadIdx.x; i < nx; i += 256) {
        float2 v = pb[i];
        s += v.x; q += v.y;
    }
    __shared__ float rs[256], rq[256];
    rs[threadIdx.x] = s; rq[threadIdx.x] = q;
    __syncthreads();
    for (int o = 128; o > 0; o >>= 1) {
        if (threadIdx.x < o) { rs[threadIdx.x] += rs[threadIdx.x + o]; rq[threadIdx.x] += rq[threadIdx.x + o]; }
        __syncthreads();
    }
    if (threadIdx.x == 0) {
        float mean = rs[0] * invN;
        float var  = rq[0] * invN - mean * mean;
        gnstats[(cam * 32 + g) * 2]     = mean;
        gnstats[(cam * 32 + g) * 2 + 1] = rsqrtf(var + EPS);
    }
}

// ---------------- in-place GN apply + ReLU on bf16-pair buffer ----------------
__global__ __launch_bounds__(256) void pairapply_k(unsigned* __restrict__ x,
                                                   const float* __restrict__ gamma,
                                                   const float* __restrict__ beta,
                                                   const float* __restrict__ gnstats,
                                                   int HW, int cpg, long zstride)
{
    x       += (long)blockIdx.z * zstride;
    gnstats += (long)blockIdx.z * 64;
    int idx4 = (blockIdx.x * 256 + threadIdx.x) * 4;   // HW%4==0 -> all in one pair-row
    int cp = idx4 / HW;
    int c0 = cp * 2;
    int g = c0 / cpg;
    float mean = gnstats[g * 2], rstd = gnstats[g * 2 + 1];
    float sa = rstd * gamma[c0],     ba = beta[c0]     - mean * sa;
    float sb = rstd * gamma[c0 + 1], bb = beta[c0 + 1] - mean * sb;
    uint4 v = *(uint4*)&x[idx4];
    unsigned* vp = (unsigned*)&v;
    #pragma unroll
    for (int j = 0; j < 4; j++) {
        float lo = fmaxf(bflo(vp[j]) * sa + ba, 0.f);
        float hi = fmaxf(bfhi(vp[j]) * sb + bb, 0.f);
        vp[j] = packbf(lo, hi);
    }
    *(uint4*)&x[idx4] = v;
}

// ---------------- GroupNorm for (1400 x 256) spatial-major, batched over cams (grid.y) ----------------
__global__ __launch_bounds__(256) void gn_stats_hwd_k(const float* __restrict__ x, float* __restrict__ stats)
{
    x += (long)blockIdx.y * 358400;
    stats += blockIdx.y * 64;
    int g = blockIdx.x;  // 32 groups
    float s = 0.f, s2 = 0.f;
    for (int i = threadIdx.x; i < 1400 * 8; i += blockDim.x) {
        int p = i >> 3, c = g * 8 + (i & 7);
        float v = x[(long)p * 256 + c];
        s += v; s2 += v * v;
    }
    __shared__ float rs[256], rq[256];
    rs[threadIdx.x] = s; rq[threadIdx.x] = s2;
    __syncthreads();
    for (int o = 128; o > 0; o >>= 1) {
        if (threadIdx.x < o) { rs[threadIdx.x] += rs[threadIdx.x + o]; rq[threadIdx.x] += rq[threadIdx.x + o]; }
        __syncthreads();
    }
    if (threadIdx.x == 0) {
        float mean = rs[0] / 11200.f;
        float var  = rq[0] / 11200.f - mean * mean;
        stats[g * 2]     = mean;
        stats[g * 2 + 1] = rsqrtf(var + EPS);
    }
}

__global__ __launch_bounds__(256) void gn_apply_hwd_k(float* __restrict__ x,
                                                      const float* __restrict__ gamma,
                                                      const float* __restrict__ beta,
                                                      const float* __restrict__ stats,
                                                      int relu)
{
    x += (long)blockIdx.y * 358400;
    stats += blockIdx.y * 64;
    long i4 = ((long)blockIdx.x * 256 + threadIdx.x) * 4;  // grid.x = 350 -> exact
    int c = (int)(i4 & 255);
    int g = c >> 3;
    float4 v  = *(float4*)&x[i4];
    float4 gm = *(const float4*)&gamma[c];
    float4 bt = *(const float4*)&beta[c];
    float m = stats[g * 2], rs = stats[g * 2 + 1];
    v.x = (v.x - m) * rs * gm.x + bt.x;
    v.y = (v.y - m) * rs * gm.y + bt.y;
    v.z = (v.z - m) * rs * gm.z + bt.z;
    v.w = (v.w - m) * rs * gm.w + bt.w;
    if (relu) {
        v.x = fmaxf(v.x, 0.f); v.y = fmaxf(v.y, 0.f);
        v.z = fmaxf(v.z, 0.f); v.w = fmaxf(v.w, 0.f);
    }
    *(float4*)&x[i4] = v;
}

// ---------------- projection of BEV grid ----------------
__global__ __launch_bounds__(256) void project_k(const float* __restrict__ Kin,
                                                 const float* __restrict__ Ein,
                                                 float* __restrict__ refp, int* __restrict__ valid)
{
    int idx = blockIdx.x * blockDim.x + threadIdx.x;
    if (idx >= 2500 * 6) return;
    int c = idx % 6, q = idx / 6;
    int i = q / 50, j = q % 50;
    float px = (i - 24.5f) * 0.5f;
    float py = (j - 24.5f) * 0.5f;
    const float* E = Ein + c * 16;
    float pc[4];
    #pragma unroll
    for (int r = 0; r < 4; r++)
        pc[r] = E[r * 4 + 0] * px + E[r * 4 + 1] * py + E[r * 4 + 3];
    const float* Km = Kin + c * 9;
    float pix[3];
    #pragma unroll
    for (int r = 0; r < 3; r++)
        pix[r] = Km[r * 3 + 0] * pc[0] + Km[r * 3 + 1] * pc[1] + Km[r * 3 + 2] * pc[2];
    float z = fmaxf(pix[2], 1e-5f);
    float u = pix[0] / z, v = pix[1] / z;
    int ok = (pc[2] > 0.f) && (u >= 0.f) && (u < 800.f) && (v >= 0.f) && (v < 448.f);
    refp[(long)idx * 2 + 0] = 2.f * u / 799.f - 1.f;
    refp[(long)idx * 2 + 1] = 2.f * v / 447.f - 1.f;
    valid[idx] = ok;
}

// ---------------- misc elementwise ----------------
__global__ __launch_bounds__(256) void qinit_k(const float* __restrict__ a, const float* __restrict__ b,
                                               float* __restrict__ y)
{
    int i = blockIdx.x * blockDim.x + threadIdx.x;
    if (i >= 2500 * 256) return;
    y[i] = a[i] + b[i];
}

// ---------------- LayerNorm ----------------
__global__ __launch_bounds__(256) void ln_k(const float* __restrict__ x,
                                            const float* __restrict__ g, const float* __restrict__ b,
                                            float* __restrict__ y)
{
    int row  = blockIdx.x * 4 + (threadIdx.x >> 6);
    int lane = threadIdx.x & 63;
    if (row >= 2500) return;
    const float* xp = x + (long)row * 256;
    float v[4];
    #pragma unroll
    for (int i = 0; i < 4; i++) v[i] = xp[lane + 64 * i];
    float s  = v[0] + v[1] + v[2] + v[3];
    float s2 = v[0] * v[0] + v[1] * v[1] + v[2] * v[2] + v[3] * v[3];
    #pragma unroll
    for (int o = 32; o > 0; o >>= 1) { s += __shfl_xor(s, o, 64); s2 += __shfl_xor(s2, o, 64); }
    float mean = s * (1.f / 256.f);
    float var  = s2 * (1.f / 256.f) - mean * mean;
    float rstd = rsqrtf(var + EPS);
    #pragma unroll
    for (int i = 0; i < 4; i++) {
        int cc = lane + 64 * i;
        y[(long)row * 256 + cc] = (v[i] - mean) * rstd * g[cc] + b[cc];
    }
}

// ---------------- MFMA flash-2 MHA with split-K (packed-QKV aware: row stride ld) ----------------
__global__ __launch_bounds__(256) void flash2_k(const float* __restrict__ Q,
                                                const float* __restrict__ K,
                                                const float* __restrict__ V,
                                                int ld,
                                                float* __restrict__ Opart,   // (S,2500,256)
                                                float* __restrict__ MLpart)  // (S,2500,8,2)
{
    const int h  = blockIdx.y;
    const int q0 = blockIdx.x * 64;
    const int sp = blockIdx.z;
    const int kstart = sp * FL_KEYS, kend = kstart + FL_KEYS;
    const int tid = threadIdx.x;
    const int wave = tid >> 6, lane = tid & 63;
    const int quad = lane >> 4, l15 = lane & 15;
    __shared__ __align__(16) short Qs[64 * 40];
    __shared__ __align__(16) short Ks[64 * 40];
    __shared__ __align__(16) short Vt[32 * 72];
    __shared__ __align__(16) short Ps[64 * 72];
    const float scale = 0.17677669529663687f;
    {
        int row = tid >> 2, kc = (tid & 3) << 3;
        int qi = q0 + row;
        short8 pk = {0, 0, 0, 0, 0, 0, 0, 0};
        if (qi < 2500) {
            const float4* qp = (const float4*)(Q + (long)qi * ld + h * 32 + kc);
            float4 v0 = qp[0], v1 = qp[1];
            pk[0] = f2s(v0.x * scale); pk[1] = f2s(v0.y * scale); pk[2] = f2s(v0.z * scale); pk[3] = f2s(v0.w * scale);
            pk[4] = f2s(v1.x * scale); pk[5] = f2s(v1.y * scale); pk[6] = f2s(v1.z * scale); pk[7] = f2s(v1.w * scale);
        }
        *(short8*)&Qs[row * 40 + kc] = pk;
    }
    __syncthreads();
    short8 aq = *(const short8*)&Qs[(wave * 16 + l15) * 40 + (quad << 3)];
    float m[4], l[4];
    f4 oacc[2];
    #pragma unroll
    for (int r = 0; r < 4; r++) { m[r] = -INFINITY; l[r] = 0.f; }
    oacc[0] = (f4){0.f, 0.f, 0.f, 0.f};
    oacc[1] = (f4){0.f, 0.f, 0.f, 0.f};
    for (int kb = kstart; kb < kend; kb += 64) {
        __syncthreads();
        {
            int row = tid >> 2, kc = (tid & 3) << 3;
            int ki = kb + row;
            short8 pk = {0, 0, 0, 0, 0, 0, 0, 0};
            float vv[8] = {0.f, 0.f, 0.f, 0.f, 0.f, 0.f, 0.f, 0.f};
            if (ki < kend) {
                const float4* kp = (const float4*)(K + (long)ki * ld + h * 32 + kc);
                float4 a0 = kp[0], a1 = kp[1];
                pk[0] = f2s(a0.x); pk[1] = f2s(a0.y); pk[2] = f2s(a0.z); pk[3] = f2s(a0.w);
                pk[4] = f2s(a1.x); pk[5] = f2s(a1.y); pk[6] = f2s(a1.z); pk[7] = f2s(a1.w);
                const float4* vp = (const float4*)(V + (long)ki * ld + h * 32 + kc);
                float4 b0 = vp[0], b1 = vp[1];
                vv[0] = b0.x; vv[1] = b0.y; vv[2] = b0.z; vv[3] = b0.w;
                vv[4] = b1.x; vv[5] = b1.y; vv[6] = b1.z; vv[7] = b1.w;
            }
            *(short8*)&Ks[row * 40 + kc] = pk;
            #pragma unroll
            for (int j = 0; j < 8; j++) Vt[(kc + j) * 72 + row] = f2s(vv[j]);
        }
        __syncthreads();
        f4 sa[4];
        #pragma unroll
        for (int ni = 0; ni < 4; ni++) {
            short8 bk = *(const short8*)&Ks[(ni * 16 + l15) * 40 + (quad << 3)];
            sa[ni] = __builtin_amdgcn_mfma_f32_16x16x32_bf16(aq, bk, (f4){0.f, 0.f, 0.f, 0.f}, 0, 0, 0);
        }
        float sv[4][4];
        #pragma unroll
        for (int ni = 0; ni < 4; ni++) {
            bool colok = (kb + ni * 16 + l15) < kend;
            #pragma unroll
            for (int r = 0; r < 4; r++) sv[ni][r] = colok ? sa[ni][r] : -1e30f;
        }
        float p[4][4];
        #pragma unroll
        for (int r = 0; r < 4; r++) {
            float rm = fmaxf(fmaxf(sv[0][r], sv[1][r]), fmaxf(sv[2][r], sv[3][r]));
            #pragma unroll
            for (int off = 1; off < 16; off <<= 1) rm = fmaxf(rm, __shfl_xor(rm, off, 16));
            float mn = fmaxf(m[r], rm);
            float alpha = __expf(m[r] - mn);
            float rs = 0.f;
            #pragma unroll
            for (int ni = 0; ni < 4; ni++) { p[ni][r] = __expf(sv[ni][r] - mn); rs += p[ni][r]; }
            #pragma unroll
            for (int off = 1; off < 16; off <<= 1) rs += __shfl_xor(rs, off, 16);
            l[r] = l[r] * alpha + rs;
            oacc[0][r] *= alpha; oacc[1][r] *= alpha;
            m[r] = mn;
        }
        #pragma unroll
        for (int ni = 0; ni < 4; ni++)
            #pragma unroll
            for (int r = 0; r < 4; r++)
                Ps[(wave * 16 + quad * 4 + r) * 72 + ni * 16 + l15] = f2s(p[ni][r]);
        #pragma unroll
        for (int kh = 0; kh < 2; kh++) {
            short8 ap = *(const short8*)&Ps[(wave * 16 + l15) * 72 + kh * 32 + (quad << 3)];
            #pragma unroll
            for (int ni = 0; ni < 2; ni++) {
                short8 bv = *(const short8*)&Vt[(ni * 16 + l15) * 72 + kh * 32 + (quad << 3)];
                oacc[ni] = __builtin_amdgcn_mfma_f32_16x16x32_bf16(ap, bv, oacc[ni], 0, 0, 0);
            }
        }
    }
    #pragma unroll
    for (int r = 0; r < 4; r++) {
        int qi = q0 + wave * 16 + quad * 4 + r;
        if (qi < 2500) {
            long ob = ((long)sp * 2500 + qi) * 256 + h * 32;
            Opart[ob + l15]      = oacc[0][r];
            Opart[ob + 16 + l15] = oacc[1][r];
            if (l15 == 0) {
                long mb = (((long)sp * 2500 + qi) * 8 + h) * 2;
                MLpart[mb]     = m[r];
                MLpart[mb + 1] = l[r];
            }
        }
    }
}

__global__ __launch_bounds__(256) void flashmerge_k(const float* __restrict__ Opart,
                                                    const float* __restrict__ MLpart,
                                                    float* __restrict__ O)
{
    int q = blockIdx.x, d = threadIdx.x;
    int h = d >> 5;
    float ms[FL_SPLITS], ls[FL_SPLITS];
    float mg = -INFINITY;
    #pragma unroll
    for (int s = 0; s < FL_SPLITS; s++) {
        long mb = (((long)s * 2500 + q) * 8 + h) * 2;
        ms[s] = MLpart[mb];
        ls[s] = MLpart[mb + 1];
        mg = fmaxf(mg, ms[s]);
    }
    float lsum = 0.f, osum = 0.f;
    #pragma unroll
    for (int s = 0; s < FL_SPLITS; s++) {
        float w = __expf(ms[s] - mg);
        lsum += ls[s] * w;
        osum += Opart[((long)s * 2500 + q) * 256 + d] * w;
    }
    O[(long)q * 256 + d] = osum / lsum;
}

// ---------------- masked softmax over 192 deformable-attn logits (row stride ld) ----------------
__global__ __launch_bounds__(64) void scasoftmax_k(float* __restrict__ logits, int ld,
                                                   const int* __restrict__ valid)
{
    int q = blockIdx.x, lane = threadIdx.x;
    float v[3]; int mk[3];
    #pragma unroll
    for (int i = 0; i < 3; i++) {
        int idx = i * 64 + lane;
        int c = idx >> 5;
        mk[i] = valid[q * 6 + c];
        v[i] = mk[i] ? logits[(long)q * ld + idx] : -1e30f;
    }
    float mx = fmaxf(fmaxf(v[0], v[1]), v[2]);
    #pragma unroll
    for (int o = 32; o > 0; o >>= 1) mx = fmaxf(mx, __shfl_xor(mx, o, 64));
    float e[3]; float s = 0.f;
    #pragma unroll
    for (int i = 0; i < 3; i++) { e[i] = expf(v[i] - mx); s += e[i]; }
    #pragma unroll
    for (int o = 32; o > 0; o >>= 1) s += __shfl_xor(s, o, 64);
    float inv = 1.f / s;
    #pragma unroll
    for (int i = 0; i < 3; i++)
        logits[(long)q * ld + i * 64 + lane] = mk[i] ? e[i] * inv : 0.f;
}

// ---------------- deformable sampling (offs/wts with row stride ld) ----------------
__global__ __launch_bounds__(256) void sample_k(const float* __restrict__ vals,
                                                const float* __restrict__ offs, int ld,
                                                const float* __restrict__ wts,
                                                const float* __restrict__ refp,
                                                const int* __restrict__ valid,
                                                float* __restrict__ out)
{
    int q = blockIdx.x, d = threadIdx.x;
    __shared__ float s_cw[32][4];
    __shared__ int   s_idx[32][4];
    float acc = 0.f;
    for (int c = 0; c < 6; c++) {
        if (!valid[q * 6 + c]) continue;
        __syncthreads();
        if (d < 32) {
            float ox = offs[(long)q * ld + (c * 32 + d) * 2 + 0];
            float oy = offs[(long)q * ld + (c * 32 + d) * 2 + 1];
            float px = refp[(q * 6 + c) * 2 + 0] + ox * (2.f / 49.f);
            float py = refp[(q * 6 + c) * 2 + 1] + oy * (2.f / 27.f);
            float gx = (px + 1.f) * 0.5f * 49.f;
            float gy = (py + 1.f) * 0.5f * 27.f;
            float x0f = floorf(gx), y0f = floorf(gy);
            float wx = gx - x0f, wy = gy - y0f;
            int x0 = (int)x0f, y0 = (int)y0f;
            float wgt = wts[(long)q * ld + c * 32 + d];
            float cw[4] = {(1.f - wx) * (1.f - wy), wx * (1.f - wy), (1.f - wx) * wy, wx * wy};
            const int dxs[4] = {0, 1, 0, 1};
            const int dys[4] = {0, 0, 1, 1};
            #pragma unroll
            for (int k2 = 0; k2 < 4; k2++) {
                int xi = x0 + dxs[k2], yi = y0 + dys[k2];
                bool ok = (xi >= 0) && (xi < 50) && (yi >= 0) && (yi < 28);
                s_cw[d][k2]  = ok ? cw[k2] * wgt : 0.f;
                s_idx[d][k2] = ok ? (yi * 50 + xi) * 256 : 0;
            }
        }
        __syncthreads();
        const float* vb = vals + (long)c * 358400 + d;
        for (int pt = 0; pt < 32; pt++) {
            #pragma unroll
            for (int k2 = 0; k2 < 4; k2++) {
                float cwv = s_cw[pt][k2];
                if (cwv != 0.f) acc += cwv * vb[s_idx[pt][k2]];
            }
        }
    }
    out[(long)q * 256 + d] = acc;
}

// =====================================================================================
extern "C" void kernel_launch(void* const* d_in, const int* in_sizes, int n_in,
                              void* d_out, int out_size, void* d_ws, size_t ws_size,
                              hipStream_t stream)
{
    const float* images = (const float*)d_in[0];
    const float* intr   = (const float*)d_in[1];
    const float* e2c    = (const float*)d_in[2];
    const float* bevq   = (const float*)d_in[3];
    const float* bevp   = (const float*)d_in[4];
    const float* bbw[5]    = {(const float*)d_in[5],  (const float*)d_in[9],  (const float*)d_in[13], (const float*)d_in[17], (const float*)d_in[21]};
    const float* bbb[5]    = {(const float*)d_in[6],  (const float*)d_in[10], (const float*)d_in[14], (const float*)d_in[18], (const float*)d_in[22]};
    const float* bbg[5]    = {(const float*)d_in[7],  (const float*)d_in[11], (const float*)d_in[15], (const float*)d_in[19], (const float*)d_in[23]};
    const float* bbbeta[5] = {(const float*)d_in[8],  (const float*)d_in[12], (const float*)d_in[16], (const float*)d_in[20], (const float*)d_in[24]};
    const float* sa_wq = (const float*)d_in[25]; const float* sa_bq = (const float*)d_in[26];
    const float* sa_wk = (const float*)d_in[27]; const float* sa_bk = (const float*)d_in[28];
    const float* sa_wv = (const float*)d_in[29]; const float* sa_bv = (const float*)d_in[30];
    const float* sa_wo = (const float*)d_in[31]; const float* sa_bo = (const float*)d_in[32];
    const float* ln1g = (const float*)d_in[33]; const float* ln1b = (const float*)d_in[34];
    const float* ln2g = (const float*)d_in[35]; const float* ln2b = (const float*)d_in[36];
    const float* ln3g = (const float*)d_in[37]; const float* ln3b = (const float*)d_in[38];
    const float* offw = (const float*)d_in[39]; const float* offb = (const float*)d_in[40];
    const float* wtw  = (const float*)d_in[41]; const float* wtb  = (const float*)d_in[42];
    const float* valw = (const float*)d_in[43]; const float* valb = (const float*)d_in[44];
    const float* outw = (const float*)d_in[45]; const float* outb = (const float*)d_in[46];
    const float* fw1  = (const float*)d_in[47]; const float* fb1  = (const float*)d_in[48];
    const float* fw2  = (const float*)d_in[49]; const float* fb2  = (const float*)d_in[50];

    // ---- pick camera-batch factor from available workspace (formula unchanged) ----
    auto needB = [](long ncb) -> unsigned long long {
        return (unsigned long long)(ncb * 8601600L + 6681600L) * 4ULL + 6307840ULL + (1 << 20);
    };
    int ncb = 1;
    if      ((unsigned long long)ws_size >= needB(6)) ncb = 6;
    else if ((unsigned long long)ws_size >= needB(3)) ncb = 3;
    else if ((unsigned long long)ws_size >= needB(2)) ncb = 2;

    // ---- workspace layout ----
    float* ws = (float*)d_ws;
    float* A     = ws; ws += (long)ncb * 5734400;  // pair-buffer ping; aliases: bQKV, OP, bOW
    float* Bu    = ws; ws += (long)ncb * 2867200;  // pair-buffer pong; aliases: valsb, MLp
    float* f3bH  = ws; ws += 2560000;              // feats3 (backbone) / ffn hidden (transformer)
    float* feats = ws; ws += 2150400;              // (6,1400,256) hwd; also GN parts (early backbone)
    float* qbuf  = ws; ws += 640000;
    float* xq    = ws; ws += 640000;
    float* bO    = ws; ws += 640000;
    float* refp  = ws; ws += 30016;
    int*   validb = (int*)ws; ws += 15040;
    float* stats = ws; ws += 384;
    float* gnst  = ws; ws += 3072;                 // per-group mean/rstd (ncb x 32 x 2)
    float* qkvb  = ws; ws += 1536;
    float* owb   = ws; ws += 1152;
    // bf16 weight buffers
    short* sb = (short*)ws;
    short* cw1b = sb; sb += 73728;                 // tap-major (128, 9*64)
    short* cw2b = sb; sb += 294912;                // tap-major (256, 9*128)
    short* cw3b = sb; sb += 589824;                // tap-major (256, 9*256)
    short* cw4b = sb; sb += 65536;
    short* qkvT = sb; sb += 393216;
    short* owT  = sb; sb += 131072;
    short* valT = sb; sb += 131072;
    short* outT = sb; sb += 131072;
    short* offwtT = sb; sb += 294912;
    short* f1T  = sb; sb += 524288;
    short* f2T  = sb; sb += 524288;
    // aliases
    float*  feats3 = f3bH;
    float*  bH     = f3bH;
    float*  bQKV   = A;
    float*  OP     = A + 1920000;
    float*  bOW    = A + 1920000;
    float*  valsb  = Bu;
    float*  MLp    = Bu + 2150400;
    unsigned* Bbf0 = (unsigned*)A;                 // pair ping (stride varies per stage)
    unsigned* Bbf1 = (unsigned*)Bu;                // pair pong
    float2* partsP = (float2*)feats;               // 6*32*1400 float2 = 2.15 MB (free until conv4)

    auto mgemm = [&](const float* Ain, int lda, const short* Bt, const float* bias, const float* resid,
                     float* C, int M, int N, int K, int act) {
        dim3 g((N + 127) / 128, (M + 127) / 128);
        mgemm_k<<<g, 256, 0, stream>>>(Ain, lda, Bt, bias, resid, C, M, N, K, act);
    };

    // ---- weight preprocessing ----
    wreord_k<<<(73728 + 255) / 256, 256, 0, stream>>>(bbw[1], cw1b, 64, 73728);
    wreord_k<<<(294912 + 255) / 256, 256, 0, stream>>>(bbw[2], cw2b, 128, 294912);
    wreord_k<<<(589824 + 255) / 256, 256, 0, stream>>>(bbw[3], cw3b, 256, 589824);
    wcast_k<<<(65536 + 255) / 256, 256, 0, stream>>>(bbw[4], cw4b, 65536);
    wtrans_k<<<dim3(4, 4, 2), 256, 0, stream>>>(sa_wq, qkvT,          256, 256,  196608);
    wtrans_k<<<dim3(4, 4, 2), 256, 0, stream>>>(sa_wk, qkvT + 65536,  256, 256,  196608);
    wtrans_k<<<dim3(4, 4, 2), 256, 0, stream>>>(sa_wv, qkvT + 131072, 256, 256,  196608);
    wtrans_k<<<dim3(4, 4, 2), 256, 0, stream>>>(sa_wo, owT,  256, 256,  65536);
    wtrans_k<<<dim3(4, 4, 2), 256, 0, stream>>>(valw,  valT, 256, 256,  65536);
    wtrans_k<<<dim3(4, 4, 2), 256, 0, stream>>>(outw,  outT, 256, 256,  65536);
    wtrans_k<<<dim3(6, 4, 2), 256, 0, stream>>>(offw, offwtT,         256, 384,  147456);
    wtrans_k<<<dim3(3, 4, 2), 256, 0, stream>>>(wtw,  offwtT + 98304, 256, 192,  147456);
    wtrans_k<<<dim3(16, 4, 2), 256, 0, stream>>>(fw1, f1T, 256, 1024, 262144);
    wtrans_k<<<dim3(4, 16, 2), 256, 0, stream>>>(fw2, f2T, 1024, 256, 262144);
    packb_k<<<dim3(3, 2), 256, 0, stream>>>(sa_bq, sa_bk, sa_bv, qkvb, 256, 256, 256);
    packb_k<<<dim3(3, 2), 256, 0, stream>>>(offb, wtb, nullptr, owb, 384, 192, 0);

    // ---- projection of BEV grid ----
    project_k<<<(15000 + 255) / 256, 256, 0, stream>>>(intr, e2c, refp, validb);

    // ---- backbone (cam-batched; bf16-pair activations) ----
    for (int c0 = 0; c0 < 6; c0 += ncb) {
        const float* img = images + (long)c0 * 1075200;
        // conv0 -> pairs (lean); stats from separate pass over bf16 buffer
        conv_gemm_k<<<dim3(1400, 1, ncb), 256, 0, stream>>>(img, bbw[0], bbb[0], Bbf0,
                                                            448, 800, 1075200L, 2867200L);
        pairstats_k<<<dim3(32, 1, ncb), 256, 0, stream>>>(Bbf0, gnst, 89600, 1.f / 179200.f, 2867200L);
        pairapply_k<<<dim3(2800, 1, ncb), 256, 0, stream>>>(Bbf0, bbg[0], bbbeta[0], gnst, 89600, 2, 2867200L);
        // conv1 -> pairs + fused stats
        mconv_k<<<dim3(350, 2, ncb), 256, 0, stream>>>(Bbf0, cw1b, bbb[1], (float*)Bbf1, partsP,
                                                       1, 128, 224, 400, 2, 4, 2867200L, 1433600L);
        gnfin_k<<<dim3(32, ncb), 256, 0, stream>>>(partsP, gnst, 350, 1.f / 89600.f);
        pairapply_k<<<dim3(1400, 1, ncb), 256, 0, stream>>>(Bbf1, bbg[1], bbbeta[1], gnst, 22400, 4, 1433600L);
        // conv2 -> pairs + fused stats
        mconv_k<<<dim3(88, 4, ncb), 256, 0, stream>>>(Bbf1, cw2b, bbb[2], (float*)Bbf0, partsP,
                                                      2, 256, 112, 200, 2, 8, 1433600L, 716800L);
        gnfin_k<<<dim3(32, ncb), 256, 0, stream>>>(partsP, gnst, 88, 1.f / 44800.f);
        pairapply_k<<<dim3(700, 1, ncb), 256, 0, stream>>>(Bbf0, bbg[2], bbbeta[2], gnst, 5600, 8, 716800L);
        // conv3 -> f32 spatial-major feats3[cam]
        mconv_k<<<dim3(22, 4, ncb), 256, 0, stream>>>(Bbf0, cw3b, bbb[3], feats3 + (long)c0 * 358400, nullptr,
                                                      3, 256, 56, 100, 1, 0, 716800L, 358400L);
    }
    // batched conv3-GN (+relu), conv4 as one 8400x256 GEMM, batched conv4-GN
    gn_stats_hwd_k<<<dim3(32, 6), 256, 0, stream>>>(feats3, stats);
    gn_apply_hwd_k<<<dim3(350, 6), 256, 0, stream>>>(feats3, bbg[3], bbbeta[3], stats, 1);
    mgemm(feats3, 256, cw4b, bbb[4], nullptr, feats, 8400, 256, 256, 0);
    gn_stats_hwd_k<<<dim3(32, 6), 256, 0, stream>>>(feats, stats);
    gn_apply_hwd_k<<<dim3(350, 6), 256, 0, stream>>>(feats, bbg[4], bbbeta[4], stats, 0);

    // ---- transformer ----
    qinit_k<<<2500, 256, 0, stream>>>(bevq, bevp, qbuf);

    for (int l = 0; l < 2; l++) {
        long o1 = (long)l * 256;

        // self-attention (fused QKV projection: 2500 x 768)
        ln_k<<<625, 256, 0, stream>>>(qbuf, ln1g + o1, ln1b + o1, xq);
        mgemm(xq, 256, qkvT + l * 196608, qkvb + l * 768, nullptr, bQKV, 2500, 768, 256, 0);
        flash2_k<<<dim3(40, 8, FL_SPLITS), 256, 0, stream>>>(bQKV, bQKV + 256, bQKV + 512, 768, OP, MLp);
        flashmerge_k<<<2500, 256, 0, stream>>>(OP, MLp, bO);
        mgemm(bO, 256, owT + l * 65536, sa_bo + o1, qbuf, qbuf, 2500, 256, 256, 0);

        // spatial cross-attention (fused offsets+logits projection: 2500 x 576)
        ln_k<<<625, 256, 0, stream>>>(qbuf, ln2g + o1, ln2b + o1, xq);
        mgemm(feats, 256, valT + l * 65536, valb + o1, nullptr, valsb, 8400, 256, 256, 0);
        mgemm(xq, 256, offwtT + l * 147456, owb + l * 576, nullptr, bOW, 2500, 576, 256, 0);
        scasoftmax_k<<<2500, 64, 0, stream>>>(bOW + 384, 576, validb);
        sample_k<<<2500, 256, 0, stream>>>(valsb, bOW, 576, bOW + 384, refp, validb, bO);
        mgemm(bO, 256, outT + l * 65536, outb + o1, qbuf, qbuf, 2500, 256, 256, 0);

        // FFN
        ln_k<<<625, 256, 0, stream>>>(qbuf, ln3g + o1, ln3b + o1, xq);
        mgemm(xq, 256, f1T + l * 262144, fb1 + (long)l * 1024, nullptr, bH, 2500, 1024, 256, 2);
        mgemm(bH, 1024, f2T + l * 262144, fb2 + o1, qbuf,
              (l == 1) ? (float*)d_out : qbuf, 2500, 256, 1024, 0);
    }
}

// Round 6
// 1156.863 us; speedup vs baseline: 1.7152x; 1.2615x over previous
//
#include <hip/hip_runtime.h>
#include <hip/hip_bf16.h>
#include <math.h>

#define EPS 1e-5f
#define FL_SPLITS 5
#define FL_KEYS 500

typedef __attribute__((ext_vector_type(8))) short short8;
typedef __attribute__((ext_vector_type(4))) float f4;

__device__ __forceinline__ short f2s(float f) {
    union { float f; unsigned u; } v; v.f = f;
    unsigned r = (v.u + 0x7fffu + ((v.u >> 16) & 1u)) >> 16;  // RNE
    return (short)r;
}
__device__ __forceinline__ unsigned packbf(float a, float b) {
    return (unsigned)(unsigned short)f2s(a) | ((unsigned)(unsigned short)f2s(b) << 16);
}
__device__ __forceinline__ float bflo(unsigned v) { union { unsigned u; float f; } t; t.u = v << 16; return t.f; }
__device__ __forceinline__ float bfhi(unsigned v) { union { unsigned u; float f; } t; t.u = v & 0xffff0000u; return t.f; }

// ---------------- weight preprocessing ----------------
__global__ __launch_bounds__(256) void wcast_k(const float* __restrict__ in, short* __restrict__ out, int n)
{
    int i = blockIdx.x * 256 + threadIdx.x;
    if (i < n) out[i] = f2s(in[i]);
}

// conv weight reorder: (Cout, Cin, 3,3) fp32 -> (Cout, 9, Cin) bf16 (tap-major)
__global__ __launch_bounds__(256) void wreord_k(const float* __restrict__ in, short* __restrict__ out,
                                                int Cin, int n)
{
    int i = blockIdx.x * 256 + threadIdx.x;
    if (i >= n) return;
    int cin9 = Cin * 9;
    int co = i / cin9, rem = i - co * cin9;
    int ci = rem / 9, t = rem - ci * 9;
    out[(long)co * cin9 + t * Cin + ci] = f2s(in[i]);
}

// (K,N) fp32 -> (N,K) bf16 ; blockIdx.z = matrix index, zstride = output stride per matrix
__global__ __launch_bounds__(256) void wtrans_k(const float* __restrict__ in, short* __restrict__ out,
                                                int K, int N, long zstride)
{
    in  += (long)blockIdx.z * K * N;
    out += (long)blockIdx.z * zstride;
    __shared__ float t[64][65];
    int k0 = blockIdx.y * 64, n0 = blockIdx.x * 64;
    int tid = threadIdx.x;
    int cl = tid & 63, rq = tid >> 6;
    #pragma unroll
    for (int i = 0; i < 16; i++) {
        int rl = rq + i * 4;
        int k = k0 + rl, n = n0 + cl;
        t[rl][cl] = (k < K && n < N) ? in[(long)k * N + n] : 0.f;
    }
    __syncthreads();
    #pragma unroll
    for (int i = 0; i < 16; i++) {
        int nl = rq + i * 4;
        int n = n0 + nl, k = k0 + cl;
        if (n < N && k < K) out[(long)n * K + k] = f2s(t[cl][nl]);
    }
}

// pack per-layer bias segments
__global__ __launch_bounds__(256) void packb_k(const float* __restrict__ a, const float* __restrict__ b,
                                               const float* __restrict__ c, float* __restrict__ y,
                                               int na, int nb, int nc)
{
    int l = blockIdx.y;
    int j = blockIdx.x * 256 + threadIdx.x;
    int ntot = na + nb + nc;
    if (j >= ntot) return;
    float v;
    if (j < na) v = a[l * na + j];
    else if (j < na + nb) v = b[l * nb + (j - na)];
    else v = c[l * nc + (j - na - nb)];
    y[(long)l * ntot + j] = v;
}

// ---------------- MFMA GEMM, 64x64 tile (4 waves, 2x2 MFMA each): C = A(fp32) @ Bt^T ----------------
// Small-M/N friendly: 4x the block count of the old 128-tile version; identical K-order numerics.
__global__ __launch_bounds__(256) void mgemm_k(const float* __restrict__ A, int lda,
                                               const short* __restrict__ Bt,
                                               const float* __restrict__ bias,
                                               const float* __restrict__ resid,
                                               float* __restrict__ C,
                                               int M, int N, int K, int act)
{
    __shared__ __align__(16) short As[2560];   // 64 rows x 40 (32 used)
    __shared__ __align__(16) short Bs[2560];
    int tid = threadIdx.x;
    int wave = tid >> 6, lane = tid & 63;
    int wm = wave >> 1, wn = wave & 1;
    int quad = lane >> 4, l15 = lane & 15;
    int m0 = blockIdx.y * 64, n0 = blockIdx.x * 64;
    int srow = tid >> 2, skc = (tid & 3) << 3;
    f4 acc[2][2];
    #pragma unroll
    for (int i = 0; i < 2; i++) { acc[i][0] = (f4){0.f,0.f,0.f,0.f}; acc[i][1] = (f4){0.f,0.f,0.f,0.f}; }
    short8 aR, bR;
    auto loadAB = [&](int kt) {
        int gm = m0 + srow;
        short8 pk = {0, 0, 0, 0, 0, 0, 0, 0};
        if (gm < M) {
            const float4* ap = (const float4*)(A + (long)gm * lda + kt + skc);
            float4 v0 = ap[0], v1 = ap[1];
            pk[0] = f2s(v0.x); pk[1] = f2s(v0.y); pk[2] = f2s(v0.z); pk[3] = f2s(v0.w);
            pk[4] = f2s(v1.x); pk[5] = f2s(v1.y); pk[6] = f2s(v1.z); pk[7] = f2s(v1.w);
        }
        aR = pk;
        int gn = n0 + srow;
        short8 pb = {0, 0, 0, 0, 0, 0, 0, 0};
        if (gn < N) pb = *(const short8*)&Bt[(long)gn * K + kt + skc];
        bR = pb;
    };
    loadAB(0);
    for (int kt = 0; kt < K; kt += 32) {
        *(short8*)&As[srow * 40 + skc] = aR;
        *(short8*)&Bs[srow * 40 + skc] = bR;
        __syncthreads();
        if (kt + 32 < K) loadAB(kt + 32);
        short8 af[2], bf[2];
        #pragma unroll
        for (int mi = 0; mi < 2; mi++) af[mi] = *(const short8*)&As[(wm * 32 + mi * 16 + l15) * 40 + (quad << 3)];
        #pragma unroll
        for (int ni = 0; ni < 2; ni++) bf[ni] = *(const short8*)&Bs[(wn * 32 + ni * 16 + l15) * 40 + (quad << 3)];
        #pragma unroll
        for (int mi = 0; mi < 2; mi++)
            #pragma unroll
            for (int ni = 0; ni < 2; ni++)
                acc[mi][ni] = __builtin_amdgcn_mfma_f32_16x16x32_bf16(af[mi], bf[ni], acc[mi][ni], 0, 0, 0);
        __syncthreads();
    }
    #pragma unroll
    for (int mi = 0; mi < 2; mi++) {
        int row = m0 + wm * 32 + mi * 16 + quad * 4;
        #pragma unroll
        for (int ni = 0; ni < 2; ni++) {
            int col = n0 + wn * 32 + ni * 16 + l15;
            if (col >= N) continue;
            float bv = bias[col];
            #pragma unroll
            for (int r = 0; r < 4; r++) {
                int rr = row + r;
                if (rr >= M) continue;
                float v = acc[mi][ni][r] + bv;
                if (act == 2) v = 0.5f * v * (1.f + erff(v * 0.70710678118654752f));
                if (resid) v += resid[(long)rr * N + col];
                C[(long)rr * N + col] = v;
            }
        }
    }
}

// ---------------- MFMA conv 3x3 s2 p1, tap-major K, bf16-pair input ----------------
// mode 1: f32 spatial-major out (ostride floats). mode 2: bf16-pair out (ostride dwords) + GN partial stats.
__global__ __launch_bounds__(256) void mconv_k(const unsigned* __restrict__ in,
                                               const short* __restrict__ wgt,
                                               const float* __restrict__ bias,
                                               float* __restrict__ out,
                                               float2* __restrict__ parts,
                                               int c5m, int Cout, int Hin, int Win,
                                               int mode, int cpg,
                                               long istride, long ostride)
{
    in  += (long)blockIdx.z * istride;
    const int Hout = Hin >> 1, Wout = Win >> 1;
    const int HWo = Hout * Wout;
    const int HW = Hin * Win;
    const int Ktot = 288 << c5m;   // 9*Cin
    const int m5 = (1 << c5m) - 1;
    const int nsteps = 9 << c5m;
    __shared__ __align__(16) short As[2560];   // 64 rows x 40
    __shared__ __align__(16) short Bs[2560];   // 64 cols x 40
    __shared__ float2 sred[16][2];             // [quad-group][wn] = (s, s2)
    int tid = threadIdx.x;
    int wave = tid >> 6, lane = tid & 63;
    int wm = wave >> 1, wn = wave & 1;
    int quad = lane >> 4, l15 = lane & 15;
    int m0 = blockIdx.y * 64, n0 = blockIdx.x * 64;
    int nn = tid & 63;
    int kp0 = tid >> 6;
    int p = n0 + nn;
    int pok = p < HWo;
    int pc = pok ? p : (HWo - 1);
    int ho = pc / Wout, wo = pc - ho * Wout;
    int hb = ho * 2 - 1, wb = wo * 2 - 1;

    f4 acc[2][2];
    #pragma unroll
    for (int i = 0; i < 2; i++) { acc[i][0] = (f4){0.f,0.f,0.f,0.f}; acc[i][1] = (f4){0.f,0.f,0.f,0.f}; }

    short8 aR;
    unsigned bR[4];
    auto loadA = [&](int s) {
        int r = tid >> 2, kc = (tid & 3) << 3;
        aR = *(const short8*)&wgt[(long)(m0 + r) * Ktot + (s << 5) + kc];
    };
    auto loadB = [&](int s) {
        int t = s >> c5m;
        int kh = (t * 11) >> 5;            // t/3 for t in 0..8
        int kw = t - kh * 3;
        int y = hb + kh, x = wb + kw;
        bool okp = pok && ((unsigned)y < (unsigned)Hin) && ((unsigned)x < (unsigned)Win);
        int base = (((s & m5) << 4) + kp0) * HW + y * Win + x;
        #pragma unroll
        for (int i = 0; i < 4; i++) {
            unsigned v = 0;
            if (okp) v = in[base + (i << 2) * HW];
            bR[i] = v;
        }
    };

    loadA(0); loadB(0);
    for (int s = 0; s < nsteps; s++) {
        {
            int r = tid >> 2, kc = (tid & 3) << 3;
            *(short8*)&As[r * 40 + kc] = aR;
        }
        #pragma unroll
        for (int i = 0; i < 4; i++)
            *(unsigned*)&Bs[nn * 40 + ((kp0 + (i << 2)) << 1)] = bR[i];
        __syncthreads();
        if (s + 1 < nsteps) { loadA(s + 1); loadB(s + 1); }
        short8 af[2], bf[2];
        #pragma unroll
        for (int mi = 0; mi < 2; mi++) af[mi] = *(const short8*)&As[(wm * 32 + mi * 16 + l15) * 40 + (quad << 3)];
        #pragma unroll
        for (int ni = 0; ni < 2; ni++) bf[ni] = *(const short8*)&Bs[(wn * 32 + ni * 16 + l15) * 40 + (quad << 3)];
        #pragma unroll
        for (int mi = 0; mi < 2; mi++)
            #pragma unroll
            for (int ni = 0; ni < 2; ni++)
                acc[mi][ni] = __builtin_amdgcn_mfma_f32_16x16x32_bf16(af[mi], bf[ni], acc[mi][ni], 0, 0, 0);
        __syncthreads();
    }

    if (mode == 1) {
        float* outf = out + (long)blockIdx.z * ostride;
        #pragma unroll
        for (int mi = 0; mi < 2; mi++) {
            int mbase = m0 + wm * 32 + mi * 16 + quad * 4;
            #pragma unroll
            for (int ni = 0; ni < 2; ni++) {
                int n = n0 + wn * 32 + ni * 16 + l15;
                if (n >= HWo) continue;
                #pragma unroll
                for (int r = 0; r < 4; r++) {
                    int m = mbase + r;
                    outf[(long)n * Cout + m] = acc[mi][ni][r] + bias[m];
                }
            }
        }
    } else {
        unsigned* outp = (unsigned*)out + (long)blockIdx.z * ostride;
        float ssum[2] = {0.f, 0.f}, qsum[2] = {0.f, 0.f};
        #pragma unroll
        for (int mi = 0; mi < 2; mi++) {
            int mbase = m0 + wm * 32 + mi * 16 + quad * 4;
            float b0 = bias[mbase], b1 = bias[mbase + 1], b2 = bias[mbase + 2], b3 = bias[mbase + 3];
            #pragma unroll
            for (int ni = 0; ni < 2; ni++) {
                int n = n0 + wn * 32 + ni * 16 + l15;
                if (n >= HWo) continue;
                float v0 = acc[mi][ni][0] + b0;
                float v1 = acc[mi][ni][1] + b1;
                float v2 = acc[mi][ni][2] + b2;
                float v3 = acc[mi][ni][3] + b3;
                long cp = (long)(mbase >> 1) * HWo + n;
                outp[cp]       = packbf(v0, v1);
                outp[cp + HWo] = packbf(v2, v3);
                ssum[mi] += v0 + v1 + v2 + v3;
                qsum[mi] += v0 * v0 + v1 * v1 + v2 * v2 + v3 * v3;
            }
        }
        #pragma unroll
        for (int mi = 0; mi < 2; mi++) {
            #pragma unroll
            for (int off = 1; off < 16; off <<= 1) {
                ssum[mi] += __shfl_xor(ssum[mi], off, 16);
                qsum[mi] += __shfl_xor(qsum[mi], off, 16);
            }
        }
        if (l15 == 0) {
            #pragma unroll
            for (int mi = 0; mi < 2; mi++)
                sred[wm * 8 + mi * 4 + quad][wn] = make_float2(ssum[mi], qsum[mi]);
        }
        __syncthreads();
        int ng = 64 / cpg;          // groups covered by this block
        int qpg = cpg >> 2;         // quad-groups per group
        if (tid < ng) {
            float s = 0.f, q = 0.f;
            for (int u = 0; u < qpg; u++) {
                float2 a = sred[(tid * cpg >> 2) + u][0];
                float2 b = sred[(tid * cpg >> 2) + u][1];
                s += a.x + b.x; q += a.y + b.y;
            }
            int gabs = m0 / cpg + tid;
            parts[((long)blockIdx.z * 32 + gabs) * 1400 + blockIdx.x] = make_float2(s, q);
        }
    }
}

// ---------------- conv0: fp32 implicit GEMM (K=27) -> bf16-pair out (lean epilogue, no stats) ----------
// Cout=64 fixed, grid.x*64 == HWo exactly. blockIdx.z = camera. float4 LDS reads (b128).
__global__ __launch_bounds__(256) void conv_gemm_k(const float* __restrict__ in,
                                                   const float* __restrict__ w,
                                                   const float* __restrict__ bias,
                                                   unsigned* __restrict__ outp,
                                                   int Hin, int Win,
                                                   long istride, long ostride)
{
    in   += (long)blockIdx.z * istride;
    outp += (long)blockIdx.z * ostride;
    const int Hout = Hin >> 1, Wout = Win >> 1;
    const int HWo = Hout * Wout;
    const int Ktot = 27;
    __shared__ __align__(16) float As[16][68];   // row = 272 B (16B multiple)
    __shared__ __align__(16) float Bs[16][68];
    int tid = threadIdx.x;
    int tx = tid & 15, ty = tid >> 4;
    int n0 = blockIdx.x * 64;
    int kb = tid >> 4;
    int nb = (tid & 15) * 4;
    int ma = tid >> 2;
    int ka0 = (tid & 3) * 4;
    int hibase[4], wibase[4];
    #pragma unroll
    for (int u = 0; u < 4; u++) {
        int p = n0 + nb + u;
        int ho = p / Wout, wo = p - ho * Wout;
        hibase[u] = ho * 2 - 1;
        wibase[u] = wo * 2 - 1;
    }
    float acc[4][4] = {{0.f}};
    const long wrow = (long)ma * Ktot;
    for (int kt = 0; kt < Ktot; kt += 16) {
        #pragma unroll
        for (int u = 0; u < 4; u++) {
            int k = kt + ka0 + u;
            As[ka0 + u][ma] = (k < Ktot) ? w[wrow + k] : 0.f;
        }
        int k = kt + kb;
        float bvals[4] = {0.f, 0.f, 0.f, 0.f};
        if (k < Ktot) {
            int ci = k / 9, r = k - ci * 9;
            int kh = r / 3, kw = r - kh * 3;
            const float* ip = in + (long)ci * Hin * Win;
            #pragma unroll
            for (int u = 0; u < 4; u++) {
                int hi = hibase[u] + kh;
                int wi = wibase[u] + kw;
                if (hi >= 0 && hi < Hin && wi >= 0 && wi < Win)
                    bvals[u] = ip[(long)hi * Win + wi];
            }
        }
        #pragma unroll
        for (int u = 0; u < 4; u++) Bs[kb][nb + u] = bvals[u];
        __syncthreads();
        #pragma unroll
        for (int kk = 0; kk < 16; kk++) {
            float4 a4 = *(const float4*)&As[kk][ty * 4];
            float4 b4 = *(const float4*)&Bs[kk][tx * 4];
            float av[4] = {a4.x, a4.y, a4.z, a4.w};
            float bv[4] = {b4.x, b4.y, b4.z, b4.w};
            #pragma unroll
            for (int i = 0; i < 4; i++)
                #pragma unroll
                for (int j = 0; j < 4; j++)
                    acc[i][j] += av[i] * bv[j];
        }
        __syncthreads();
    }
    // lean epilogue: bias + bf16-pair pack + store only
    int nbase = n0 + tx * 4;
    #pragma unroll
    for (int h = 0; h < 2; h++) {
        float b0 = bias[ty * 4 + 2 * h], b1 = bias[ty * 4 + 2 * h + 1];
        uint4 o;
        #pragma unroll
        for (int j = 0; j < 4; j++)
            ((unsigned*)&o)[j] = packbf(acc[2 * h][j] + b0, acc[2 * h + 1][j] + b1);
        *(uint4*)&outp[(long)(ty * 2 + h) * HWo + nbase] = o;
    }
}

// ---------------- stats over bf16-pair buffer: one group (= pair-rows) per block ----------------
__global__ __launch_bounds__(256) void pairstats_k(const unsigned* __restrict__ x,
                                                   float* __restrict__ gnstats,
                                                   int HWdw, float invN, long zstride)
{
    x       += (long)blockIdx.z * zstride + (long)blockIdx.x * HWdw;
    gnstats += (long)blockIdx.z * 64;
    float s = 0.f, q = 0.f;
    int n4 = HWdw >> 2;
    for (int i = threadIdx.x; i < n4; i += 256) {
        uint4 v = *(const uint4*)&x[i << 2];
        #pragma unroll
        for (int j = 0; j < 4; j++) {
            unsigned u = ((const unsigned*)&v)[j];
            float lo = bflo(u), hi = bfhi(u);
            s += lo + hi;
            q += lo * lo + hi * hi;
        }
    }
    __shared__ float rs[256], rq[256];
    rs[threadIdx.x] = s; rq[threadIdx.x] = q;
    __syncthreads();
    for (int o = 128; o > 0; o >>= 1) {
        if (threadIdx.x < o) { rs[threadIdx.x] += rs[threadIdx.x + o]; rq[threadIdx.x] += rq[threadIdx.x + o]; }
        __syncthreads();
    }
    if (threadIdx.x == 0) {
        float mean = rs[0] * invN;
        float var  = rq[0] * invN - mean * mean;
        gnstats[blockIdx.x * 2]     = mean;
        gnstats[blockIdx.x * 2 + 1] = rsqrtf(var + EPS);
    }
}

// ---------------- GN finalize: reduce per-block partials -> mean/rstd ----------------
__global__ __launch_bounds__(256) void gnfin_k(const float2* __restrict__ parts,
                                               float* __restrict__ gnstats, int nx, float invN)
{
    int g = blockIdx.x, cam = blockIdx.y;
    const float2* pb = parts + ((long)cam * 32 + g) * 1400;
    float s = 0.f, q = 0.f;
    for (int i = threadIdx.x; i < nx; i += 256) {
        float2 v = pb[i];
        s += v.x; q += v.y;
    }
    __shared__ float rs[256], rq[256];
    rs[threadIdx.x] = s; rq[threadIdx.x] = q;
    __syncthreads();
    for (int o = 128; o > 0; o >>= 1) {
        if (threadIdx.x < o) { rs[threadIdx.x] += rs[threadIdx.x + o]; rq[threadIdx.x] += rq[threadIdx.x + o]; }
        __syncthreads();
    }
    if (threadIdx.x == 0) {
        float mean = rs[0] * invN;
        float var  = rq[0] * invN - mean * mean;
        gnstats[(cam * 32 + g) * 2]     = mean;
        gnstats[(cam * 32 + g) * 2 + 1] = rsqrtf(var + EPS);
    }
}

// ---------------- in-place GN apply + ReLU on bf16-pair buffer ----------------
__global__ __launch_bounds__(256) void pairapply_k(unsigned* __restrict__ x,
                                                   const float* __restrict__ gamma,
                                                   const float* __restrict__ beta,
                                                   const float* __restrict__ gnstats,
                                                   int HW, int cpg, long zstride)
{
    x       += (long)blockIdx.z * zstride;
    gnstats += (long)blockIdx.z * 64;
    int idx4 = (blockIdx.x * 256 + threadIdx.x) * 4;   // HW%4==0 -> all in one pair-row
    int cp = idx4 / HW;
    int c0 = cp * 2;
    int g = c0 / cpg;
    float mean = gnstats[g * 2], rstd = gnstats[g * 2 + 1];
    float sa = rstd * gamma[c0],     ba = beta[c0]     - mean * sa;
    float sb = rstd * gamma[c0 + 1], bb = beta[c0 + 1] - mean * sb;
    uint4 v = *(uint4*)&x[idx4];
    unsigned* vp = (unsigned*)&v;
    #pragma unroll
    for (int j = 0; j < 4; j++) {
        float lo = fmaxf(bflo(vp[j]) * sa + ba, 0.f);
        float hi = fmaxf(bfhi(vp[j]) * sb + bb, 0.f);
        vp[j] = packbf(lo, hi);
    }
    *(uint4*)&x[idx4] = v;
}

// ---------------- GroupNorm for (1400 x 256) spatial-major, batched over cams (grid.y) ----------------
__global__ __launch_bounds__(256) void gn_stats_hwd_k(const float* __restrict__ x, float* __restrict__ stats)
{
    x += (long)blockIdx.y * 358400;
    stats += blockIdx.y * 64;
    int g = blockIdx.x;  // 32 groups
    float s = 0.f, s2 = 0.f;
    for (int i = threadIdx.x; i < 1400 * 8; i += blockDim.x) {
        int p = i >> 3, c = g * 8 + (i & 7);
        float v = x[(long)p * 256 + c];
        s += v; s2 += v * v;
    }
    __shared__ float rs[256], rq[256];
    rs[threadIdx.x] = s; rq[threadIdx.x] = s2;
    __syncthreads();
    for (int o = 128; o > 0; o >>= 1) {
        if (threadIdx.x < o) { rs[threadIdx.x] += rs[threadIdx.x + o]; rq[threadIdx.x] += rq[threadIdx.x + o]; }
        __syncthreads();
    }
    if (threadIdx.x == 0) {
        float mean = rs[0] / 11200.f;
        float var  = rq[0] / 11200.f - mean * mean;
        stats[g * 2]     = mean;
        stats[g * 2 + 1] = rsqrtf(var + EPS);
    }
}

__global__ __launch_bounds__(256) void gn_apply_hwd_k(float* __restrict__ x,
                                                      const float* __restrict__ gamma,
                                                      const float* __restrict__ beta,
                                                      const float* __restrict__ stats,
                                                      int relu)
{
    x += (long)blockIdx.y * 358400;
    stats += blockIdx.y * 64;
    long i4 = ((long)blockIdx.x * 256 + threadIdx.x) * 4;  // grid.x = 350 -> exact
    int c = (int)(i4 & 255);
    int g = c >> 3;
    float4 v  = *(float4*)&x[i4];
    float4 gm = *(const float4*)&gamma[c];
    float4 bt = *(const float4*)&beta[c];
    float m = stats[g * 2], rs = stats[g * 2 + 1];
    v.x = (v.x - m) * rs * gm.x + bt.x;
    v.y = (v.y - m) * rs * gm.y + bt.y;
    v.z = (v.z - m) * rs * gm.z + bt.z;
    v.w = (v.w - m) * rs * gm.w + bt.w;
    if (relu) {
        v.x = fmaxf(v.x, 0.f); v.y = fmaxf(v.y, 0.f);
        v.z = fmaxf(v.z, 0.f); v.w = fmaxf(v.w, 0.f);
    }
    *(float4*)&x[i4] = v;
}

// ---------------- projection of BEV grid ----------------
__global__ __launch_bounds__(256) void project_k(const float* __restrict__ Kin,
                                                 const float* __restrict__ Ein,
                                                 float* __restrict__ refp, int* __restrict__ valid)
{
    int idx = blockIdx.x * blockDim.x + threadIdx.x;
    if (idx >= 2500 * 6) return;
    int c = idx % 6, q = idx / 6;
    int i = q / 50, j = q % 50;
    float px = (i - 24.5f) * 0.5f;
    float py = (j - 24.5f) * 0.5f;
    const float* E = Ein + c * 16;
    float pc[4];
    #pragma unroll
    for (int r = 0; r < 4; r++)
        pc[r] = E[r * 4 + 0] * px + E[r * 4 + 1] * py + E[r * 4 + 3];
    const float* Km = Kin + c * 9;
    float pix[3];
    #pragma unroll
    for (int r = 0; r < 3; r++)
        pix[r] = Km[r * 3 + 0] * pc[0] + Km[r * 3 + 1] * pc[1] + Km[r * 3 + 2] * pc[2];
    float z = fmaxf(pix[2], 1e-5f);
    float u = pix[0] / z, v = pix[1] / z;
    int ok = (pc[2] > 0.f) && (u >= 0.f) && (u < 800.f) && (v >= 0.f) && (v < 448.f);
    refp[(long)idx * 2 + 0] = 2.f * u / 799.f - 1.f;
    refp[(long)idx * 2 + 1] = 2.f * v / 447.f - 1.f;
    valid[idx] = ok;
}

// ---------------- misc elementwise ----------------
__global__ __launch_bounds__(256) void qinit_k(const float* __restrict__ a, const float* __restrict__ b,
                                               float* __restrict__ y)
{
    int i = blockIdx.x * blockDim.x + threadIdx.x;
    if (i >= 2500 * 256) return;
    y[i] = a[i] + b[i];
}

// ---------------- LayerNorm ----------------
__global__ __launch_bounds__(256) void ln_k(const float* __restrict__ x,
                                            const float* __restrict__ g, const float* __restrict__ b,
                                            float* __restrict__ y)
{
    int row  = blockIdx.x * 4 + (threadIdx.x >> 6);
    int lane = threadIdx.x & 63;
    if (row >= 2500) return;
    const float* xp = x + (long)row * 256;
    float v[4];
    #pragma unroll
    for (int i = 0; i < 4; i++) v[i] = xp[lane + 64 * i];
    float s  = v[0] + v[1] + v[2] + v[3];
    float s2 = v[0] * v[0] + v[1] * v[1] + v[2] * v[2] + v[3] * v[3];
    #pragma unroll
    for (int o = 32; o > 0; o >>= 1) { s += __shfl_xor(s, o, 64); s2 += __shfl_xor(s2, o, 64); }
    float mean = s * (1.f / 256.f);
    float var  = s2 * (1.f / 256.f) - mean * mean;
    float rstd = rsqrtf(var + EPS);
    #pragma unroll
    for (int i = 0; i < 4; i++) {
        int cc = lane + 64 * i;
        y[(long)row * 256 + cc] = (v[i] - mean) * rstd * g[cc] + b[cc];
    }
}

// ---------------- MFMA flash-2 MHA with split-K (packed-QKV aware: row stride ld) ----------------
__global__ __launch_bounds__(256) void flash2_k(const float* __restrict__ Q,
                                                const float* __restrict__ K,
                                                const float* __restrict__ V,
                                                int ld,
                                                float* __restrict__ Opart,   // (S,2500,256)
                                                float* __restrict__ MLpart)  // (S,2500,8,2)
{
    const int h  = blockIdx.y;
    const int q0 = blockIdx.x * 64;
    const int sp = blockIdx.z;
    const int kstart = sp * FL_KEYS, kend = kstart + FL_KEYS;
    const int tid = threadIdx.x;
    const int wave = tid >> 6, lane = tid & 63;
    const int quad = lane >> 4, l15 = lane & 15;
    __shared__ __align__(16) short Qs[64 * 40];
    __shared__ __align__(16) short Ks[64 * 40];
    __shared__ __align__(16) short Vt[32 * 72];
    __shared__ __align__(16) short Ps[64 * 72];
    const float scale = 0.17677669529663687f;
    {
        int row = tid >> 2, kc = (tid & 3) << 3;
        int qi = q0 + row;
        short8 pk = {0, 0, 0, 0, 0, 0, 0, 0};
        if (qi < 2500) {
            const float4* qp = (const float4*)(Q + (long)qi * ld + h * 32 + kc);
            float4 v0 = qp[0], v1 = qp[1];
            pk[0] = f2s(v0.x * scale); pk[1] = f2s(v0.y * scale); pk[2] = f2s(v0.z * scale); pk[3] = f2s(v0.w * scale);
            pk[4] = f2s(v1.x * scale); pk[5] = f2s(v1.y * scale); pk[6] = f2s(v1.z * scale); pk[7] = f2s(v1.w * scale);
        }
        *(short8*)&Qs[row * 40 + kc] = pk;
    }
    __syncthreads();
    short8 aq = *(const short8*)&Qs[(wave * 16 + l15) * 40 + (quad << 3)];
    float m[4], l[4];
    f4 oacc[2];
    #pragma unroll
    for (int r = 0; r < 4; r++) { m[r] = -INFINITY; l[r] = 0.f; }
    oacc[0] = (f4){0.f, 0.f, 0.f, 0.f};
    oacc[1] = (f4){0.f, 0.f, 0.f, 0.f};
    for (int kb = kstart; kb < kend; kb += 64) {
        __syncthreads();
        {
            int row = tid >> 2, kc = (tid & 3) << 3;
            int ki = kb + row;
            short8 pk = {0, 0, 0, 0, 0, 0, 0, 0};
            float vv[8] = {0.f, 0.f, 0.f, 0.f, 0.f, 0.f, 0.f, 0.f};
            if (ki < kend) {
                const float4* kp = (const float4*)(K + (long)ki * ld + h * 32 + kc);
                float4 a0 = kp[0], a1 = kp[1];
                pk[0] = f2s(a0.x); pk[1] = f2s(a0.y); pk[2] = f2s(a0.z); pk[3] = f2s(a0.w);
                pk[4] = f2s(a1.x); pk[5] = f2s(a1.y); pk[6] = f2s(a1.z); pk[7] = f2s(a1.w);
                const float4* vp = (const float4*)(V + (long)ki * ld + h * 32 + kc);
                float4 b0 = vp[0], b1 = vp[1];
                vv[0] = b0.x; vv[1] = b0.y; vv[2] = b0.z; vv[3] = b0.w;
                vv[4] = b1.x; vv[5] = b1.y; vv[6] = b1.z; vv[7] = b1.w;
            }
            *(short8*)&Ks[row * 40 + kc] = pk;
            #pragma unroll
            for (int j = 0; j < 8; j++) Vt[(kc + j) * 72 + row] = f2s(vv[j]);
        }
        __syncthreads();
        f4 sa[4];
        #pragma unroll
        for (int ni = 0; ni < 4; ni++) {
            short8 bk = *(const short8*)&Ks[(ni * 16 + l15) * 40 + (quad << 3)];
            sa[ni] = __builtin_amdgcn_mfma_f32_16x16x32_bf16(aq, bk, (f4){0.f, 0.f, 0.f, 0.f}, 0, 0, 0);
        }
        float sv[4][4];
        #pragma unroll
        for (int ni = 0; ni < 4; ni++) {
            bool colok = (kb + ni * 16 + l15) < kend;
            #pragma unroll
            for (int r = 0; r < 4; r++) sv[ni][r] = colok ? sa[ni][r] : -1e30f;
        }
        float p[4][4];
        #pragma unroll
        for (int r = 0; r < 4; r++) {
            float rm = fmaxf(fmaxf(sv[0][r], sv[1][r]), fmaxf(sv[2][r], sv[3][r]));
            #pragma unroll
            for (int off = 1; off < 16; off <<= 1) rm = fmaxf(rm, __shfl_xor(rm, off, 16));
            float mn = fmaxf(m[r], rm);
            float alpha = __expf(m[r] - mn);
            float rs = 0.f;
            #pragma unroll
            for (int ni = 0; ni < 4; ni++) { p[ni][r] = __expf(sv[ni][r] - mn); rs += p[ni][r]; }
            #pragma unroll
            for (int off = 1; off < 16; off <<= 1) rs += __shfl_xor(rs, off, 16);
            l[r] = l[r] * alpha + rs;
            oacc[0][r] *= alpha; oacc[1][r] *= alpha;
            m[r] = mn;
        }
        #pragma unroll
        for (int ni = 0; ni < 4; ni++)
            #pragma unroll
            for (int r = 0; r < 4; r++)
                Ps[(wave * 16 + quad * 4 + r) * 72 + ni * 16 + l15] = f2s(p[ni][r]);
        #pragma unroll
        for (int kh = 0; kh < 2; kh++) {
            short8 ap = *(const short8*)&Ps[(wave * 16 + l15) * 72 + kh * 32 + (quad << 3)];
            #pragma unroll
            for (int ni = 0; ni < 2; ni++) {
                short8 bv = *(const short8*)&Vt[(ni * 16 + l15) * 72 + kh * 32 + (quad << 3)];
                oacc[ni] = __builtin_amdgcn_mfma_f32_16x16x32_bf16(ap, bv, oacc[ni], 0, 0, 0);
            }
        }
    }
    #pragma unroll
    for (int r = 0; r < 4; r++) {
        int qi = q0 + wave * 16 + quad * 4 + r;
        if (qi < 2500) {
            long ob = ((long)sp * 2500 + qi) * 256 + h * 32;
            Opart[ob + l15]      = oacc[0][r];
            Opart[ob + 16 + l15] = oacc[1][r];
            if (l15 == 0) {
                long mb = (((long)sp * 2500 + qi) * 8 + h) * 2;
                MLpart[mb]     = m[r];
                MLpart[mb + 1] = l[r];
            }
        }
    }
}

__global__ __launch_bounds__(256) void flashmerge_k(const float* __restrict__ Opart,
                                                    const float* __restrict__ MLpart,
                                                    float* __restrict__ O)
{
    int q = blockIdx.x, d = threadIdx.x;
    int h = d >> 5;
    float ms[FL_SPLITS], ls[FL_SPLITS];
    float mg = -INFINITY;
    #pragma unroll
    for (int s = 0; s < FL_SPLITS; s++) {
        long mb = (((long)s * 2500 + q) * 8 + h) * 2;
        ms[s] = MLpart[mb];
        ls[s] = MLpart[mb + 1];
        mg = fmaxf(mg, ms[s]);
    }
    float lsum = 0.f, osum = 0.f;
    #pragma unroll
    for (int s = 0; s < FL_SPLITS; s++) {
        float w = __expf(ms[s] - mg);
        lsum += ls[s] * w;
        osum += Opart[((long)s * 2500 + q) * 256 + d] * w;
    }
    O[(long)q * 256 + d] = osum / lsum;
}

// ---------------- masked softmax over 192 deformable-attn logits (row stride ld) ----------------
__global__ __launch_bounds__(64) void scasoftmax_k(float* __restrict__ logits, int ld,
                                                   const int* __restrict__ valid)
{
    int q = blockIdx.x, lane = threadIdx.x;
    float v[3]; int mk[3];
    #pragma unroll
    for (int i = 0; i < 3; i++) {
        int idx = i * 64 + lane;
        int c = idx >> 5;
        mk[i] = valid[q * 6 + c];
        v[i] = mk[i] ? logits[(long)q * ld + idx] : -1e30f;
    }
    float mx = fmaxf(fmaxf(v[0], v[1]), v[2]);
    #pragma unroll
    for (int o = 32; o > 0; o >>= 1) mx = fmaxf(mx, __shfl_xor(mx, o, 64));
    float e[3]; float s = 0.f;
    #pragma unroll
    for (int i = 0; i < 3; i++) { e[i] = expf(v[i] - mx); s += e[i]; }
    #pragma unroll
    for (int o = 32; o > 0; o >>= 1) s += __shfl_xor(s, o, 64);
    float inv = 1.f / s;
    #pragma unroll
    for (int i = 0; i < 3; i++)
        logits[(long)q * ld + i * 64 + lane] = mk[i] ? e[i] * inv : 0.f;
}

// ---------------- deformable sampling (offs/wts with row stride ld); one setup pass for all cams ------
__global__ __launch_bounds__(256) void sample_k(const float* __restrict__ vals,
                                                const float* __restrict__ offs, int ld,
                                                const float* __restrict__ wts,
                                                const float* __restrict__ refp,
                                                const int* __restrict__ valid,
                                                float* __restrict__ out)
{
    int q = blockIdx.x, d = threadIdx.x;
    __shared__ float s_cw[6][32][4];
    __shared__ int   s_idx[6][32][4];
    if (d < 192) {
        int c = d >> 5, pt = d & 31;
        if (valid[q * 6 + c]) {
            float ox = offs[(long)q * ld + (c * 32 + pt) * 2 + 0];
            float oy = offs[(long)q * ld + (c * 32 + pt) * 2 + 1];
            float px = refp[(q * 6 + c) * 2 + 0] + ox * (2.f / 49.f);
            float py = refp[(q * 6 + c) * 2 + 1] + oy * (2.f / 27.f);
            float gx = (px + 1.f) * 0.5f * 49.f;
            float gy = (py + 1.f) * 0.5f * 27.f;
            float x0f = floorf(gx), y0f = floorf(gy);
            float wx = gx - x0f, wy = gy - y0f;
            int x0 = (int)x0f, y0 = (int)y0f;
            float wgt = wts[(long)q * ld + c * 32 + pt];
            float cw[4] = {(1.f - wx) * (1.f - wy), wx * (1.f - wy), (1.f - wx) * wy, wx * wy};
            const int dxs[4] = {0, 1, 0, 1};
            const int dys[4] = {0, 0, 1, 1};
            #pragma unroll
            for (int k2 = 0; k2 < 4; k2++) {
                int xi = x0 + dxs[k2], yi = y0 + dys[k2];
                bool ok = (xi >= 0) && (xi < 50) && (yi >= 0) && (yi < 28);
                s_cw[c][pt][k2]  = ok ? cw[k2] * wgt : 0.f;
                s_idx[c][pt][k2] = ok ? (yi * 50 + xi) * 256 : 0;
            }
        }
    }
    __syncthreads();
    float acc = 0.f;
    for (int c = 0; c < 6; c++) {
        if (!valid[q * 6 + c]) continue;
        const float* vb = vals + (long)c * 358400 + d;
        for (int pt = 0; pt < 32; pt++) {
            #pragma unroll
            for (int k2 = 0; k2 < 4; k2++) {
                float cwv = s_cw[c][pt][k2];
                if (cwv != 0.f) acc += cwv * vb[s_idx[c][pt][k2]];
            }
        }
    }
    out[(long)q * 256 + d] = acc;
}

// =====================================================================================
extern "C" void kernel_launch(void* const* d_in, const int* in_sizes, int n_in,
                              void* d_out, int out_size, void* d_ws, size_t ws_size,
                              hipStream_t stream)
{
    const float* images = (const float*)d_in[0];
    const float* intr   = (const float*)d_in[1];
    const float* e2c    = (const float*)d_in[2];
    const float* bevq   = (const float*)d_in[3];
    const float* bevp   = (const float*)d_in[4];
    const float* bbw[5]    = {(const float*)d_in[5],  (const float*)d_in[9],  (const float*)d_in[13], (const float*)d_in[17], (const float*)d_in[21]};
    const float* bbb[5]    = {(const float*)d_in[6],  (const float*)d_in[10], (const float*)d_in[14], (const float*)d_in[18], (const float*)d_in[22]};
    const float* bbg[5]    = {(const float*)d_in[7],  (const float*)d_in[11], (const float*)d_in[15], (const float*)d_in[19], (const float*)d_in[23]};
    const float* bbbeta[5] = {(const float*)d_in[8],  (const float*)d_in[12], (const float*)d_in[16], (const float*)d_in[20], (const float*)d_in[24]};
    const float* sa_wq = (const float*)d_in[25]; const float* sa_bq = (const float*)d_in[26];
    const float* sa_wk = (const float*)d_in[27]; const float* sa_bk = (const float*)d_in[28];
    const float* sa_wv = (const float*)d_in[29]; const float* sa_bv = (const float*)d_in[30];
    const float* sa_wo = (const float*)d_in[31]; const float* sa_bo = (const float*)d_in[32];
    const float* ln1g = (const float*)d_in[33]; const float* ln1b = (const float*)d_in[34];
    const float* ln2g = (const float*)d_in[35]; const float* ln2b = (const float*)d_in[36];
    const float* ln3g = (const float*)d_in[37]; const float* ln3b = (const float*)d_in[38];
    const float* offw = (const float*)d_in[39]; const float* offb = (const float*)d_in[40];
    const float* wtw  = (const float*)d_in[41]; const float* wtb  = (const float*)d_in[42];
    const float* valw = (const float*)d_in[43]; const float* valb = (const float*)d_in[44];
    const float* outw = (const float*)d_in[45]; const float* outb = (const float*)d_in[46];
    const float* fw1  = (const float*)d_in[47]; const float* fb1  = (const float*)d_in[48];
    const float* fw2  = (const float*)d_in[49]; const float* fb2  = (const float*)d_in[50];

    // ---- pick camera-batch factor from available workspace (formula unchanged) ----
    auto needB = [](long ncb) -> unsigned long long {
        return (unsigned long long)(ncb * 8601600L + 6681600L) * 4ULL + 6307840ULL + (1 << 20);
    };
    int ncb = 1;
    if      ((unsigned long long)ws_size >= needB(6)) ncb = 6;
    else if ((unsigned long long)ws_size >= needB(3)) ncb = 3;
    else if ((unsigned long long)ws_size >= needB(2)) ncb = 2;

    // ---- workspace layout ----
    float* ws = (float*)d_ws;
    float* A     = ws; ws += (long)ncb * 5734400;  // pair-buffer ping; aliases: bQKV, OP, bOW
    float* Bu    = ws; ws += (long)ncb * 2867200;  // pair-buffer pong; aliases: valsb, MLp
    float* f3bH  = ws; ws += 2560000;              // feats3 (backbone) / ffn hidden (transformer)
    float* feats = ws; ws += 2150400;              // (6,1400,256) hwd; also GN parts (early backbone)
    float* qbuf  = ws; ws += 640000;
    float* xq    = ws; ws += 640000;
    float* bO    = ws; ws += 640000;
    float* refp  = ws; ws += 30016;
    int*   validb = (int*)ws; ws += 15040;
    float* stats = ws; ws += 384;
    float* gnst  = ws; ws += 3072;                 // per-group mean/rstd (ncb x 32 x 2)
    float* qkvb  = ws; ws += 1536;
    float* owb   = ws; ws += 1152;
    // bf16 weight buffers
    short* sb = (short*)ws;
    short* cw1b = sb; sb += 73728;                 // tap-major (128, 9*64)
    short* cw2b = sb; sb += 294912;                // tap-major (256, 9*128)
    short* cw3b = sb; sb += 589824;                // tap-major (256, 9*256)
    short* cw4b = sb; sb += 65536;
    short* qkvT = sb; sb += 393216;
    short* owT  = sb; sb += 131072;
    short* valT = sb; sb += 131072;
    short* outT = sb; sb += 131072;
    short* offwtT = sb; sb += 294912;
    short* f1T  = sb; sb += 524288;
    short* f2T  = sb; sb += 524288;
    // aliases
    float*  feats3 = f3bH;
    float*  bH     = f3bH;
    float*  bQKV   = A;
    float*  OP     = A + 1920000;
    float*  bOW    = A + 1920000;
    float*  valsb  = Bu;
    float*  MLp    = Bu + 2150400;
    unsigned* Bbf0 = (unsigned*)A;                 // pair ping (stride varies per stage)
    unsigned* Bbf1 = (unsigned*)Bu;                // pair pong
    float2* partsP = (float2*)feats;               // 6*32*1400 float2 = 2.15 MB (free until conv4)

    auto mgemm = [&](const float* Ain, int lda, const short* Bt, const float* bias, const float* resid,
                     float* C, int M, int N, int K, int act) {
        dim3 g((N + 63) / 64, (M + 63) / 64);
        mgemm_k<<<g, 256, 0, stream>>>(Ain, lda, Bt, bias, resid, C, M, N, K, act);
    };

    // ---- weight preprocessing ----
    wreord_k<<<(73728 + 255) / 256, 256, 0, stream>>>(bbw[1], cw1b, 64, 73728);
    wreord_k<<<(294912 + 255) / 256, 256, 0, stream>>>(bbw[2], cw2b, 128, 294912);
    wreord_k<<<(589824 + 255) / 256, 256, 0, stream>>>(bbw[3], cw3b, 256, 589824);
    wcast_k<<<(65536 + 255) / 256, 256, 0, stream>>>(bbw[4], cw4b, 65536);
    wtrans_k<<<dim3(4, 4, 2), 256, 0, stream>>>(sa_wq, qkvT,          256, 256,  196608);
    wtrans_k<<<dim3(4, 4, 2), 256, 0, stream>>>(sa_wk, qkvT + 65536,  256, 256,  196608);
    wtrans_k<<<dim3(4, 4, 2), 256, 0, stream>>>(sa_wv, qkvT + 131072, 256, 256,  196608);
    wtrans_k<<<dim3(4, 4, 2), 256, 0, stream>>>(sa_wo, owT,  256, 256,  65536);
    wtrans_k<<<dim3(4, 4, 2), 256, 0, stream>>>(valw,  valT, 256, 256,  65536);
    wtrans_k<<<dim3(4, 4, 2), 256, 0, stream>>>(outw,  outT, 256, 256,  65536);
    wtrans_k<<<dim3(6, 4, 2), 256, 0, stream>>>(offw, offwtT,         256, 384,  147456);
    wtrans_k<<<dim3(3, 4, 2), 256, 0, stream>>>(wtw,  offwtT + 98304, 256, 192,  147456);
    wtrans_k<<<dim3(16, 4, 2), 256, 0, stream>>>(fw1, f1T, 256, 1024, 262144);
    wtrans_k<<<dim3(4, 16, 2), 256, 0, stream>>>(fw2, f2T, 1024, 256, 262144);
    packb_k<<<dim3(3, 2), 256, 0, stream>>>(sa_bq, sa_bk, sa_bv, qkvb, 256, 256, 256);
    packb_k<<<dim3(3, 2), 256, 0, stream>>>(offb, wtb, nullptr, owb, 384, 192, 0);

    // ---- projection of BEV grid ----
    project_k<<<(15000 + 255) / 256, 256, 0, stream>>>(intr, e2c, refp, validb);

    // ---- backbone (cam-batched; bf16-pair activations) ----
    for (int c0 = 0; c0 < 6; c0 += ncb) {
        const float* img = images + (long)c0 * 1075200;
        // conv0 -> pairs (lean); stats from separate pass over bf16 buffer
        conv_gemm_k<<<dim3(1400, 1, ncb), 256, 0, stream>>>(img, bbw[0], bbb[0], Bbf0,
                                                            448, 800, 1075200L, 2867200L);
        pairstats_k<<<dim3(32, 1, ncb), 256, 0, stream>>>(Bbf0, gnst, 89600, 1.f / 179200.f, 2867200L);
        pairapply_k<<<dim3(2800, 1, ncb), 256, 0, stream>>>(Bbf0, bbg[0], bbbeta[0], gnst, 89600, 2, 2867200L);
        // conv1 -> pairs + fused stats
        mconv_k<<<dim3(350, 2, ncb), 256, 0, stream>>>(Bbf0, cw1b, bbb[1], (float*)Bbf1, partsP,
                                                       1, 128, 224, 400, 2, 4, 2867200L, 1433600L);
        gnfin_k<<<dim3(32, ncb), 256, 0, stream>>>(partsP, gnst, 350, 1.f / 89600.f);
        pairapply_k<<<dim3(1400, 1, ncb), 256, 0, stream>>>(Bbf1, bbg[1], bbbeta[1], gnst, 22400, 4, 1433600L);
        // conv2 -> pairs + fused stats
        mconv_k<<<dim3(88, 4, ncb), 256, 0, stream>>>(Bbf1, cw2b, bbb[2], (float*)Bbf0, partsP,
                                                      2, 256, 112, 200, 2, 8, 1433600L, 716800L);
        gnfin_k<<<dim3(32, ncb), 256, 0, stream>>>(partsP, gnst, 88, 1.f / 44800.f);
        pairapply_k<<<dim3(700, 1, ncb), 256, 0, stream>>>(Bbf0, bbg[2], bbbeta[2], gnst, 5600, 8, 716800L);
        // conv3 -> f32 spatial-major feats3[cam]
        mconv_k<<<dim3(22, 4, ncb), 256, 0, stream>>>(Bbf0, cw3b, bbb[3], feats3 + (long)c0 * 358400, nullptr,
                                                      3, 256, 56, 100, 1, 0, 716800L, 358400L);
    }
    // batched conv3-GN (+relu), conv4 as one 8400x256 GEMM, batched conv4-GN
    gn_stats_hwd_k<<<dim3(32, 6), 256, 0, stream>>>(feats3, stats);
    gn_apply_hwd_k<<<dim3(350, 6), 256, 0, stream>>>(feats3, bbg[3], bbbeta[3], stats, 1);
    mgemm(feats3, 256, cw4b, bbb[4], nullptr, feats, 8400, 256, 256, 0);
    gn_stats_hwd_k<<<dim3(32, 6), 256, 0, stream>>>(feats, stats);
    gn_apply_hwd_k<<<dim3(350, 6), 256, 0, stream>>>(feats, bbg[4], bbbeta[4], stats, 0);

    // ---- transformer ----
    qinit_k<<<2500, 256, 0, stream>>>(bevq, bevp, qbuf);

    for (int l = 0; l < 2; l++) {
        long o1 = (long)l * 256;

        // self-attention (fused QKV projection: 2500 x 768)
        ln_k<<<625, 256, 0, stream>>>(qbuf, ln1g + o1, ln1b + o1, xq);
        mgemm(xq, 256, qkvT + l * 196608, qkvb + l * 768, nullptr, bQKV, 2500, 768, 256, 0);
        flash2_k<<<dim3(40, 8, FL_SPLITS), 256, 0, stream>>>(bQKV, bQKV + 256, bQKV + 512, 768, OP, MLp);
        flashmerge_k<<<2500, 256, 0, stream>>>(OP, MLp, bO);
        mgemm(bO, 256, owT + l * 65536, sa_bo + o1, qbuf, qbuf, 2500, 256, 256, 0);

        // spatial cross-attention (fused offsets+logits projection: 2500 x 576)
        ln_k<<<625, 256, 0, stream>>>(qbuf, ln2g + o1, ln2b + o1, xq);
        mgemm(feats, 256, valT + l * 65536, valb + o1, nullptr, valsb, 8400, 256, 256, 0);
        mgemm(xq, 256, offwtT + l * 147456, owb + l * 576, nullptr, bOW, 2500, 576, 256, 0);
        scasoftmax_k<<<2500, 64, 0, stream>>>(bOW + 384, 576, validb);
        sample_k<<<2500, 256, 0, stream>>>(valsb, bOW, 576, bOW + 384, refp, validb, bO);
        mgemm(bO, 256, outT + l * 65536, outb + o1, qbuf, qbuf, 2500, 256, 256, 0);

        // FFN
        ln_k<<<625, 256, 0, stream>>>(qbuf, ln3g + o1, ln3b + o1, xq);
        mgemm(xq, 256, f1T + l * 262144, fb1 + (long)l * 1024, nullptr, bH, 2500, 1024, 256, 2);
        mgemm(bH, 1024, f2T + l * 262144, fb2 + o1, qbuf,
              (l == 1) ? (float*)d_out : qbuf, 2500, 256, 1024, 0);
    }
}

// Round 7
// 1031.280 us; speedup vs baseline: 1.9241x; 1.1218x over previous
//
#include <hip/hip_runtime.h>
#include <hip/hip_bf16.h>
#include <math.h>

#define EPS 1e-5f
#define FL_SPLITS 5
#define FL_KEYS 500

typedef __attribute__((ext_vector_type(8))) short short8;
typedef __attribute__((ext_vector_type(4))) float f4;

__device__ __forceinline__ short f2s(float f) {
    union { float f; unsigned u; } v; v.f = f;
    unsigned r = (v.u + 0x7fffu + ((v.u >> 16) & 1u)) >> 16;  // RNE
    return (short)r;
}
__device__ __forceinline__ unsigned packbf(float a, float b) {
    return (unsigned)(unsigned short)f2s(a) | ((unsigned)(unsigned short)f2s(b) << 16);
}
__device__ __forceinline__ float bflo(unsigned v) { union { unsigned u; float f; } t; t.u = v << 16; return t.f; }
__device__ __forceinline__ float bfhi(unsigned v) { union { unsigned u; float f; } t; t.u = v & 0xffff0000u; return t.f; }

// ---------------- weight preprocessing ----------------
__global__ __launch_bounds__(256) void wcast_k(const float* __restrict__ in, short* __restrict__ out, int n)
{
    int i = blockIdx.x * 256 + threadIdx.x;
    if (i < n) out[i] = f2s(in[i]);
}

// conv0 weight pack: (64,3,3,3) fp32 -> (64,32) bf16, k = ci*9 + t, pad 27..31 = 0
__global__ __launch_bounds__(256) void wcast0_k(const float* __restrict__ in, short* __restrict__ out)
{
    int i = blockIdx.x * 256 + threadIdx.x;
    if (i >= 2048) return;
    int k = i & 31;
    out[i] = (k < 27) ? f2s(in[(i >> 5) * 27 + k]) : (short)0;
}

// conv weight reorder: (Cout, Cin, 3,3) fp32 -> (Cout, 9, Cin) bf16 (tap-major)
__global__ __launch_bounds__(256) void wreord_k(const float* __restrict__ in, short* __restrict__ out,
                                                int Cin, int n)
{
    int i = blockIdx.x * 256 + threadIdx.x;
    if (i >= n) return;
    int cin9 = Cin * 9;
    int co = i / cin9, rem = i - co * cin9;
    int ci = rem / 9, t = rem - ci * 9;
    out[(long)co * cin9 + t * Cin + ci] = f2s(in[i]);
}

// (K,N) fp32 -> (N,K) bf16 ; blockIdx.z = matrix index, zstride = output stride per matrix
__global__ __launch_bounds__(256) void wtrans_k(const float* __restrict__ in, short* __restrict__ out,
                                                int K, int N, long zstride)
{
    in  += (long)blockIdx.z * K * N;
    out += (long)blockIdx.z * zstride;
    __shared__ float t[64][65];
    int k0 = blockIdx.y * 64, n0 = blockIdx.x * 64;
    int tid = threadIdx.x;
    int cl = tid & 63, rq = tid >> 6;
    #pragma unroll
    for (int i = 0; i < 16; i++) {
        int rl = rq + i * 4;
        int k = k0 + rl, n = n0 + cl;
        t[rl][cl] = (k < K && n < N) ? in[(long)k * N + n] : 0.f;
    }
    __syncthreads();
    #pragma unroll
    for (int i = 0; i < 16; i++) {
        int nl = rq + i * 4;
        int n = n0 + nl, k = k0 + cl;
        if (n < N && k < K) out[(long)n * K + k] = f2s(t[cl][nl]);
    }
}

// six 256x256 (K,N)->(N,K) transposes in one dispatch; blockIdx.z = mat*2 + layer
__global__ __launch_bounds__(256) void wtrans6_k(const float* __restrict__ s0, const float* __restrict__ s1,
                                                 const float* __restrict__ s2, const float* __restrict__ s3,
                                                 const float* __restrict__ s4, const float* __restrict__ s5,
                                                 short* __restrict__ d0, short* __restrict__ d1,
                                                 short* __restrict__ d2, short* __restrict__ d3,
                                                 short* __restrict__ d4, short* __restrict__ d5)
{
    int mat = blockIdx.z >> 1, l = blockIdx.z & 1;
    const float* in; short* out; long zs;
    if      (mat == 0) { in = s0; out = d0; zs = 196608; }
    else if (mat == 1) { in = s1; out = d1; zs = 196608; }
    else if (mat == 2) { in = s2; out = d2; zs = 196608; }
    else if (mat == 3) { in = s3; out = d3; zs = 65536; }
    else if (mat == 4) { in = s4; out = d4; zs = 65536; }
    else               { in = s5; out = d5; zs = 65536; }
    in  += (long)l * 65536;
    out += (long)l * zs;
    __shared__ float t[64][65];
    int k0 = blockIdx.y * 64, n0 = blockIdx.x * 64;
    int tid = threadIdx.x;
    int cl = tid & 63, rq = tid >> 6;
    #pragma unroll
    for (int i = 0; i < 16; i++) {
        int rl = rq + i * 4;
        t[rl][cl] = in[(long)(k0 + rl) * 256 + n0 + cl];
    }
    __syncthreads();
    #pragma unroll
    for (int i = 0; i < 16; i++) {
        int nl = rq + i * 4;
        out[(long)(n0 + nl) * 256 + k0 + cl] = f2s(t[cl][nl]);
    }
}

// pack per-layer bias segments
__global__ __launch_bounds__(256) void packb_k(const float* __restrict__ a, const float* __restrict__ b,
                                               const float* __restrict__ c, float* __restrict__ y,
                                               int na, int nb, int nc)
{
    int l = blockIdx.y;
    int j = blockIdx.x * 256 + threadIdx.x;
    int ntot = na + nb + nc;
    if (j >= ntot) return;
    float v;
    if (j < na) v = a[l * na + j];
    else if (j < na + nb) v = b[l * nb + (j - na)];
    else v = c[l * nc + (j - na - nb)];
    y[(long)l * ntot + j] = v;
}

// ---------------- MFMA GEMM, 64x64 tile (4 waves, 2x2 MFMA each): C = A(fp32) @ Bt^T ----------------
__global__ __launch_bounds__(256) void mgemm_k(const float* __restrict__ A, int lda,
                                               const short* __restrict__ Bt,
                                               const float* __restrict__ bias,
                                               const float* __restrict__ resid,
                                               float* __restrict__ C,
                                               int M, int N, int K, int act)
{
    __shared__ __align__(16) short As[2560];   // 64 rows x 40 (32 used)
    __shared__ __align__(16) short Bs[2560];
    int tid = threadIdx.x;
    int wave = tid >> 6, lane = tid & 63;
    int wm = wave >> 1, wn = wave & 1;
    int quad = lane >> 4, l15 = lane & 15;
    int m0 = blockIdx.y * 64, n0 = blockIdx.x * 64;
    int srow = tid >> 2, skc = (tid & 3) << 3;
    f4 acc[2][2];
    #pragma unroll
    for (int i = 0; i < 2; i++) { acc[i][0] = (f4){0.f,0.f,0.f,0.f}; acc[i][1] = (f4){0.f,0.f,0.f,0.f}; }
    short8 aR, bR;
    auto loadAB = [&](int kt) {
        int gm = m0 + srow;
        short8 pk = {0, 0, 0, 0, 0, 0, 0, 0};
        if (gm < M) {
            const float4* ap = (const float4*)(A + (long)gm * lda + kt + skc);
            float4 v0 = ap[0], v1 = ap[1];
            pk[0] = f2s(v0.x); pk[1] = f2s(v0.y); pk[2] = f2s(v0.z); pk[3] = f2s(v0.w);
            pk[4] = f2s(v1.x); pk[5] = f2s(v1.y); pk[6] = f2s(v1.z); pk[7] = f2s(v1.w);
        }
        aR = pk;
        int gn = n0 + srow;
        short8 pb = {0, 0, 0, 0, 0, 0, 0, 0};
        if (gn < N) pb = *(const short8*)&Bt[(long)gn * K + kt + skc];
        bR = pb;
    };
    loadAB(0);
    for (int kt = 0; kt < K; kt += 32) {
        *(short8*)&As[srow * 40 + skc] = aR;
        *(short8*)&Bs[srow * 40 + skc] = bR;
        __syncthreads();
        if (kt + 32 < K) loadAB(kt + 32);
        short8 af[2], bf[2];
        #pragma unroll
        for (int mi = 0; mi < 2; mi++) af[mi] = *(const short8*)&As[(wm * 32 + mi * 16 + l15) * 40 + (quad << 3)];
        #pragma unroll
        for (int ni = 0; ni < 2; ni++) bf[ni] = *(const short8*)&Bs[(wn * 32 + ni * 16 + l15) * 40 + (quad << 3)];
        #pragma unroll
        for (int mi = 0; mi < 2; mi++)
            #pragma unroll
            for (int ni = 0; ni < 2; ni++)
                acc[mi][ni] = __builtin_amdgcn_mfma_f32_16x16x32_bf16(af[mi], bf[ni], acc[mi][ni], 0, 0, 0);
        __syncthreads();
    }
    #pragma unroll
    for (int mi = 0; mi < 2; mi++) {
        int row = m0 + wm * 32 + mi * 16 + quad * 4;
        #pragma unroll
        for (int ni = 0; ni < 2; ni++) {
            int col = n0 + wn * 32 + ni * 16 + l15;
            if (col >= N) continue;
            float bv = bias[col];
            #pragma unroll
            for (int r = 0; r < 4; r++) {
                int rr = row + r;
                if (rr >= M) continue;
                float v = acc[mi][ni][r] + bv;
                if (act == 2) v = 0.5f * v * (1.f + erff(v * 0.70710678118654752f));
                if (resid) v += resid[(long)rr * N + col];
                C[(long)rr * N + col] = v;
            }
        }
    }
}

// ---------------- MFMA conv 3x3 s2 p1, tap-major K, bf16-pair input ----------------
// mode 1: f32 spatial-major out (ostride floats). mode 2: bf16-pair out (ostride dwords) + GN partial stats.
__global__ __launch_bounds__(256) void mconv_k(const unsigned* __restrict__ in,
                                               const short* __restrict__ wgt,
                                               const float* __restrict__ bias,
                                               float* __restrict__ out,
                                               float2* __restrict__ parts,
                                               int c5m, int Cout, int Hin, int Win,
                                               int mode, int cpg,
                                               long istride, long ostride)
{
    in  += (long)blockIdx.z * istride;
    const int Hout = Hin >> 1, Wout = Win >> 1;
    const int HWo = Hout * Wout;
    const int HW = Hin * Win;
    const int Ktot = 288 << c5m;   // 9*Cin
    const int m5 = (1 << c5m) - 1;
    const int nsteps = 9 << c5m;
    __shared__ __align__(16) short As[2560];   // 64 rows x 40
    __shared__ __align__(16) short Bs[2560];   // 64 cols x 40
    __shared__ float2 sred[16][2];             // [quad-group][wn] = (s, s2)
    int tid = threadIdx.x;
    int wave = tid >> 6, lane = tid & 63;
    int wm = wave >> 1, wn = wave & 1;
    int quad = lane >> 4, l15 = lane & 15;
    int m0 = blockIdx.y * 64, n0 = blockIdx.x * 64;
    int nn = tid & 63;
    int kp0 = tid >> 6;
    int p = n0 + nn;
    int pok = p < HWo;
    int pc = pok ? p : (HWo - 1);
    int ho = pc / Wout, wo = pc - ho * Wout;
    int hb = ho * 2 - 1, wb = wo * 2 - 1;

    f4 acc[2][2];
    #pragma unroll
    for (int i = 0; i < 2; i++) { acc[i][0] = (f4){0.f,0.f,0.f,0.f}; acc[i][1] = (f4){0.f,0.f,0.f,0.f}; }

    short8 aR;
    unsigned bR[4];
    auto loadA = [&](int s) {
        int r = tid >> 2, kc = (tid & 3) << 3;
        aR = *(const short8*)&wgt[(long)(m0 + r) * Ktot + (s << 5) + kc];
    };
    auto loadB = [&](int s) {
        int t = s >> c5m;
        int kh = (t * 11) >> 5;            // t/3 for t in 0..8
        int kw = t - kh * 3;
        int y = hb + kh, x = wb + kw;
        bool okp = pok && ((unsigned)y < (unsigned)Hin) && ((unsigned)x < (unsigned)Win);
        int base = (((s & m5) << 4) + kp0) * HW + y * Win + x;
        #pragma unroll
        for (int i = 0; i < 4; i++) {
            unsigned v = 0;
            if (okp) v = in[base + (i << 2) * HW];
            bR[i] = v;
        }
    };

    loadA(0); loadB(0);
    for (int s = 0; s < nsteps; s++) {
        {
            int r = tid >> 2, kc = (tid & 3) << 3;
            *(short8*)&As[r * 40 + kc] = aR;
        }
        #pragma unroll
        for (int i = 0; i < 4; i++)
            *(unsigned*)&Bs[nn * 40 + ((kp0 + (i << 2)) << 1)] = bR[i];
        __syncthreads();
        if (s + 1 < nsteps) { loadA(s + 1); loadB(s + 1); }
        short8 af[2], bf[2];
        #pragma unroll
        for (int mi = 0; mi < 2; mi++) af[mi] = *(const short8*)&As[(wm * 32 + mi * 16 + l15) * 40 + (quad << 3)];
        #pragma unroll
        for (int ni = 0; ni < 2; ni++) bf[ni] = *(const short8*)&Bs[(wn * 32 + ni * 16 + l15) * 40 + (quad << 3)];
        #pragma unroll
        for (int mi = 0; mi < 2; mi++)
            #pragma unroll
            for (int ni = 0; ni < 2; ni++)
                acc[mi][ni] = __builtin_amdgcn_mfma_f32_16x16x32_bf16(af[mi], bf[ni], acc[mi][ni], 0, 0, 0);
        __syncthreads();
    }

    if (mode == 1) {
        float* outf = out + (long)blockIdx.z * ostride;
        #pragma unroll
        for (int mi = 0; mi < 2; mi++) {
            int mbase = m0 + wm * 32 + mi * 16 + quad * 4;
            #pragma unroll
            for (int ni = 0; ni < 2; ni++) {
                int n = n0 + wn * 32 + ni * 16 + l15;
                if (n >= HWo) continue;
                #pragma unroll
                for (int r = 0; r < 4; r++) {
                    int m = mbase + r;
                    outf[(long)n * Cout + m] = acc[mi][ni][r] + bias[m];
                }
            }
        }
    } else {
        unsigned* outp = (unsigned*)out + (long)blockIdx.z * ostride;
        float ssum[2] = {0.f, 0.f}, qsum[2] = {0.f, 0.f};
        #pragma unroll
        for (int mi = 0; mi < 2; mi++) {
            int mbase = m0 + wm * 32 + mi * 16 + quad * 4;
            float b0 = bias[mbase], b1 = bias[mbase + 1], b2 = bias[mbase + 2], b3 = bias[mbase + 3];
            #pragma unroll
            for (int ni = 0; ni < 2; ni++) {
                int n = n0 + wn * 32 + ni * 16 + l15;
                if (n >= HWo) continue;
                float v0 = acc[mi][ni][0] + b0;
                float v1 = acc[mi][ni][1] + b1;
                float v2 = acc[mi][ni][2] + b2;
                float v3 = acc[mi][ni][3] + b3;
                long cp = (long)(mbase >> 1) * HWo + n;
                outp[cp]       = packbf(v0, v1);
                outp[cp + HWo] = packbf(v2, v3);
                ssum[mi] += v0 + v1 + v2 + v3;
                qsum[mi] += v0 * v0 + v1 * v1 + v2 * v2 + v3 * v3;
            }
        }
        #pragma unroll
        for (int mi = 0; mi < 2; mi++) {
            #pragma unroll
            for (int off = 1; off < 16; off <<= 1) {
                ssum[mi] += __shfl_xor(ssum[mi], off, 16);
                qsum[mi] += __shfl_xor(qsum[mi], off, 16);
            }
        }
        if (l15 == 0) {
            #pragma unroll
            for (int mi = 0; mi < 2; mi++)
                sred[wm * 8 + mi * 4 + quad][wn] = make_float2(ssum[mi], qsum[mi]);
        }
        __syncthreads();
        int ng = 64 / cpg;          // groups covered by this block
        int qpg = cpg >> 2;         // quad-groups per group
        if (tid < ng) {
            float s = 0.f, q = 0.f;
            for (int u = 0; u < qpg; u++) {
                float2 a = sred[(tid * cpg >> 2) + u][0];
                float2 b = sred[(tid * cpg >> 2) + u][1];
                s += a.x + b.x; q += a.y + b.y;
            }
            int gabs = m0 / cpg + tid;
            parts[((long)blockIdx.z * 32 + gabs) * 1400 + blockIdx.x] = make_float2(s, q);
        }
    }
}

// ---------------- conv0 fused MFMA: fp32 image gather -> bf16 MFMA (K=32) -> pair out + GN stats ------
// 64 pixels x 64 Cout per block; grid (1400,1,ncb); cpg=2 stats. wgt = (64,32) bf16, k = ci*9+t.
__global__ __launch_bounds__(256) void conv0f_k(const float* __restrict__ img,
                                                const short* __restrict__ wgt,
                                                const float* __restrict__ bias,
                                                unsigned* __restrict__ outp,
                                                float2* __restrict__ parts,
                                                long istride, long ostride)
{
    img  += (long)blockIdx.z * istride;
    outp += (long)blockIdx.z * ostride;
    const int HWo = 89600;
    __shared__ __align__(16) short As[2560];
    __shared__ __align__(16) short Bs[2560];
    __shared__ float2 sred[32][2];
    int tid = threadIdx.x;
    int wave = tid >> 6, lane = tid & 63;
    int wm = wave >> 1, wn = wave & 1;
    int quad = lane >> 4, l15 = lane & 15;
    int n0 = blockIdx.x * 64;
    int srow = tid >> 2, skc = (tid & 3) << 3;
    // A: weights (64x32)
    *(short8*)&As[srow * 40 + skc] = *(const short8*)&wgt[srow * 32 + skc];
    // B: gather 8 K-values for pixel n0+srow
    {
        int p = n0 + srow;
        int ho = p / 400, wo = p - ho * 400;
        int hb = ho * 2 - 1, wb = wo * 2 - 1;
        short8 pb;
        #pragma unroll
        for (int j = 0; j < 8; j++) {
            int k = skc + j;
            float v = 0.f;
            if (k < 27) {
                int ci = (k < 9) ? 0 : (k < 18 ? 1 : 2);
                int t = k - ci * 9;
                int kh = (t < 3) ? 0 : (t < 6 ? 1 : 2);
                int kw = t - kh * 3;
                int y = hb + kh, x = wb + kw;
                if ((unsigned)y < 448u && (unsigned)x < 800u)
                    v = img[ci * 358400 + y * 800 + x];
            }
            pb[j] = f2s(v);
        }
        *(short8*)&Bs[srow * 40 + skc] = pb;
    }
    __syncthreads();
    f4 acc[2][2];
    #pragma unroll
    for (int i = 0; i < 2; i++) { acc[i][0] = (f4){0.f,0.f,0.f,0.f}; acc[i][1] = (f4){0.f,0.f,0.f,0.f}; }
    short8 af[2], bf[2];
    #pragma unroll
    for (int mi = 0; mi < 2; mi++) af[mi] = *(const short8*)&As[(wm * 32 + mi * 16 + l15) * 40 + (quad << 3)];
    #pragma unroll
    for (int ni = 0; ni < 2; ni++) bf[ni] = *(const short8*)&Bs[(wn * 32 + ni * 16 + l15) * 40 + (quad << 3)];
    #pragma unroll
    for (int mi = 0; mi < 2; mi++)
        #pragma unroll
        for (int ni = 0; ni < 2; ni++)
            acc[mi][ni] = __builtin_amdgcn_mfma_f32_16x16x32_bf16(af[mi], bf[ni], acc[mi][ni], 0, 0, 0);
    // epilogue: bias + pair store + per-channel-pair (cpg=2) stats
    #pragma unroll
    for (int mi = 0; mi < 2; mi++) {
        int mbase = wm * 32 + mi * 16 + quad * 4;
        float b0 = bias[mbase], b1 = bias[mbase + 1], b2 = bias[mbase + 2], b3 = bias[mbase + 3];
        float s0 = 0.f, q0 = 0.f, s1 = 0.f, q1 = 0.f;
        #pragma unroll
        for (int ni = 0; ni < 2; ni++) {
            int n = n0 + wn * 32 + ni * 16 + l15;
            float v0 = acc[mi][ni][0] + b0;
            float v1 = acc[mi][ni][1] + b1;
            float v2 = acc[mi][ni][2] + b2;
            float v3 = acc[mi][ni][3] + b3;
            long cp = (long)(mbase >> 1) * HWo + n;
            outp[cp]       = packbf(v0, v1);
            outp[cp + HWo] = packbf(v2, v3);
            s0 += v0 + v1; q0 += v0 * v0 + v1 * v1;
            s1 += v2 + v3; q1 += v2 * v2 + v3 * v3;
        }
        #pragma unroll
        for (int off = 1; off < 16; off <<= 1) {
            s0 += __shfl_xor(s0, off, 16); q0 += __shfl_xor(q0, off, 16);
            s1 += __shfl_xor(s1, off, 16); q1 += __shfl_xor(q1, off, 16);
        }
        if (l15 == 0) {
            int pi = wm * 16 + mi * 8 + quad * 2;
            sred[pi][wn]     = make_float2(s0, q0);
            sred[pi + 1][wn] = make_float2(s1, q1);
        }
    }
    __syncthreads();
    if (tid < 32) {
        float2 a = sred[tid][0], b = sred[tid][1];
        parts[((long)blockIdx.z * 32 + tid) * 1400 + blockIdx.x] = make_float2(a.x + b.x, a.y + b.y);
    }
}

// ---------------- GN finalize: reduce per-block partials -> mean/rstd ----------------
__global__ __launch_bounds__(256) void gnfin_k(const float2* __restrict__ parts,
                                               float* __restrict__ gnstats, int nx, float invN)
{
    int g = blockIdx.x, cam = blockIdx.y;
    const float2* pb = parts + ((long)cam * 32 + g) * 1400;
    float s = 0.f, q = 0.f;
    for (int i = threadIdx.x; i < nx; i += 256) {
        float2 v = pb[i];
        s += v.x; q += v.y;
    }
    __shared__ float rs[256], rq[256];
    rs[threadIdx.x] = s; rq[threadIdx.x] = q;
    __syncthreads();
    for (int o = 128; o > 0; o >>= 1) {
        if (threadIdx.x < o) { rs[threadIdx.x] += rs[threadIdx.x + o]; rq[threadIdx.x] += rq[threadIdx.x + o]; }
        __syncthreads();
    }
    if (threadIdx.x == 0) {
        float mean = rs[0] * invN;
        float var  = rq[0] * invN - mean * mean;
        gnstats[(cam * 32 + g) * 2]     = mean;
        gnstats[(cam * 32 + g) * 2 + 1] = rsqrtf(var + EPS);
    }
}

// ---------------- in-place GN apply + ReLU on bf16-pair buffer ----------------
__global__ __launch_bounds__(256) void pairapply_k(unsigned* __restrict__ x,
                                                   const float* __restrict__ gamma,
                                                   const float* __restrict__ beta,
                                                   const float* __restrict__ gnstats,
                                                   int HW, int cpg, long zstride)
{
    x       += (long)blockIdx.z * zstride;
    gnstats += (long)blockIdx.z * 64;
    int idx4 = (blockIdx.x * 256 + threadIdx.x) * 4;   // HW%4==0 -> all in one pair-row
    int cp = idx4 / HW;
    int c0 = cp * 2;
    int g = c0 / cpg;
    float mean = gnstats[g * 2], rstd = gnstats[g * 2 + 1];
    float sa = rstd * gamma[c0],     ba = beta[c0]     - mean * sa;
    float sb = rstd * gamma[c0 + 1], bb = beta[c0 + 1] - mean * sb;
    uint4 v = *(uint4*)&x[idx4];
    unsigned* vp = (unsigned*)&v;
    #pragma unroll
    for (int j = 0; j < 4; j++) {
        float lo = fmaxf(bflo(vp[j]) * sa + ba, 0.f);
        float hi = fmaxf(bfhi(vp[j]) * sb + bb, 0.f);
        vp[j] = packbf(lo, hi);
    }
    *(uint4*)&x[idx4] = v;
}

// ---------------- GroupNorm for (1400 x 256) spatial-major, batched over cams (grid.y) ----------------
__global__ __launch_bounds__(256) void gn_stats_hwd_k(const float* __restrict__ x, float* __restrict__ stats)
{
    x += (long)blockIdx.y * 358400;
    stats += blockIdx.y * 64;
    int g = blockIdx.x;  // 32 groups
    float s = 0.f, s2 = 0.f;
    for (int i = threadIdx.x; i < 1400 * 8; i += blockDim.x) {
        int p = i >> 3, c = g * 8 + (i & 7);
        float v = x[(long)p * 256 + c];
        s += v; s2 += v * v;
    }
    __shared__ float rs[256], rq[256];
    rs[threadIdx.x] = s; rq[threadIdx.x] = s2;
    __syncthreads();
    for (int o = 128; o > 0; o >>= 1) {
        if (threadIdx.x < o) { rs[threadIdx.x] += rs[threadIdx.x + o]; rq[threadIdx.x] += rq[threadIdx.x + o]; }
        __syncthreads();
    }
    if (threadIdx.x == 0) {
        float mean = rs[0] / 11200.f;
        float var  = rq[0] / 11200.f - mean * mean;
        stats[g * 2]     = mean;
        stats[g * 2 + 1] = rsqrtf(var + EPS);
    }
}

__global__ __launch_bounds__(256) void gn_apply_hwd_k(float* __restrict__ x,
                                                      const float* __restrict__ gamma,
                                                      const float* __restrict__ beta,
                                                      const float* __restrict__ stats,
                                                      int relu)
{
    x += (long)blockIdx.y * 358400;
    stats += blockIdx.y * 64;
    long i4 = ((long)blockIdx.x * 256 + threadIdx.x) * 4;  // grid.x = 350 -> exact
    int c = (int)(i4 & 255);
    int g = c >> 3;
    float4 v  = *(float4*)&x[i4];
    float4 gm = *(const float4*)&gamma[c];
    float4 bt = *(const float4*)&beta[c];
    float m = stats[g * 2], rs = stats[g * 2 + 1];
    v.x = (v.x - m) * rs * gm.x + bt.x;
    v.y = (v.y - m) * rs * gm.y + bt.y;
    v.z = (v.z - m) * rs * gm.z + bt.z;
    v.w = (v.w - m) * rs * gm.w + bt.w;
    if (relu) {
        v.x = fmaxf(v.x, 0.f); v.y = fmaxf(v.y, 0.f);
        v.z = fmaxf(v.z, 0.f); v.w = fmaxf(v.w, 0.f);
    }
    *(float4*)&x[i4] = v;
}

// ---------------- projection of BEV grid ----------------
__global__ __launch_bounds__(256) void project_k(const float* __restrict__ Kin,
                                                 const float* __restrict__ Ein,
                                                 float* __restrict__ refp, int* __restrict__ valid)
{
    int idx = blockIdx.x * blockDim.x + threadIdx.x;
    if (idx >= 2500 * 6) return;
    int c = idx % 6, q = idx / 6;
    int i = q / 50, j = q % 50;
    float px = (i - 24.5f) * 0.5f;
    float py = (j - 24.5f) * 0.5f;
    const float* E = Ein + c * 16;
    float pc[4];
    #pragma unroll
    for (int r = 0; r < 4; r++)
        pc[r] = E[r * 4 + 0] * px + E[r * 4 + 1] * py + E[r * 4 + 3];
    const float* Km = Kin + c * 9;
    float pix[3];
    #pragma unroll
    for (int r = 0; r < 3; r++)
        pix[r] = Km[r * 3 + 0] * pc[0] + Km[r * 3 + 1] * pc[1] + Km[r * 3 + 2] * pc[2];
    float z = fmaxf(pix[2], 1e-5f);
    float u = pix[0] / z, v = pix[1] / z;
    int ok = (pc[2] > 0.f) && (u >= 0.f) && (u < 800.f) && (v >= 0.f) && (v < 448.f);
    refp[(long)idx * 2 + 0] = 2.f * u / 799.f - 1.f;
    refp[(long)idx * 2 + 1] = 2.f * v / 447.f - 1.f;
    valid[idx] = ok;
}

// ---------------- misc elementwise ----------------
__global__ __launch_bounds__(256) void qinit_k(const float* __restrict__ a, const float* __restrict__ b,
                                               float* __restrict__ y)
{
    int i = blockIdx.x * blockDim.x + threadIdx.x;
    if (i >= 2500 * 256) return;
    y[i] = a[i] + b[i];
}

// ---------------- LayerNorm ----------------
__global__ __launch_bounds__(256) void ln_k(const float* __restrict__ x,
                                            const float* __restrict__ g, const float* __restrict__ b,
                                            float* __restrict__ y)
{
    int row  = blockIdx.x * 4 + (threadIdx.x >> 6);
    int lane = threadIdx.x & 63;
    if (row >= 2500) return;
    const float* xp = x + (long)row * 256;
    float v[4];
    #pragma unroll
    for (int i = 0; i < 4; i++) v[i] = xp[lane + 64 * i];
    float s  = v[0] + v[1] + v[2] + v[3];
    float s2 = v[0] * v[0] + v[1] * v[1] + v[2] * v[2] + v[3] * v[3];
    #pragma unroll
    for (int o = 32; o > 0; o >>= 1) { s += __shfl_xor(s, o, 64); s2 += __shfl_xor(s2, o, 64); }
    float mean = s * (1.f / 256.f);
    float var  = s2 * (1.f / 256.f) - mean * mean;
    float rstd = rsqrtf(var + EPS);
    #pragma unroll
    for (int i = 0; i < 4; i++) {
        int cc = lane + 64 * i;
        y[(long)row * 256 + cc] = (v[i] - mean) * rstd * g[cc] + b[cc];
    }
}

// ---------------- MFMA flash-2 MHA with split-K (packed-QKV aware: row stride ld) ----------------
__global__ __launch_bounds__(256) void flash2_k(const float* __restrict__ Q,
                                                const float* __restrict__ K,
                                                const float* __restrict__ V,
                                                int ld,
                                                float* __restrict__ Opart,   // (S,2500,256)
                                                float* __restrict__ MLpart)  // (S,2500,8,2)
{
    const int h  = blockIdx.y;
    const int q0 = blockIdx.x * 64;
    const int sp = blockIdx.z;
    const int kstart = sp * FL_KEYS, kend = kstart + FL_KEYS;
    const int tid = threadIdx.x;
    const int wave = tid >> 6, lane = tid & 63;
    const int quad = lane >> 4, l15 = lane & 15;
    __shared__ __align__(16) short Qs[64 * 40];
    __shared__ __align__(16) short Ks[64 * 40];
    __shared__ __align__(16) short Vt[32 * 72];
    __shared__ __align__(16) short Ps[64 * 72];
    const float scale = 0.17677669529663687f;
    {
        int row = tid >> 2, kc = (tid & 3) << 3;
        int qi = q0 + row;
        short8 pk = {0, 0, 0, 0, 0, 0, 0, 0};
        if (qi < 2500) {
            const float4* qp = (const float4*)(Q + (long)qi * ld + h * 32 + kc);
            float4 v0 = qp[0], v1 = qp[1];
            pk[0] = f2s(v0.x * scale); pk[1] = f2s(v0.y * scale); pk[2] = f2s(v0.z * scale); pk[3] = f2s(v0.w * scale);
            pk[4] = f2s(v1.x * scale); pk[5] = f2s(v1.y * scale); pk[6] = f2s(v1.z * scale); pk[7] = f2s(v1.w * scale);
        }
        *(short8*)&Qs[row * 40 + kc] = pk;
    }
    __syncthreads();
    short8 aq = *(const short8*)&Qs[(wave * 16 + l15) * 40 + (quad << 3)];
    float m[4], l[4];
    f4 oacc[2];
    #pragma unroll
    for (int r = 0; r < 4; r++) { m[r] = -INFINITY; l[r] = 0.f; }
    oacc[0] = (f4){0.f, 0.f, 0.f, 0.f};
    oacc[1] = (f4){0.f, 0.f, 0.f, 0.f};
    for (int kb = kstart; kb < kend; kb += 64) {
        __syncthreads();
        {
            int row = tid >> 2, kc = (tid & 3) << 3;
            int ki = kb + row;
            short8 pk = {0, 0, 0, 0, 0, 0, 0, 0};
            float vv[8] = {0.f, 0.f, 0.f, 0.f, 0.f, 0.f, 0.f, 0.f};
            if (ki < kend) {
                const float4* kp = (const float4*)(K + (long)ki * ld + h * 32 + kc);
                float4 a0 = kp[0], a1 = kp[1];
                pk[0] = f2s(a0.x); pk[1] = f2s(a0.y); pk[2] = f2s(a0.z); pk[3] = f2s(a0.w);
                pk[4] = f2s(a1.x); pk[5] = f2s(a1.y); pk[6] = f2s(a1.z); pk[7] = f2s(a1.w);
                const float4* vp = (const float4*)(V + (long)ki * ld + h * 32 + kc);
                float4 b0 = vp[0], b1 = vp[1];
                vv[0] = b0.x; vv[1] = b0.y; vv[2] = b0.z; vv[3] = b0.w;
                vv[4] = b1.x; vv[5] = b1.y; vv[6] = b1.z; vv[7] = b1.w;
            }
            *(short8*)&Ks[row * 40 + kc] = pk;
            #pragma unroll
            for (int j = 0; j < 8; j++) Vt[(kc + j) * 72 + row] = f2s(vv[j]);
        }
        __syncthreads();
        f4 sa[4];
        #pragma unroll
        for (int ni = 0; ni < 4; ni++) {
            short8 bk = *(const short8*)&Ks[(ni * 16 + l15) * 40 + (quad << 3)];
            sa[ni] = __builtin_amdgcn_mfma_f32_16x16x32_bf16(aq, bk, (f4){0.f, 0.f, 0.f, 0.f}, 0, 0, 0);
        }
        float sv[4][4];
        #pragma unroll
        for (int ni = 0; ni < 4; ni++) {
            bool colok = (kb + ni * 16 + l15) < kend;
            #pragma unroll
            for (int r = 0; r < 4; r++) sv[ni][r] = colok ? sa[ni][r] : -1e30f;
        }
        float p[4][4];
        #pragma unroll
        for (int r = 0; r < 4; r++) {
            float rm = fmaxf(fmaxf(sv[0][r], sv[1][r]), fmaxf(sv[2][r], sv[3][r]));
            #pragma unroll
            for (int off = 1; off < 16; off <<= 1) rm = fmaxf(rm, __shfl_xor(rm, off, 16));
            float mn = fmaxf(m[r], rm);
            float alpha = __expf(m[r] - mn);
            float rs = 0.f;
            #pragma unroll
            for (int ni = 0; ni < 4; ni++) { p[ni][r] = __expf(sv[ni][r] - mn); rs += p[ni][r]; }
            #pragma unroll
            for (int off = 1; off < 16; off <<= 1) rs += __shfl_xor(rs, off, 16);
            l[r] = l[r] * alpha + rs;
            oacc[0][r] *= alpha; oacc[1][r] *= alpha;
            m[r] = mn;
        }
        #pragma unroll
        for (int ni = 0; ni < 4; ni++)
            #pragma unroll
            for (int r = 0; r < 4; r++)
                Ps[(wave * 16 + quad * 4 + r) * 72 + ni * 16 + l15] = f2s(p[ni][r]);
        #pragma unroll
        for (int kh = 0; kh < 2; kh++) {
            short8 ap = *(const short8*)&Ps[(wave * 16 + l15) * 72 + kh * 32 + (quad << 3)];
            #pragma unroll
            for (int ni = 0; ni < 2; ni++) {
                short8 bv = *(const short8*)&Vt[(ni * 16 + l15) * 72 + kh * 32 + (quad << 3)];
                oacc[ni] = __builtin_amdgcn_mfma_f32_16x16x32_bf16(ap, bv, oacc[ni], 0, 0, 0);
            }
        }
    }
    #pragma unroll
    for (int r = 0; r < 4; r++) {
        int qi = q0 + wave * 16 + quad * 4 + r;
        if (qi < 2500) {
            long ob = ((long)sp * 2500 + qi) * 256 + h * 32;
            Opart[ob + l15]      = oacc[0][r];
            Opart[ob + 16 + l15] = oacc[1][r];
            if (l15 == 0) {
                long mb = (((long)sp * 2500 + qi) * 8 + h) * 2;
                MLpart[mb]     = m[r];
                MLpart[mb + 1] = l[r];
            }
        }
    }
}

__global__ __launch_bounds__(256) void flashmerge_k(const float* __restrict__ Opart,
                                                    const float* __restrict__ MLpart,
                                                    float* __restrict__ O)
{
    int q = blockIdx.x, d = threadIdx.x;
    int h = d >> 5;
    float ms[FL_SPLITS], ls[FL_SPLITS];
    float mg = -INFINITY;
    #pragma unroll
    for (int s = 0; s < FL_SPLITS; s++) {
        long mb = (((long)s * 2500 + q) * 8 + h) * 2;
        ms[s] = MLpart[mb];
        ls[s] = MLpart[mb + 1];
        mg = fmaxf(mg, ms[s]);
    }
    float lsum = 0.f, osum = 0.f;
    #pragma unroll
    for (int s = 0; s < FL_SPLITS; s++) {
        float w = __expf(ms[s] - mg);
        lsum += ls[s] * w;
        osum += Opart[((long)s * 2500 + q) * 256 + d] * w;
    }
    O[(long)q * 256 + d] = osum / lsum;
}

// ---------------- masked softmax over 192 deformable-attn logits (row stride ld) ----------------
__global__ __launch_bounds__(64) void scasoftmax_k(float* __restrict__ logits, int ld,
                                                   const int* __restrict__ valid)
{
    int q = blockIdx.x, lane = threadIdx.x;
    float v[3]; int mk[3];
    #pragma unroll
    for (int i = 0; i < 3; i++) {
        int idx = i * 64 + lane;
        int c = idx >> 5;
        mk[i] = valid[q * 6 + c];
        v[i] = mk[i] ? logits[(long)q * ld + idx] : -1e30f;
    }
    float mx = fmaxf(fmaxf(v[0], v[1]), v[2]);
    #pragma unroll
    for (int o = 32; o > 0; o >>= 1) mx = fmaxf(mx, __shfl_xor(mx, o, 64));
    float e[3]; float s = 0.f;
    #pragma unroll
    for (int i = 0; i < 3; i++) { e[i] = expf(v[i] - mx); s += e[i]; }
    #pragma unroll
    for (int o = 32; o > 0; o >>= 1) s += __shfl_xor(s, o, 64);
    float inv = 1.f / s;
    #pragma unroll
    for (int i = 0; i < 3; i++)
        logits[(long)q * ld + i * 64 + lane] = mk[i] ? e[i] * inv : 0.f;
}

// ---------------- deformable sampling (offs/wts with row stride ld); one setup pass for all cams ------
__global__ __launch_bounds__(256) void sample_k(const float* __restrict__ vals,
                                                const float* __restrict__ offs, int ld,
                                                const float* __restrict__ wts,
                                                const float* __restrict__ refp,
                                                const int* __restrict__ valid,
                                                float* __restrict__ out)
{
    int q = blockIdx.x, d = threadIdx.x;
    __shared__ float s_cw[6][32][4];
    __shared__ int   s_idx[6][32][4];
    if (d < 192) {
        int c = d >> 5, pt = d & 31;
        if (valid[q * 6 + c]) {
            float ox = offs[(long)q * ld + (c * 32 + pt) * 2 + 0];
            float oy = offs[(long)q * ld + (c * 32 + pt) * 2 + 1];
            float px = refp[(q * 6 + c) * 2 + 0] + ox * (2.f / 49.f);
            float py = refp[(q * 6 + c) * 2 + 1] + oy * (2.f / 27.f);
            float gx = (px + 1.f) * 0.5f * 49.f;
            float gy = (py + 1.f) * 0.5f * 27.f;
            float x0f = floorf(gx), y0f = floorf(gy);
            float wx = gx - x0f, wy = gy - y0f;
            int x0 = (int)x0f, y0 = (int)y0f;
            float wgt = wts[(long)q * ld + c * 32 + pt];
            float cw[4] = {(1.f - wx) * (1.f - wy), wx * (1.f - wy), (1.f - wx) * wy, wx * wy};
            const int dxs[4] = {0, 1, 0, 1};
            const int dys[4] = {0, 0, 1, 1};
            #pragma unroll
            for (int k2 = 0; k2 < 4; k2++) {
                int xi = x0 + dxs[k2], yi = y0 + dys[k2];
                bool ok = (xi >= 0) && (xi < 50) && (yi >= 0) && (yi < 28);
                s_cw[c][pt][k2]  = ok ? cw[k2] * wgt : 0.f;
                s_idx[c][pt][k2] = ok ? (yi * 50 + xi) * 256 : 0;
            }
        }
    }
    __syncthreads();
    float acc = 0.f;
    for (int c = 0; c < 6; c++) {
        if (!valid[q * 6 + c]) continue;
        const float* vb = vals + (long)c * 358400 + d;
        for (int pt = 0; pt < 32; pt++) {
            #pragma unroll
            for (int k2 = 0; k2 < 4; k2++) {
                float cwv = s_cw[c][pt][k2];
                if (cwv != 0.f) acc += cwv * vb[s_idx[c][pt][k2]];
            }
        }
    }
    out[(long)q * 256 + d] = acc;
}

// =====================================================================================
extern "C" void kernel_launch(void* const* d_in, const int* in_sizes, int n_in,
                              void* d_out, int out_size, void* d_ws, size_t ws_size,
                              hipStream_t stream)
{
    const float* images = (const float*)d_in[0];
    const float* intr   = (const float*)d_in[1];
    const float* e2c    = (const float*)d_in[2];
    const float* bevq   = (const float*)d_in[3];
    const float* bevp   = (const float*)d_in[4];
    const float* bbw[5]    = {(const float*)d_in[5],  (const float*)d_in[9],  (const float*)d_in[13], (const float*)d_in[17], (const float*)d_in[21]};
    const float* bbb[5]    = {(const float*)d_in[6],  (const float*)d_in[10], (const float*)d_in[14], (const float*)d_in[18], (const float*)d_in[22]};
    const float* bbg[5]    = {(const float*)d_in[7],  (const float*)d_in[11], (const float*)d_in[15], (const float*)d_in[19], (const float*)d_in[23]};
    const float* bbbeta[5] = {(const float*)d_in[8],  (const float*)d_in[12], (const float*)d_in[16], (const float*)d_in[20], (const float*)d_in[24]};
    const float* sa_wq = (const float*)d_in[25]; const float* sa_bq = (const float*)d_in[26];
    const float* sa_wk = (const float*)d_in[27]; const float* sa_bk = (const float*)d_in[28];
    const float* sa_wv = (const float*)d_in[29]; const float* sa_bv = (const float*)d_in[30];
    const float* sa_wo = (const float*)d_in[31]; const float* sa_bo = (const float*)d_in[32];
    const float* ln1g = (const float*)d_in[33]; const float* ln1b = (const float*)d_in[34];
    const float* ln2g = (const float*)d_in[35]; const float* ln2b = (const float*)d_in[36];
    const float* ln3g = (const float*)d_in[37]; const float* ln3b = (const float*)d_in[38];
    const float* offw = (const float*)d_in[39]; const float* offb = (const float*)d_in[40];
    const float* wtw  = (const float*)d_in[41]; const float* wtb  = (const float*)d_in[42];
    const float* valw = (const float*)d_in[43]; const float* valb = (const float*)d_in[44];
    const float* outw = (const float*)d_in[45]; const float* outb = (const float*)d_in[46];
    const float* fw1  = (const float*)d_in[47]; const float* fb1  = (const float*)d_in[48];
    const float* fw2  = (const float*)d_in[49]; const float* fb2  = (const float*)d_in[50];

    // ---- pick camera-batch factor from available workspace (formula unchanged) ----
    auto needB = [](long ncb) -> unsigned long long {
        return (unsigned long long)(ncb * 8601600L + 6681600L) * 4ULL + 6307840ULL + (1 << 20);
    };
    int ncb = 1;
    if      ((unsigned long long)ws_size >= needB(6)) ncb = 6;
    else if ((unsigned long long)ws_size >= needB(3)) ncb = 3;
    else if ((unsigned long long)ws_size >= needB(2)) ncb = 2;

    // ---- workspace layout ----
    float* ws = (float*)d_ws;
    float* A     = ws; ws += (long)ncb * 5734400;  // pair-buffer ping; aliases: bQKV, OP, bOW
    float* Bu    = ws; ws += (long)ncb * 2867200;  // pair-buffer pong; aliases: valsb, MLp
    float* f3bH  = ws; ws += 2560000;              // feats3 (backbone) / ffn hidden (transformer)
    float* feats = ws; ws += 2150400;              // (6,1400,256) hwd; also GN parts (early backbone)
    float* qbuf  = ws; ws += 640000;
    float* xq    = ws; ws += 640000;
    float* bO    = ws; ws += 640000;
    float* refp  = ws; ws += 30016;
    int*   validb = (int*)ws; ws += 15040;
    float* stats = ws; ws += 384;
    float* gnst  = ws; ws += 3072;                 // per-group mean/rstd (ncb x 32 x 2)
    float* qkvb  = ws; ws += 1536;
    float* owb   = ws; ws += 1152;
    // bf16 weight buffers
    short* sb = (short*)ws;
    short* cw0b = sb; sb += 2048;                  // conv0 (64,32) padded, k = ci*9+t
    short* cw1b = sb; sb += 73728;                 // tap-major (128, 9*64)
    short* cw2b = sb; sb += 294912;                // tap-major (256, 9*128)
    short* cw3b = sb; sb += 589824;                // tap-major (256, 9*256)
    short* cw4b = sb; sb += 65536;
    short* qkvT = sb; sb += 393216;
    short* owT  = sb; sb += 131072;
    short* valT = sb; sb += 131072;
    short* outT = sb; sb += 131072;
    short* offwtT = sb; sb += 294912;
    short* f1T  = sb; sb += 524288;
    short* f2T  = sb; sb += 524288;
    // aliases
    float*  feats3 = f3bH;
    float*  bH     = f3bH;
    float*  bQKV   = A;
    float*  OP     = A + 1920000;
    float*  bOW    = A + 1920000;
    float*  valsb  = Bu;
    float*  MLp    = Bu + 2150400;
    unsigned* Bbf0 = (unsigned*)A;                 // pair ping (stride varies per stage)
    unsigned* Bbf1 = (unsigned*)Bu;                // pair pong
    float2* partsP = (float2*)feats;               // 6*32*1400 float2 = 2.15 MB (free until conv4)

    auto mgemm = [&](const float* Ain, int lda, const short* Bt, const float* bias, const float* resid,
                     float* C, int M, int N, int K, int act) {
        dim3 g((N + 63) / 64, (M + 63) / 64);
        mgemm_k<<<g, 256, 0, stream>>>(Ain, lda, Bt, bias, resid, C, M, N, K, act);
    };

    // ---- weight preprocessing ----
    wcast0_k<<<8, 256, 0, stream>>>(bbw[0], cw0b);
    wreord_k<<<(73728 + 255) / 256, 256, 0, stream>>>(bbw[1], cw1b, 64, 73728);
    wreord_k<<<(294912 + 255) / 256, 256, 0, stream>>>(bbw[2], cw2b, 128, 294912);
    wreord_k<<<(589824 + 255) / 256, 256, 0, stream>>>(bbw[3], cw3b, 256, 589824);
    wcast_k<<<(65536 + 255) / 256, 256, 0, stream>>>(bbw[4], cw4b, 65536);
    wtrans6_k<<<dim3(4, 4, 12), 256, 0, stream>>>(sa_wq, sa_wk, sa_wv, sa_wo, valw, outw,
                                                  qkvT, qkvT + 65536, qkvT + 131072, owT, valT, outT);
    wtrans_k<<<dim3(6, 4, 2), 256, 0, stream>>>(offw, offwtT,         256, 384,  147456);
    wtrans_k<<<dim3(3, 4, 2), 256, 0, stream>>>(wtw,  offwtT + 98304, 256, 192,  147456);
    wtrans_k<<<dim3(16, 4, 2), 256, 0, stream>>>(fw1, f1T, 256, 1024, 262144);
    wtrans_k<<<dim3(4, 16, 2), 256, 0, stream>>>(fw2, f2T, 1024, 256, 262144);
    packb_k<<<dim3(3, 2), 256, 0, stream>>>(sa_bq, sa_bk, sa_bv, qkvb, 256, 256, 256);
    packb_k<<<dim3(3, 2), 256, 0, stream>>>(offb, wtb, nullptr, owb, 384, 192, 0);

    // ---- projection of BEV grid ----
    project_k<<<(15000 + 255) / 256, 256, 0, stream>>>(intr, e2c, refp, validb);

    // ---- backbone (cam-batched; bf16-pair activations) ----
    for (int c0 = 0; c0 < 6; c0 += ncb) {
        const float* img = images + (long)c0 * 1075200;
        // conv0 fused MFMA -> pairs + stats
        conv0f_k<<<dim3(1400, 1, ncb), 256, 0, stream>>>(img, cw0b, bbb[0], Bbf0, partsP,
                                                         1075200L, 2867200L);
        gnfin_k<<<dim3(32, ncb), 256, 0, stream>>>(partsP, gnst, 1400, 1.f / 179200.f);
        pairapply_k<<<dim3(2800, 1, ncb), 256, 0, stream>>>(Bbf0, bbg[0], bbbeta[0], gnst, 89600, 2, 2867200L);
        // conv1 -> pairs + fused stats
        mconv_k<<<dim3(350, 2, ncb), 256, 0, stream>>>(Bbf0, cw1b, bbb[1], (float*)Bbf1, partsP,
                                                       1, 128, 224, 400, 2, 4, 2867200L, 1433600L);
        gnfin_k<<<dim3(32, ncb), 256, 0, stream>>>(partsP, gnst, 350, 1.f / 89600.f);
        pairapply_k<<<dim3(1400, 1, ncb), 256, 0, stream>>>(Bbf1, bbg[1], bbbeta[1], gnst, 22400, 4, 1433600L);
        // conv2 -> pairs + fused stats
        mconv_k<<<dim3(88, 4, ncb), 256, 0, stream>>>(Bbf1, cw2b, bbb[2], (float*)Bbf0, partsP,
                                                      2, 256, 112, 200, 2, 8, 1433600L, 716800L);
        gnfin_k<<<dim3(32, ncb), 256, 0, stream>>>(partsP, gnst, 88, 1.f / 44800.f);
        pairapply_k<<<dim3(700, 1, ncb), 256, 0, stream>>>(Bbf0, bbg[2], bbbeta[2], gnst, 5600, 8, 716800L);
        // conv3 -> f32 spatial-major feats3[cam]
        mconv_k<<<dim3(22, 4, ncb), 256, 0, stream>>>(Bbf0, cw3b, bbb[3], feats3 + (long)c0 * 358400, nullptr,
                                                      3, 256, 56, 100, 1, 0, 716800L, 358400L);
    }
    // batched conv3-GN (+relu), conv4 as one 8400x256 GEMM, batched conv4-GN
    gn_stats_hwd_k<<<dim3(32, 6), 256, 0, stream>>>(feats3, stats);
    gn_apply_hwd_k<<<dim3(350, 6), 256, 0, stream>>>(feats3, bbg[3], bbbeta[3], stats, 1);
    mgemm(feats3, 256, cw4b, bbb[4], nullptr, feats, 8400, 256, 256, 0);
    gn_stats_hwd_k<<<dim3(32, 6), 256, 0, stream>>>(feats, stats);
    gn_apply_hwd_k<<<dim3(350, 6), 256, 0, stream>>>(feats, bbg[4], bbbeta[4], stats, 0);

    // ---- transformer ----
    qinit_k<<<2500, 256, 0, stream>>>(bevq, bevp, qbuf);

    for (int l = 0; l < 2; l++) {
        long o1 = (long)l * 256;

        // self-attention (fused QKV projection: 2500 x 768)
        ln_k<<<625, 256, 0, stream>>>(qbuf, ln1g + o1, ln1b + o1, xq);
        mgemm(xq, 256, qkvT + l * 196608, qkvb + l * 768, nullptr, bQKV, 2500, 768, 256, 0);
        flash2_k<<<dim3(40, 8, FL_SPLITS), 256, 0, stream>>>(bQKV, bQKV + 256, bQKV + 512, 768, OP, MLp);
        flashmerge_k<<<2500, 256, 0, stream>>>(OP, MLp, bO);
        mgemm(bO, 256, owT + l * 65536, sa_bo + o1, qbuf, qbuf, 2500, 256, 256, 0);

        // spatial cross-attention (fused offsets+logits projection: 2500 x 576)
        ln_k<<<625, 256, 0, stream>>>(qbuf, ln2g + o1, ln2b + o1, xq);
        mgemm(feats, 256, valT + l * 65536, valb + o1, nullptr, valsb, 8400, 256, 256, 0);
        mgemm(xq, 256, offwtT + l * 147456, owb + l * 576, nullptr, bOW, 2500, 576, 256, 0);
        scasoftmax_k<<<2500, 64, 0, stream>>>(bOW + 384, 576, validb);
        sample_k<<<2500, 256, 0, stream>>>(valsb, bOW, 576, bOW + 384, refp, validb, bO);
        mgemm(bO, 256, outT + l * 65536, outb + o1, qbuf, qbuf, 2500, 256, 256, 0);

        // FFN
        ln_k<<<625, 256, 0, stream>>>(qbuf, ln3g + o1, ln3b + o1, xq);
        mgemm(xq, 256, f1T + l * 262144, fb1 + (long)l * 1024, nullptr, bH, 2500, 1024, 256, 2);
        mgemm(bH, 1024, f2T + l * 262144, fb2 + o1, qbuf,
              (l == 1) ? (float*)d_out : qbuf, 2500, 256, 1024, 0);
    }
}

// Round 9
// 990.668 us; speedup vs baseline: 2.0030x; 1.0410x over previous
//
#include <hip/hip_runtime.h>
#include <hip/hip_bf16.h>
#include <math.h>

#define EPS 1e-5f
#define FL_SPLITS 5
#define FL_KEYS 500

typedef __attribute__((ext_vector_type(8))) short short8;
typedef __attribute__((ext_vector_type(4))) float f4;

__device__ __forceinline__ short f2s(float f) {
    union { float f; unsigned u; } v; v.f = f;
    unsigned r = (v.u + 0x7fffu + ((v.u >> 16) & 1u)) >> 16;  // RNE
    return (short)r;
}
__device__ __forceinline__ unsigned packbf(float a, float b) {
    return (unsigned)(unsigned short)f2s(a) | ((unsigned)(unsigned short)f2s(b) << 16);
}
__device__ __forceinline__ float bflo(unsigned v) { union { unsigned u; float f; } t; t.u = v << 16; return t.f; }
__device__ __forceinline__ float bfhi(unsigned v) { union { unsigned u; float f; } t; t.u = v & 0xffff0000u; return t.f; }

// ---------------- weight preprocessing ----------------
__global__ __launch_bounds__(256) void wcast_k(const float* __restrict__ in, short* __restrict__ out, int n)
{
    int i = blockIdx.x * 256 + threadIdx.x;
    if (i < n) out[i] = f2s(in[i]);
}

// conv0 weight pack: (64,3,3,3) fp32 -> (64,32) bf16, k = ci*9 + t, pad 27..31 = 0
__global__ __launch_bounds__(256) void wcast0_k(const float* __restrict__ in, short* __restrict__ out)
{
    int i = blockIdx.x * 256 + threadIdx.x;
    if (i >= 2048) return;
    int k = i & 31;
    out[i] = (k < 27) ? f2s(in[(i >> 5) * 27 + k]) : (short)0;
}

// conv weight reorder: (Cout, Cin, 3,3) fp32 -> (Cout, 9, Cin) bf16 (tap-major)
__global__ __launch_bounds__(256) void wreord_k(const float* __restrict__ in, short* __restrict__ out,
                                                int Cin, int n)
{
    int i = blockIdx.x * 256 + threadIdx.x;
    if (i >= n) return;
    int cin9 = Cin * 9;
    int co = i / cin9, rem = i - co * cin9;
    int ci = rem / 9, t = rem - ci * 9;
    out[(long)co * cin9 + t * Cin + ci] = f2s(in[i]);
}

// (K,N) fp32 -> (N,K) bf16 ; blockIdx.z = matrix index, zstride = output stride per matrix
__global__ __launch_bounds__(256) void wtrans_k(const float* __restrict__ in, short* __restrict__ out,
                                                int K, int N, long zstride)
{
    in  += (long)blockIdx.z * K * N;
    out += (long)blockIdx.z * zstride;
    __shared__ float t[64][65];
    int k0 = blockIdx.y * 64, n0 = blockIdx.x * 64;
    int tid = threadIdx.x;
    int cl = tid & 63, rq = tid >> 6;
    #pragma unroll
    for (int i = 0; i < 16; i++) {
        int rl = rq + i * 4;
        int k = k0 + rl, n = n0 + cl;
        t[rl][cl] = (k < K && n < N) ? in[(long)k * N + n] : 0.f;
    }
    __syncthreads();
    #pragma unroll
    for (int i = 0; i < 16; i++) {
        int nl = rq + i * 4;
        int n = n0 + nl, k = k0 + cl;
        if (n < N && k < K) out[(long)n * K + k] = f2s(t[cl][nl]);
    }
}

// six 256x256 (K,N)->(N,K) transposes in one dispatch; blockIdx.z = mat*2 + layer
__global__ __launch_bounds__(256) void wtrans6_k(const float* __restrict__ s0, const float* __restrict__ s1,
                                                 const float* __restrict__ s2, const float* __restrict__ s3,
                                                 const float* __restrict__ s4, const float* __restrict__ s5,
                                                 short* __restrict__ d0, short* __restrict__ d1,
                                                 short* __restrict__ d2, short* __restrict__ d3,
                                                 short* __restrict__ d4, short* __restrict__ d5)
{
    int mat = blockIdx.z >> 1, l = blockIdx.z & 1;
    const float* in; short* out; long zs;
    if      (mat == 0) { in = s0; out = d0; zs = 196608; }
    else if (mat == 1) { in = s1; out = d1; zs = 196608; }
    else if (mat == 2) { in = s2; out = d2; zs = 196608; }
    else if (mat == 3) { in = s3; out = d3; zs = 65536; }
    else if (mat == 4) { in = s4; out = d4; zs = 65536; }
    else               { in = s5; out = d5; zs = 65536; }
    in  += (long)l * 65536;
    out += (long)l * zs;
    __shared__ float t[64][65];
    int k0 = blockIdx.y * 64, n0 = blockIdx.x * 64;
    int tid = threadIdx.x;
    int cl = tid & 63, rq = tid >> 6;
    #pragma unroll
    for (int i = 0; i < 16; i++) {
        int rl = rq + i * 4;
        t[rl][cl] = in[(long)(k0 + rl) * 256 + n0 + cl];
    }
    __syncthreads();
    #pragma unroll
    for (int i = 0; i < 16; i++) {
        int nl = rq + i * 4;
        out[(long)(n0 + nl) * 256 + k0 + cl] = f2s(t[cl][nl]);
    }
}

// pack per-layer bias segments
__global__ __launch_bounds__(256) void packb_k(const float* __restrict__ a, const float* __restrict__ b,
                                               const float* __restrict__ c, float* __restrict__ y,
                                               int na, int nb, int nc)
{
    int l = blockIdx.y;
    int j = blockIdx.x * 256 + threadIdx.x;
    int ntot = na + nb + nc;
    if (j >= ntot) return;
    float v;
    if (j < na) v = a[l * na + j];
    else if (j < na + nb) v = b[l * nb + (j - na)];
    else v = c[l * nc + (j - na - nb)];
    y[(long)l * ntot + j] = v;
}

// ---------------- MFMA GEMM, 64x64 tile (4 waves, 2x2 MFMA each): C = A(fp32) @ Bt^T ----------------
__global__ __launch_bounds__(256) void mgemm_k(const float* __restrict__ A, int lda,
                                               const short* __restrict__ Bt,
                                               const float* __restrict__ bias,
                                               const float* __restrict__ resid,
                                               float* __restrict__ C,
                                               int M, int N, int K, int act)
{
    __shared__ __align__(16) short As[2560];   // 64 rows x 40 (32 used)
    __shared__ __align__(16) short Bs[2560];
    int tid = threadIdx.x;
    int wave = tid >> 6, lane = tid & 63;
    int wm = wave >> 1, wn = wave & 1;
    int quad = lane >> 4, l15 = lane & 15;
    int m0 = blockIdx.y * 64, n0 = blockIdx.x * 64;
    int srow = tid >> 2, skc = (tid & 3) << 3;
    f4 acc[2][2];
    #pragma unroll
    for (int i = 0; i < 2; i++) { acc[i][0] = (f4){0.f,0.f,0.f,0.f}; acc[i][1] = (f4){0.f,0.f,0.f,0.f}; }
    short8 aR, bR;
    auto loadAB = [&](int kt) {
        int gm = m0 + srow;
        short8 pk = {0, 0, 0, 0, 0, 0, 0, 0};
        if (gm < M) {
            const float4* ap = (const float4*)(A + (long)gm * lda + kt + skc);
            float4 v0 = ap[0], v1 = ap[1];
            pk[0] = f2s(v0.x); pk[1] = f2s(v0.y); pk[2] = f2s(v0.z); pk[3] = f2s(v0.w);
            pk[4] = f2s(v1.x); pk[5] = f2s(v1.y); pk[6] = f2s(v1.z); pk[7] = f2s(v1.w);
        }
        aR = pk;
        int gn = n0 + srow;
        short8 pb = {0, 0, 0, 0, 0, 0, 0, 0};
        if (gn < N) pb = *(const short8*)&Bt[(long)gn * K + kt + skc];
        bR = pb;
    };
    loadAB(0);
    for (int kt = 0; kt < K; kt += 32) {
        *(short8*)&As[srow * 40 + skc] = aR;
        *(short8*)&Bs[srow * 40 + skc] = bR;
        __syncthreads();
        if (kt + 32 < K) loadAB(kt + 32);
        short8 af[2], bf[2];
        #pragma unroll
        for (int mi = 0; mi < 2; mi++) af[mi] = *(const short8*)&As[(wm * 32 + mi * 16 + l15) * 40 + (quad << 3)];
        #pragma unroll
        for (int ni = 0; ni < 2; ni++) bf[ni] = *(const short8*)&Bs[(wn * 32 + ni * 16 + l15) * 40 + (quad << 3)];
        #pragma unroll
        for (int mi = 0; mi < 2; mi++)
            #pragma unroll
            for (int ni = 0; ni < 2; ni++)
                acc[mi][ni] = __builtin_amdgcn_mfma_f32_16x16x32_bf16(af[mi], bf[ni], acc[mi][ni], 0, 0, 0);
        __syncthreads();
    }
    #pragma unroll
    for (int mi = 0; mi < 2; mi++) {
        int row = m0 + wm * 32 + mi * 16 + quad * 4;
        #pragma unroll
        for (int ni = 0; ni < 2; ni++) {
            int col = n0 + wn * 32 + ni * 16 + l15;
            if (col >= N) continue;
            float bv = bias[col];
            #pragma unroll
            for (int r = 0; r < 4; r++) {
                int rr = row + r;
                if (rr >= M) continue;
                float v = acc[mi][ni][r] + bv;
                if (act == 2) v = 0.5f * v * (1.f + erff(v * 0.70710678118654752f));
                if (resid) v += resid[(long)rr * N + col];
                C[(long)rr * N + col] = v;
            }
        }
    }
}

// ---------------- MFMA conv 3x3 s2 p1, tap-major K, bf16-pair input ----------------
// Flattened grid (nSpatial<<ctshift, 1, ncb) with XCD-chunk bijective swizzle: the (1<<ctshift)
// Cout-tiles of one spatial tile are adjacent within one XCD's chunk -> share input via that XCD's L2.
// mode 1: f32 spatial-major out (ostride floats). mode 2: bf16-pair out (ostride dwords) + GN stats.
__global__ __launch_bounds__(256) void mconv_k(const unsigned* __restrict__ in,
                                               const short* __restrict__ wgt,
                                               const float* __restrict__ bias,
                                               float* __restrict__ out,
                                               float2* __restrict__ parts,
                                               int c5m, int Cout, int Hin, int Win,
                                               int mode, int cpg, int ctshift,
                                               long istride, long ostride)
{
    // bijective XCD-chunk swizzle (m204): lin -> wgid, couttile fastest
    int lin = blockIdx.x + gridDim.x * blockIdx.z;
    int nwgT = gridDim.x * gridDim.z;
    int xcd = lin & 7, seq = lin >> 3;
    int qd = nwgT >> 3, rd = nwgT & 7;
    int wgid = (xcd < rd ? xcd * (qd + 1) : rd * (qd + 1) + (xcd - rd) * qd) + seq;
    int cam = wgid / gridDim.x;
    int rem = wgid - cam * gridDim.x;
    int couttile = rem & ((1 << ctshift) - 1);
    int spatial = rem >> ctshift;

    in  += (long)cam * istride;
    const int Hout = Hin >> 1, Wout = Win >> 1;
    const int HWo = Hout * Wout;
    const int HW = Hin * Win;
    const int Ktot = 288 << c5m;   // 9*Cin
    const int m5 = (1 << c5m) - 1;
    const int nsteps = 9 << c5m;
    __shared__ __align__(16) short As[2560];   // 64 rows x 40
    __shared__ __align__(16) short Bs[2560];   // 64 cols x 40
    __shared__ float2 sred[16][2];             // [quad-group][wn] = (s, s2)
    int tid = threadIdx.x;
    int wave = tid >> 6, lane = tid & 63;
    int wm = wave >> 1, wn = wave & 1;
    int quad = lane >> 4, l15 = lane & 15;
    int m0 = couttile << 6, n0 = spatial << 6;
    int nn = tid & 63;
    int kp0 = tid >> 6;
    int p = n0 + nn;
    int pok = p < HWo;
    int pc = pok ? p : (HWo - 1);
    int ho = pc / Wout, wo = pc - ho * Wout;
    int hb = ho * 2 - 1, wb = wo * 2 - 1;

    f4 acc[2][2];
    #pragma unroll
    for (int i = 0; i < 2; i++) { acc[i][0] = (f4){0.f,0.f,0.f,0.f}; acc[i][1] = (f4){0.f,0.f,0.f,0.f}; }

    short8 aR;
    unsigned bR[4];
    auto loadA = [&](int s) {
        int r = tid >> 2, kc = (tid & 3) << 3;
        aR = *(const short8*)&wgt[(long)(m0 + r) * Ktot + (s << 5) + kc];
    };
    // thread owns 4 CONTIGUOUS column-pairs kp = kp0*4 .. kp0*4+3 -> one b128 LDS write
    auto loadB = [&](int s) {
        int t = s >> c5m;
        int kh = (t * 11) >> 5;            // t/3 for t in 0..8
        int kw = t - kh * 3;
        int y = hb + kh, x = wb + kw;
        bool okp = pok && ((unsigned)y < (unsigned)Hin) && ((unsigned)x < (unsigned)Win);
        int base = (((s & m5) << 4) + (kp0 << 2)) * HW + y * Win + x;
        #pragma unroll
        for (int i = 0; i < 4; i++) {
            unsigned v = 0;
            if (okp) v = in[base + i * HW];
            bR[i] = v;
        }
    };

    loadA(0); loadB(0);
    for (int s = 0; s < nsteps; s++) {
        {
            int r = tid >> 2, kc = (tid & 3) << 3;
            *(short8*)&As[r * 40 + kc] = aR;
        }
        *(uint4*)&Bs[nn * 40 + (kp0 << 3)] = *(uint4*)bR;
        __syncthreads();
        if (s + 1 < nsteps) { loadA(s + 1); loadB(s + 1); }
        short8 af[2], bf[2];
        #pragma unroll
        for (int mi = 0; mi < 2; mi++) af[mi] = *(const short8*)&As[(wm * 32 + mi * 16 + l15) * 40 + (quad << 3)];
        #pragma unroll
        for (int ni = 0; ni < 2; ni++) bf[ni] = *(const short8*)&Bs[(wn * 32 + ni * 16 + l15) * 40 + (quad << 3)];
        #pragma unroll
        for (int mi = 0; mi < 2; mi++)
            #pragma unroll
            for (int ni = 0; ni < 2; ni++)
                acc[mi][ni] = __builtin_amdgcn_mfma_f32_16x16x32_bf16(af[mi], bf[ni], acc[mi][ni], 0, 0, 0);
        __syncthreads();
    }

    if (mode == 1) {
        float* outf = out + (long)cam * ostride;
        #pragma unroll
        for (int mi = 0; mi < 2; mi++) {
            int mbase = m0 + wm * 32 + mi * 16 + quad * 4;
            #pragma unroll
            for (int ni = 0; ni < 2; ni++) {
                int n = n0 + wn * 32 + ni * 16 + l15;
                if (n >= HWo) continue;
                #pragma unroll
                for (int r = 0; r < 4; r++) {
                    int m = mbase + r;
                    outf[(long)n * Cout + m] = acc[mi][ni][r] + bias[m];
                }
            }
        }
    } else {
        unsigned* outp = (unsigned*)out + (long)cam * ostride;
        float ssum[2] = {0.f, 0.f}, qsum[2] = {0.f, 0.f};
        #pragma unroll
        for (int mi = 0; mi < 2; mi++) {
            int mbase = m0 + wm * 32 + mi * 16 + quad * 4;
            float b0 = bias[mbase], b1 = bias[mbase + 1], b2 = bias[mbase + 2], b3 = bias[mbase + 3];
            #pragma unroll
            for (int ni = 0; ni < 2; ni++) {
                int n = n0 + wn * 32 + ni * 16 + l15;
                if (n >= HWo) continue;
                float v0 = acc[mi][ni][0] + b0;
                float v1 = acc[mi][ni][1] + b1;
                float v2 = acc[mi][ni][2] + b2;
                float v3 = acc[mi][ni][3] + b3;
                long cp = (long)(mbase >> 1) * HWo + n;
                outp[cp]       = packbf(v0, v1);
                outp[cp + HWo] = packbf(v2, v3);
                ssum[mi] += v0 + v1 + v2 + v3;
                qsum[mi] += v0 * v0 + v1 * v1 + v2 * v2 + v3 * v3;
            }
        }
        #pragma unroll
        for (int mi = 0; mi < 2; mi++) {
            #pragma unroll
            for (int off = 1; off < 16; off <<= 1) {
                ssum[mi] += __shfl_xor(ssum[mi], off, 16);
                qsum[mi] += __shfl_xor(qsum[mi], off, 16);
            }
        }
        if (l15 == 0) {
            #pragma unroll
            for (int mi = 0; mi < 2; mi++)
                sred[wm * 8 + mi * 4 + quad][wn] = make_float2(ssum[mi], qsum[mi]);
        }
        __syncthreads();
        int ng = 64 / cpg;          // groups covered by this block
        int qpg = cpg >> 2;         // quad-groups per group
        if (tid < ng) {
            float s = 0.f, q = 0.f;
            for (int u = 0; u < qpg; u++) {
                float2 a = sred[(tid * cpg >> 2) + u][0];
                float2 b = sred[(tid * cpg >> 2) + u][1];
                s += a.x + b.x; q += a.y + b.y;
            }
            int gabs = m0 / cpg + tid;
            parts[((long)cam * 32 + gabs) * 1400 + spatial] = make_float2(s, q);
        }
    }
}

// ---------------- conv0 fused MFMA: fp32 image gather -> bf16 MFMA (K=32) -> pair out + GN stats ------
__global__ __launch_bounds__(256) void conv0f_k(const float* __restrict__ img,
                                                const short* __restrict__ wgt,
                                                const float* __restrict__ bias,
                                                unsigned* __restrict__ outp,
                                                float2* __restrict__ parts,
                                                long istride, long ostride)
{
    img  += (long)blockIdx.z * istride;
    outp += (long)blockIdx.z * ostride;
    const int HWo = 89600;
    __shared__ __align__(16) short As[2560];
    __shared__ __align__(16) short Bs[2560];
    __shared__ float2 sred[32][2];
    int tid = threadIdx.x;
    int wave = tid >> 6, lane = tid & 63;
    int wm = wave >> 1, wn = wave & 1;
    int quad = lane >> 4, l15 = lane & 15;
    int n0 = blockIdx.x * 64;
    int srow = tid >> 2, skc = (tid & 3) << 3;
    *(short8*)&As[srow * 40 + skc] = *(const short8*)&wgt[srow * 32 + skc];
    {
        int p = n0 + srow;
        int ho = p / 400, wo = p - ho * 400;
        int hb = ho * 2 - 1, wb = wo * 2 - 1;
        short8 pb;
        #pragma unroll
        for (int j = 0; j < 8; j++) {
            int k = skc + j;
            float v = 0.f;
            if (k < 27) {
                int ci = (k < 9) ? 0 : (k < 18 ? 1 : 2);
                int t = k - ci * 9;
                int kh = (t < 3) ? 0 : (t < 6 ? 1 : 2);
                int kw = t - kh * 3;
                int y = hb + kh, x = wb + kw;
                if ((unsigned)y < 448u && (unsigned)x < 800u)
                    v = img[ci * 358400 + y * 800 + x];
            }
            pb[j] = f2s(v);
        }
        *(short8*)&Bs[srow * 40 + skc] = pb;
    }
    __syncthreads();
    f4 acc[2][2];
    #pragma unroll
    for (int i = 0; i < 2; i++) { acc[i][0] = (f4){0.f,0.f,0.f,0.f}; acc[i][1] = (f4){0.f,0.f,0.f,0.f}; }
    short8 af[2], bf[2];
    #pragma unroll
    for (int mi = 0; mi < 2; mi++) af[mi] = *(const short8*)&As[(wm * 32 + mi * 16 + l15) * 40 + (quad << 3)];
    #pragma unroll
    for (int ni = 0; ni < 2; ni++) bf[ni] = *(const short8*)&Bs[(wn * 32 + ni * 16 + l15) * 40 + (quad << 3)];
    #pragma unroll
    for (int mi = 0; mi < 2; mi++)
        #pragma unroll
        for (int ni = 0; ni < 2; ni++)
            acc[mi][ni] = __builtin_amdgcn_mfma_f32_16x16x32_bf16(af[mi], bf[ni], acc[mi][ni], 0, 0, 0);
    #pragma unroll
    for (int mi = 0; mi < 2; mi++) {
        int mbase = wm * 32 + mi * 16 + quad * 4;
        float b0 = bias[mbase], b1 = bias[mbase + 1], b2 = bias[mbase + 2], b3 = bias[mbase + 3];
        float s0 = 0.f, q0 = 0.f, s1 = 0.f, q1 = 0.f;
        #pragma unroll
        for (int ni = 0; ni < 2; ni++) {
            int n = n0 + wn * 32 + ni * 16 + l15;
            float v0 = acc[mi][ni][0] + b0;
            float v1 = acc[mi][ni][1] + b1;
            float v2 = acc[mi][ni][2] + b2;
            float v3 = acc[mi][ni][3] + b3;
            long cp = (long)(mbase >> 1) * HWo + n;
            outp[cp]       = packbf(v0, v1);
            outp[cp + HWo] = packbf(v2, v3);
            s0 += v0 + v1; q0 += v0 * v0 + v1 * v1;
            s1 += v2 + v3; q1 += v2 * v2 + v3 * v3;
        }
        #pragma unroll
        for (int off = 1; off < 16; off <<= 1) {
            s0 += __shfl_xor(s0, off, 16); q0 += __shfl_xor(q0, off, 16);
            s1 += __shfl_xor(s1, off, 16); q1 += __shfl_xor(q1, off, 16);
        }
        if (l15 == 0) {
            int pi = wm * 16 + mi * 8 + quad * 2;
            sred[pi][wn]     = make_float2(s0, q0);
            sred[pi + 1][wn] = make_float2(s1, q1);
        }
    }
    __syncthreads();
    if (tid < 32) {
        float2 a = sred[tid][0], b = sred[tid][1];
        parts[((long)blockIdx.z * 32 + tid) * 1400 + blockIdx.x] = make_float2(a.x + b.x, a.y + b.y);
    }
}

// ---------------- GN finalize: reduce per-block partials -> mean/rstd ----------------
__global__ __launch_bounds__(256) void gnfin_k(const float2* __restrict__ parts,
                                               float* __restrict__ gnstats, int nx, float invN)
{
    int g = blockIdx.x, cam = blockIdx.y;
    const float2* pb = parts + ((long)cam * 32 + g) * 1400;
    float s = 0.f, q = 0.f;
    for (int i = threadIdx.x; i < nx; i += 256) {
        float2 v = pb[i];
        s += v.x; q += v.y;
    }
    __shared__ float rs[256], rq[256];
    rs[threadIdx.x] = s; rq[threadIdx.x] = q;
    __syncthreads();
    for (int o = 128; o > 0; o >>= 1) {
        if (threadIdx.x < o) { rs[threadIdx.x] += rs[threadIdx.x + o]; rq[threadIdx.x] += rq[threadIdx.x + o]; }
        __syncthreads();
    }
    if (threadIdx.x == 0) {
        float mean = rs[0] * invN;
        float var  = rq[0] * invN - mean * mean;
        gnstats[(cam * 32 + g) * 2]     = mean;
        gnstats[(cam * 32 + g) * 2 + 1] = rsqrtf(var + EPS);
    }
}

// ---------------- in-place GN apply + ReLU on bf16-pair buffer ----------------
__global__ __launch_bounds__(256) void pairapply_k(unsigned* __restrict__ x,
                                                   const float* __restrict__ gamma,
                                                   const float* __restrict__ beta,
                                                   const float* __restrict__ gnstats,
                                                   int HW, int cpg, long zstride)
{
    x       += (long)blockIdx.z * zstride;
    gnstats += (long)blockIdx.z * 64;
    int idx4 = (blockIdx.x * 256 + threadIdx.x) * 4;   // HW%4==0 -> all in one pair-row
    int cp = idx4 / HW;
    int c0 = cp * 2;
    int g = c0 / cpg;
    float mean = gnstats[g * 2], rstd = gnstats[g * 2 + 1];
    float sa = rstd * gamma[c0],     ba = beta[c0]     - mean * sa;
    float sb = rstd * gamma[c0 + 1], bb = beta[c0 + 1] - mean * sb;
    uint4 v = *(uint4*)&x[idx4];
    unsigned* vp = (unsigned*)&v;
    #pragma unroll
    for (int j = 0; j < 4; j++) {
        float lo = fmaxf(bflo(vp[j]) * sa + ba, 0.f);
        float hi = fmaxf(bfhi(vp[j]) * sb + bb, 0.f);
        vp[j] = packbf(lo, hi);
    }
    *(uint4*)&x[idx4] = v;
}

// ---------------- GroupNorm for (1400 x 256) spatial-major, batched over cams (grid.y) ----------------
__global__ __launch_bounds__(256) void gn_stats_hwd_k(const float* __restrict__ x, float* __restrict__ stats)
{
    x += (long)blockIdx.y * 358400;
    stats += blockIdx.y * 64;
    int g = blockIdx.x;  // 32 groups
    float s = 0.f, s2 = 0.f;
    for (int i = threadIdx.x; i < 1400 * 8; i += blockDim.x) {
        int p = i >> 3, c = g * 8 + (i & 7);
        float v = x[(long)p * 256 + c];
        s += v; s2 += v * v;
    }
    __shared__ float rs[256], rq[256];
    rs[threadIdx.x] = s; rq[threadIdx.x] = s2;
    __syncthreads();
    for (int o = 128; o > 0; o >>= 1) {
        if (threadIdx.x < o) { rs[threadIdx.x] += rs[threadIdx.x + o]; rq[threadIdx.x] += rq[threadIdx.x + o]; }
        __syncthreads();
    }
    if (threadIdx.x == 0) {
        float mean = rs[0] / 11200.f;
        float var  = rq[0] / 11200.f - mean * mean;
        stats[g * 2]     = mean;
        stats[g * 2 + 1] = rsqrtf(var + EPS);
    }
}

__global__ __launch_bounds__(256) void gn_apply_hwd_k(float* __restrict__ x,
                                                      const float* __restrict__ gamma,
                                                      const float* __restrict__ beta,
                                                      const float* __restrict__ stats,
                                                      int relu)
{
    x += (long)blockIdx.y * 358400;
    stats += blockIdx.y * 64;
    long i4 = ((long)blockIdx.x * 256 + threadIdx.x) * 4;  // grid.x = 350 -> exact
    int c = (int)(i4 & 255);
    int g = c >> 3;
    float4 v  = *(float4*)&x[i4];
    float4 gm = *(const float4*)&gamma[c];
    float4 bt = *(const float4*)&beta[c];
    float m = stats[g * 2], rs = stats[g * 2 + 1];
    v.x = (v.x - m) * rs * gm.x + bt.x;
    v.y = (v.y - m) * rs * gm.y + bt.y;
    v.z = (v.z - m) * rs * gm.z + bt.z;
    v.w = (v.w - m) * rs * gm.w + bt.w;
    if (relu) {
        v.x = fmaxf(v.x, 0.f); v.y = fmaxf(v.y, 0.f);
        v.z = fmaxf(v.z, 0.f); v.w = fmaxf(v.w, 0.f);
    }
    *(float4*)&x[i4] = v;
}

// ---------------- projection of BEV grid ----------------
__global__ __launch_bounds__(256) void project_k(const float* __restrict__ Kin,
                                                 const float* __restrict__ Ein,
                                                 float* __restrict__ refp, int* __restrict__ valid)
{
    int idx = blockIdx.x * blockDim.x + threadIdx.x;
    if (idx >= 2500 * 6) return;
    int c = idx % 6, q = idx / 6;
    int i = q / 50, j = q % 50;
    float px = (i - 24.5f) * 0.5f;
    float py = (j - 24.5f) * 0.5f;
    const float* E = Ein + c * 16;
    float pc[4];
    #pragma unroll
    for (int r = 0; r < 4; r++)
        pc[r] = E[r * 4 + 0] * px + E[r * 4 + 1] * py + E[r * 4 + 3];
    const float* Km = Kin + c * 9;
    float pix[3];
    #pragma unroll
    for (int r = 0; r < 3; r++)
        pix[r] = Km[r * 3 + 0] * pc[0] + Km[r * 3 + 1] * pc[1] + Km[r * 3 + 2] * pc[2];
    float z = fmaxf(pix[2], 1e-5f);
    float u = pix[0] / z, v = pix[1] / z;
    int ok = (pc[2] > 0.f) && (u >= 0.f) && (u < 800.f) && (v >= 0.f) && (v < 448.f);
    refp[(long)idx * 2 + 0] = 2.f * u / 799.f - 1.f;
    refp[(long)idx * 2 + 1] = 2.f * v / 447.f - 1.f;
    valid[idx] = ok;
}

// ---------------- misc elementwise ----------------
__global__ __launch_bounds__(256) void qinit_k(const float* __restrict__ a, const float* __restrict__ b,
                                               float* __restrict__ y)
{
    int i = blockIdx.x * blockDim.x + threadIdx.x;
    if (i >= 2500 * 256) return;
    y[i] = a[i] + b[i];
}

// ---------------- LayerNorm ----------------
__global__ __launch_bounds__(256) void ln_k(const float* __restrict__ x,
                                            const float* __restrict__ g, const float* __restrict__ b,
                                            float* __restrict__ y)
{
    int row  = blockIdx.x * 4 + (threadIdx.x >> 6);
    int lane = threadIdx.x & 63;
    if (row >= 2500) return;
    const float* xp = x + (long)row * 256;
    float v[4];
    #pragma unroll
    for (int i = 0; i < 4; i++) v[i] = xp[lane + 64 * i];
    float s  = v[0] + v[1] + v[2] + v[3];
    float s2 = v[0] * v[0] + v[1] * v[1] + v[2] * v[2] + v[3] * v[3];
    #pragma unroll
    for (int o = 32; o > 0; o >>= 1) { s += __shfl_xor(s, o, 64); s2 += __shfl_xor(s2, o, 64); }
    float mean = s * (1.f / 256.f);
    float var  = s2 * (1.f / 256.f) - mean * mean;
    float rstd = rsqrtf(var + EPS);
    #pragma unroll
    for (int i = 0; i < 4; i++) {
        int cc = lane + 64 * i;
        y[(long)row * 256 + cc] = (v[i] - mean) * rstd * g[cc] + b[cc];
    }
}

// ---------------- MFMA flash-2 MHA with split-K (packed-QKV aware: row stride ld) ----------------
__global__ __launch_bounds__(256) void flash2_k(const float* __restrict__ Q,
                                                const float* __restrict__ K,
                                                const float* __restrict__ V,
                                                int ld,
                                                float* __restrict__ Opart,   // (S,2500,256)
                                                float* __restrict__ MLpart)  // (S,2500,8,2)
{
    const int h  = blockIdx.y;
    const int q0 = blockIdx.x * 64;
    const int sp = blockIdx.z;
    const int kstart = sp * FL_KEYS, kend = kstart + FL_KEYS;
    const int tid = threadIdx.x;
    const int wave = tid >> 6, lane = tid & 63;
    const int quad = lane >> 4, l15 = lane & 15;
    __shared__ __align__(16) short Qs[64 * 40];
    __shared__ __align__(16) short Ks[64 * 40];
    __shared__ __align__(16) short Vt[32 * 72];
    __shared__ __align__(16) short Ps[64 * 72];
    const float scale = 0.17677669529663687f;
    {
        int row = tid >> 2, kc = (tid & 3) << 3;
        int qi = q0 + row;
        short8 pk = {0, 0, 0, 0, 0, 0, 0, 0};
        if (qi < 2500) {
            const float4* qp = (const float4*)(Q + (long)qi * ld + h * 32 + kc);
            float4 v0 = qp[0], v1 = qp[1];
            pk[0] = f2s(v0.x * scale); pk[1] = f2s(v0.y * scale); pk[2] = f2s(v0.z * scale); pk[3] = f2s(v0.w * scale);
            pk[4] = f2s(v1.x * scale); pk[5] = f2s(v1.y * scale); pk[6] = f2s(v1.z * scale); pk[7] = f2s(v1.w * scale);
        }
        *(short8*)&Qs[row * 40 + kc] = pk;
    }
    __syncthreads();
    short8 aq = *(const short8*)&Qs[(wave * 16 + l15) * 40 + (quad << 3)];
    float m[4], l[4];
    f4 oacc[2];
    #pragma unroll
    for (int r = 0; r < 4; r++) { m[r] = -INFINITY; l[r] = 0.f; }
    oacc[0] = (f4){0.f, 0.f, 0.f, 0.f};
    oacc[1] = (f4){0.f, 0.f, 0.f, 0.f};
    for (int kb = kstart; kb < kend; kb += 64) {
        __syncthreads();
        {
            int row = tid >> 2, kc = (tid & 3) << 3;
            int ki = kb + row;
            short8 pk = {0, 0, 0, 0, 0, 0, 0, 0};
            float vv[8] = {0.f, 0.f, 0.f, 0.f, 0.f, 0.f, 0.f, 0.f};
            if (ki < kend) {
                const float4* kp = (const float4*)(K + (long)ki * ld + h * 32 + kc);
                float4 a0 = kp[0], a1 = kp[1];
                pk[0] = f2s(a0.x); pk[1] = f2s(a0.y); pk[2] = f2s(a0.z); pk[3] = f2s(a0.w);
                pk[4] = f2s(a1.x); pk[5] = f2s(a1.y); pk[6] = f2s(a1.z); pk[7] = f2s(a1.w);
                const float4* vp = (const float4*)(V + (long)ki * ld + h * 32 + kc);
                float4 b0 = vp[0], b1 = vp[1];
                vv[0] = b0.x; vv[1] = b0.y; vv[2] = b0.z; vv[3] = b0.w;
                vv[4] = b1.x; vv[5] = b1.y; vv[6] = b1.z; vv[7] = b1.w;
            }
            *(short8*)&Ks[row * 40 + kc] = pk;
            #pragma unroll
            for (int j = 0; j < 8; j++) Vt[(kc + j) * 72 + row] = f2s(vv[j]);
        }
        __syncthreads();
        f4 sa[4];
        #pragma unroll
        for (int ni = 0; ni < 4; ni++) {
            short8 bk = *(const short8*)&Ks[(ni * 16 + l15) * 40 + (quad << 3)];
            sa[ni] = __builtin_amdgcn_mfma_f32_16x16x32_bf16(aq, bk, (f4){0.f, 0.f, 0.f, 0.f}, 0, 0, 0);
        }
        float sv[4][4];
        #pragma unroll
        for (int ni = 0; ni < 4; ni++) {
            bool colok = (kb + ni * 16 + l15) < kend;
            #pragma unroll
            for (int r = 0; r < 4; r++) sv[ni][r] = colok ? sa[ni][r] : -1e30f;
        }
        float p[4][4];
        #pragma unroll
        for (int r = 0; r < 4; r++) {
            float rm = fmaxf(fmaxf(sv[0][r], sv[1][r]), fmaxf(sv[2][r], sv[3][r]));
            #pragma unroll
            for (int off = 1; off < 16; off <<= 1) rm = fmaxf(rm, __shfl_xor(rm, off, 16));
            float mn = fmaxf(m[r], rm);
            float alpha = __expf(m[r] - mn);
            float rs = 0.f;
            #pragma unroll
            for (int ni = 0; ni < 4; ni++) { p[ni][r] = __expf(sv[ni][r] - mn); rs += p[ni][r]; }
            #pragma unroll
            for (int off = 1; off < 16; off <<= 1) rs += __shfl_xor(rs, off, 16);
            l[r] = l[r] * alpha + rs;
            oacc[0][r] *= alpha; oacc[1][r] *= alpha;
            m[r] = mn;
        }
        #pragma unroll
        for (int ni = 0; ni < 4; ni++)
            #pragma unroll
            for (int r = 0; r < 4; r++)
                Ps[(wave * 16 + quad * 4 + r) * 72 + ni * 16 + l15] = f2s(p[ni][r]);
        #pragma unroll
        for (int kh = 0; kh < 2; kh++) {
            short8 ap = *(const short8*)&Ps[(wave * 16 + l15) * 72 + kh * 32 + (quad << 3)];
            #pragma unroll
            for (int ni = 0; ni < 2; ni++) {
                short8 bv = *(const short8*)&Vt[(ni * 16 + l15) * 72 + kh * 32 + (quad << 3)];
                oacc[ni] = __builtin_amdgcn_mfma_f32_16x16x32_bf16(ap, bv, oacc[ni], 0, 0, 0);
            }
        }
    }
    #pragma unroll
    for (int r = 0; r < 4; r++) {
        int qi = q0 + wave * 16 + quad * 4 + r;
        if (qi < 2500) {
            long ob = ((long)sp * 2500 + qi) * 256 + h * 32;
            Opart[ob + l15]      = oacc[0][r];
            Opart[ob + 16 + l15] = oacc[1][r];
            if (l15 == 0) {
                long mb = (((long)sp * 2500 + qi) * 8 + h) * 2;
                MLpart[mb]     = m[r];
                MLpart[mb + 1] = l[r];
            }
        }
    }
}

__global__ __launch_bounds__(256) void flashmerge_k(const float* __restrict__ Opart,
                                                    const float* __restrict__ MLpart,
                                                    float* __restrict__ O)
{
    int q = blockIdx.x, d = threadIdx.x;
    int h = d >> 5;
    float ms[FL_SPLITS], ls[FL_SPLITS];
    float mg = -INFINITY;
    #pragma unroll
    for (int s = 0; s < FL_SPLITS; s++) {
        long mb = (((long)s * 2500 + q) * 8 + h) * 2;
        ms[s] = MLpart[mb];
        ls[s] = MLpart[mb + 1];
        mg = fmaxf(mg, ms[s]);
    }
    float lsum = 0.f, osum = 0.f;
    #pragma unroll
    for (int s = 0; s < FL_SPLITS; s++) {
        float w = __expf(ms[s] - mg);
        lsum += ls[s] * w;
        osum += Opart[((long)s * 2500 + q) * 256 + d] * w;
    }
    O[(long)q * 256 + d] = osum / lsum;
}

// ---------------- masked softmax over 192 deformable-attn logits (row stride ld) ----------------
__global__ __launch_bounds__(64) void scasoftmax_k(float* __restrict__ logits, int ld,
                                                   const int* __restrict__ valid)
{
    int q = blockIdx.x, lane = threadIdx.x;
    float v[3]; int mk[3];
    #pragma unroll
    for (int i = 0; i < 3; i++) {
        int idx = i * 64 + lane;
        int c = idx >> 5;
        mk[i] = valid[q * 6 + c];
        v[i] = mk[i] ? logits[(long)q * ld + idx] : -1e30f;
    }
    float mx = fmaxf(fmaxf(v[0], v[1]), v[2]);
    #pragma unroll
    for (int o = 32; o > 0; o >>= 1) mx = fmaxf(mx, __shfl_xor(mx, o, 64));
    float e[3]; float s = 0.f;
    #pragma unroll
    for (int i = 0; i < 3; i++) { e[i] = expf(v[i] - mx); s += e[i]; }
    #pragma unroll
    for (int o = 32; o > 0; o >>= 1) s += __shfl_xor(s, o, 64);
    float inv = 1.f / s;
    #pragma unroll
    for (int i = 0; i < 3; i++)
        logits[(long)q * ld + i * 64 + lane] = mk[i] ? e[i] * inv : 0.f;
}

// ---------------- deformable sampling (offs/wts with row stride ld); one setup pass for all cams ------
__global__ __launch_bounds__(256) void sample_k(const float* __restrict__ vals,
                                                const float* __restrict__ offs, int ld,
                                                const float* __restrict__ wts,
                                                const float* __restrict__ refp,
                                                const int* __restrict__ valid,
                                                float* __restrict__ out)
{
    int q = blockIdx.x, d = threadIdx.x;
    __shared__ float s_cw[6][32][4];
    __shared__ int   s_idx[6][32][4];
    if (d < 192) {
        int c = d >> 5, pt = d & 31;
        if (valid[q * 6 + c]) {
            float ox = offs[(long)q * ld + (c * 32 + pt) * 2 + 0];
            float oy = offs[(long)q * ld + (c * 32 + pt) * 2 + 1];
            float px = refp[(q * 6 + c) * 2 + 0] + ox * (2.f / 49.f);
            float py = refp[(q * 6 + c) * 2 + 1] + oy * (2.f / 27.f);
            float gx = (px + 1.f) * 0.5f * 49.f;
            float gy = (py + 1.f) * 0.5f * 27.f;
            float x0f = floorf(gx), y0f = floorf(gy);
            float wx = gx - x0f, wy = gy - y0f;
            int x0 = (int)x0f, y0 = (int)y0f;
            float wgt = wts[(long)q * ld + c * 32 + pt];
            float cw[4] = {(1.f - wx) * (1.f - wy), wx * (1.f - wy), (1.f - wx) * wy, wx * wy};
            const int dxs[4] = {0, 1, 0, 1};
            const int dys[4] = {0, 0, 1, 1};
            #pragma unroll
            for (int k2 = 0; k2 < 4; k2++) {
                int xi = x0 + dxs[k2], yi = y0 + dys[k2];
                bool ok = (xi >= 0) && (xi < 50) && (yi >= 0) && (yi < 28);
                s_cw[c][pt][k2]  = ok ? cw[k2] * wgt : 0.f;
                s_idx[c][pt][k2] = ok ? (yi * 50 + xi) * 256 : 0;
            }
        }
    }
    __syncthreads();
    float acc = 0.f;
    for (int c = 0; c < 6; c++) {
        if (!valid[q * 6 + c]) continue;
        const float* vb = vals + (long)c * 358400 + d;
        for (int pt = 0; pt < 32; pt++) {
            #pragma unroll
            for (int k2 = 0; k2 < 4; k2++) {
                float cwv = s_cw[c][pt][k2];
                if (cwv != 0.f) acc += cwv * vb[s_idx[c][pt][k2]];
            }
        }
    }
    out[(long)q * 256 + d] = acc;
}

// =====================================================================================
extern "C" void kernel_launch(void* const* d_in, const int* in_sizes, int n_in,
                              void* d_out, int out_size, void* d_ws, size_t ws_size,
                              hipStream_t stream)
{
    const float* images = (const float*)d_in[0];
    const float* intr   = (const float*)d_in[1];
    const float* e2c    = (const float*)d_in[2];
    const float* bevq   = (const float*)d_in[3];
    const float* bevp   = (const float*)d_in[4];
    const float* bbw[5]    = {(const float*)d_in[5],  (const float*)d_in[9],  (const float*)d_in[13], (const float*)d_in[17], (const float*)d_in[21]};
    const float* bbb[5]    = {(const float*)d_in[6],  (const float*)d_in[10], (const float*)d_in[14], (const float*)d_in[18], (const float*)d_in[22]};
    const float* bbg[5]    = {(const float*)d_in[7],  (const float*)d_in[11], (const float*)d_in[15], (const float*)d_in[19], (const float*)d_in[23]};
    const float* bbbeta[5] = {(const float*)d_in[8],  (const float*)d_in[12], (const float*)d_in[16], (const float*)d_in[20], (const float*)d_in[24]};
    const float* sa_wq = (const float*)d_in[25]; const float* sa_bq = (const float*)d_in[26];
    const float* sa_wk = (const float*)d_in[27]; const float* sa_bk = (const float*)d_in[28];
    const float* sa_wv = (const float*)d_in[29]; const float* sa_bv = (const float*)d_in[30];
    const float* sa_wo = (const float*)d_in[31]; const float* sa_bo = (const float*)d_in[32];
    const float* ln1g = (const float*)d_in[33]; const float* ln1b = (const float*)d_in[34];
    const float* ln2g = (const float*)d_in[35]; const float* ln2b = (const float*)d_in[36];
    const float* ln3g = (const float*)d_in[37]; const float* ln3b = (const float*)d_in[38];
    const float* offw = (const float*)d_in[39]; const float* offb = (const float*)d_in[40];
    const float* wtw  = (const float*)d_in[41]; const float* wtb  = (const float*)d_in[42];
    const float* valw = (const float*)d_in[43]; const float* valb = (const float*)d_in[44];
    const float* outw = (const float*)d_in[45]; const float* outb = (const float*)d_in[46];
    const float* fw1  = (const float*)d_in[47]; const float* fb1  = (const float*)d_in[48];
    const float* fw2  = (const float*)d_in[49]; const float* fb2  = (const float*)d_in[50];

    // ---- pick camera-batch factor from available workspace (formula unchanged) ----
    auto needB = [](long ncb) -> unsigned long long {
        return (unsigned long long)(ncb * 8601600L + 6681600L) * 4ULL + 6307840ULL + (1 << 20);
    };
    int ncb = 1;
    if      ((unsigned long long)ws_size >= needB(6)) ncb = 6;
    else if ((unsigned long long)ws_size >= needB(3)) ncb = 3;
    else if ((unsigned long long)ws_size >= needB(2)) ncb = 2;

    // ---- workspace layout ----
    float* ws = (float*)d_ws;
    float* A     = ws; ws += (long)ncb * 5734400;  // pair-buffer ping; aliases: bQKV, OP, bOW
    float* Bu    = ws; ws += (long)ncb * 2867200;  // pair-buffer pong; aliases: valsb, MLp
    float* f3bH  = ws; ws += 2560000;              // feats3 (backbone) / ffn hidden (transformer)
    float* feats = ws; ws += 2150400;              // (6,1400,256) hwd; also GN parts (early backbone)
    float* qbuf  = ws; ws += 640000;
    float* xq    = ws; ws += 640000;
    float* bO    = ws; ws += 640000;
    float* refp  = ws; ws += 30016;
    int*   validb = (int*)ws; ws += 15040;
    float* stats = ws; ws += 384;
    float* gnst  = ws; ws += 3072;                 // per-group mean/rstd (ncb x 32 x 2)
    float* qkvb  = ws; ws += 1536;
    float* owb   = ws; ws += 1152;
    // bf16 weight buffers
    short* sb = (short*)ws;
    short* cw0b = sb; sb += 2048;                  // conv0 (64,32) padded, k = ci*9+t
    short* cw1b = sb; sb += 73728;                 // tap-major (128, 9*64)
    short* cw2b = sb; sb += 294912;                // tap-major (256, 9*128)
    short* cw3b = sb; sb += 589824;                // tap-major (256, 9*256)
    short* cw4b = sb; sb += 65536;
    short* qkvT = sb; sb += 393216;
    short* owT  = sb; sb += 131072;
    short* valT = sb; sb += 131072;
    short* outT = sb; sb += 131072;
    short* offwtT = sb; sb += 294912;
    short* f1T  = sb; sb += 524288;
    short* f2T  = sb; sb += 524288;
    // aliases
    float*  feats3 = f3bH;
    float*  bH     = f3bH;
    float*  bQKV   = A;
    float*  OP     = A + 1920000;
    float*  bOW    = A + 1920000;
    float*  valsb  = Bu;
    float*  MLp    = Bu + 2150400;
    unsigned* Bbf0 = (unsigned*)A;                 // pair ping (stride varies per stage)
    unsigned* Bbf1 = (unsigned*)Bu;                // pair pong
    float2* partsP = (float2*)feats;               // 6*32*1400 float2 = 2.15 MB (free until conv4)

    auto mgemm = [&](const float* Ain, int lda, const short* Bt, const float* bias, const float* resid,
                     float* C, int M, int N, int K, int act) {
        dim3 g((N + 63) / 64, (M + 63) / 64);
        mgemm_k<<<g, 256, 0, stream>>>(Ain, lda, Bt, bias, resid, C, M, N, K, act);
    };

    // ---- weight preprocessing ----
    wcast0_k<<<8, 256, 0, stream>>>(bbw[0], cw0b);
    wreord_k<<<(73728 + 255) / 256, 256, 0, stream>>>(bbw[1], cw1b, 64, 73728);
    wreord_k<<<(294912 + 255) / 256, 256, 0, stream>>>(bbw[2], cw2b, 128, 294912);
    wreord_k<<<(589824 + 255) / 256, 256, 0, stream>>>(bbw[3], cw3b, 256, 589824);
    wcast_k<<<(65536 + 255) / 256, 256, 0, stream>>>(bbw[4], cw4b, 65536);
    wtrans6_k<<<dim3(4, 4, 12), 256, 0, stream>>>(sa_wq, sa_wk, sa_wv, sa_wo, valw, outw,
                                                  qkvT, qkvT + 65536, qkvT + 131072, owT, valT, outT);
    wtrans_k<<<dim3(6, 4, 2), 256, 0, stream>>>(offw, offwtT,         256, 384,  147456);
    wtrans_k<<<dim3(3, 4, 2), 256, 0, stream>>>(wtw,  offwtT + 98304, 256, 192,  147456);
    wtrans_k<<<dim3(16, 4, 2), 256, 0, stream>>>(fw1, f1T, 256, 1024, 262144);
    wtrans_k<<<dim3(4, 16, 2), 256, 0, stream>>>(fw2, f2T, 1024, 256, 262144);
    packb_k<<<dim3(3, 2), 256, 0, stream>>>(sa_bq, sa_bk, sa_bv, qkvb, 256, 256, 256);
    packb_k<<<dim3(3, 2), 256, 0, stream>>>(offb, wtb, nullptr, owb, 384, 192, 0);

    // ---- projection of BEV grid ----
    project_k<<<(15000 + 255) / 256, 256, 0, stream>>>(intr, e2c, refp, validb);

    // ---- backbone (cam-batched; bf16-pair activations) ----
    for (int c0 = 0; c0 < 6; c0 += ncb) {
        const float* img = images + (long)c0 * 1075200;
        // conv0 fused MFMA -> pairs + stats
        conv0f_k<<<dim3(1400, 1, ncb), 256, 0, stream>>>(img, cw0b, bbb[0], Bbf0, partsP,
                                                         1075200L, 2867200L);
        gnfin_k<<<dim3(32, ncb), 256, 0, stream>>>(partsP, gnst, 1400, 1.f / 179200.f);
        pairapply_k<<<dim3(2800, 1, ncb), 256, 0, stream>>>(Bbf0, bbg[0], bbbeta[0], gnst, 89600, 2, 2867200L);
        // conv1 -> pairs + fused stats (flat grid 350*2, XCD-chunk swizzle)
        mconv_k<<<dim3(700, 1, ncb), 256, 0, stream>>>(Bbf0, cw1b, bbb[1], (float*)Bbf1, partsP,
                                                       1, 128, 224, 400, 2, 4, 1, 2867200L, 1433600L);
        gnfin_k<<<dim3(32, ncb), 256, 0, stream>>>(partsP, gnst, 350, 1.f / 89600.f);
        pairapply_k<<<dim3(1400, 1, ncb), 256, 0, stream>>>(Bbf1, bbg[1], bbbeta[1], gnst, 22400, 4, 1433600L);
        // conv2 -> pairs + fused stats (flat grid 88*4)
        mconv_k<<<dim3(352, 1, ncb), 256, 0, stream>>>(Bbf1, cw2b, bbb[2], (float*)Bbf0, partsP,
                                                       2, 256, 112, 200, 2, 8, 2, 1433600L, 716800L);
        gnfin_k<<<dim3(32, ncb), 256, 0, stream>>>(partsP, gnst, 88, 1.f / 44800.f);
        pairapply_k<<<dim3(700, 1, ncb), 256, 0, stream>>>(Bbf0, bbg[2], bbbeta[2], gnst, 5600, 8, 716800L);
        // conv3 -> f32 spatial-major feats3[cam] (flat grid 22*4)
        mconv_k<<<dim3(88, 1, ncb), 256, 0, stream>>>(Bbf0, cw3b, bbb[3], feats3 + (long)c0 * 358400, nullptr,
                                                      3, 256, 56, 100, 1, 0, 2, 716800L, 358400L);
    }
    // batched conv3-GN (+relu), conv4 as one 8400x256 GEMM, batched conv4-GN
    gn_stats_hwd_k<<<dim3(32, 6), 256, 0, stream>>>(feats3, stats);
    gn_apply_hwd_k<<<dim3(350, 6), 256, 0, stream>>>(feats3, bbg[3], bbbeta[3], stats, 1);
    mgemm(feats3, 256, cw4b, bbb[4], nullptr, feats, 8400, 256, 256, 0);
    gn_stats_hwd_k<<<dim3(32, 6), 256, 0, stream>>>(feats, stats);
    gn_apply_hwd_k<<<dim3(350, 6), 256, 0, stream>>>(feats, bbg[4], bbbeta[4], stats, 0);

    // ---- transformer ----
    qinit_k<<<2500, 256, 0, stream>>>(bevq, bevp, qbuf);

    for (int l = 0; l < 2; l++) {
        long o1 = (long)l * 256;

        // self-attention (fused QKV projection: 2500 x 768)
        ln_k<<<625, 256, 0, stream>>>(qbuf, ln1g + o1, ln1b + o1, xq);
        mgemm(xq, 256, qkvT + l * 196608, qkvb + l * 768, nullptr, bQKV, 2500, 768, 256, 0);
        flash2_k<<<dim3(40, 8, FL_SPLITS), 256, 0, stream>>>(bQKV, bQKV + 256, bQKV + 512, 768, OP, MLp);
        flashmerge_k<<<2500, 256, 0, stream>>>(OP, MLp, bO);
        mgemm(bO, 256, owT + l * 65536, sa_bo + o1, qbuf, qbuf, 2500, 256, 256, 0);

        // spatial cross-attention (fused offsets+logits projection: 2500 x 576)
        ln_k<<<625, 256, 0, stream>>>(qbuf, ln2g + o1, ln2b + o1, xq);
        mgemm(feats, 256, valT + l * 65536, valb + o1, nullptr, valsb, 8400, 256, 256, 0);
        mgemm(xq, 256, offwtT + l * 147456, owb + l * 576, nullptr, bOW, 2500, 576, 256, 0);
        scasoftmax_k<<<2500, 64, 0, stream>>>(bOW + 384, 576, validb);
        sample_k<<<2500, 256, 0, stream>>>(valsb, bOW, 576, bOW + 384, refp, validb, bO);
        mgemm(bO, 256, outT + l * 65536, outb + o1, qbuf, qbuf, 2500, 256, 256, 0);

        // FFN
        ln_k<<<625, 256, 0, stream>>>(qbuf, ln3g + o1, ln3b + o1, xq);
        mgemm(xq, 256, f1T + l * 262144, fb1 + (long)l * 1024, nullptr, bH, 2500, 1024, 256, 2);
        mgemm(bH, 1024, f2T + l * 262144, fb2 + o1, qbuf,
              (l == 1) ? (float*)d_out : qbuf, 2500, 256, 1024, 0);
    }
}

// Round 10
// 990.539 us; speedup vs baseline: 2.0032x; 1.0001x over previous
//
#include <hip/hip_runtime.h>
#include <hip/hip_bf16.h>
#include <math.h>

#define EPS 1e-5f
#define FL_SPLITS 5
#define FL_KEYS 500

typedef __attribute__((ext_vector_type(8))) short short8;
typedef __attribute__((ext_vector_type(4))) float f4;

__device__ __forceinline__ short f2s(float f) {
    union { float f; unsigned u; } v; v.f = f;
    unsigned r = (v.u + 0x7fffu + ((v.u >> 16) & 1u)) >> 16;  // RNE
    return (short)r;
}
__device__ __forceinline__ unsigned packbf(float a, float b) {
    return (unsigned)(unsigned short)f2s(a) | ((unsigned)(unsigned short)f2s(b) << 16);
}
__device__ __forceinline__ float bflo(unsigned v) { union { unsigned u; float f; } t; t.u = v << 16; return t.f; }
__device__ __forceinline__ float bfhi(unsigned v) { union { unsigned u; float f; } t; t.u = v & 0xffff0000u; return t.f; }

// ---------------- weight preprocessing ----------------
__global__ __launch_bounds__(256) void wcast_k(const float* __restrict__ in, short* __restrict__ out, int n)
{
    int i = blockIdx.x * 256 + threadIdx.x;
    if (i < n) out[i] = f2s(in[i]);
}

// conv0 weight pack: (64,3,3,3) fp32 -> (64,32) bf16, k = ci*9 + t, pad 27..31 = 0
__global__ __launch_bounds__(256) void wcast0_k(const float* __restrict__ in, short* __restrict__ out)
{
    int i = blockIdx.x * 256 + threadIdx.x;
    if (i >= 2048) return;
    int k = i & 31;
    out[i] = (k < 27) ? f2s(in[(i >> 5) * 27 + k]) : (short)0;
}

// conv weight reorder: (Cout, Cin, 3,3) fp32 -> (Cout, 9, Cin) bf16 (tap-major)
__global__ __launch_bounds__(256) void wreord_k(const float* __restrict__ in, short* __restrict__ out,
                                                int Cin, int n)
{
    int i = blockIdx.x * 256 + threadIdx.x;
    if (i >= n) return;
    int cin9 = Cin * 9;
    int co = i / cin9, rem = i - co * cin9;
    int ci = rem / 9, t = rem - ci * 9;
    out[(long)co * cin9 + t * Cin + ci] = f2s(in[i]);
}

// (K,N) fp32 -> (N,K) bf16 ; blockIdx.z = matrix index, zstride = output stride per matrix
__global__ __launch_bounds__(256) void wtrans_k(const float* __restrict__ in, short* __restrict__ out,
                                                int K, int N, long zstride)
{
    in  += (long)blockIdx.z * K * N;
    out += (long)blockIdx.z * zstride;
    __shared__ float t[64][65];
    int k0 = blockIdx.y * 64, n0 = blockIdx.x * 64;
    int tid = threadIdx.x;
    int cl = tid & 63, rq = tid >> 6;
    #pragma unroll
    for (int i = 0; i < 16; i++) {
        int rl = rq + i * 4;
        int k = k0 + rl, n = n0 + cl;
        t[rl][cl] = (k < K && n < N) ? in[(long)k * N + n] : 0.f;
    }
    __syncthreads();
    #pragma unroll
    for (int i = 0; i < 16; i++) {
        int nl = rq + i * 4;
        int n = n0 + nl, k = k0 + cl;
        if (n < N && k < K) out[(long)n * K + k] = f2s(t[cl][nl]);
    }
}

// six 256x256 (K,N)->(N,K) transposes in one dispatch; blockIdx.z = mat*2 + layer
__global__ __launch_bounds__(256) void wtrans6_k(const float* __restrict__ s0, const float* __restrict__ s1,
                                                 const float* __restrict__ s2, const float* __restrict__ s3,
                                                 const float* __restrict__ s4, const float* __restrict__ s5,
                                                 short* __restrict__ d0, short* __restrict__ d1,
                                                 short* __restrict__ d2, short* __restrict__ d3,
                                                 short* __restrict__ d4, short* __restrict__ d5)
{
    int mat = blockIdx.z >> 1, l = blockIdx.z & 1;
    const float* in; short* out; long zs;
    if      (mat == 0) { in = s0; out = d0; zs = 196608; }
    else if (mat == 1) { in = s1; out = d1; zs = 196608; }
    else if (mat == 2) { in = s2; out = d2; zs = 196608; }
    else if (mat == 3) { in = s3; out = d3; zs = 65536; }
    else if (mat == 4) { in = s4; out = d4; zs = 65536; }
    else               { in = s5; out = d5; zs = 65536; }
    in  += (long)l * 65536;
    out += (long)l * zs;
    __shared__ float t[64][65];
    int k0 = blockIdx.y * 64, n0 = blockIdx.x * 64;
    int tid = threadIdx.x;
    int cl = tid & 63, rq = tid >> 6;
    #pragma unroll
    for (int i = 0; i < 16; i++) {
        int rl = rq + i * 4;
        t[rl][cl] = in[(long)(k0 + rl) * 256 + n0 + cl];
    }
    __syncthreads();
    #pragma unroll
    for (int i = 0; i < 16; i++) {
        int nl = rq + i * 4;
        out[(long)(n0 + nl) * 256 + k0 + cl] = f2s(t[cl][nl]);
    }
}

// pack per-layer bias segments
__global__ __launch_bounds__(256) void packb_k(const float* __restrict__ a, const float* __restrict__ b,
                                               const float* __restrict__ c, float* __restrict__ y,
                                               int na, int nb, int nc)
{
    int l = blockIdx.y;
    int j = blockIdx.x * 256 + threadIdx.x;
    int ntot = na + nb + nc;
    if (j >= ntot) return;
    float v;
    if (j < na) v = a[l * na + j];
    else if (j < na + nb) v = b[l * nb + (j - na)];
    else v = c[l * nc + (j - na - nb)];
    y[(long)l * ntot + j] = v;
}

// ---------------- MFMA GEMM, 64x64 tile (4 waves, 2x2 MFMA each): C = A(fp32) @ Bt^T ----------------
__global__ __launch_bounds__(256) void mgemm_k(const float* __restrict__ A, int lda,
                                               const short* __restrict__ Bt,
                                               const float* __restrict__ bias,
                                               const float* __restrict__ resid,
                                               float* __restrict__ C,
                                               int M, int N, int K, int act)
{
    __shared__ __align__(16) short As[2560];   // 64 rows x 40 (32 used)
    __shared__ __align__(16) short Bs[2560];
    int tid = threadIdx.x;
    int wave = tid >> 6, lane = tid & 63;
    int wm = wave >> 1, wn = wave & 1;
    int quad = lane >> 4, l15 = lane & 15;
    int m0 = blockIdx.y * 64, n0 = blockIdx.x * 64;
    int srow = tid >> 2, skc = (tid & 3) << 3;
    f4 acc[2][2];
    #pragma unroll
    for (int i = 0; i < 2; i++) { acc[i][0] = (f4){0.f,0.f,0.f,0.f}; acc[i][1] = (f4){0.f,0.f,0.f,0.f}; }
    short8 aR, bR;
    auto loadAB = [&](int kt) {
        int gm = m0 + srow;
        short8 pk = {0, 0, 0, 0, 0, 0, 0, 0};
        if (gm < M) {
            const float4* ap = (const float4*)(A + (long)gm * lda + kt + skc);
            float4 v0 = ap[0], v1 = ap[1];
            pk[0] = f2s(v0.x); pk[1] = f2s(v0.y); pk[2] = f2s(v0.z); pk[3] = f2s(v0.w);
            pk[4] = f2s(v1.x); pk[5] = f2s(v1.y); pk[6] = f2s(v1.z); pk[7] = f2s(v1.w);
        }
        aR = pk;
        int gn = n0 + srow;
        short8 pb = {0, 0, 0, 0, 0, 0, 0, 0};
        if (gn < N) pb = *(const short8*)&Bt[(long)gn * K + kt + skc];
        bR = pb;
    };
    loadAB(0);
    for (int kt = 0; kt < K; kt += 32) {
        *(short8*)&As[srow * 40 + skc] = aR;
        *(short8*)&Bs[srow * 40 + skc] = bR;
        __syncthreads();
        if (kt + 32 < K) loadAB(kt + 32);
        short8 af[2], bf[2];
        #pragma unroll
        for (int mi = 0; mi < 2; mi++) af[mi] = *(const short8*)&As[(wm * 32 + mi * 16 + l15) * 40 + (quad << 3)];
        #pragma unroll
        for (int ni = 0; ni < 2; ni++) bf[ni] = *(const short8*)&Bs[(wn * 32 + ni * 16 + l15) * 40 + (quad << 3)];
        #pragma unroll
        for (int mi = 0; mi < 2; mi++)
            #pragma unroll
            for (int ni = 0; ni < 2; ni++)
                acc[mi][ni] = __builtin_amdgcn_mfma_f32_16x16x32_bf16(af[mi], bf[ni], acc[mi][ni], 0, 0, 0);
        __syncthreads();
    }
    #pragma unroll
    for (int mi = 0; mi < 2; mi++) {
        int row = m0 + wm * 32 + mi * 16 + quad * 4;
        #pragma unroll
        for (int ni = 0; ni < 2; ni++) {
            int col = n0 + wn * 32 + ni * 16 + l15;
            if (col >= N) continue;
            float bv = bias[col];
            #pragma unroll
            for (int r = 0; r < 4; r++) {
                int rr = row + r;
                if (rr >= M) continue;
                float v = acc[mi][ni][r] + bv;
                if (act == 2) v = 0.5f * v * (1.f + erff(v * 0.70710678118654752f));
                if (resid) v += resid[(long)rr * N + col];
                C[(long)rr * N + col] = v;
            }
        }
    }
}

// ---------------- MFMA conv 3x3 s2 p1, tap-major K, bf16-pair input, BK=64 ----------------
// Flattened grid (nSpatial<<ctshift, 1, ncb) with XCD-chunk bijective swizzle.
// Each K-step covers 64 k (one tap for Cin=64, half for 128, quarter for 256): 8 MFMAs per barrier pair.
// LDS row stride 72 shorts (144B = 9x16B). mode 1: f32 spatial-major out. mode 2: bf16-pair out + GN stats.
__global__ __launch_bounds__(256) void mconv_k(const unsigned* __restrict__ in,
                                               const short* __restrict__ wgt,
                                               const float* __restrict__ bias,
                                               float* __restrict__ out,
                                               float2* __restrict__ parts,
                                               int c5m, int Cout, int Hin, int Win,
                                               int mode, int cpg, int ctshift,
                                               long istride, long ostride)
{
    // bijective XCD-chunk swizzle (m204): lin -> wgid, couttile fastest
    int lin = blockIdx.x + gridDim.x * blockIdx.z;
    int nwgT = gridDim.x * gridDim.z;
    int xcd = lin & 7, seq = lin >> 3;
    int qd = nwgT >> 3, rd = nwgT & 7;
    int wgid = (xcd < rd ? xcd * (qd + 1) : rd * (qd + 1) + (xcd - rd) * qd) + seq;
    int cam = wgid / gridDim.x;
    int rem = wgid - cam * gridDim.x;
    int couttile = rem & ((1 << ctshift) - 1);
    int spatial = rem >> ctshift;

    in  += (long)cam * istride;
    const int Hout = Hin >> 1, Wout = Win >> 1;
    const int HWo = Hout * Wout;
    const int HW = Hin * Win;
    const int Ktot = 288 << c5m;       // 9*Cin
    const int ch_sh = c5m - 1;         // 64-chunk shift (Cin/64 chunks per tap)
    const int ch_m  = (1 << ch_sh) - 1;
    const int nsteps = 9 << ch_sh;
    __shared__ __align__(16) short As[4608];   // 64 rows x 72 (64 used)
    __shared__ __align__(16) short Bs[4608];
    __shared__ float2 sred[16][2];             // [quad-group][wn] = (s, s2)
    int tid = threadIdx.x;
    int wave = tid >> 6, lane = tid & 63;
    int wm = wave >> 1, wn = wave & 1;
    int quad = lane >> 4, l15 = lane & 15;
    int m0 = couttile << 6, n0 = spatial << 6;
    int nn = tid & 63;
    int kp0 = tid >> 6;
    int p = n0 + nn;
    int pok = p < HWo;
    int pc = pok ? p : (HWo - 1);
    int ho = pc / Wout, wo = pc - ho * Wout;
    int hb = ho * 2 - 1, wb = wo * 2 - 1;

    f4 acc[2][2];
    #pragma unroll
    for (int i = 0; i < 2; i++) { acc[i][0] = (f4){0.f,0.f,0.f,0.f}; acc[i][1] = (f4){0.f,0.f,0.f,0.f}; }

    int srow = tid >> 2, skc = (tid & 3) << 4;     // 16-short granule per thread
    short8 aR0, aR1;
    unsigned bR[8];
    auto loadA = [&](int s) {
        const short* ap = &wgt[(long)(m0 + srow) * Ktot + (s << 6) + skc];
        aR0 = *(const short8*)ap;
        aR1 = *(const short8*)(ap + 8);
    };
    // thread owns 8 CONTIGUOUS channel-pairs kp = kp0*8 .. kp0*8+7 -> two b128 LDS writes
    auto loadB = [&](int s) {
        int t = s >> ch_sh;
        int kh3 = (t * 11) >> 5;           // t/3 for t in 0..8
        int kw3 = t - kh3 * 3;
        int y = hb + kh3, x = wb + kw3;
        bool okp = pok && ((unsigned)y < (unsigned)Hin) && ((unsigned)x < (unsigned)Win);
        int base = (((s & ch_m) << 5) + (kp0 << 3)) * HW + y * Win + x;
        #pragma unroll
        for (int i = 0; i < 8; i++) {
            unsigned v = 0;
            if (okp) v = in[base + i * HW];
            bR[i] = v;
        }
    };

    loadA(0); loadB(0);
    for (int s = 0; s < nsteps; s++) {
        *(short8*)&As[srow * 72 + skc]     = aR0;
        *(short8*)&As[srow * 72 + skc + 8] = aR1;
        *(uint4*)&Bs[nn * 72 + (kp0 << 4)]     = *(uint4*)&bR[0];
        *(uint4*)&Bs[nn * 72 + (kp0 << 4) + 8] = *(uint4*)&bR[4];
        __syncthreads();
        if (s + 1 < nsteps) { loadA(s + 1); loadB(s + 1); }
        #pragma unroll
        for (int kh = 0; kh < 2; kh++) {
            short8 af[2], bf[2];
            #pragma unroll
            for (int mi = 0; mi < 2; mi++)
                af[mi] = *(const short8*)&As[(wm * 32 + mi * 16 + l15) * 72 + kh * 32 + (quad << 3)];
            #pragma unroll
            for (int ni = 0; ni < 2; ni++)
                bf[ni] = *(const short8*)&Bs[(wn * 32 + ni * 16 + l15) * 72 + kh * 32 + (quad << 3)];
            #pragma unroll
            for (int mi = 0; mi < 2; mi++)
                #pragma unroll
                for (int ni = 0; ni < 2; ni++)
                    acc[mi][ni] = __builtin_amdgcn_mfma_f32_16x16x32_bf16(af[mi], bf[ni], acc[mi][ni], 0, 0, 0);
        }
        __syncthreads();
    }

    if (mode == 1) {
        float* outf = out + (long)cam * ostride;
        #pragma unroll
        for (int mi = 0; mi < 2; mi++) {
            int mbase = m0 + wm * 32 + mi * 16 + quad * 4;
            #pragma unroll
            for (int ni = 0; ni < 2; ni++) {
                int n = n0 + wn * 32 + ni * 16 + l15;
                if (n >= HWo) continue;
                #pragma unroll
                for (int r = 0; r < 4; r++) {
                    int m = mbase + r;
                    outf[(long)n * Cout + m] = acc[mi][ni][r] + bias[m];
                }
            }
        }
    } else {
        unsigned* outp = (unsigned*)out + (long)cam * ostride;
        float ssum[2] = {0.f, 0.f}, qsum[2] = {0.f, 0.f};
        #pragma unroll
        for (int mi = 0; mi < 2; mi++) {
            int mbase = m0 + wm * 32 + mi * 16 + quad * 4;
            float b0 = bias[mbase], b1 = bias[mbase + 1], b2 = bias[mbase + 2], b3 = bias[mbase + 3];
            #pragma unroll
            for (int ni = 0; ni < 2; ni++) {
                int n = n0 + wn * 32 + ni * 16 + l15;
                if (n >= HWo) continue;
                float v0 = acc[mi][ni][0] + b0;
                float v1 = acc[mi][ni][1] + b1;
                float v2 = acc[mi][ni][2] + b2;
                float v3 = acc[mi][ni][3] + b3;
                long cp = (long)(mbase >> 1) * HWo + n;
                outp[cp]       = packbf(v0, v1);
                outp[cp + HWo] = packbf(v2, v3);
                ssum[mi] += v0 + v1 + v2 + v3;
                qsum[mi] += v0 * v0 + v1 * v1 + v2 * v2 + v3 * v3;
            }
        }
        #pragma unroll
        for (int mi = 0; mi < 2; mi++) {
            #pragma unroll
            for (int off = 1; off < 16; off <<= 1) {
                ssum[mi] += __shfl_xor(ssum[mi], off, 16);
                qsum[mi] += __shfl_xor(qsum[mi], off, 16);
            }
        }
        if (l15 == 0) {
            #pragma unroll
            for (int mi = 0; mi < 2; mi++)
                sred[wm * 8 + mi * 4 + quad][wn] = make_float2(ssum[mi], qsum[mi]);
        }
        __syncthreads();
        int ng = 64 / cpg;          // groups covered by this block
        int qpg = cpg >> 2;         // quad-groups per group
        if (tid < ng) {
            float s = 0.f, q = 0.f;
            for (int u = 0; u < qpg; u++) {
                float2 a = sred[(tid * cpg >> 2) + u][0];
                float2 b = sred[(tid * cpg >> 2) + u][1];
                s += a.x + b.x; q += a.y + b.y;
            }
            int gabs = m0 / cpg + tid;
            parts[((long)cam * 32 + gabs) * 1400 + spatial] = make_float2(s, q);
        }
    }
}

// ---------------- conv0 fused MFMA: fp32 image gather -> bf16 MFMA (K=32) -> pair out + GN stats ------
__global__ __launch_bounds__(256) void conv0f_k(const float* __restrict__ img,
                                                const short* __restrict__ wgt,
                                                const float* __restrict__ bias,
                                                unsigned* __restrict__ outp,
                                                float2* __restrict__ parts,
                                                long istride, long ostride)
{
    img  += (long)blockIdx.z * istride;
    outp += (long)blockIdx.z * ostride;
    const int HWo = 89600;
    __shared__ __align__(16) short As[2560];
    __shared__ __align__(16) short Bs[2560];
    __shared__ float2 sred[32][2];
    int tid = threadIdx.x;
    int wave = tid >> 6, lane = tid & 63;
    int wm = wave >> 1, wn = wave & 1;
    int quad = lane >> 4, l15 = lane & 15;
    int n0 = blockIdx.x * 64;
    int srow = tid >> 2, skc = (tid & 3) << 3;
    *(short8*)&As[srow * 40 + skc] = *(const short8*)&wgt[srow * 32 + skc];
    {
        int p = n0 + srow;
        int ho = p / 400, wo = p - ho * 400;
        int hb = ho * 2 - 1, wb = wo * 2 - 1;
        short8 pb;
        #pragma unroll
        for (int j = 0; j < 8; j++) {
            int k = skc + j;
            float v = 0.f;
            if (k < 27) {
                int ci = (k < 9) ? 0 : (k < 18 ? 1 : 2);
                int t = k - ci * 9;
                int kh = (t < 3) ? 0 : (t < 6 ? 1 : 2);
                int kw = t - kh * 3;
                int y = hb + kh, x = wb + kw;
                if ((unsigned)y < 448u && (unsigned)x < 800u)
                    v = img[ci * 358400 + y * 800 + x];
            }
            pb[j] = f2s(v);
        }
        *(short8*)&Bs[srow * 40 + skc] = pb;
    }
    __syncthreads();
    f4 acc[2][2];
    #pragma unroll
    for (int i = 0; i < 2; i++) { acc[i][0] = (f4){0.f,0.f,0.f,0.f}; acc[i][1] = (f4){0.f,0.f,0.f,0.f}; }
    short8 af[2], bf[2];
    #pragma unroll
    for (int mi = 0; mi < 2; mi++) af[mi] = *(const short8*)&As[(wm * 32 + mi * 16 + l15) * 40 + (quad << 3)];
    #pragma unroll
    for (int ni = 0; ni < 2; ni++) bf[ni] = *(const short8*)&Bs[(wn * 32 + ni * 16 + l15) * 40 + (quad << 3)];
    #pragma unroll
    for (int mi = 0; mi < 2; mi++)
        #pragma unroll
        for (int ni = 0; ni < 2; ni++)
            acc[mi][ni] = __builtin_amdgcn_mfma_f32_16x16x32_bf16(af[mi], bf[ni], acc[mi][ni], 0, 0, 0);
    #pragma unroll
    for (int mi = 0; mi < 2; mi++) {
        int mbase = wm * 32 + mi * 16 + quad * 4;
        float b0 = bias[mbase], b1 = bias[mbase + 1], b2 = bias[mbase + 2], b3 = bias[mbase + 3];
        float s0 = 0.f, q0 = 0.f, s1 = 0.f, q1 = 0.f;
        #pragma unroll
        for (int ni = 0; ni < 2; ni++) {
            int n = n0 + wn * 32 + ni * 16 + l15;
            float v0 = acc[mi][ni][0] + b0;
            float v1 = acc[mi][ni][1] + b1;
            float v2 = acc[mi][ni][2] + b2;
            float v3 = acc[mi][ni][3] + b3;
            long cp = (long)(mbase >> 1) * HWo + n;
            outp[cp]       = packbf(v0, v1);
            outp[cp + HWo] = packbf(v2, v3);
            s0 += v0 + v1; q0 += v0 * v0 + v1 * v1;
            s1 += v2 + v3; q1 += v2 * v2 + v3 * v3;
        }
        #pragma unroll
        for (int off = 1; off < 16; off <<= 1) {
            s0 += __shfl_xor(s0, off, 16); q0 += __shfl_xor(q0, off, 16);
            s1 += __shfl_xor(s1, off, 16); q1 += __shfl_xor(q1, off, 16);
        }
        if (l15 == 0) {
            int pi = wm * 16 + mi * 8 + quad * 2;
            sred[pi][wn]     = make_float2(s0, q0);
            sred[pi + 1][wn] = make_float2(s1, q1);
        }
    }
    __syncthreads();
    if (tid < 32) {
        float2 a = sred[tid][0], b = sred[tid][1];
        parts[((long)blockIdx.z * 32 + tid) * 1400 + blockIdx.x] = make_float2(a.x + b.x, a.y + b.y);
    }
}

// ---------------- GN finalize: reduce per-block partials -> mean/rstd ----------------
__global__ __launch_bounds__(256) void gnfin_k(const float2* __restrict__ parts,
                                               float* __restrict__ gnstats, int nx, float invN)
{
    int g = blockIdx.x, cam = blockIdx.y;
    const float2* pb = parts + ((long)cam * 32 + g) * 1400;
    float s = 0.f, q = 0.f;
    for (int i = threadIdx.x; i < nx; i += 256) {
        float2 v = pb[i];
        s += v.x; q += v.y;
    }
    __shared__ float rs[256], rq[256];
    rs[threadIdx.x] = s; rq[threadIdx.x] = q;
    __syncthreads();
    for (int o = 128; o > 0; o >>= 1) {
        if (threadIdx.x < o) { rs[threadIdx.x] += rs[threadIdx.x + o]; rq[threadIdx.x] += rq[threadIdx.x + o]; }
        __syncthreads();
    }
    if (threadIdx.x == 0) {
        float mean = rs[0] * invN;
        float var  = rq[0] * invN - mean * mean;
        gnstats[(cam * 32 + g) * 2]     = mean;
        gnstats[(cam * 32 + g) * 2 + 1] = rsqrtf(var + EPS);
    }
}

// ---------------- in-place GN apply + ReLU on bf16-pair buffer ----------------
__global__ __launch_bounds__(256) void pairapply_k(unsigned* __restrict__ x,
                                                   const float* __restrict__ gamma,
                                                   const float* __restrict__ beta,
                                                   const float* __restrict__ gnstats,
                                                   int HW, int cpg, long zstride)
{
    x       += (long)blockIdx.z * zstride;
    gnstats += (long)blockIdx.z * 64;
    int idx4 = (blockIdx.x * 256 + threadIdx.x) * 4;   // HW%4==0 -> all in one pair-row
    int cp = idx4 / HW;
    int c0 = cp * 2;
    int g = c0 / cpg;
    float mean = gnstats[g * 2], rstd = gnstats[g * 2 + 1];
    float sa = rstd * gamma[c0],     ba = beta[c0]     - mean * sa;
    float sb = rstd * gamma[c0 + 1], bb = beta[c0 + 1] - mean * sb;
    uint4 v = *(uint4*)&x[idx4];
    unsigned* vp = (unsigned*)&v;
    #pragma unroll
    for (int j = 0; j < 4; j++) {
        float lo = fmaxf(bflo(vp[j]) * sa + ba, 0.f);
        float hi = fmaxf(bfhi(vp[j]) * sb + bb, 0.f);
        vp[j] = packbf(lo, hi);
    }
    *(uint4*)&x[idx4] = v;
}

// ---------------- GroupNorm for (1400 x 256) spatial-major, batched over cams (grid.y) ----------------
__global__ __launch_bounds__(256) void gn_stats_hwd_k(const float* __restrict__ x, float* __restrict__ stats)
{
    x += (long)blockIdx.y * 358400;
    stats += blockIdx.y * 64;
    int g = blockIdx.x;  // 32 groups
    float s = 0.f, s2 = 0.f;
    for (int i = threadIdx.x; i < 1400 * 8; i += blockDim.x) {
        int p = i >> 3, c = g * 8 + (i & 7);
        float v = x[(long)p * 256 + c];
        s += v; s2 += v * v;
    }
    __shared__ float rs[256], rq[256];
    rs[threadIdx.x] = s; rq[threadIdx.x] = s2;
    __syncthreads();
    for (int o = 128; o > 0; o >>= 1) {
        if (threadIdx.x < o) { rs[threadIdx.x] += rs[threadIdx.x + o]; rq[threadIdx.x] += rq[threadIdx.x + o]; }
        __syncthreads();
    }
    if (threadIdx.x == 0) {
        float mean = rs[0] / 11200.f;
        float var  = rq[0] / 11200.f - mean * mean;
        stats[g * 2]     = mean;
        stats[g * 2 + 1] = rsqrtf(var + EPS);
    }
}

__global__ __launch_bounds__(256) void gn_apply_hwd_k(float* __restrict__ x,
                                                      const float* __restrict__ gamma,
                                                      const float* __restrict__ beta,
                                                      const float* __restrict__ stats,
                                                      int relu)
{
    x += (long)blockIdx.y * 358400;
    stats += blockIdx.y * 64;
    long i4 = ((long)blockIdx.x * 256 + threadIdx.x) * 4;  // grid.x = 350 -> exact
    int c = (int)(i4 & 255);
    int g = c >> 3;
    float4 v  = *(float4*)&x[i4];
    float4 gm = *(const float4*)&gamma[c];
    float4 bt = *(const float4*)&beta[c];
    float m = stats[g * 2], rs = stats[g * 2 + 1];
    v.x = (v.x - m) * rs * gm.x + bt.x;
    v.y = (v.y - m) * rs * gm.y + bt.y;
    v.z = (v.z - m) * rs * gm.z + bt.z;
    v.w = (v.w - m) * rs * gm.w + bt.w;
    if (relu) {
        v.x = fmaxf(v.x, 0.f); v.y = fmaxf(v.y, 0.f);
        v.z = fmaxf(v.z, 0.f); v.w = fmaxf(v.w, 0.f);
    }
    *(float4*)&x[i4] = v;
}

// ---------------- projection of BEV grid ----------------
__global__ __launch_bounds__(256) void project_k(const float* __restrict__ Kin,
                                                 const float* __restrict__ Ein,
                                                 float* __restrict__ refp, int* __restrict__ valid)
{
    int idx = blockIdx.x * blockDim.x + threadIdx.x;
    if (idx >= 2500 * 6) return;
    int c = idx % 6, q = idx / 6;
    int i = q / 50, j = q % 50;
    float px = (i - 24.5f) * 0.5f;
    float py = (j - 24.5f) * 0.5f;
    const float* E = Ein + c * 16;
    float pc[4];
    #pragma unroll
    for (int r = 0; r < 4; r++)
        pc[r] = E[r * 4 + 0] * px + E[r * 4 + 1] * py + E[r * 4 + 3];
    const float* Km = Kin + c * 9;
    float pix[3];
    #pragma unroll
    for (int r = 0; r < 3; r++)
        pix[r] = Km[r * 3 + 0] * pc[0] + Km[r * 3 + 1] * pc[1] + Km[r * 3 + 2] * pc[2];
    float z = fmaxf(pix[2], 1e-5f);
    float u = pix[0] / z, v = pix[1] / z;
    int ok = (pc[2] > 0.f) && (u >= 0.f) && (u < 800.f) && (v >= 0.f) && (v < 448.f);
    refp[(long)idx * 2 + 0] = 2.f * u / 799.f - 1.f;
    refp[(long)idx * 2 + 1] = 2.f * v / 447.f - 1.f;
    valid[idx] = ok;
}

// ---------------- misc elementwise ----------------
__global__ __launch_bounds__(256) void qinit_k(const float* __restrict__ a, const float* __restrict__ b,
                                               float* __restrict__ y)
{
    int i = blockIdx.x * blockDim.x + threadIdx.x;
    if (i >= 2500 * 256) return;
    y[i] = a[i] + b[i];
}

// ---------------- LayerNorm ----------------
__global__ __launch_bounds__(256) void ln_k(const float* __restrict__ x,
                                            const float* __restrict__ g, const float* __restrict__ b,
                                            float* __restrict__ y)
{
    int row  = blockIdx.x * 4 + (threadIdx.x >> 6);
    int lane = threadIdx.x & 63;
    if (row >= 2500) return;
    const float* xp = x + (long)row * 256;
    float v[4];
    #pragma unroll
    for (int i = 0; i < 4; i++) v[i] = xp[lane + 64 * i];
    float s  = v[0] + v[1] + v[2] + v[3];
    float s2 = v[0] * v[0] + v[1] * v[1] + v[2] * v[2] + v[3] * v[3];
    #pragma unroll
    for (int o = 32; o > 0; o >>= 1) { s += __shfl_xor(s, o, 64); s2 += __shfl_xor(s2, o, 64); }
    float mean = s * (1.f / 256.f);
    float var  = s2 * (1.f / 256.f) - mean * mean;
    float rstd = rsqrtf(var + EPS);
    #pragma unroll
    for (int i = 0; i < 4; i++) {
        int cc = lane + 64 * i;
        y[(long)row * 256 + cc] = (v[i] - mean) * rstd * g[cc] + b[cc];
    }
}

// ---------------- MFMA flash-2 MHA with split-K (packed-QKV aware: row stride ld) ----------------
__global__ __launch_bounds__(256) void flash2_k(const float* __restrict__ Q,
                                                const float* __restrict__ K,
                                                const float* __restrict__ V,
                                                int ld,
                                                float* __restrict__ Opart,   // (S,2500,256)
                                                float* __restrict__ MLpart)  // (S,2500,8,2)
{
    const int h  = blockIdx.y;
    const int q0 = blockIdx.x * 64;
    const int sp = blockIdx.z;
    const int kstart = sp * FL_KEYS, kend = kstart + FL_KEYS;
    const int tid = threadIdx.x;
    const int wave = tid >> 6, lane = tid & 63;
    const int quad = lane >> 4, l15 = lane & 15;
    __shared__ __align__(16) short Qs[64 * 40];
    __shared__ __align__(16) short Ks[64 * 40];
    __shared__ __align__(16) short Vt[32 * 72];
    __shared__ __align__(16) short Ps[64 * 72];
    const float scale = 0.17677669529663687f;
    {
        int row = tid >> 2, kc = (tid & 3) << 3;
        int qi = q0 + row;
        short8 pk = {0, 0, 0, 0, 0, 0, 0, 0};
        if (qi < 2500) {
            const float4* qp = (const float4*)(Q + (long)qi * ld + h * 32 + kc);
            float4 v0 = qp[0], v1 = qp[1];
            pk[0] = f2s(v0.x * scale); pk[1] = f2s(v0.y * scale); pk[2] = f2s(v0.z * scale); pk[3] = f2s(v0.w * scale);
            pk[4] = f2s(v1.x * scale); pk[5] = f2s(v1.y * scale); pk[6] = f2s(v1.z * scale); pk[7] = f2s(v1.w * scale);
        }
        *(short8*)&Qs[row * 40 + kc] = pk;
    }
    __syncthreads();
    short8 aq = *(const short8*)&Qs[(wave * 16 + l15) * 40 + (quad << 3)];
    float m[4], l[4];
    f4 oacc[2];
    #pragma unroll
    for (int r = 0; r < 4; r++) { m[r] = -INFINITY; l[r] = 0.f; }
    oacc[0] = (f4){0.f, 0.f, 0.f, 0.f};
    oacc[1] = (f4){0.f, 0.f, 0.f, 0.f};
    for (int kb = kstart; kb < kend; kb += 64) {
        __syncthreads();
        {
            int row = tid >> 2, kc = (tid & 3) << 3;
            int ki = kb + row;
            short8 pk = {0, 0, 0, 0, 0, 0, 0, 0};
            float vv[8] = {0.f, 0.f, 0.f, 0.f, 0.f, 0.f, 0.f, 0.f};
            if (ki < kend) {
                const float4* kp = (const float4*)(K + (long)ki * ld + h * 32 + kc);
                float4 a0 = kp[0], a1 = kp[1];
                pk[0] = f2s(a0.x); pk[1] = f2s(a0.y); pk[2] = f2s(a0.z); pk[3] = f2s(a0.w);
                pk[4] = f2s(a1.x); pk[5] = f2s(a1.y); pk[6] = f2s(a1.z); pk[7] = f2s(a1.w);
                const float4* vp = (const float4*)(V + (long)ki * ld + h * 32 + kc);
                float4 b0 = vp[0], b1 = vp[1];
                vv[0] = b0.x; vv[1] = b0.y; vv[2] = b0.z; vv[3] = b0.w;
                vv[4] = b1.x; vv[5] = b1.y; vv[6] = b1.z; vv[7] = b1.w;
            }
            *(short8*)&Ks[row * 40 + kc] = pk;
            #pragma unroll
            for (int j = 0; j < 8; j++) Vt[(kc + j) * 72 + row] = f2s(vv[j]);
        }
        __syncthreads();
        f4 sa[4];
        #pragma unroll
        for (int ni = 0; ni < 4; ni++) {
            short8 bk = *(const short8*)&Ks[(ni * 16 + l15) * 40 + (quad << 3)];
            sa[ni] = __builtin_amdgcn_mfma_f32_16x16x32_bf16(aq, bk, (f4){0.f, 0.f, 0.f, 0.f}, 0, 0, 0);
        }
        float sv[4][4];
        #pragma unroll
        for (int ni = 0; ni < 4; ni++) {
            bool colok = (kb + ni * 16 + l15) < kend;
            #pragma unroll
            for (int r = 0; r < 4; r++) sv[ni][r] = colok ? sa[ni][r] : -1e30f;
        }
        float p[4][4];
        #pragma unroll
        for (int r = 0; r < 4; r++) {
            float rm = fmaxf(fmaxf(sv[0][r], sv[1][r]), fmaxf(sv[2][r], sv[3][r]));
            #pragma unroll
            for (int off = 1; off < 16; off <<= 1) rm = fmaxf(rm, __shfl_xor(rm, off, 16));
            float mn = fmaxf(m[r], rm);
            float alpha = __expf(m[r] - mn);
            float rs = 0.f;
            #pragma unroll
            for (int ni = 0; ni < 4; ni++) { p[ni][r] = __expf(sv[ni][r] - mn); rs += p[ni][r]; }
            #pragma unroll
            for (int off = 1; off < 16; off <<= 1) rs += __shfl_xor(rs, off, 16);
            l[r] = l[r] * alpha + rs;
            oacc[0][r] *= alpha; oacc[1][r] *= alpha;
            m[r] = mn;
        }
        #pragma unroll
        for (int ni = 0; ni < 4; ni++)
            #pragma unroll
            for (int r = 0; r < 4; r++)
                Ps[(wave * 16 + quad * 4 + r) * 72 + ni * 16 + l15] = f2s(p[ni][r]);
        #pragma unroll
        for (int kh = 0; kh < 2; kh++) {
            short8 ap = *(const short8*)&Ps[(wave * 16 + l15) * 72 + kh * 32 + (quad << 3)];
            #pragma unroll
            for (int ni = 0; ni < 2; ni++) {
                short8 bv = *(const short8*)&Vt[(ni * 16 + l15) * 72 + kh * 32 + (quad << 3)];
                oacc[ni] = __builtin_amdgcn_mfma_f32_16x16x32_bf16(ap, bv, oacc[ni], 0, 0, 0);
            }
        }
    }
    #pragma unroll
    for (int r = 0; r < 4; r++) {
        int qi = q0 + wave * 16 + quad * 4 + r;
        if (qi < 2500) {
            long ob = ((long)sp * 2500 + qi) * 256 + h * 32;
            Opart[ob + l15]      = oacc[0][r];
            Opart[ob + 16 + l15] = oacc[1][r];
            if (l15 == 0) {
                long mb = (((long)sp * 2500 + qi) * 8 + h) * 2;
                MLpart[mb]     = m[r];
                MLpart[mb + 1] = l[r];
            }
        }
    }
}

__global__ __launch_bounds__(256) void flashmerge_k(const float* __restrict__ Opart,
                                                    const float* __restrict__ MLpart,
                                                    float* __restrict__ O)
{
    int q = blockIdx.x, d = threadIdx.x;
    int h = d >> 5;
    float ms[FL_SPLITS], ls[FL_SPLITS];
    float mg = -INFINITY;
    #pragma unroll
    for (int s = 0; s < FL_SPLITS; s++) {
        long mb = (((long)s * 2500 + q) * 8 + h) * 2;
        ms[s] = MLpart[mb];
        ls[s] = MLpart[mb + 1];
        mg = fmaxf(mg, ms[s]);
    }
    float lsum = 0.f, osum = 0.f;
    #pragma unroll
    for (int s = 0; s < FL_SPLITS; s++) {
        float w = __expf(ms[s] - mg);
        lsum += ls[s] * w;
        osum += Opart[((long)s * 2500 + q) * 256 + d] * w;
    }
    O[(long)q * 256 + d] = osum / lsum;
}

// ---------------- masked softmax over 192 deformable-attn logits (row stride ld) ----------------
__global__ __launch_bounds__(64) void scasoftmax_k(float* __restrict__ logits, int ld,
                                                   const int* __restrict__ valid)
{
    int q = blockIdx.x, lane = threadIdx.x;
    float v[3]; int mk[3];
    #pragma unroll
    for (int i = 0; i < 3; i++) {
        int idx = i * 64 + lane;
        int c = idx >> 5;
        mk[i] = valid[q * 6 + c];
        v[i] = mk[i] ? logits[(long)q * ld + idx] : -1e30f;
    }
    float mx = fmaxf(fmaxf(v[0], v[1]), v[2]);
    #pragma unroll
    for (int o = 32; o > 0; o >>= 1) mx = fmaxf(mx, __shfl_xor(mx, o, 64));
    float e[3]; float s = 0.f;
    #pragma unroll
    for (int i = 0; i < 3; i++) { e[i] = expf(v[i] - mx); s += e[i]; }
    #pragma unroll
    for (int o = 32; o > 0; o >>= 1) s += __shfl_xor(s, o, 64);
    float inv = 1.f / s;
    #pragma unroll
    for (int i = 0; i < 3; i++)
        logits[(long)q * ld + i * 64 + lane] = mk[i] ? e[i] * inv : 0.f;
}

// ---------------- deformable sampling (offs/wts with row stride ld); one setup pass for all cams ------
__global__ __launch_bounds__(256) void sample_k(const float* __restrict__ vals,
                                                const float* __restrict__ offs, int ld,
                                                const float* __restrict__ wts,
                                                const float* __restrict__ refp,
                                                const int* __restrict__ valid,
                                                float* __restrict__ out)
{
    int q = blockIdx.x, d = threadIdx.x;
    __shared__ float s_cw[6][32][4];
    __shared__ int   s_idx[6][32][4];
    if (d < 192) {
        int c = d >> 5, pt = d & 31;
        if (valid[q * 6 + c]) {
            float ox = offs[(long)q * ld + (c * 32 + pt) * 2 + 0];
            float oy = offs[(long)q * ld + (c * 32 + pt) * 2 + 1];
            float px = refp[(q * 6 + c) * 2 + 0] + ox * (2.f / 49.f);
            float py = refp[(q * 6 + c) * 2 + 1] + oy * (2.f / 27.f);
            float gx = (px + 1.f) * 0.5f * 49.f;
            float gy = (py + 1.f) * 0.5f * 27.f;
            float x0f = floorf(gx), y0f = floorf(gy);
            float wx = gx - x0f, wy = gy - y0f;
            int x0 = (int)x0f, y0 = (int)y0f;
            float wgt = wts[(long)q * ld + c * 32 + pt];
            float cw[4] = {(1.f - wx) * (1.f - wy), wx * (1.f - wy), (1.f - wx) * wy, wx * wy};
            const int dxs[4] = {0, 1, 0, 1};
            const int dys[4] = {0, 0, 1, 1};
            #pragma unroll
            for (int k2 = 0; k2 < 4; k2++) {
                int xi = x0 + dxs[k2], yi = y0 + dys[k2];
                bool ok = (xi >= 0) && (xi < 50) && (yi >= 0) && (yi < 28);
                s_cw[c][pt][k2]  = ok ? cw[k2] * wgt : 0.f;
                s_idx[c][pt][k2] = ok ? (yi * 50 + xi) * 256 : 0;
            }
        }
    }
    __syncthreads();
    float acc = 0.f;
    for (int c = 0; c < 6; c++) {
        if (!valid[q * 6 + c]) continue;
        const float* vb = vals + (long)c * 358400 + d;
        for (int pt = 0; pt < 32; pt++) {
            #pragma unroll
            for (int k2 = 0; k2 < 4; k2++) {
                float cwv = s_cw[c][pt][k2];
                if (cwv != 0.f) acc += cwv * vb[s_idx[c][pt][k2]];
            }
        }
    }
    out[(long)q * 256 + d] = acc;
}

// =====================================================================================
extern "C" void kernel_launch(void* const* d_in, const int* in_sizes, int n_in,
                              void* d_out, int out_size, void* d_ws, size_t ws_size,
                              hipStream_t stream)
{
    const float* images = (const float*)d_in[0];
    const float* intr   = (const float*)d_in[1];
    const float* e2c    = (const float*)d_in[2];
    const float* bevq   = (const float*)d_in[3];
    const float* bevp   = (const float*)d_in[4];
    const float* bbw[5]    = {(const float*)d_in[5],  (const float*)d_in[9],  (const float*)d_in[13], (const float*)d_in[17], (const float*)d_in[21]};
    const float* bbb[5]    = {(const float*)d_in[6],  (const float*)d_in[10], (const float*)d_in[14], (const float*)d_in[18], (const float*)d_in[22]};
    const float* bbg[5]    = {(const float*)d_in[7],  (const float*)d_in[11], (const float*)d_in[15], (const float*)d_in[19], (const float*)d_in[23]};
    const float* bbbeta[5] = {(const float*)d_in[8],  (const float*)d_in[12], (const float*)d_in[16], (const float*)d_in[20], (const float*)d_in[24]};
    const float* sa_wq = (const float*)d_in[25]; const float* sa_bq = (const float*)d_in[26];
    const float* sa_wk = (const float*)d_in[27]; const float* sa_bk = (const float*)d_in[28];
    const float* sa_wv = (const float*)d_in[29]; const float* sa_bv = (const float*)d_in[30];
    const float* sa_wo = (const float*)d_in[31]; const float* sa_bo = (const float*)d_in[32];
    const float* ln1g = (const float*)d_in[33]; const float* ln1b = (const float*)d_in[34];
    const float* ln2g = (const float*)d_in[35]; const float* ln2b = (const float*)d_in[36];
    const float* ln3g = (const float*)d_in[37]; const float* ln3b = (const float*)d_in[38];
    const float* offw = (const float*)d_in[39]; const float* offb = (const float*)d_in[40];
    const float* wtw  = (const float*)d_in[41]; const float* wtb  = (const float*)d_in[42];
    const float* valw = (const float*)d_in[43]; const float* valb = (const float*)d_in[44];
    const float* outw = (const float*)d_in[45]; const float* outb = (const float*)d_in[46];
    const float* fw1  = (const float*)d_in[47]; const float* fb1  = (const float*)d_in[48];
    const float* fw2  = (const float*)d_in[49]; const float* fb2  = (const float*)d_in[50];

    // ---- pick camera-batch factor from available workspace (formula unchanged) ----
    auto needB = [](long ncb) -> unsigned long long {
        return (unsigned long long)(ncb * 8601600L + 6681600L) * 4ULL + 6307840ULL + (1 << 20);
    };
    int ncb = 1;
    if      ((unsigned long long)ws_size >= needB(6)) ncb = 6;
    else if ((unsigned long long)ws_size >= needB(3)) ncb = 3;
    else if ((unsigned long long)ws_size >= needB(2)) ncb = 2;

    // ---- workspace layout ----
    float* ws = (float*)d_ws;
    float* A     = ws; ws += (long)ncb * 5734400;  // pair-buffer ping; aliases: bQKV, OP, bOW
    float* Bu    = ws; ws += (long)ncb * 2867200;  // pair-buffer pong; aliases: valsb, MLp
    float* f3bH  = ws; ws += 2560000;              // feats3 (backbone) / ffn hidden (transformer)
    float* feats = ws; ws += 2150400;              // (6,1400,256) hwd; also GN parts (early backbone)
    float* qbuf  = ws; ws += 640000;
    float* xq    = ws; ws += 640000;
    float* bO    = ws; ws += 640000;
    float* refp  = ws; ws += 30016;
    int*   validb = (int*)ws; ws += 15040;
    float* stats = ws; ws += 384;
    float* gnst  = ws; ws += 3072;                 // per-group mean/rstd (ncb x 32 x 2)
    float* qkvb  = ws; ws += 1536;
    float* owb   = ws; ws += 1152;
    // bf16 weight buffers
    short* sb = (short*)ws;
    short* cw0b = sb; sb += 2048;                  // conv0 (64,32) padded, k = ci*9+t
    short* cw1b = sb; sb += 73728;                 // tap-major (128, 9*64)
    short* cw2b = sb; sb += 294912;                // tap-major (256, 9*128)
    short* cw3b = sb; sb += 589824;                // tap-major (256, 9*256)
    short* cw4b = sb; sb += 65536;
    short* qkvT = sb; sb += 393216;
    short* owT  = sb; sb += 131072;
    short* valT = sb; sb += 131072;
    short* outT = sb; sb += 131072;
    short* offwtT = sb; sb += 294912;
    short* f1T  = sb; sb += 524288;
    short* f2T  = sb; sb += 524288;
    // aliases
    float*  feats3 = f3bH;
    float*  bH     = f3bH;
    float*  bQKV   = A;
    float*  OP     = A + 1920000;
    float*  bOW    = A + 1920000;
    float*  valsb  = Bu;
    float*  MLp    = Bu + 2150400;
    unsigned* Bbf0 = (unsigned*)A;                 // pair ping (stride varies per stage)
    unsigned* Bbf1 = (unsigned*)Bu;                // pair pong
    float2* partsP = (float2*)feats;               // 6*32*1400 float2 = 2.15 MB (free until conv4)

    auto mgemm = [&](const float* Ain, int lda, const short* Bt, const float* bias, const float* resid,
                     float* C, int M, int N, int K, int act) {
        dim3 g((N + 63) / 64, (M + 63) / 64);
        mgemm_k<<<g, 256, 0, stream>>>(Ain, lda, Bt, bias, resid, C, M, N, K, act);
    };

    // ---- weight preprocessing ----
    wcast0_k<<<8, 256, 0, stream>>>(bbw[0], cw0b);
    wreord_k<<<(73728 + 255) / 256, 256, 0, stream>>>(bbw[1], cw1b, 64, 73728);
    wreord_k<<<(294912 + 255) / 256, 256, 0, stream>>>(bbw[2], cw2b, 128, 294912);
    wreord_k<<<(589824 + 255) / 256, 256, 0, stream>>>(bbw[3], cw3b, 256, 589824);
    wcast_k<<<(65536 + 255) / 256, 256, 0, stream>>>(bbw[4], cw4b, 65536);
    wtrans6_k<<<dim3(4, 4, 12), 256, 0, stream>>>(sa_wq, sa_wk, sa_wv, sa_wo, valw, outw,
                                                  qkvT, qkvT + 65536, qkvT + 131072, owT, valT, outT);
    wtrans_k<<<dim3(6, 4, 2), 256, 0, stream>>>(offw, offwtT,         256, 384,  147456);
    wtrans_k<<<dim3(3, 4, 2), 256, 0, stream>>>(wtw,  offwtT + 98304, 256, 192,  147456);
    wtrans_k<<<dim3(16, 4, 2), 256, 0, stream>>>(fw1, f1T, 256, 1024, 262144);
    wtrans_k<<<dim3(4, 16, 2), 256, 0, stream>>>(fw2, f2T, 1024, 256, 262144);
    packb_k<<<dim3(3, 2), 256, 0, stream>>>(sa_bq, sa_bk, sa_bv, qkvb, 256, 256, 256);
    packb_k<<<dim3(3, 2), 256, 0, stream>>>(offb, wtb, nullptr, owb, 384, 192, 0);

    // ---- projection of BEV grid ----
    project_k<<<(15000 + 255) / 256, 256, 0, stream>>>(intr, e2c, refp, validb);

    // ---- backbone (cam-batched; bf16-pair activations) ----
    for (int c0 = 0; c0 < 6; c0 += ncb) {
        const float* img = images + (long)c0 * 1075200;
        // conv0 fused MFMA -> pairs + stats
        conv0f_k<<<dim3(1400, 1, ncb), 256, 0, stream>>>(img, cw0b, bbb[0], Bbf0, partsP,
                                                         1075200L, 2867200L);
        gnfin_k<<<dim3(32, ncb), 256, 0, stream>>>(partsP, gnst, 1400, 1.f / 179200.f);
        pairapply_k<<<dim3(2800, 1, ncb), 256, 0, stream>>>(Bbf0, bbg[0], bbbeta[0], gnst, 89600, 2, 2867200L);
        // conv1 -> pairs + fused stats (flat grid 350*2, XCD-chunk swizzle)
        mconv_k<<<dim3(700, 1, ncb), 256, 0, stream>>>(Bbf0, cw1b, bbb[1], (float*)Bbf1, partsP,
                                                       1, 128, 224, 400, 2, 4, 1, 2867200L, 1433600L);
        gnfin_k<<<dim3(32, ncb), 256, 0, stream>>>(partsP, gnst, 350, 1.f / 89600.f);
        pairapply_k<<<dim3(1400, 1, ncb), 256, 0, stream>>>(Bbf1, bbg[1], bbbeta[1], gnst, 22400, 4, 1433600L);
        // conv2 -> pairs + fused stats (flat grid 88*4)
        mconv_k<<<dim3(352, 1, ncb), 256, 0, stream>>>(Bbf1, cw2b, bbb[2], (float*)Bbf0, partsP,
                                                       2, 256, 112, 200, 2, 8, 2, 1433600L, 716800L);
        gnfin_k<<<dim3(32, ncb), 256, 0, stream>>>(partsP, gnst, 88, 1.f / 44800.f);
        pairapply_k<<<dim3(700, 1, ncb), 256, 0, stream>>>(Bbf0, bbg[2], bbbeta[2], gnst, 5600, 8, 716800L);
        // conv3 -> f32 spatial-major feats3[cam] (flat grid 22*4)
        mconv_k<<<dim3(88, 1, ncb), 256, 0, stream>>>(Bbf0, cw3b, bbb[3], feats3 + (long)c0 * 358400, nullptr,
                                                      3, 256, 56, 100, 1, 0, 2, 716800L, 358400L);
    }
    // batched conv3-GN (+relu), conv4 as one 8400x256 GEMM, batched conv4-GN
    gn_stats_hwd_k<<<dim3(32, 6), 256, 0, stream>>>(feats3, stats);
    gn_apply_hwd_k<<<dim3(350, 6), 256, 0, stream>>>(feats3, bbg[3], bbbeta[3], stats, 1);
    mgemm(feats3, 256, cw4b, bbb[4], nullptr, feats, 8400, 256, 256, 0);
    gn_stats_hwd_k<<<dim3(32, 6), 256, 0, stream>>>(feats, stats);
    gn_apply_hwd_k<<<dim3(350, 6), 256, 0, stream>>>(feats, bbg[4], bbbeta[4], stats, 0);

    // ---- transformer ----
    qinit_k<<<2500, 256, 0, stream>>>(bevq, bevp, qbuf);

    for (int l = 0; l < 2; l++) {
        long o1 = (long)l * 256;

        // self-attention (fused QKV projection: 2500 x 768)
        ln_k<<<625, 256, 0, stream>>>(qbuf, ln1g + o1, ln1b + o1, xq);
        mgemm(xq, 256, qkvT + l * 196608, qkvb + l * 768, nullptr, bQKV, 2500, 768, 256, 0);
        flash2_k<<<dim3(40, 8, FL_SPLITS), 256, 0, stream>>>(bQKV, bQKV + 256, bQKV + 512, 768, OP, MLp);
        flashmerge_k<<<2500, 256, 0, stream>>>(OP, MLp, bO);
        mgemm(bO, 256, owT + l * 65536, sa_bo + o1, qbuf, qbuf, 2500, 256, 256, 0);

        // spatial cross-attention (fused offsets+logits projection: 2500 x 576)
        ln_k<<<625, 256, 0, stream>>>(qbuf, ln2g + o1, ln2b + o1, xq);
        mgemm(feats, 256, valT + l * 65536, valb + o1, nullptr, valsb, 8400, 256, 256, 0);
        mgemm(xq, 256, offwtT + l * 147456, owb + l * 576, nullptr, bOW, 2500, 576, 256, 0);
        scasoftmax_k<<<2500, 64, 0, stream>>>(bOW + 384, 576, validb);
        sample_k<<<2500, 256, 0, stream>>>(valsb, bOW, 576, bOW + 384, refp, validb, bO);
        mgemm(bO, 256, outT + l * 65536, outb + o1, qbuf, qbuf, 2500, 256, 256, 0);

        // FFN
        ln_k<<<625, 256, 0, stream>>>(qbuf, ln3g + o1, ln3b + o1, xq);
        mgemm(xq, 256, f1T + l * 262144, fb1 + (long)l * 1024, nullptr, bH, 2500, 1024, 256, 2);
        mgemm(bH, 1024, f2T + l * 262144, fb2 + o1, qbuf,
              (l == 1) ? (float*)d_out : qbuf, 2500, 256, 1024, 0);
    }
}

// Round 11
// 893.258 us; speedup vs baseline: 2.2214x; 1.1089x over previous
//
#include <hip/hip_runtime.h>
#include <hip/hip_bf16.h>
#include <math.h>

#define EPS 1e-5f
#define FL_SPLITS 5
#define FL_KEYS 500

typedef __attribute__((ext_vector_type(8))) short short8;
typedef __attribute__((ext_vector_type(4))) float f4;

__device__ __forceinline__ short f2s(float f) {
    union { float f; unsigned u; } v; v.f = f;
    unsigned r = (v.u + 0x7fffu + ((v.u >> 16) & 1u)) >> 16;  // RNE
    return (short)r;
}
__device__ __forceinline__ unsigned packbf(float a, float b) {
    return (unsigned)(unsigned short)f2s(a) | ((unsigned)(unsigned short)f2s(b) << 16);
}
__device__ __forceinline__ float bflo(unsigned v) { union { unsigned u; float f; } t; t.u = v << 16; return t.f; }
__device__ __forceinline__ float bfhi(unsigned v) { union { unsigned u; float f; } t; t.u = v & 0xffff0000u; return t.f; }

// ---------------- weight preprocessing ----------------
__global__ __launch_bounds__(256) void wcast_k(const float* __restrict__ in, short* __restrict__ out, int n)
{
    int i = blockIdx.x * 256 + threadIdx.x;
    if (i < n) out[i] = f2s(in[i]);
}

// conv0 weight pack: (64,3,3,3) fp32 -> (64,32) bf16, k = ci*9 + t, pad 27..31 = 0
__global__ __launch_bounds__(256) void wcast0_k(const float* __restrict__ in, short* __restrict__ out)
{
    int i = blockIdx.x * 256 + threadIdx.x;
    if (i >= 2048) return;
    int k = i & 31;
    out[i] = (k < 27) ? f2s(in[(i >> 5) * 27 + k]) : (short)0;
}

// conv weight reorder: (Cout, Cin, 3,3) fp32 -> (Cout, 9, Cin) bf16 (tap-major)
__global__ __launch_bounds__(256) void wreord_k(const float* __restrict__ in, short* __restrict__ out,
                                                int Cin, int n)
{
    int i = blockIdx.x * 256 + threadIdx.x;
    if (i >= n) return;
    int cin9 = Cin * 9;
    int co = i / cin9, rem = i - co * cin9;
    int ci = rem / 9, t = rem - ci * 9;
    out[(long)co * cin9 + t * Cin + ci] = f2s(in[i]);
}

// (K,N) fp32 -> (N,K) bf16 ; blockIdx.z = matrix index, zstride = output stride per matrix
__global__ __launch_bounds__(256) void wtrans_k(const float* __restrict__ in, short* __restrict__ out,
                                                int K, int N, long zstride)
{
    in  += (long)blockIdx.z * K * N;
    out += (long)blockIdx.z * zstride;
    __shared__ float t[64][65];
    int k0 = blockIdx.y * 64, n0 = blockIdx.x * 64;
    int tid = threadIdx.x;
    int cl = tid & 63, rq = tid >> 6;
    #pragma unroll
    for (int i = 0; i < 16; i++) {
        int rl = rq + i * 4;
        int k = k0 + rl, n = n0 + cl;
        t[rl][cl] = (k < K && n < N) ? in[(long)k * N + n] : 0.f;
    }
    __syncthreads();
    #pragma unroll
    for (int i = 0; i < 16; i++) {
        int nl = rq + i * 4;
        int n = n0 + nl, k = k0 + cl;
        if (n < N && k < K) out[(long)n * K + k] = f2s(t[cl][nl]);
    }
}

// six 256x256 (K,N)->(N,K) transposes in one dispatch; blockIdx.z = mat*2 + layer
__global__ __launch_bounds__(256) void wtrans6_k(const float* __restrict__ s0, const float* __restrict__ s1,
                                                 const float* __restrict__ s2, const float* __restrict__ s3,
                                                 const float* __restrict__ s4, const float* __restrict__ s5,
                                                 short* __restrict__ d0, short* __restrict__ d1,
                                                 short* __restrict__ d2, short* __restrict__ d3,
                                                 short* __restrict__ d4, short* __restrict__ d5)
{
    int mat = blockIdx.z >> 1, l = blockIdx.z & 1;
    const float* in; short* out; long zs;
    if      (mat == 0) { in = s0; out = d0; zs = 196608; }
    else if (mat == 1) { in = s1; out = d1; zs = 196608; }
    else if (mat == 2) { in = s2; out = d2; zs = 196608; }
    else if (mat == 3) { in = s3; out = d3; zs = 65536; }
    else if (mat == 4) { in = s4; out = d4; zs = 65536; }
    else               { in = s5; out = d5; zs = 65536; }
    in  += (long)l * 65536;
    out += (long)l * zs;
    __shared__ float t[64][65];
    int k0 = blockIdx.y * 64, n0 = blockIdx.x * 64;
    int tid = threadIdx.x;
    int cl = tid & 63, rq = tid >> 6;
    #pragma unroll
    for (int i = 0; i < 16; i++) {
        int rl = rq + i * 4;
        t[rl][cl] = in[(long)(k0 + rl) * 256 + n0 + cl];
    }
    __syncthreads();
    #pragma unroll
    for (int i = 0; i < 16; i++) {
        int nl = rq + i * 4;
        out[(long)(n0 + nl) * 256 + k0 + cl] = f2s(t[cl][nl]);
    }
}

// pack per-layer bias segments
__global__ __launch_bounds__(256) void packb_k(const float* __restrict__ a, const float* __restrict__ b,
                                               const float* __restrict__ c, float* __restrict__ y,
                                               int na, int nb, int nc)
{
    int l = blockIdx.y;
    int j = blockIdx.x * 256 + threadIdx.x;
    int ntot = na + nb + nc;
    if (j >= ntot) return;
    float v;
    if (j < na) v = a[l * na + j];
    else if (j < na + nb) v = b[l * nb + (j - na)];
    else v = c[l * nc + (j - na - nb)];
    y[(long)l * ntot + j] = v;
}

// ---------------- MFMA GEMM, 64x64 tile (4 waves, 2x2 MFMA each): C = A(fp32) @ Bt^T ----------------
__global__ __launch_bounds__(256) void mgemm_k(const float* __restrict__ A, int lda,
                                               const short* __restrict__ Bt,
                                               const float* __restrict__ bias,
                                               const float* __restrict__ resid,
                                               float* __restrict__ C,
                                               int M, int N, int K, int act)
{
    __shared__ __align__(16) short As[2560];   // 64 rows x 40 (32 used)
    __shared__ __align__(16) short Bs[2560];
    int tid = threadIdx.x;
    int wave = tid >> 6, lane = tid & 63;
    int wm = wave >> 1, wn = wave & 1;
    int quad = lane >> 4, l15 = lane & 15;
    int m0 = blockIdx.y * 64, n0 = blockIdx.x * 64;
    int srow = tid >> 2, skc = (tid & 3) << 3;
    f4 acc[2][2];
    #pragma unroll
    for (int i = 0; i < 2; i++) { acc[i][0] = (f4){0.f,0.f,0.f,0.f}; acc[i][1] = (f4){0.f,0.f,0.f,0.f}; }
    short8 aR, bR;
    auto loadAB = [&](int kt) {
        int gm = m0 + srow;
        short8 pk = {0, 0, 0, 0, 0, 0, 0, 0};
        if (gm < M) {
            const float4* ap = (const float4*)(A + (long)gm * lda + kt + skc);
            float4 v0 = ap[0], v1 = ap[1];
            pk[0] = f2s(v0.x); pk[1] = f2s(v0.y); pk[2] = f2s(v0.z); pk[3] = f2s(v0.w);
            pk[4] = f2s(v1.x); pk[5] = f2s(v1.y); pk[6] = f2s(v1.z); pk[7] = f2s(v1.w);
        }
        aR = pk;
        int gn = n0 + srow;
        short8 pb = {0, 0, 0, 0, 0, 0, 0, 0};
        if (gn < N) pb = *(const short8*)&Bt[(long)gn * K + kt + skc];
        bR = pb;
    };
    loadAB(0);
    for (int kt = 0; kt < K; kt += 32) {
        *(short8*)&As[srow * 40 + skc] = aR;
        *(short8*)&Bs[srow * 40 + skc] = bR;
        __syncthreads();
        if (kt + 32 < K) loadAB(kt + 32);
        short8 af[2], bf[2];
        #pragma unroll
        for (int mi = 0; mi < 2; mi++) af[mi] = *(const short8*)&As[(wm * 32 + mi * 16 + l15) * 40 + (quad << 3)];
        #pragma unroll
        for (int ni = 0; ni < 2; ni++) bf[ni] = *(const short8*)&Bs[(wn * 32 + ni * 16 + l15) * 40 + (quad << 3)];
        #pragma unroll
        for (int mi = 0; mi < 2; mi++)
            #pragma unroll
            for (int ni = 0; ni < 2; ni++)
                acc[mi][ni] = __builtin_amdgcn_mfma_f32_16x16x32_bf16(af[mi], bf[ni], acc[mi][ni], 0, 0, 0);
        __syncthreads();
    }
    #pragma unroll
    for (int mi = 0; mi < 2; mi++) {
        int row = m0 + wm * 32 + mi * 16 + quad * 4;
        #pragma unroll
        for (int ni = 0; ni < 2; ni++) {
            int col = n0 + wn * 32 + ni * 16 + l15;
            if (col >= N) continue;
            float bv = bias[col];
            #pragma unroll
            for (int r = 0; r < 4; r++) {
                int rr = row + r;
                if (rr >= M) continue;
                float v = acc[mi][ni][r] + bv;
                if (act == 2) v = 0.5f * v * (1.f + erff(v * 0.70710678118654752f));
                if (resid) v += resid[(long)rr * N + col];
                C[(long)rr * N + col] = v;
            }
        }
    }
}

// ---------------- MFMA conv 3x3 s2 p1, tap-major K, bf16-pair input, BK=64 ----------------
// Flattened grid (nSpatial<<ctshift, 1, ncb) with XCD-chunk bijective swizzle.
__global__ __launch_bounds__(256) void mconv_k(const unsigned* __restrict__ in,
                                               const short* __restrict__ wgt,
                                               const float* __restrict__ bias,
                                               float* __restrict__ out,
                                               float2* __restrict__ parts,
                                               int c5m, int Cout, int Hin, int Win,
                                               int mode, int cpg, int ctshift,
                                               long istride, long ostride)
{
    // bijective XCD-chunk swizzle (m204): lin -> wgid, couttile fastest
    int lin = blockIdx.x + gridDim.x * blockIdx.z;
    int nwgT = gridDim.x * gridDim.z;
    int xcd = lin & 7, seq = lin >> 3;
    int qd = nwgT >> 3, rd = nwgT & 7;
    int wgid = (xcd < rd ? xcd * (qd + 1) : rd * (qd + 1) + (xcd - rd) * qd) + seq;
    int cam = wgid / gridDim.x;
    int rem = wgid - cam * gridDim.x;
    int couttile = rem & ((1 << ctshift) - 1);
    int spatial = rem >> ctshift;

    in  += (long)cam * istride;
    const int Hout = Hin >> 1, Wout = Win >> 1;
    const int HWo = Hout * Wout;
    const int HW = Hin * Win;
    const int Ktot = 288 << c5m;       // 9*Cin
    const int ch_sh = c5m - 1;         // 64-chunk shift (Cin/64 chunks per tap)
    const int ch_m  = (1 << ch_sh) - 1;
    const int nsteps = 9 << ch_sh;
    __shared__ __align__(16) short As[4608];   // 64 rows x 72 (64 used)
    __shared__ __align__(16) short Bs[4608];
    __shared__ float2 sred[16][2];             // [quad-group][wn] = (s, s2)
    int tid = threadIdx.x;
    int wave = tid >> 6, lane = tid & 63;
    int wm = wave >> 1, wn = wave & 1;
    int quad = lane >> 4, l15 = lane & 15;
    int m0 = couttile << 6, n0 = spatial << 6;
    int nn = tid & 63;
    int kp0 = tid >> 6;
    int p = n0 + nn;
    int pok = p < HWo;
    int pc = pok ? p : (HWo - 1);
    int ho = pc / Wout, wo = pc - ho * Wout;
    int hb = ho * 2 - 1, wb = wo * 2 - 1;

    f4 acc[2][2];
    #pragma unroll
    for (int i = 0; i < 2; i++) { acc[i][0] = (f4){0.f,0.f,0.f,0.f}; acc[i][1] = (f4){0.f,0.f,0.f,0.f}; }

    int srow = tid >> 2, skc = (tid & 3) << 4;     // 16-short granule per thread
    short8 aR0, aR1;
    unsigned bR[8];
    auto loadA = [&](int s) {
        const short* ap = &wgt[(long)(m0 + srow) * Ktot + (s << 6) + skc];
        aR0 = *(const short8*)ap;
        aR1 = *(const short8*)(ap + 8);
    };
    // thread owns 8 CONTIGUOUS channel-pairs kp = kp0*8 .. kp0*8+7 -> two b128 LDS writes
    auto loadB = [&](int s) {
        int t = s >> ch_sh;
        int kh3 = (t * 11) >> 5;           // t/3 for t in 0..8
        int kw3 = t - kh3 * 3;
        int y = hb + kh3, x = wb + kw3;
        bool okp = pok && ((unsigned)y < (unsigned)Hin) && ((unsigned)x < (unsigned)Win);
        int base = (((s & ch_m) << 5) + (kp0 << 3)) * HW + y * Win + x;
        #pragma unroll
        for (int i = 0; i < 8; i++) {
            unsigned v = 0;
            if (okp) v = in[base + i * HW];
            bR[i] = v;
        }
    };

    loadA(0); loadB(0);
    for (int s = 0; s < nsteps; s++) {
        *(short8*)&As[srow * 72 + skc]     = aR0;
        *(short8*)&As[srow * 72 + skc + 8] = aR1;
        *(uint4*)&Bs[nn * 72 + (kp0 << 4)]     = *(uint4*)&bR[0];
        *(uint4*)&Bs[nn * 72 + (kp0 << 4) + 8] = *(uint4*)&bR[4];
        __syncthreads();
        if (s + 1 < nsteps) { loadA(s + 1); loadB(s + 1); }
        #pragma unroll
        for (int kh = 0; kh < 2; kh++) {
            short8 af[2], bf[2];
            #pragma unroll
            for (int mi = 0; mi < 2; mi++)
                af[mi] = *(const short8*)&As[(wm * 32 + mi * 16 + l15) * 72 + kh * 32 + (quad << 3)];
            #pragma unroll
            for (int ni = 0; ni < 2; ni++)
                bf[ni] = *(const short8*)&Bs[(wn * 32 + ni * 16 + l15) * 72 + kh * 32 + (quad << 3)];
            #pragma unroll
            for (int mi = 0; mi < 2; mi++)
                #pragma unroll
                for (int ni = 0; ni < 2; ni++)
                    acc[mi][ni] = __builtin_amdgcn_mfma_f32_16x16x32_bf16(af[mi], bf[ni], acc[mi][ni], 0, 0, 0);
        }
        __syncthreads();
    }

    if (mode == 1) {
        float* outf = out + (long)cam * ostride;
        #pragma unroll
        for (int mi = 0; mi < 2; mi++) {
            int mbase = m0 + wm * 32 + mi * 16 + quad * 4;
            #pragma unroll
            for (int ni = 0; ni < 2; ni++) {
                int n = n0 + wn * 32 + ni * 16 + l15;
                if (n >= HWo) continue;
                #pragma unroll
                for (int r = 0; r < 4; r++) {
                    int m = mbase + r;
                    outf[(long)n * Cout + m] = acc[mi][ni][r] + bias[m];
                }
            }
        }
    } else {
        unsigned* outp = (unsigned*)out + (long)cam * ostride;
        float ssum[2] = {0.f, 0.f}, qsum[2] = {0.f, 0.f};
        #pragma unroll
        for (int mi = 0; mi < 2; mi++) {
            int mbase = m0 + wm * 32 + mi * 16 + quad * 4;
            float b0 = bias[mbase], b1 = bias[mbase + 1], b2 = bias[mbase + 2], b3 = bias[mbase + 3];
            #pragma unroll
            for (int ni = 0; ni < 2; ni++) {
                int n = n0 + wn * 32 + ni * 16 + l15;
                if (n >= HWo) continue;
                float v0 = acc[mi][ni][0] + b0;
                float v1 = acc[mi][ni][1] + b1;
                float v2 = acc[mi][ni][2] + b2;
                float v3 = acc[mi][ni][3] + b3;
                long cp = (long)(mbase >> 1) * HWo + n;
                outp[cp]       = packbf(v0, v1);
                outp[cp + HWo] = packbf(v2, v3);
                ssum[mi] += v0 + v1 + v2 + v3;
                qsum[mi] += v0 * v0 + v1 * v1 + v2 * v2 + v3 * v3;
            }
        }
        #pragma unroll
        for (int mi = 0; mi < 2; mi++) {
            #pragma unroll
            for (int off = 1; off < 16; off <<= 1) {
                ssum[mi] += __shfl_xor(ssum[mi], off, 16);
                qsum[mi] += __shfl_xor(qsum[mi], off, 16);
            }
        }
        if (l15 == 0) {
            #pragma unroll
            for (int mi = 0; mi < 2; mi++)
                sred[wm * 8 + mi * 4 + quad][wn] = make_float2(ssum[mi], qsum[mi]);
        }
        __syncthreads();
        int ng = 64 / cpg;          // groups covered by this block
        int qpg = cpg >> 2;         // quad-groups per group
        if (tid < ng) {
            float s = 0.f, q = 0.f;
            for (int u = 0; u < qpg; u++) {
                float2 a = sred[(tid * cpg >> 2) + u][0];
                float2 b = sred[(tid * cpg >> 2) + u][1];
                s += a.x + b.x; q += a.y + b.y;
            }
            int gabs = m0 / cpg + tid;
            parts[((long)cam * 32 + gabs) * 1400 + spatial] = make_float2(s, q);
        }
    }
}

// ---------------- conv0 fused MFMA: fp32 image gather -> bf16 MFMA (K=32) -> pair out + GN stats ------
__global__ __launch_bounds__(256) void conv0f_k(const float* __restrict__ img,
                                                const short* __restrict__ wgt,
                                                const float* __restrict__ bias,
                                                unsigned* __restrict__ outp,
                                                float2* __restrict__ parts,
                                                long istride, long ostride)
{
    img  += (long)blockIdx.z * istride;
    outp += (long)blockIdx.z * ostride;
    const int HWo = 89600;
    __shared__ __align__(16) short As[2560];
    __shared__ __align__(16) short Bs[2560];
    __shared__ float2 sred[32][2];
    int tid = threadIdx.x;
    int wave = tid >> 6, lane = tid & 63;
    int wm = wave >> 1, wn = wave & 1;
    int quad = lane >> 4, l15 = lane & 15;
    int n0 = blockIdx.x * 64;
    int srow = tid >> 2, skc = (tid & 3) << 3;
    *(short8*)&As[srow * 40 + skc] = *(const short8*)&wgt[srow * 32 + skc];
    {
        int p = n0 + srow;
        int ho = p / 400, wo = p - ho * 400;
        int hb = ho * 2 - 1, wb = wo * 2 - 1;
        short8 pb;
        #pragma unroll
        for (int j = 0; j < 8; j++) {
            int k = skc + j;
            float v = 0.f;
            if (k < 27) {
                int ci = (k < 9) ? 0 : (k < 18 ? 1 : 2);
                int t = k - ci * 9;
                int kh = (t < 3) ? 0 : (t < 6 ? 1 : 2);
                int kw = t - kh * 3;
                int y = hb + kh, x = wb + kw;
                if ((unsigned)y < 448u && (unsigned)x < 800u)
                    v = img[ci * 358400 + y * 800 + x];
            }
            pb[j] = f2s(v);
        }
        *(short8*)&Bs[srow * 40 + skc] = pb;
    }
    __syncthreads();
    f4 acc[2][2];
    #pragma unroll
    for (int i = 0; i < 2; i++) { acc[i][0] = (f4){0.f,0.f,0.f,0.f}; acc[i][1] = (f4){0.f,0.f,0.f,0.f}; }
    short8 af[2], bf[2];
    #pragma unroll
    for (int mi = 0; mi < 2; mi++) af[mi] = *(const short8*)&As[(wm * 32 + mi * 16 + l15) * 40 + (quad << 3)];
    #pragma unroll
    for (int ni = 0; ni < 2; ni++) bf[ni] = *(const short8*)&Bs[(wn * 32 + ni * 16 + l15) * 40 + (quad << 3)];
    #pragma unroll
    for (int mi = 0; mi < 2; mi++)
        #pragma unroll
        for (int ni = 0; ni < 2; ni++)
            acc[mi][ni] = __builtin_amdgcn_mfma_f32_16x16x32_bf16(af[mi], bf[ni], acc[mi][ni], 0, 0, 0);
    #pragma unroll
    for (int mi = 0; mi < 2; mi++) {
        int mbase = wm * 32 + mi * 16 + quad * 4;
        float b0 = bias[mbase], b1 = bias[mbase + 1], b2 = bias[mbase + 2], b3 = bias[mbase + 3];
        float s0 = 0.f, q0 = 0.f, s1 = 0.f, q1 = 0.f;
        #pragma unroll
        for (int ni = 0; ni < 2; ni++) {
            int n = n0 + wn * 32 + ni * 16 + l15;
            float v0 = acc[mi][ni][0] + b0;
            float v1 = acc[mi][ni][1] + b1;
            float v2 = acc[mi][ni][2] + b2;
            float v3 = acc[mi][ni][3] + b3;
            long cp = (long)(mbase >> 1) * HWo + n;
            outp[cp]       = packbf(v0, v1);
            outp[cp + HWo] = packbf(v2, v3);
            s0 += v0 + v1; q0 += v0 * v0 + v1 * v1;
            s1 += v2 + v3; q1 += v2 * v2 + v3 * v3;
        }
        #pragma unroll
        for (int off = 1; off < 16; off <<= 1) {
            s0 += __shfl_xor(s0, off, 16); q0 += __shfl_xor(q0, off, 16);
            s1 += __shfl_xor(s1, off, 16); q1 += __shfl_xor(q1, off, 16);
        }
        if (l15 == 0) {
            int pi = wm * 16 + mi * 8 + quad * 2;
            sred[pi][wn]     = make_float2(s0, q0);
            sred[pi + 1][wn] = make_float2(s1, q1);
        }
    }
    __syncthreads();
    if (tid < 32) {
        float2 a = sred[tid][0], b = sred[tid][1];
        parts[((long)blockIdx.z * 32 + tid) * 1400 + blockIdx.x] = make_float2(a.x + b.x, a.y + b.y);
    }
}

// ---------------- GN finalize: reduce per-block partials -> mean/rstd ----------------
__global__ __launch_bounds__(256) void gnfin_k(const float2* __restrict__ parts,
                                               float* __restrict__ gnstats, int nx, float invN)
{
    int g = blockIdx.x, cam = blockIdx.y;
    const float2* pb = parts + ((long)cam * 32 + g) * 1400;
    float s = 0.f, q = 0.f;
    for (int i = threadIdx.x; i < nx; i += 256) {
        float2 v = pb[i];
        s += v.x; q += v.y;
    }
    __shared__ float rs[256], rq[256];
    rs[threadIdx.x] = s; rq[threadIdx.x] = q;
    __syncthreads();
    for (int o = 128; o > 0; o >>= 1) {
        if (threadIdx.x < o) { rs[threadIdx.x] += rs[threadIdx.x + o]; rq[threadIdx.x] += rq[threadIdx.x + o]; }
        __syncthreads();
    }
    if (threadIdx.x == 0) {
        float mean = rs[0] * invN;
        float var  = rq[0] * invN - mean * mean;
        gnstats[(cam * 32 + g) * 2]     = mean;
        gnstats[(cam * 32 + g) * 2 + 1] = rsqrtf(var + EPS);
    }
}

// ---------------- in-place GN apply + ReLU on bf16-pair buffer ----------------
__global__ __launch_bounds__(256) void pairapply_k(unsigned* __restrict__ x,
                                                   const float* __restrict__ gamma,
                                                   const float* __restrict__ beta,
                                                   const float* __restrict__ gnstats,
                                                   int HW, int cpg, long zstride)
{
    x       += (long)blockIdx.z * zstride;
    gnstats += (long)blockIdx.z * 64;
    int idx4 = (blockIdx.x * 256 + threadIdx.x) * 4;   // HW%4==0 -> all in one pair-row
    int cp = idx4 / HW;
    int c0 = cp * 2;
    int g = c0 / cpg;
    float mean = gnstats[g * 2], rstd = gnstats[g * 2 + 1];
    float sa = rstd * gamma[c0],     ba = beta[c0]     - mean * sa;
    float sb = rstd * gamma[c0 + 1], bb = beta[c0 + 1] - mean * sb;
    uint4 v = *(uint4*)&x[idx4];
    unsigned* vp = (unsigned*)&v;
    #pragma unroll
    for (int j = 0; j < 4; j++) {
        float lo = fmaxf(bflo(vp[j]) * sa + ba, 0.f);
        float hi = fmaxf(bfhi(vp[j]) * sb + bb, 0.f);
        vp[j] = packbf(lo, hi);
    }
    *(uint4*)&x[idx4] = v;
}

// ---------------- GroupNorm for (1400 x 256) spatial-major, batched over cams (grid.y) ----------------
__global__ __launch_bounds__(256) void gn_stats_hwd_k(const float* __restrict__ x, float* __restrict__ stats)
{
    x += (long)blockIdx.y * 358400;
    stats += blockIdx.y * 64;
    int g = blockIdx.x;  // 32 groups
    float s = 0.f, s2 = 0.f;
    for (int i = threadIdx.x; i < 1400 * 8; i += blockDim.x) {
        int p = i >> 3, c = g * 8 + (i & 7);
        float v = x[(long)p * 256 + c];
        s += v; s2 += v * v;
    }
    __shared__ float rs[256], rq[256];
    rs[threadIdx.x] = s; rq[threadIdx.x] = s2;
    __syncthreads();
    for (int o = 128; o > 0; o >>= 1) {
        if (threadIdx.x < o) { rs[threadIdx.x] += rs[threadIdx.x + o]; rq[threadIdx.x] += rq[threadIdx.x + o]; }
        __syncthreads();
    }
    if (threadIdx.x == 0) {
        float mean = rs[0] / 11200.f;
        float var  = rq[0] / 11200.f - mean * mean;
        stats[g * 2]     = mean;
        stats[g * 2 + 1] = rsqrtf(var + EPS);
    }
}

__global__ __launch_bounds__(256) void gn_apply_hwd_k(float* __restrict__ x,
                                                      const float* __restrict__ gamma,
                                                      const float* __restrict__ beta,
                                                      const float* __restrict__ stats,
                                                      int relu)
{
    x += (long)blockIdx.y * 358400;
    stats += blockIdx.y * 64;
    long i4 = ((long)blockIdx.x * 256 + threadIdx.x) * 4;  // grid.x = 350 -> exact
    int c = (int)(i4 & 255);
    int g = c >> 3;
    float4 v  = *(float4*)&x[i4];
    float4 gm = *(const float4*)&gamma[c];
    float4 bt = *(const float4*)&beta[c];
    float m = stats[g * 2], rs = stats[g * 2 + 1];
    v.x = (v.x - m) * rs * gm.x + bt.x;
    v.y = (v.y - m) * rs * gm.y + bt.y;
    v.z = (v.z - m) * rs * gm.z + bt.z;
    v.w = (v.w - m) * rs * gm.w + bt.w;
    if (relu) {
        v.x = fmaxf(v.x, 0.f); v.y = fmaxf(v.y, 0.f);
        v.z = fmaxf(v.z, 0.f); v.w = fmaxf(v.w, 0.f);
    }
    *(float4*)&x[i4] = v;
}

// ---------------- projection of BEV grid ----------------
__global__ __launch_bounds__(256) void project_k(const float* __restrict__ Kin,
                                                 const float* __restrict__ Ein,
                                                 float* __restrict__ refp, int* __restrict__ valid)
{
    int idx = blockIdx.x * blockDim.x + threadIdx.x;
    if (idx >= 2500 * 6) return;
    int c = idx % 6, q = idx / 6;
    int i = q / 50, j = q % 50;
    float px = (i - 24.5f) * 0.5f;
    float py = (j - 24.5f) * 0.5f;
    const float* E = Ein + c * 16;
    float pc[4];
    #pragma unroll
    for (int r = 0; r < 4; r++)
        pc[r] = E[r * 4 + 0] * px + E[r * 4 + 1] * py + E[r * 4 + 3];
    const float* Km = Kin + c * 9;
    float pix[3];
    #pragma unroll
    for (int r = 0; r < 3; r++)
        pix[r] = Km[r * 3 + 0] * pc[0] + Km[r * 3 + 1] * pc[1] + Km[r * 3 + 2] * pc[2];
    float z = fmaxf(pix[2], 1e-5f);
    float u = pix[0] / z, v = pix[1] / z;
    int ok = (pc[2] > 0.f) && (u >= 0.f) && (u < 800.f) && (v >= 0.f) && (v < 448.f);
    refp[(long)idx * 2 + 0] = 2.f * u / 799.f - 1.f;
    refp[(long)idx * 2 + 1] = 2.f * v / 447.f - 1.f;
    valid[idx] = ok;
}

// ---------------- misc elementwise ----------------
__global__ __launch_bounds__(256) void qinit_k(const float* __restrict__ a, const float* __restrict__ b,
                                               float* __restrict__ y)
{
    int i = blockIdx.x * blockDim.x + threadIdx.x;
    if (i >= 2500 * 256) return;
    y[i] = a[i] + b[i];
}

// ---------------- LayerNorm ----------------
__global__ __launch_bounds__(256) void ln_k(const float* __restrict__ x,
                                            const float* __restrict__ g, const float* __restrict__ b,
                                            float* __restrict__ y)
{
    int row  = blockIdx.x * 4 + (threadIdx.x >> 6);
    int lane = threadIdx.x & 63;
    if (row >= 2500) return;
    const float* xp = x + (long)row * 256;
    float v[4];
    #pragma unroll
    for (int i = 0; i < 4; i++) v[i] = xp[lane + 64 * i];
    float s  = v[0] + v[1] + v[2] + v[3];
    float s2 = v[0] * v[0] + v[1] * v[1] + v[2] * v[2] + v[3] * v[3];
    #pragma unroll
    for (int o = 32; o > 0; o >>= 1) { s += __shfl_xor(s, o, 64); s2 += __shfl_xor(s2, o, 64); }
    float mean = s * (1.f / 256.f);
    float var  = s2 * (1.f / 256.f) - mean * mean;
    float rstd = rsqrtf(var + EPS);
    #pragma unroll
    for (int i = 0; i < 4; i++) {
        int cc = lane + 64 * i;
        y[(long)row * 256 + cc] = (v[i] - mean) * rstd * g[cc] + b[cc];
    }
}

// ---------------- MFMA flash-2 MHA with split-K (packed-QKV aware: row stride ld) ----------------
__global__ __launch_bounds__(256) void flash2_k(const float* __restrict__ Q,
                                                const float* __restrict__ K,
                                                const float* __restrict__ V,
                                                int ld,
                                                float* __restrict__ Opart,   // (S,2500,256)
                                                float* __restrict__ MLpart)  // (S,2500,8,2)
{
    const int h  = blockIdx.y;
    const int q0 = blockIdx.x * 64;
    const int sp = blockIdx.z;
    const int kstart = sp * FL_KEYS, kend = kstart + FL_KEYS;
    const int tid = threadIdx.x;
    const int wave = tid >> 6, lane = tid & 63;
    const int quad = lane >> 4, l15 = lane & 15;
    __shared__ __align__(16) short Qs[64 * 40];
    __shared__ __align__(16) short Ks[64 * 40];
    __shared__ __align__(16) short Vt[32 * 72];
    __shared__ __align__(16) short Ps[64 * 72];
    const float scale = 0.17677669529663687f;
    {
        int row = tid >> 2, kc = (tid & 3) << 3;
        int qi = q0 + row;
        short8 pk = {0, 0, 0, 0, 0, 0, 0, 0};
        if (qi < 2500) {
            const float4* qp = (const float4*)(Q + (long)qi * ld + h * 32 + kc);
            float4 v0 = qp[0], v1 = qp[1];
            pk[0] = f2s(v0.x * scale); pk[1] = f2s(v0.y * scale); pk[2] = f2s(v0.z * scale); pk[3] = f2s(v0.w * scale);
            pk[4] = f2s(v1.x * scale); pk[5] = f2s(v1.y * scale); pk[6] = f2s(v1.z * scale); pk[7] = f2s(v1.w * scale);
        }
        *(short8*)&Qs[row * 40 + kc] = pk;
    }
    __syncthreads();
    short8 aq = *(const short8*)&Qs[(wave * 16 + l15) * 40 + (quad << 3)];
    float m[4], l[4];
    f4 oacc[2];
    #pragma unroll
    for (int r = 0; r < 4; r++) { m[r] = -INFINITY; l[r] = 0.f; }
    oacc[0] = (f4){0.f, 0.f, 0.f, 0.f};
    oacc[1] = (f4){0.f, 0.f, 0.f, 0.f};
    for (int kb = kstart; kb < kend; kb += 64) {
        __syncthreads();
        {
            int row = tid >> 2, kc = (tid & 3) << 3;
            int ki = kb + row;
            short8 pk = {0, 0, 0, 0, 0, 0, 0, 0};
            float vv[8] = {0.f, 0.f, 0.f, 0.f, 0.f, 0.f, 0.f, 0.f};
            if (ki < kend) {
                const float4* kp = (const float4*)(K + (long)ki * ld + h * 32 + kc);
                float4 a0 = kp[0], a1 = kp[1];
                pk[0] = f2s(a0.x); pk[1] = f2s(a0.y); pk[2] = f2s(a0.z); pk[3] = f2s(a0.w);
                pk[4] = f2s(a1.x); pk[5] = f2s(a1.y); pk[6] = f2s(a1.z); pk[7] = f2s(a1.w);
                const float4* vp = (const float4*)(V + (long)ki * ld + h * 32 + kc);
                float4 b0 = vp[0], b1 = vp[1];
                vv[0] = b0.x; vv[1] = b0.y; vv[2] = b0.z; vv[3] = b0.w;
                vv[4] = b1.x; vv[5] = b1.y; vv[6] = b1.z; vv[7] = b1.w;
            }
            *(short8*)&Ks[row * 40 + kc] = pk;
            #pragma unroll
            for (int j = 0; j < 8; j++) Vt[(kc + j) * 72 + row] = f2s(vv[j]);
        }
        __syncthreads();
        f4 sa[4];
        #pragma unroll
        for (int ni = 0; ni < 4; ni++) {
            short8 bk = *(const short8*)&Ks[(ni * 16 + l15) * 40 + (quad << 3)];
            sa[ni] = __builtin_amdgcn_mfma_f32_16x16x32_bf16(aq, bk, (f4){0.f, 0.f, 0.f, 0.f}, 0, 0, 0);
        }
        float sv[4][4];
        #pragma unroll
        for (int ni = 0; ni < 4; ni++) {
            bool colok = (kb + ni * 16 + l15) < kend;
            #pragma unroll
            for (int r = 0; r < 4; r++) sv[ni][r] = colok ? sa[ni][r] : -1e30f;
        }
        float p[4][4];
        #pragma unroll
        for (int r = 0; r < 4; r++) {
            float rm = fmaxf(fmaxf(sv[0][r], sv[1][r]), fmaxf(sv[2][r], sv[3][r]));
            #pragma unroll
            for (int off = 1; off < 16; off <<= 1) rm = fmaxf(rm, __shfl_xor(rm, off, 16));
            float mn = fmaxf(m[r], rm);
            float alpha = __expf(m[r] - mn);
            float rs = 0.f;
            #pragma unroll
            for (int ni = 0; ni < 4; ni++) { p[ni][r] = __expf(sv[ni][r] - mn); rs += p[ni][r]; }
            #pragma unroll
            for (int off = 1; off < 16; off <<= 1) rs += __shfl_xor(rs, off, 16);
            l[r] = l[r] * alpha + rs;
            oacc[0][r] *= alpha; oacc[1][r] *= alpha;
            m[r] = mn;
        }
        #pragma unroll
        for (int ni = 0; ni < 4; ni++)
            #pragma unroll
            for (int r = 0; r < 4; r++)
                Ps[(wave * 16 + quad * 4 + r) * 72 + ni * 16 + l15] = f2s(p[ni][r]);
        #pragma unroll
        for (int kh = 0; kh < 2; kh++) {
            short8 ap = *(const short8*)&Ps[(wave * 16 + l15) * 72 + kh * 32 + (quad << 3)];
            #pragma unroll
            for (int ni = 0; ni < 2; ni++) {
                short8 bv = *(const short8*)&Vt[(ni * 16 + l15) * 72 + kh * 32 + (quad << 3)];
                oacc[ni] = __builtin_amdgcn_mfma_f32_16x16x32_bf16(ap, bv, oacc[ni], 0, 0, 0);
            }
        }
    }
    #pragma unroll
    for (int r = 0; r < 4; r++) {
        int qi = q0 + wave * 16 + quad * 4 + r;
        if (qi < 2500) {
            long ob = ((long)sp * 2500 + qi) * 256 + h * 32;
            Opart[ob + l15]      = oacc[0][r];
            Opart[ob + 16 + l15] = oacc[1][r];
            if (l15 == 0) {
                long mb = (((long)sp * 2500 + qi) * 8 + h) * 2;
                MLpart[mb]     = m[r];
                MLpart[mb + 1] = l[r];
            }
        }
    }
}

__global__ __launch_bounds__(256) void flashmerge_k(const float* __restrict__ Opart,
                                                    const float* __restrict__ MLpart,
                                                    float* __restrict__ O)
{
    int q = blockIdx.x, d = threadIdx.x;
    int h = d >> 5;
    float ms[FL_SPLITS], ls[FL_SPLITS];
    float mg = -INFINITY;
    #pragma unroll
    for (int s = 0; s < FL_SPLITS; s++) {
        long mb = (((long)s * 2500 + q) * 8 + h) * 2;
        ms[s] = MLpart[mb];
        ls[s] = MLpart[mb + 1];
        mg = fmaxf(mg, ms[s]);
    }
    float lsum = 0.f, osum = 0.f;
    #pragma unroll
    for (int s = 0; s < FL_SPLITS; s++) {
        float w = __expf(ms[s] - mg);
        lsum += ls[s] * w;
        osum += Opart[((long)s * 2500 + q) * 256 + d] * w;
    }
    O[(long)q * 256 + d] = osum / lsum;
}

// ---------------- masked softmax over 192 deformable-attn logits (row stride ld) ----------------
__global__ __launch_bounds__(64) void scasoftmax_k(float* __restrict__ logits, int ld,
                                                   const int* __restrict__ valid)
{
    int q = blockIdx.x, lane = threadIdx.x;
    float v[3]; int mk[3];
    #pragma unroll
    for (int i = 0; i < 3; i++) {
        int idx = i * 64 + lane;
        int c = idx >> 5;
        mk[i] = valid[q * 6 + c];
        v[i] = mk[i] ? logits[(long)q * ld + idx] : -1e30f;
    }
    float mx = fmaxf(fmaxf(v[0], v[1]), v[2]);
    #pragma unroll
    for (int o = 32; o > 0; o >>= 1) mx = fmaxf(mx, __shfl_xor(mx, o, 64));
    float e[3]; float s = 0.f;
    #pragma unroll
    for (int i = 0; i < 3; i++) { e[i] = expf(v[i] - mx); s += e[i]; }
    #pragma unroll
    for (int o = 32; o > 0; o >>= 1) s += __shfl_xor(s, o, 64);
    float inv = 1.f / s;
    #pragma unroll
    for (int i = 0; i < 3; i++)
        logits[(long)q * ld + i * 64 + lane] = mk[i] ? e[i] * inv : 0.f;
}

// ---------------- deformable sampling: batched gathers for memory-level parallelism ----------------
// Unconditional loads (invalid corners have cw=0, idx=0); 32 loads in flight per batch.
__global__ __launch_bounds__(256) void sample_k(const float* __restrict__ vals,
                                                const float* __restrict__ offs, int ld,
                                                const float* __restrict__ wts,
                                                const float* __restrict__ refp,
                                                const int* __restrict__ valid,
                                                float* __restrict__ out)
{
    int q = blockIdx.x, d = threadIdx.x;
    __shared__ float s_cw[6][32][4];
    __shared__ int   s_idx[6][32][4];
    if (d < 192) {
        int c = d >> 5, pt = d & 31;
        if (valid[q * 6 + c]) {
            float ox = offs[(long)q * ld + (c * 32 + pt) * 2 + 0];
            float oy = offs[(long)q * ld + (c * 32 + pt) * 2 + 1];
            float px = refp[(q * 6 + c) * 2 + 0] + ox * (2.f / 49.f);
            float py = refp[(q * 6 + c) * 2 + 1] + oy * (2.f / 27.f);
            float gx = (px + 1.f) * 0.5f * 49.f;
            float gy = (py + 1.f) * 0.5f * 27.f;
            float x0f = floorf(gx), y0f = floorf(gy);
            float wx = gx - x0f, wy = gy - y0f;
            int x0 = (int)x0f, y0 = (int)y0f;
            float wgt = wts[(long)q * ld + c * 32 + pt];
            float cw[4] = {(1.f - wx) * (1.f - wy), wx * (1.f - wy), (1.f - wx) * wy, wx * wy};
            const int dxs[4] = {0, 1, 0, 1};
            const int dys[4] = {0, 0, 1, 1};
            #pragma unroll
            for (int k2 = 0; k2 < 4; k2++) {
                int xi = x0 + dxs[k2], yi = y0 + dys[k2];
                bool ok = (xi >= 0) && (xi < 50) && (yi >= 0) && (yi < 28);
                s_cw[c][pt][k2]  = ok ? cw[k2] * wgt : 0.f;
                s_idx[c][pt][k2] = ok ? (yi * 50 + xi) * 256 : 0;
            }
        }
    }
    __syncthreads();
    float acc = 0.f;
    for (int c = 0; c < 6; c++) {
        if (!valid[q * 6 + c]) continue;
        const float* vb = vals + (long)c * 358400 + d;
        #pragma unroll
        for (int pt0 = 0; pt0 < 32; pt0 += 8) {
            float vv[8][4];
            #pragma unroll
            for (int i = 0; i < 8; i++)
                #pragma unroll
                for (int k2 = 0; k2 < 4; k2++)
                    vv[i][k2] = vb[s_idx[c][pt0 + i][k2]];
            #pragma unroll
            for (int i = 0; i < 8; i++)
                #pragma unroll
                for (int k2 = 0; k2 < 4; k2++)
                    acc += s_cw[c][pt0 + i][k2] * vv[i][k2];
        }
    }
    out[(long)q * 256 + d] = acc;
}

// =====================================================================================
extern "C" void kernel_launch(void* const* d_in, const int* in_sizes, int n_in,
                              void* d_out, int out_size, void* d_ws, size_t ws_size,
                              hipStream_t stream)
{
    const float* images = (const float*)d_in[0];
    const float* intr   = (const float*)d_in[1];
    const float* e2c    = (const float*)d_in[2];
    const float* bevq   = (const float*)d_in[3];
    const float* bevp   = (const float*)d_in[4];
    const float* bbw[5]    = {(const float*)d_in[5],  (const float*)d_in[9],  (const float*)d_in[13], (const float*)d_in[17], (const float*)d_in[21]};
    const float* bbb[5]    = {(const float*)d_in[6],  (const float*)d_in[10], (const float*)d_in[14], (const float*)d_in[18], (const float*)d_in[22]};
    const float* bbg[5]    = {(const float*)d_in[7],  (const float*)d_in[11], (const float*)d_in[15], (const float*)d_in[19], (const float*)d_in[23]};
    const float* bbbeta[5] = {(const float*)d_in[8],  (const float*)d_in[12], (const float*)d_in[16], (const float*)d_in[20], (const float*)d_in[24]};
    const float* sa_wq = (const float*)d_in[25]; const float* sa_bq = (const float*)d_in[26];
    const float* sa_wk = (const float*)d_in[27]; const float* sa_bk = (const float*)d_in[28];
    const float* sa_wv = (const float*)d_in[29]; const float* sa_bv = (const float*)d_in[30];
    const float* sa_wo = (const float*)d_in[31]; const float* sa_bo = (const float*)d_in[32];
    const float* ln1g = (const float*)d_in[33]; const float* ln1b = (const float*)d_in[34];
    const float* ln2g = (const float*)d_in[35]; const float* ln2b = (const float*)d_in[36];
    const float* ln3g = (const float*)d_in[37]; const float* ln3b = (const float*)d_in[38];
    const float* offw = (const float*)d_in[39]; const float* offb = (const float*)d_in[40];
    const float* wtw  = (const float*)d_in[41]; const float* wtb  = (const float*)d_in[42];
    const float* valw = (const float*)d_in[43]; const float* valb = (const float*)d_in[44];
    const float* outw = (const float*)d_in[45]; const float* outb = (const float*)d_in[46];
    const float* fw1  = (const float*)d_in[47]; const float* fb1  = (const float*)d_in[48];
    const float* fw2  = (const float*)d_in[49]; const float* fb2  = (const float*)d_in[50];

    // ---- pick camera-batch factor from available workspace (formula unchanged) ----
    auto needB = [](long ncb) -> unsigned long long {
        return (unsigned long long)(ncb * 8601600L + 6681600L) * 4ULL + 6307840ULL + (1 << 20);
    };
    int ncb = 1;
    if      ((unsigned long long)ws_size >= needB(6)) ncb = 6;
    else if ((unsigned long long)ws_size >= needB(3)) ncb = 3;
    else if ((unsigned long long)ws_size >= needB(2)) ncb = 2;

    // ---- workspace layout ----
    float* ws = (float*)d_ws;
    float* A     = ws; ws += (long)ncb * 5734400;  // pair-buffer ping; aliases: bQKV, OP, bOW
    float* Bu    = ws; ws += (long)ncb * 2867200;  // pair-buffer pong; aliases: valsb, MLp
    float* f3bH  = ws; ws += 2560000;              // feats3 (backbone) / ffn hidden (transformer)
    float* feats = ws; ws += 2150400;              // (6,1400,256) hwd; also GN parts (early backbone)
    float* qbuf  = ws; ws += 640000;
    float* xq    = ws; ws += 640000;
    float* bO    = ws; ws += 640000;
    float* refp  = ws; ws += 30016;
    int*   validb = (int*)ws; ws += 15040;
    float* stats = ws; ws += 384;
    float* gnst  = ws; ws += 3072;                 // per-group mean/rstd (ncb x 32 x 2)
    float* qkvb  = ws; ws += 1536;
    float* owb   = ws; ws += 1152;
    // bf16 weight buffers
    short* sb = (short*)ws;
    short* cw0b = sb; sb += 2048;                  // conv0 (64,32) padded, k = ci*9+t
    short* cw1b = sb; sb += 73728;                 // tap-major (128, 9*64)
    short* cw2b = sb; sb += 294912;                // tap-major (256, 9*128)
    short* cw3b = sb; sb += 589824;                // tap-major (256, 9*256)
    short* cw4b = sb; sb += 65536;
    short* qkvT = sb; sb += 393216;
    short* owT  = sb; sb += 131072;
    short* valT = sb; sb += 131072;
    short* outT = sb; sb += 131072;
    short* offwtT = sb; sb += 294912;
    short* f1T  = sb; sb += 524288;
    short* f2T  = sb; sb += 524288;
    // aliases
    float*  feats3 = f3bH;
    float*  bH     = f3bH;
    float*  bQKV   = A;
    float*  OP     = A + 1920000;
    float*  bOW    = A + 1920000;
    float*  valsb  = Bu;
    float*  MLp    = Bu + 2150400;
    unsigned* Bbf0 = (unsigned*)A;                 // pair ping (stride varies per stage)
    unsigned* Bbf1 = (unsigned*)Bu;                // pair pong
    float2* partsP = (float2*)feats;               // 6*32*1400 float2 = 2.15 MB (free until conv4)

    auto mgemm = [&](const float* Ain, int lda, const short* Bt, const float* bias, const float* resid,
                     float* C, int M, int N, int K, int act) {
        dim3 g((N + 63) / 64, (M + 63) / 64);
        mgemm_k<<<g, 256, 0, stream>>>(Ain, lda, Bt, bias, resid, C, M, N, K, act);
    };

    // ---- weight preprocessing ----
    wcast0_k<<<8, 256, 0, stream>>>(bbw[0], cw0b);
    wreord_k<<<(73728 + 255) / 256, 256, 0, stream>>>(bbw[1], cw1b, 64, 73728);
    wreord_k<<<(294912 + 255) / 256, 256, 0, stream>>>(bbw[2], cw2b, 128, 294912);
    wreord_k<<<(589824 + 255) / 256, 256, 0, stream>>>(bbw[3], cw3b, 256, 589824);
    wcast_k<<<(65536 + 255) / 256, 256, 0, stream>>>(bbw[4], cw4b, 65536);
    wtrans6_k<<<dim3(4, 4, 12), 256, 0, stream>>>(sa_wq, sa_wk, sa_wv, sa_wo, valw, outw,
                                                  qkvT, qkvT + 65536, qkvT + 131072, owT, valT, outT);
    wtrans_k<<<dim3(6, 4, 2), 256, 0, stream>>>(offw, offwtT,         256, 384,  147456);
    wtrans_k<<<dim3(3, 4, 2), 256, 0, stream>>>(wtw,  offwtT + 98304, 256, 192,  147456);
    wtrans_k<<<dim3(16, 4, 2), 256, 0, stream>>>(fw1, f1T, 256, 1024, 262144);
    wtrans_k<<<dim3(4, 16, 2), 256, 0, stream>>>(fw2, f2T, 1024, 256, 262144);
    packb_k<<<dim3(3, 2), 256, 0, stream>>>(sa_bq, sa_bk, sa_bv, qkvb, 256, 256, 256);
    packb_k<<<dim3(3, 2), 256, 0, stream>>>(offb, wtb, nullptr, owb, 384, 192, 0);

    // ---- projection of BEV grid ----
    project_k<<<(15000 + 255) / 256, 256, 0, stream>>>(intr, e2c, refp, validb);

    // ---- backbone (cam-batched; bf16-pair activations) ----
    for (int c0 = 0; c0 < 6; c0 += ncb) {
        const float* img = images + (long)c0 * 1075200;
        // conv0 fused MFMA -> pairs + stats
        conv0f_k<<<dim3(1400, 1, ncb), 256, 0, stream>>>(img, cw0b, bbb[0], Bbf0, partsP,
                                                         1075200L, 2867200L);
        gnfin_k<<<dim3(32, ncb), 256, 0, stream>>>(partsP, gnst, 1400, 1.f / 179200.f);
        pairapply_k<<<dim3(2800, 1, ncb), 256, 0, stream>>>(Bbf0, bbg[0], bbbeta[0], gnst, 89600, 2, 2867200L);
        // conv1 -> pairs + fused stats (flat grid 350*2, XCD-chunk swizzle)
        mconv_k<<<dim3(700, 1, ncb), 256, 0, stream>>>(Bbf0, cw1b, bbb[1], (float*)Bbf1, partsP,
                                                       1, 128, 224, 400, 2, 4, 1, 2867200L, 1433600L);
        gnfin_k<<<dim3(32, ncb), 256, 0, stream>>>(partsP, gnst, 350, 1.f / 89600.f);
        pairapply_k<<<dim3(1400, 1, ncb), 256, 0, stream>>>(Bbf1, bbg[1], bbbeta[1], gnst, 22400, 4, 1433600L);
        // conv2 -> pairs + fused stats (flat grid 88*4)
        mconv_k<<<dim3(352, 1, ncb), 256, 0, stream>>>(Bbf1, cw2b, bbb[2], (float*)Bbf0, partsP,
                                                       2, 256, 112, 200, 2, 8, 2, 1433600L, 716800L);
        gnfin_k<<<dim3(32, ncb), 256, 0, stream>>>(partsP, gnst, 88, 1.f / 44800.f);
        pairapply_k<<<dim3(700, 1, ncb), 256, 0, stream>>>(Bbf0, bbg[2], bbbeta[2], gnst, 5600, 8, 716800L);
        // conv3 -> f32 spatial-major feats3[cam] (flat grid 22*4)
        mconv_k<<<dim3(88, 1, ncb), 256, 0, stream>>>(Bbf0, cw3b, bbb[3], feats3 + (long)c0 * 358400, nullptr,
                                                      3, 256, 56, 100, 1, 0, 2, 716800L, 358400L);
    }
    // batched conv3-GN (+relu), conv4 as one 8400x256 GEMM, batched conv4-GN
    gn_stats_hwd_k<<<dim3(32, 6), 256, 0, stream>>>(feats3, stats);
    gn_apply_hwd_k<<<dim3(350, 6), 256, 0, stream>>>(feats3, bbg[3], bbbeta[3], stats, 1);
    mgemm(feats3, 256, cw4b, bbb[4], nullptr, feats, 8400, 256, 256, 0);
    gn_stats_hwd_k<<<dim3(32, 6), 256, 0, stream>>>(feats, stats);
    gn_apply_hwd_k<<<dim3(350, 6), 256, 0, stream>>>(feats, bbg[4], bbbeta[4], stats, 0);

    // ---- transformer ----
    qinit_k<<<2500, 256, 0, stream>>>(bevq, bevp, qbuf);

    for (int l = 0; l < 2; l++) {
        long o1 = (long)l * 256;

        // self-attention (fused QKV projection: 2500 x 768)
        ln_k<<<625, 256, 0, stream>>>(qbuf, ln1g + o1, ln1b + o1, xq);
        mgemm(xq, 256, qkvT + l * 196608, qkvb + l * 768, nullptr, bQKV, 2500, 768, 256, 0);
        flash2_k<<<dim3(40, 8, FL_SPLITS), 256, 0, stream>>>(bQKV, bQKV + 256, bQKV + 512, 768, OP, MLp);
        flashmerge_k<<<2500, 256, 0, stream>>>(OP, MLp, bO);
        mgemm(bO, 256, owT + l * 65536, sa_bo + o1, qbuf, qbuf, 2500, 256, 256, 0);

        // spatial cross-attention (fused offsets+logits projection: 2500 x 576)
        ln_k<<<625, 256, 0, stream>>>(qbuf, ln2g + o1, ln2b + o1, xq);
        mgemm(feats, 256, valT + l * 65536, valb + o1, nullptr, valsb, 8400, 256, 256, 0);
        mgemm(xq, 256, offwtT + l * 147456, owb + l * 576, nullptr, bOW, 2500, 576, 256, 0);
        scasoftmax_k<<<2500, 64, 0, stream>>>(bOW + 384, 576, validb);
        sample_k<<<2500, 256, 0, stream>>>(valsb, bOW, 576, bOW + 384, refp, validb, bO);
        mgemm(bO, 256, outT + l * 65536, outb + o1, qbuf, qbuf, 2500, 256, 256, 0);

        // FFN
        ln_k<<<625, 256, 0, stream>>>(qbuf, ln3g + o1, ln3b + o1, xq);
        mgemm(xq, 256, f1T + l * 262144, fb1 + (long)l * 1024, nullptr, bH, 2500, 1024, 256, 2);
        mgemm(bH, 1024, f2T + l * 262144, fb2 + o1, qbuf,
              (l == 1) ? (float*)d_out : qbuf, 2500, 256, 1024, 0);
    }
}

// Round 12
// 874.904 us; speedup vs baseline: 2.2680x; 1.0210x over previous
//
#include <hip/hip_runtime.h>
#include <hip/hip_bf16.h>
#include <math.h>

#define EPS 1e-5f
#define FL_SPLITS 5
#define FL_KEYS 500

typedef __attribute__((ext_vector_type(8))) short short8;
typedef __attribute__((ext_vector_type(4))) float f4;

__device__ __forceinline__ short f2s(float f) {
    union { float f; unsigned u; } v; v.f = f;
    unsigned r = (v.u + 0x7fffu + ((v.u >> 16) & 1u)) >> 16;  // RNE
    return (short)r;
}
__device__ __forceinline__ unsigned packbf(float a, float b) {
    return (unsigned)(unsigned short)f2s(a) | ((unsigned)(unsigned short)f2s(b) << 16);
}
__device__ __forceinline__ float bflo(unsigned v) { union { unsigned u; float f; } t; t.u = v << 16; return t.f; }
__device__ __forceinline__ float bfhi(unsigned v) { union { unsigned u; float f; } t; t.u = v & 0xffff0000u; return t.f; }

// ---------------- weight preprocessing ----------------
__global__ __launch_bounds__(256) void wcast_k(const float* __restrict__ in, short* __restrict__ out, int n)
{
    int i = blockIdx.x * 256 + threadIdx.x;
    if (i < n) out[i] = f2s(in[i]);
}

// conv0 weight pack: (64,3,3,3) fp32 -> (64,32) bf16, k = ci*9 + t, pad 27..31 = 0
__global__ __launch_bounds__(256) void wcast0_k(const float* __restrict__ in, short* __restrict__ out)
{
    int i = blockIdx.x * 256 + threadIdx.x;
    if (i >= 2048) return;
    int k = i & 31;
    out[i] = (k < 27) ? f2s(in[(i >> 5) * 27 + k]) : (short)0;
}

// conv weight reorder: (Cout, Cin, 3,3) fp32 -> (Cout, 9, Cin) bf16 (tap-major)
__global__ __launch_bounds__(256) void wreord_k(const float* __restrict__ in, short* __restrict__ out,
                                                int Cin, int n)
{
    int i = blockIdx.x * 256 + threadIdx.x;
    if (i >= n) return;
    int cin9 = Cin * 9;
    int co = i / cin9, rem = i - co * cin9;
    int ci = rem / 9, t = rem - ci * 9;
    out[(long)co * cin9 + t * Cin + ci] = f2s(in[i]);
}

// (K,N) fp32 -> (N,K) bf16 ; blockIdx.z = matrix index, zstride = output stride per matrix
__global__ __launch_bounds__(256) void wtrans_k(const float* __restrict__ in, short* __restrict__ out,
                                                int K, int N, long zstride)
{
    in  += (long)blockIdx.z * K * N;
    out += (long)blockIdx.z * zstride;
    __shared__ float t[64][65];
    int k0 = blockIdx.y * 64, n0 = blockIdx.x * 64;
    int tid = threadIdx.x;
    int cl = tid & 63, rq = tid >> 6;
    #pragma unroll
    for (int i = 0; i < 16; i++) {
        int rl = rq + i * 4;
        int k = k0 + rl, n = n0 + cl;
        t[rl][cl] = (k < K && n < N) ? in[(long)k * N + n] : 0.f;
    }
    __syncthreads();
    #pragma unroll
    for (int i = 0; i < 16; i++) {
        int nl = rq + i * 4;
        int n = n0 + nl, k = k0 + cl;
        if (n < N && k < K) out[(long)n * K + k] = f2s(t[cl][nl]);
    }
}

// six 256x256 (K,N)->(N,K) transposes in one dispatch; blockIdx.z = mat*2 + layer
__global__ __launch_bounds__(256) void wtrans6_k(const float* __restrict__ s0, const float* __restrict__ s1,
                                                 const float* __restrict__ s2, const float* __restrict__ s3,
                                                 const float* __restrict__ s4, const float* __restrict__ s5,
                                                 short* __restrict__ d0, short* __restrict__ d1,
                                                 short* __restrict__ d2, short* __restrict__ d3,
                                                 short* __restrict__ d4, short* __restrict__ d5)
{
    int mat = blockIdx.z >> 1, l = blockIdx.z & 1;
    const float* in; short* out; long zs;
    if      (mat == 0) { in = s0; out = d0; zs = 196608; }
    else if (mat == 1) { in = s1; out = d1; zs = 196608; }
    else if (mat == 2) { in = s2; out = d2; zs = 196608; }
    else if (mat == 3) { in = s3; out = d3; zs = 65536; }
    else if (mat == 4) { in = s4; out = d4; zs = 65536; }
    else               { in = s5; out = d5; zs = 65536; }
    in  += (long)l * 65536;
    out += (long)l * zs;
    __shared__ float t[64][65];
    int k0 = blockIdx.y * 64, n0 = blockIdx.x * 64;
    int tid = threadIdx.x;
    int cl = tid & 63, rq = tid >> 6;
    #pragma unroll
    for (int i = 0; i < 16; i++) {
        int rl = rq + i * 4;
        t[rl][cl] = in[(long)(k0 + rl) * 256 + n0 + cl];
    }
    __syncthreads();
    #pragma unroll
    for (int i = 0; i < 16; i++) {
        int nl = rq + i * 4;
        out[(long)(n0 + nl) * 256 + k0 + cl] = f2s(t[cl][nl]);
    }
}

// pack per-layer bias segments
__global__ __launch_bounds__(256) void packb_k(const float* __restrict__ a, const float* __restrict__ b,
                                               const float* __restrict__ c, float* __restrict__ y,
                                               int na, int nb, int nc)
{
    int l = blockIdx.y;
    int j = blockIdx.x * 256 + threadIdx.x;
    int ntot = na + nb + nc;
    if (j >= ntot) return;
    float v;
    if (j < na) v = a[l * na + j];
    else if (j < na + nb) v = b[l * nb + (j - na)];
    else v = c[l * nc + (j - na - nb)];
    y[(long)l * ntot + j] = v;
}

// ---------------- MFMA GEMM, 64x64 tile (4 waves, 2x2 MFMA each): C = A(fp32) @ Bt^T ----------------
__global__ __launch_bounds__(256) void mgemm_k(const float* __restrict__ A, int lda,
                                               const short* __restrict__ Bt,
                                               const float* __restrict__ bias,
                                               const float* __restrict__ resid,
                                               float* __restrict__ C,
                                               int M, int N, int K, int act)
{
    __shared__ __align__(16) short As[2560];   // 64 rows x 40 (32 used)
    __shared__ __align__(16) short Bs[2560];
    int tid = threadIdx.x;
    int wave = tid >> 6, lane = tid & 63;
    int wm = wave >> 1, wn = wave & 1;
    int quad = lane >> 4, l15 = lane & 15;
    int m0 = blockIdx.y * 64, n0 = blockIdx.x * 64;
    int srow = tid >> 2, skc = (tid & 3) << 3;
    f4 acc[2][2];
    #pragma unroll
    for (int i = 0; i < 2; i++) { acc[i][0] = (f4){0.f,0.f,0.f,0.f}; acc[i][1] = (f4){0.f,0.f,0.f,0.f}; }
    short8 aR, bR;
    auto loadAB = [&](int kt) {
        int gm = m0 + srow;
        short8 pk = {0, 0, 0, 0, 0, 0, 0, 0};
        if (gm < M) {
            const float4* ap = (const float4*)(A + (long)gm * lda + kt + skc);
            float4 v0 = ap[0], v1 = ap[1];
            pk[0] = f2s(v0.x); pk[1] = f2s(v0.y); pk[2] = f2s(v0.z); pk[3] = f2s(v0.w);
            pk[4] = f2s(v1.x); pk[5] = f2s(v1.y); pk[6] = f2s(v1.z); pk[7] = f2s(v1.w);
        }
        aR = pk;
        int gn = n0 + srow;
        short8 pb = {0, 0, 0, 0, 0, 0, 0, 0};
        if (gn < N) pb = *(const short8*)&Bt[(long)gn * K + kt + skc];
        bR = pb;
    };
    loadAB(0);
    for (int kt = 0; kt < K; kt += 32) {
        *(short8*)&As[srow * 40 + skc] = aR;
        *(short8*)&Bs[srow * 40 + skc] = bR;
        __syncthreads();
        if (kt + 32 < K) loadAB(kt + 32);
        short8 af[2], bf[2];
        #pragma unroll
        for (int mi = 0; mi < 2; mi++) af[mi] = *(const short8*)&As[(wm * 32 + mi * 16 + l15) * 40 + (quad << 3)];
        #pragma unroll
        for (int ni = 0; ni < 2; ni++) bf[ni] = *(const short8*)&Bs[(wn * 32 + ni * 16 + l15) * 40 + (quad << 3)];
        #pragma unroll
        for (int mi = 0; mi < 2; mi++)
            #pragma unroll
            for (int ni = 0; ni < 2; ni++)
                acc[mi][ni] = __builtin_amdgcn_mfma_f32_16x16x32_bf16(af[mi], bf[ni], acc[mi][ni], 0, 0, 0);
        __syncthreads();
    }
    #pragma unroll
    for (int mi = 0; mi < 2; mi++) {
        int row = m0 + wm * 32 + mi * 16 + quad * 4;
        #pragma unroll
        for (int ni = 0; ni < 2; ni++) {
            int col = n0 + wn * 32 + ni * 16 + l15;
            if (col >= N) continue;
            float bv = bias[col];
            #pragma unroll
            for (int r = 0; r < 4; r++) {
                int rr = row + r;
                if (rr >= M) continue;
                float v = acc[mi][ni][r] + bv;
                if (act == 2) v = 0.5f * v * (1.f + erff(v * 0.70710678118654752f));
                if (resid) v += resid[(long)rr * N + col];
                C[(long)rr * N + col] = v;
            }
        }
    }
}

// ---------------- MFMA conv 3x3 s2 p1, tap-major K, bf16-pair input, BK=64, M-tile=128 ----------------
// Flattened grid (nSpatial<<ctshift, 1, ncb) with XCD-chunk bijective swizzle; 128 Cout rows per block.
// 16 MFMAs per barrier pair. mode 1: f32 spatial-major out. mode 2: bf16-pair out + GN stats.
__global__ __launch_bounds__(256) void mconv_k(const unsigned* __restrict__ in,
                                               const short* __restrict__ wgt,
                                               const float* __restrict__ bias,
                                               float* __restrict__ out,
                                               float2* __restrict__ parts,
                                               int c5m, int Cout, int Hin, int Win,
                                               int mode, int cpg, int ctshift,
                                               long istride, long ostride)
{
    // bijective XCD-chunk swizzle (m204): lin -> wgid, couttile fastest
    int lin = blockIdx.x + gridDim.x * blockIdx.z;
    int nwgT = gridDim.x * gridDim.z;
    int xcd = lin & 7, seq = lin >> 3;
    int qd = nwgT >> 3, rd = nwgT & 7;
    int wgid = (xcd < rd ? xcd * (qd + 1) : rd * (qd + 1) + (xcd - rd) * qd) + seq;
    int cam = wgid / gridDim.x;
    int rem = wgid - cam * gridDim.x;
    int couttile = rem & ((1 << ctshift) - 1);
    int spatial = rem >> ctshift;

    in  += (long)cam * istride;
    const int Hout = Hin >> 1, Wout = Win >> 1;
    const int HWo = Hout * Wout;
    const int HW = Hin * Win;
    const int Ktot = 288 << c5m;       // 9*Cin
    const int ch_sh = c5m - 1;         // 64-chunk shift (Cin/64 chunks per tap)
    const int ch_m  = (1 << ch_sh) - 1;
    const int nsteps = 9 << ch_sh;
    __shared__ __align__(16) short As[9216];   // 128 rows x 72 (64 used)
    __shared__ __align__(16) short Bs[4608];   // 64 px x 72
    __shared__ float2 sred[32][2];             // [quad-group][wn] = (s, s2)
    int tid = threadIdx.x;
    int wave = tid >> 6, lane = tid & 63;
    int wm = wave >> 1, wn = wave & 1;
    int quad = lane >> 4, l15 = lane & 15;
    int m0 = couttile << 7, n0 = spatial << 6;
    int nn = tid & 63;
    int kp0 = tid >> 6;
    int p = n0 + nn;
    int pok = p < HWo;
    int pc = pok ? p : (HWo - 1);
    int ho = pc / Wout, wo = pc - ho * Wout;
    int hb = ho * 2 - 1, wb = wo * 2 - 1;

    f4 acc[4][2];
    #pragma unroll
    for (int i = 0; i < 4; i++) { acc[i][0] = (f4){0.f,0.f,0.f,0.f}; acc[i][1] = (f4){0.f,0.f,0.f,0.f}; }

    int arow = tid >> 1, akc = (tid & 1) << 5;     // 32-short granule per thread, 128 rows
    short8 aR0, aR1, aR2, aR3;
    unsigned bR[8];
    auto loadA = [&](int s) {
        const short* ap = &wgt[(long)(m0 + arow) * Ktot + (s << 6) + akc];
        aR0 = *(const short8*)ap;
        aR1 = *(const short8*)(ap + 8);
        aR2 = *(const short8*)(ap + 16);
        aR3 = *(const short8*)(ap + 24);
    };
    // thread owns 8 CONTIGUOUS channel-pairs kp = kp0*8 .. kp0*8+7 -> two b128 LDS writes
    auto loadB = [&](int s) {
        int t = s >> ch_sh;
        int kh3 = (t * 11) >> 5;           // t/3 for t in 0..8
        int kw3 = t - kh3 * 3;
        int y = hb + kh3, x = wb + kw3;
        bool okp = pok && ((unsigned)y < (unsigned)Hin) && ((unsigned)x < (unsigned)Win);
        int base = (((s & ch_m) << 5) + (kp0 << 3)) * HW + y * Win + x;
        #pragma unroll
        for (int i = 0; i < 8; i++) {
            unsigned v = 0;
            if (okp) v = in[base + i * HW];
            bR[i] = v;
        }
    };

    loadA(0); loadB(0);
    for (int s = 0; s < nsteps; s++) {
        *(short8*)&As[arow * 72 + akc]      = aR0;
        *(short8*)&As[arow * 72 + akc + 8]  = aR1;
        *(short8*)&As[arow * 72 + akc + 16] = aR2;
        *(short8*)&As[arow * 72 + akc + 24] = aR3;
        *(uint4*)&Bs[nn * 72 + (kp0 << 4)]     = *(uint4*)&bR[0];
        *(uint4*)&Bs[nn * 72 + (kp0 << 4) + 8] = *(uint4*)&bR[4];
        __syncthreads();
        if (s + 1 < nsteps) { loadA(s + 1); loadB(s + 1); }
        #pragma unroll
        for (int kh = 0; kh < 2; kh++) {
            short8 af[4], bf[2];
            #pragma unroll
            for (int mi = 0; mi < 4; mi++)
                af[mi] = *(const short8*)&As[(wm * 64 + mi * 16 + l15) * 72 + kh * 32 + (quad << 3)];
            #pragma unroll
            for (int ni = 0; ni < 2; ni++)
                bf[ni] = *(const short8*)&Bs[(wn * 32 + ni * 16 + l15) * 72 + kh * 32 + (quad << 3)];
            #pragma unroll
            for (int mi = 0; mi < 4; mi++)
                #pragma unroll
                for (int ni = 0; ni < 2; ni++)
                    acc[mi][ni] = __builtin_amdgcn_mfma_f32_16x16x32_bf16(af[mi], bf[ni], acc[mi][ni], 0, 0, 0);
        }
        __syncthreads();
    }

    if (mode == 1) {
        float* outf = out + (long)cam * ostride;
        #pragma unroll
        for (int mi = 0; mi < 4; mi++) {
            int mbase = m0 + wm * 64 + mi * 16 + quad * 4;
            #pragma unroll
            for (int ni = 0; ni < 2; ni++) {
                int n = n0 + wn * 32 + ni * 16 + l15;
                if (n >= HWo) continue;
                #pragma unroll
                for (int r = 0; r < 4; r++) {
                    int m = mbase + r;
                    outf[(long)n * Cout + m] = acc[mi][ni][r] + bias[m];
                }
            }
        }
    } else {
        unsigned* outp = (unsigned*)out + (long)cam * ostride;
        float ssum[4] = {0.f, 0.f, 0.f, 0.f}, qsum[4] = {0.f, 0.f, 0.f, 0.f};
        #pragma unroll
        for (int mi = 0; mi < 4; mi++) {
            int mbase = m0 + wm * 64 + mi * 16 + quad * 4;
            float b0 = bias[mbase], b1 = bias[mbase + 1], b2 = bias[mbase + 2], b3 = bias[mbase + 3];
            #pragma unroll
            for (int ni = 0; ni < 2; ni++) {
                int n = n0 + wn * 32 + ni * 16 + l15;
                if (n >= HWo) continue;
                float v0 = acc[mi][ni][0] + b0;
                float v1 = acc[mi][ni][1] + b1;
                float v2 = acc[mi][ni][2] + b2;
                float v3 = acc[mi][ni][3] + b3;
                long cp = (long)(mbase >> 1) * HWo + n;
                outp[cp]       = packbf(v0, v1);
                outp[cp + HWo] = packbf(v2, v3);
                ssum[mi] += v0 + v1 + v2 + v3;
                qsum[mi] += v0 * v0 + v1 * v1 + v2 * v2 + v3 * v3;
            }
        }
        #pragma unroll
        for (int mi = 0; mi < 4; mi++) {
            #pragma unroll
            for (int off = 1; off < 16; off <<= 1) {
                ssum[mi] += __shfl_xor(ssum[mi], off, 16);
                qsum[mi] += __shfl_xor(qsum[mi], off, 16);
            }
        }
        if (l15 == 0) {
            #pragma unroll
            for (int mi = 0; mi < 4; mi++)
                sred[wm * 16 + mi * 4 + quad][wn] = make_float2(ssum[mi], qsum[mi]);
        }
        __syncthreads();
        int ng = 128 / cpg;         // groups covered by this block
        int qpg = cpg >> 2;         // quad-groups per group
        if (tid < ng) {
            float s = 0.f, q = 0.f;
            for (int u = 0; u < qpg; u++) {
                float2 a = sred[tid * qpg + u][0];
                float2 b = sred[tid * qpg + u][1];
                s += a.x + b.x; q += a.y + b.y;
            }
            int gabs = m0 / cpg + tid;
            parts[((long)cam * 32 + gabs) * 1400 + spatial] = make_float2(s, q);
        }
    }
}

// ---------------- conv0 fused MFMA: fp32 image gather -> bf16 MFMA (K=32) -> pair out + GN stats ------
__global__ __launch_bounds__(256) void conv0f_k(const float* __restrict__ img,
                                                const short* __restrict__ wgt,
                                                const float* __restrict__ bias,
                                                unsigned* __restrict__ outp,
                                                float2* __restrict__ parts,
                                                long istride, long ostride)
{
    img  += (long)blockIdx.z * istride;
    outp += (long)blockIdx.z * ostride;
    const int HWo = 89600;
    __shared__ __align__(16) short As[2560];
    __shared__ __align__(16) short Bs[2560];
    __shared__ float2 sred[32][2];
    int tid = threadIdx.x;
    int wave = tid >> 6, lane = tid & 63;
    int wm = wave >> 1, wn = wave & 1;
    int quad = lane >> 4, l15 = lane & 15;
    int n0 = blockIdx.x * 64;
    int srow = tid >> 2, skc = (tid & 3) << 3;
    *(short8*)&As[srow * 40 + skc] = *(const short8*)&wgt[srow * 32 + skc];
    {
        int p = n0 + srow;
        int ho = p / 400, wo = p - ho * 400;
        int hb = ho * 2 - 1, wb = wo * 2 - 1;
        short8 pb;
        #pragma unroll
        for (int j = 0; j < 8; j++) {
            int k = skc + j;
            float v = 0.f;
            if (k < 27) {
                int ci = (k < 9) ? 0 : (k < 18 ? 1 : 2);
                int t = k - ci * 9;
                int kh = (t < 3) ? 0 : (t < 6 ? 1 : 2);
                int kw = t - kh * 3;
                int y = hb + kh, x = wb + kw;
                if ((unsigned)y < 448u && (unsigned)x < 800u)
                    v = img[ci * 358400 + y * 800 + x];
            }
            pb[j] = f2s(v);
        }
        *(short8*)&Bs[srow * 40 + skc] = pb;
    }
    __syncthreads();
    f4 acc[2][2];
    #pragma unroll
    for (int i = 0; i < 2; i++) { acc[i][0] = (f4){0.f,0.f,0.f,0.f}; acc[i][1] = (f4){0.f,0.f,0.f,0.f}; }
    short8 af[2], bf[2];
    #pragma unroll
    for (int mi = 0; mi < 2; mi++) af[mi] = *(const short8*)&As[(wm * 32 + mi * 16 + l15) * 40 + (quad << 3)];
    #pragma unroll
    for (int ni = 0; ni < 2; ni++) bf[ni] = *(const short8*)&Bs[(wn * 32 + ni * 16 + l15) * 40 + (quad << 3)];
    #pragma unroll
    for (int mi = 0; mi < 2; mi++)
        #pragma unroll
        for (int ni = 0; ni < 2; ni++)
            acc[mi][ni] = __builtin_amdgcn_mfma_f32_16x16x32_bf16(af[mi], bf[ni], acc[mi][ni], 0, 0, 0);
    #pragma unroll
    for (int mi = 0; mi < 2; mi++) {
        int mbase = wm * 32 + mi * 16 + quad * 4;
        float b0 = bias[mbase], b1 = bias[mbase + 1], b2 = bias[mbase + 2], b3 = bias[mbase + 3];
        float s0 = 0.f, q0 = 0.f, s1 = 0.f, q1 = 0.f;
        #pragma unroll
        for (int ni = 0; ni < 2; ni++) {
            int n = n0 + wn * 32 + ni * 16 + l15;
            float v0 = acc[mi][ni][0] + b0;
            float v1 = acc[mi][ni][1] + b1;
            float v2 = acc[mi][ni][2] + b2;
            float v3 = acc[mi][ni][3] + b3;
            long cp = (long)(mbase >> 1) * HWo + n;
            outp[cp]       = packbf(v0, v1);
            outp[cp + HWo] = packbf(v2, v3);
            s0 += v0 + v1; q0 += v0 * v0 + v1 * v1;
            s1 += v2 + v3; q1 += v2 * v2 + v3 * v3;
        }
        #pragma unroll
        for (int off = 1; off < 16; off <<= 1) {
            s0 += __shfl_xor(s0, off, 16); q0 += __shfl_xor(q0, off, 16);
            s1 += __shfl_xor(s1, off, 16); q1 += __shfl_xor(q1, off, 16);
        }
        if (l15 == 0) {
            int pi = wm * 16 + mi * 8 + quad * 2;
            sred[pi][wn]     = make_float2(s0, q0);
            sred[pi + 1][wn] = make_float2(s1, q1);
        }
    }
    __syncthreads();
    if (tid < 32) {
        float2 a = sred[tid][0], b = sred[tid][1];
        parts[((long)blockIdx.z * 32 + tid) * 1400 + blockIdx.x] = make_float2(a.x + b.x, a.y + b.y);
    }
}

// ---------------- GN finalize: reduce per-block partials -> mean/rstd ----------------
__global__ __launch_bounds__(256) void gnfin_k(const float2* __restrict__ parts,
                                               float* __restrict__ gnstats, int nx, float invN)
{
    int g = blockIdx.x, cam = blockIdx.y;
    const float2* pb = parts + ((long)cam * 32 + g) * 1400;
    float s = 0.f, q = 0.f;
    for (int i = threadIdx.x; i < nx; i += 256) {
        float2 v = pb[i];
        s += v.x; q += v.y;
    }
    __shared__ float rs[256], rq[256];
    rs[threadIdx.x] = s; rq[threadIdx.x] = q;
    __syncthreads();
    for (int o = 128; o > 0; o >>= 1) {
        if (threadIdx.x < o) { rs[threadIdx.x] += rs[threadIdx.x + o]; rq[threadIdx.x] += rq[threadIdx.x + o]; }
        __syncthreads();
    }
    if (threadIdx.x == 0) {
        float mean = rs[0] * invN;
        float var  = rq[0] * invN - mean * mean;
        gnstats[(cam * 32 + g) * 2]     = mean;
        gnstats[(cam * 32 + g) * 2 + 1] = rsqrtf(var + EPS);
    }
}

// ---------------- in-place GN apply + ReLU on bf16-pair buffer ----------------
__global__ __launch_bounds__(256) void pairapply_k(unsigned* __restrict__ x,
                                                   const float* __restrict__ gamma,
                                                   const float* __restrict__ beta,
                                                   const float* __restrict__ gnstats,
                                                   int HW, int cpg, long zstride)
{
    x       += (long)blockIdx.z * zstride;
    gnstats += (long)blockIdx.z * 64;
    int idx4 = (blockIdx.x * 256 + threadIdx.x) * 4;   // HW%4==0 -> all in one pair-row
    int cp = idx4 / HW;
    int c0 = cp * 2;
    int g = c0 / cpg;
    float mean = gnstats[g * 2], rstd = gnstats[g * 2 + 1];
    float sa = rstd * gamma[c0],     ba = beta[c0]     - mean * sa;
    float sb = rstd * gamma[c0 + 1], bb = beta[c0 + 1] - mean * sb;
    uint4 v = *(uint4*)&x[idx4];
    unsigned* vp = (unsigned*)&v;
    #pragma unroll
    for (int j = 0; j < 4; j++) {
        float lo = fmaxf(bflo(vp[j]) * sa + ba, 0.f);
        float hi = fmaxf(bfhi(vp[j]) * sb + bb, 0.f);
        vp[j] = packbf(lo, hi);
    }
    *(uint4*)&x[idx4] = v;
}

// ---------------- GroupNorm for (1400 x 256) spatial-major, batched over cams (grid.y) ----------------
__global__ __launch_bounds__(256) void gn_stats_hwd_k(const float* __restrict__ x, float* __restrict__ stats)
{
    x += (long)blockIdx.y * 358400;
    stats += blockIdx.y * 64;
    int g = blockIdx.x;  // 32 groups
    float s = 0.f, s2 = 0.f;
    for (int i = threadIdx.x; i < 1400 * 8; i += blockDim.x) {
        int p = i >> 3, c = g * 8 + (i & 7);
        float v = x[(long)p * 256 + c];
        s += v; s2 += v * v;
    }
    __shared__ float rs[256], rq[256];
    rs[threadIdx.x] = s; rq[threadIdx.x] = s2;
    __syncthreads();
    for (int o = 128; o > 0; o >>= 1) {
        if (threadIdx.x < o) { rs[threadIdx.x] += rs[threadIdx.x + o]; rq[threadIdx.x] += rq[threadIdx.x + o]; }
        __syncthreads();
    }
    if (threadIdx.x == 0) {
        float mean = rs[0] / 11200.f;
        float var  = rq[0] / 11200.f - mean * mean;
        stats[g * 2]     = mean;
        stats[g * 2 + 1] = rsqrtf(var + EPS);
    }
}

__global__ __launch_bounds__(256) void gn_apply_hwd_k(float* __restrict__ x,
                                                      const float* __restrict__ gamma,
                                                      const float* __restrict__ beta,
                                                      const float* __restrict__ stats,
                                                      int relu)
{
    x += (long)blockIdx.y * 358400;
    stats += blockIdx.y * 64;
    long i4 = ((long)blockIdx.x * 256 + threadIdx.x) * 4;  // grid.x = 350 -> exact
    int c = (int)(i4 & 255);
    int g = c >> 3;
    float4 v  = *(float4*)&x[i4];
    float4 gm = *(const float4*)&gamma[c];
    float4 bt = *(const float4*)&beta[c];
    float m = stats[g * 2], rs = stats[g * 2 + 1];
    v.x = (v.x - m) * rs * gm.x + bt.x;
    v.y = (v.y - m) * rs * gm.y + bt.y;
    v.z = (v.z - m) * rs * gm.z + bt.z;
    v.w = (v.w - m) * rs * gm.w + bt.w;
    if (relu) {
        v.x = fmaxf(v.x, 0.f); v.y = fmaxf(v.y, 0.f);
        v.z = fmaxf(v.z, 0.f); v.w = fmaxf(v.w, 0.f);
    }
    *(float4*)&x[i4] = v;
}

// ---------------- projection of BEV grid ----------------
__global__ __launch_bounds__(256) void project_k(const float* __restrict__ Kin,
                                                 const float* __restrict__ Ein,
                                                 float* __restrict__ refp, int* __restrict__ valid)
{
    int idx = blockIdx.x * blockDim.x + threadIdx.x;
    if (idx >= 2500 * 6) return;
    int c = idx % 6, q = idx / 6;
    int i = q / 50, j = q % 50;
    float px = (i - 24.5f) * 0.5f;
    float py = (j - 24.5f) * 0.5f;
    const float* E = Ein + c * 16;
    float pc[4];
    #pragma unroll
    for (int r = 0; r < 4; r++)
        pc[r] = E[r * 4 + 0] * px + E[r * 4 + 1] * py + E[r * 4 + 3];
    const float* Km = Kin + c * 9;
    float pix[3];
    #pragma unroll
    for (int r = 0; r < 3; r++)
        pix[r] = Km[r * 3 + 0] * pc[0] + Km[r * 3 + 1] * pc[1] + Km[r * 3 + 2] * pc[2];
    float z = fmaxf(pix[2], 1e-5f);
    float u = pix[0] / z, v = pix[1] / z;
    int ok = (pc[2] > 0.f) && (u >= 0.f) && (u < 800.f) && (v >= 0.f) && (v < 448.f);
    refp[(long)idx * 2 + 0] = 2.f * u / 799.f - 1.f;
    refp[(long)idx * 2 + 1] = 2.f * v / 447.f - 1.f;
    valid[idx] = ok;
}

// ---------------- misc elementwise ----------------
__global__ __launch_bounds__(256) void qinit_k(const float* __restrict__ a, const float* __restrict__ b,
                                               float* __restrict__ y)
{
    int i = blockIdx.x * blockDim.x + threadIdx.x;
    if (i >= 2500 * 256) return;
    y[i] = a[i] + b[i];
}

// ---------------- LayerNorm ----------------
__global__ __launch_bounds__(256) void ln_k(const float* __restrict__ x,
                                            const float* __restrict__ g, const float* __restrict__ b,
                                            float* __restrict__ y)
{
    int row  = blockIdx.x * 4 + (threadIdx.x >> 6);
    int lane = threadIdx.x & 63;
    if (row >= 2500) return;
    const float* xp = x + (long)row * 256;
    float v[4];
    #pragma unroll
    for (int i = 0; i < 4; i++) v[i] = xp[lane + 64 * i];
    float s  = v[0] + v[1] + v[2] + v[3];
    float s2 = v[0] * v[0] + v[1] * v[1] + v[2] * v[2] + v[3] * v[3];
    #pragma unroll
    for (int o = 32; o > 0; o >>= 1) { s += __shfl_xor(s, o, 64); s2 += __shfl_xor(s2, o, 64); }
    float mean = s * (1.f / 256.f);
    float var  = s2 * (1.f / 256.f) - mean * mean;
    float rstd = rsqrtf(var + EPS);
    #pragma unroll
    for (int i = 0; i < 4; i++) {
        int cc = lane + 64 * i;
        y[(long)row * 256 + cc] = (v[i] - mean) * rstd * g[cc] + b[cc];
    }
}

// ---------------- MFMA flash-2 MHA with split-K (packed-QKV aware: row stride ld) ----------------
__global__ __launch_bounds__(256) void flash2_k(const float* __restrict__ Q,
                                                const float* __restrict__ K,
                                                const float* __restrict__ V,
                                                int ld,
                                                float* __restrict__ Opart,   // (S,2500,256)
                                                float* __restrict__ MLpart)  // (S,2500,8,2)
{
    const int h  = blockIdx.y;
    const int q0 = blockIdx.x * 64;
    const int sp = blockIdx.z;
    const int kstart = sp * FL_KEYS, kend = kstart + FL_KEYS;
    const int tid = threadIdx.x;
    const int wave = tid >> 6, lane = tid & 63;
    const int quad = lane >> 4, l15 = lane & 15;
    __shared__ __align__(16) short Qs[64 * 40];
    __shared__ __align__(16) short Ks[64 * 40];
    __shared__ __align__(16) short Vt[32 * 72];
    __shared__ __align__(16) short Ps[64 * 72];
    const float scale = 0.17677669529663687f;
    {
        int row = tid >> 2, kc = (tid & 3) << 3;
        int qi = q0 + row;
        short8 pk = {0, 0, 0, 0, 0, 0, 0, 0};
        if (qi < 2500) {
            const float4* qp = (const float4*)(Q + (long)qi * ld + h * 32 + kc);
            float4 v0 = qp[0], v1 = qp[1];
            pk[0] = f2s(v0.x * scale); pk[1] = f2s(v0.y * scale); pk[2] = f2s(v0.z * scale); pk[3] = f2s(v0.w * scale);
            pk[4] = f2s(v1.x * scale); pk[5] = f2s(v1.y * scale); pk[6] = f2s(v1.z * scale); pk[7] = f2s(v1.w * scale);
        }
        *(short8*)&Qs[row * 40 + kc] = pk;
    }
    __syncthreads();
    short8 aq = *(const short8*)&Qs[(wave * 16 + l15) * 40 + (quad << 3)];
    float m[4], l[4];
    f4 oacc[2];
    #pragma unroll
    for (int r = 0; r < 4; r++) { m[r] = -INFINITY; l[r] = 0.f; }
    oacc[0] = (f4){0.f, 0.f, 0.f, 0.f};
    oacc[1] = (f4){0.f, 0.f, 0.f, 0.f};
    for (int kb = kstart; kb < kend; kb += 64) {
        __syncthreads();
        {
            int row = tid >> 2, kc = (tid & 3) << 3;
            int ki = kb + row;
            short8 pk = {0, 0, 0, 0, 0, 0, 0, 0};
            float vv[8] = {0.f, 0.f, 0.f, 0.f, 0.f, 0.f, 0.f, 0.f};
            if (ki < kend) {
                const float4* kp = (const float4*)(K + (long)ki * ld + h * 32 + kc);
                float4 a0 = kp[0], a1 = kp[1];
                pk[0] = f2s(a0.x); pk[1] = f2s(a0.y); pk[2] = f2s(a0.z); pk[3] = f2s(a0.w);
                pk[4] = f2s(a1.x); pk[5] = f2s(a1.y); pk[6] = f2s(a1.z); pk[7] = f2s(a1.w);
                const float4* vp = (const float4*)(V + (long)ki * ld + h * 32 + kc);
                float4 b0 = vp[0], b1 = vp[1];
                vv[0] = b0.x; vv[1] = b0.y; vv[2] = b0.z; vv[3] = b0.w;
                vv[4] = b1.x; vv[5] = b1.y; vv[6] = b1.z; vv[7] = b1.w;
            }
            *(short8*)&Ks[row * 40 + kc] = pk;
            #pragma unroll
            for (int j = 0; j < 8; j++) Vt[(kc + j) * 72 + row] = f2s(vv[j]);
        }
        __syncthreads();
        f4 sa[4];
        #pragma unroll
        for (int ni = 0; ni < 4; ni++) {
            short8 bk = *(const short8*)&Ks[(ni * 16 + l15) * 40 + (quad << 3)];
            sa[ni] = __builtin_amdgcn_mfma_f32_16x16x32_bf16(aq, bk, (f4){0.f, 0.f, 0.f, 0.f}, 0, 0, 0);
        }
        float sv[4][4];
        #pragma unroll
        for (int ni = 0; ni < 4; ni++) {
            bool colok = (kb + ni * 16 + l15) < kend;
            #pragma unroll
            for (int r = 0; r < 4; r++) sv[ni][r] = colok ? sa[ni][r] : -1e30f;
        }
        float p[4][4];
        #pragma unroll
        for (int r = 0; r < 4; r++) {
            float rm = fmaxf(fmaxf(sv[0][r], sv[1][r]), fmaxf(sv[2][r], sv[3][r]));
            #pragma unroll
            for (int off = 1; off < 16; off <<= 1) rm = fmaxf(rm, __shfl_xor(rm, off, 16));
            float mn = fmaxf(m[r], rm);
            float alpha = __expf(m[r] - mn);
            float rs = 0.f;
            #pragma unroll
            for (int ni = 0; ni < 4; ni++) { p[ni][r] = __expf(sv[ni][r] - mn); rs += p[ni][r]; }
            #pragma unroll
            for (int off = 1; off < 16; off <<= 1) rs += __shfl_xor(rs, off, 16);
            l[r] = l[r] * alpha + rs;
            oacc[0][r] *= alpha; oacc[1][r] *= alpha;
            m[r] = mn;
        }
        #pragma unroll
        for (int ni = 0; ni < 4; ni++)
            #pragma unroll
            for (int r = 0; r < 4; r++)
                Ps[(wave * 16 + quad * 4 + r) * 72 + ni * 16 + l15] = f2s(p[ni][r]);
        #pragma unroll
        for (int kh = 0; kh < 2; kh++) {
            short8 ap = *(const short8*)&Ps[(wave * 16 + l15) * 72 + kh * 32 + (quad << 3)];
            #pragma unroll
            for (int ni = 0; ni < 2; ni++) {
                short8 bv = *(const short8*)&Vt[(ni * 16 + l15) * 72 + kh * 32 + (quad << 3)];
                oacc[ni] = __builtin_amdgcn_mfma_f32_16x16x32_bf16(ap, bv, oacc[ni], 0, 0, 0);
            }
        }
    }
    #pragma unroll
    for (int r = 0; r < 4; r++) {
        int qi = q0 + wave * 16 + quad * 4 + r;
        if (qi < 2500) {
            long ob = ((long)sp * 2500 + qi) * 256 + h * 32;
            Opart[ob + l15]      = oacc[0][r];
            Opart[ob + 16 + l15] = oacc[1][r];
            if (l15 == 0) {
                long mb = (((long)sp * 2500 + qi) * 8 + h) * 2;
                MLpart[mb]     = m[r];
                MLpart[mb + 1] = l[r];
            }
        }
    }
}

__global__ __launch_bounds__(256) void flashmerge_k(const float* __restrict__ Opart,
                                                    const float* __restrict__ MLpart,
                                                    float* __restrict__ O)
{
    int q = blockIdx.x, d = threadIdx.x;
    int h = d >> 5;
    float ms[FL_SPLITS], ls[FL_SPLITS];
    float mg = -INFINITY;
    #pragma unroll
    for (int s = 0; s < FL_SPLITS; s++) {
        long mb = (((long)s * 2500 + q) * 8 + h) * 2;
        ms[s] = MLpart[mb];
        ls[s] = MLpart[mb + 1];
        mg = fmaxf(mg, ms[s]);
    }
    float lsum = 0.f, osum = 0.f;
    #pragma unroll
    for (int s = 0; s < FL_SPLITS; s++) {
        float w = __expf(ms[s] - mg);
        lsum += ls[s] * w;
        osum += Opart[((long)s * 2500 + q) * 256 + d] * w;
    }
    O[(long)q * 256 + d] = osum / lsum;
}

// ---------------- masked softmax over 192 deformable-attn logits (row stride ld) ----------------
__global__ __launch_bounds__(64) void scasoftmax_k(float* __restrict__ logits, int ld,
                                                   const int* __restrict__ valid)
{
    int q = blockIdx.x, lane = threadIdx.x;
    float v[3]; int mk[3];
    #pragma unroll
    for (int i = 0; i < 3; i++) {
        int idx = i * 64 + lane;
        int c = idx >> 5;
        mk[i] = valid[q * 6 + c];
        v[i] = mk[i] ? logits[(long)q * ld + idx] : -1e30f;
    }
    float mx = fmaxf(fmaxf(v[0], v[1]), v[2]);
    #pragma unroll
    for (int o = 32; o > 0; o >>= 1) mx = fmaxf(mx, __shfl_xor(mx, o, 64));
    float e[3]; float s = 0.f;
    #pragma unroll
    for (int i = 0; i < 3; i++) { e[i] = expf(v[i] - mx); s += e[i]; }
    #pragma unroll
    for (int o = 32; o > 0; o >>= 1) s += __shfl_xor(s, o, 64);
    float inv = 1.f / s;
    #pragma unroll
    for (int i = 0; i < 3; i++)
        logits[(long)q * ld + i * 64 + lane] = mk[i] ? e[i] * inv : 0.f;
}

// ---------------- deformable sampling: batched gathers for memory-level parallelism ----------------
__global__ __launch_bounds__(256) void sample_k(const float* __restrict__ vals,
                                                const float* __restrict__ offs, int ld,
                                                const float* __restrict__ wts,
                                                const float* __restrict__ refp,
                                                const int* __restrict__ valid,
                                                float* __restrict__ out)
{
    int q = blockIdx.x, d = threadIdx.x;
    __shared__ float s_cw[6][32][4];
    __shared__ int   s_idx[6][32][4];
    if (d < 192) {
        int c = d >> 5, pt = d & 31;
        if (valid[q * 6 + c]) {
            float ox = offs[(long)q * ld + (c * 32 + pt) * 2 + 0];
            float oy = offs[(long)q * ld + (c * 32 + pt) * 2 + 1];
            float px = refp[(q * 6 + c) * 2 + 0] + ox * (2.f / 49.f);
            float py = refp[(q * 6 + c) * 2 + 1] + oy * (2.f / 27.f);
            float gx = (px + 1.f) * 0.5f * 49.f;
            float gy = (py + 1.f) * 0.5f * 27.f;
            float x0f = floorf(gx), y0f = floorf(gy);
            float wx = gx - x0f, wy = gy - y0f;
            int x0 = (int)x0f, y0 = (int)y0f;
            float wgt = wts[(long)q * ld + c * 32 + pt];
            float cw[4] = {(1.f - wx) * (1.f - wy), wx * (1.f - wy), (1.f - wx) * wy, wx * wy};
            const int dxs[4] = {0, 1, 0, 1};
            const int dys[4] = {0, 0, 1, 1};
            #pragma unroll
            for (int k2 = 0; k2 < 4; k2++) {
                int xi = x0 + dxs[k2], yi = y0 + dys[k2];
                bool ok = (xi >= 0) && (xi < 50) && (yi >= 0) && (yi < 28);
                s_cw[c][pt][k2]  = ok ? cw[k2] * wgt : 0.f;
                s_idx[c][pt][k2] = ok ? (yi * 50 + xi) * 256 : 0;
            }
        }
    }
    __syncthreads();
    float acc = 0.f;
    for (int c = 0; c < 6; c++) {
        if (!valid[q * 6 + c]) continue;
        const float* vb = vals + (long)c * 358400 + d;
        #pragma unroll
        for (int pt0 = 0; pt0 < 32; pt0 += 8) {
            float vv[8][4];
            #pragma unroll
            for (int i = 0; i < 8; i++)
                #pragma unroll
                for (int k2 = 0; k2 < 4; k2++)
                    vv[i][k2] = vb[s_idx[c][pt0 + i][k2]];
            #pragma unroll
            for (int i = 0; i < 8; i++)
                #pragma unroll
                for (int k2 = 0; k2 < 4; k2++)
                    acc += s_cw[c][pt0 + i][k2] * vv[i][k2];
        }
    }
    out[(long)q * 256 + d] = acc;
}

// =====================================================================================
extern "C" void kernel_launch(void* const* d_in, const int* in_sizes, int n_in,
                              void* d_out, int out_size, void* d_ws, size_t ws_size,
                              hipStream_t stream)
{
    const float* images = (const float*)d_in[0];
    const float* intr   = (const float*)d_in[1];
    const float* e2c    = (const float*)d_in[2];
    const float* bevq   = (const float*)d_in[3];
    const float* bevp   = (const float*)d_in[4];
    const float* bbw[5]    = {(const float*)d_in[5],  (const float*)d_in[9],  (const float*)d_in[13], (const float*)d_in[17], (const float*)d_in[21]};
    const float* bbb[5]    = {(const float*)d_in[6],  (const float*)d_in[10], (const float*)d_in[14], (const float*)d_in[18], (const float*)d_in[22]};
    const float* bbg[5]    = {(const float*)d_in[7],  (const float*)d_in[11], (const float*)d_in[15], (const float*)d_in[19], (const float*)d_in[23]};
    const float* bbbeta[5] = {(const float*)d_in[8],  (const float*)d_in[12], (const float*)d_in[16], (const float*)d_in[20], (const float*)d_in[24]};
    const float* sa_wq = (const float*)d_in[25]; const float* sa_bq = (const float*)d_in[26];
    const float* sa_wk = (const float*)d_in[27]; const float* sa_bk = (const float*)d_in[28];
    const float* sa_wv = (const float*)d_in[29]; const float* sa_bv = (const float*)d_in[30];
    const float* sa_wo = (const float*)d_in[31]; const float* sa_bo = (const float*)d_in[32];
    const float* ln1g = (const float*)d_in[33]; const float* ln1b = (const float*)d_in[34];
    const float* ln2g = (const float*)d_in[35]; const float* ln2b = (const float*)d_in[36];
    const float* ln3g = (const float*)d_in[37]; const float* ln3b = (const float*)d_in[38];
    const float* offw = (const float*)d_in[39]; const float* offb = (const float*)d_in[40];
    const float* wtw  = (const float*)d_in[41]; const float* wtb  = (const float*)d_in[42];
    const float* valw = (const float*)d_in[43]; const float* valb = (const float*)d_in[44];
    const float* outw = (const float*)d_in[45]; const float* outb = (const float*)d_in[46];
    const float* fw1  = (const float*)d_in[47]; const float* fb1  = (const float*)d_in[48];
    const float* fw2  = (const float*)d_in[49]; const float* fb2  = (const float*)d_in[50];

    // ---- pick camera-batch factor from available workspace (formula unchanged) ----
    auto needB = [](long ncb) -> unsigned long long {
        return (unsigned long long)(ncb * 8601600L + 6681600L) * 4ULL + 6307840ULL + (1 << 20);
    };
    int ncb = 1;
    if      ((unsigned long long)ws_size >= needB(6)) ncb = 6;
    else if ((unsigned long long)ws_size >= needB(3)) ncb = 3;
    else if ((unsigned long long)ws_size >= needB(2)) ncb = 2;

    // ---- workspace layout ----
    float* ws = (float*)d_ws;
    float* A     = ws; ws += (long)ncb * 5734400;  // pair-buffer ping; aliases: bQKV, OP, bOW
    float* Bu    = ws; ws += (long)ncb * 2867200;  // pair-buffer pong; aliases: valsb, MLp
    float* f3bH  = ws; ws += 2560000;              // feats3 (backbone) / ffn hidden (transformer)
    float* feats = ws; ws += 2150400;              // (6,1400,256) hwd; also GN parts (early backbone)
    float* qbuf  = ws; ws += 640000;
    float* xq    = ws; ws += 640000;
    float* bO    = ws; ws += 640000;
    float* refp  = ws; ws += 30016;
    int*   validb = (int*)ws; ws += 15040;
    float* stats = ws; ws += 384;
    float* gnst  = ws; ws += 3072;                 // per-group mean/rstd (ncb x 32 x 2)
    float* qkvb  = ws; ws += 1536;
    float* owb   = ws; ws += 1152;
    // bf16 weight buffers
    short* sb = (short*)ws;
    short* cw0b = sb; sb += 2048;                  // conv0 (64,32) padded, k = ci*9+t
    short* cw1b = sb; sb += 73728;                 // tap-major (128, 9*64)
    short* cw2b = sb; sb += 294912;                // tap-major (256, 9*128)
    short* cw3b = sb; sb += 589824;                // tap-major (256, 9*256)
    short* cw4b = sb; sb += 65536;
    short* qkvT = sb; sb += 393216;
    short* owT  = sb; sb += 131072;
    short* valT = sb; sb += 131072;
    short* outT = sb; sb += 131072;
    short* offwtT = sb; sb += 294912;
    short* f1T  = sb; sb += 524288;
    short* f2T  = sb; sb += 524288;
    // aliases
    float*  feats3 = f3bH;
    float*  bH     = f3bH;
    float*  bQKV   = A;
    float*  OP     = A + 1920000;
    float*  bOW    = A + 1920000;
    float*  valsb  = Bu;
    float*  MLp    = Bu + 2150400;
    unsigned* Bbf0 = (unsigned*)A;                 // pair ping (stride varies per stage)
    unsigned* Bbf1 = (unsigned*)Bu;                // pair pong
    float2* partsP = (float2*)feats;               // 6*32*1400 float2 = 2.15 MB (free until conv4)

    auto mgemm = [&](const float* Ain, int lda, const short* Bt, const float* bias, const float* resid,
                     float* C, int M, int N, int K, int act) {
        dim3 g((N + 63) / 64, (M + 63) / 64);
        mgemm_k<<<g, 256, 0, stream>>>(Ain, lda, Bt, bias, resid, C, M, N, K, act);
    };

    // ---- weight preprocessing ----
    wcast0_k<<<8, 256, 0, stream>>>(bbw[0], cw0b);
    wreord_k<<<(73728 + 255) / 256, 256, 0, stream>>>(bbw[1], cw1b, 64, 73728);
    wreord_k<<<(294912 + 255) / 256, 256, 0, stream>>>(bbw[2], cw2b, 128, 294912);
    wreord_k<<<(589824 + 255) / 256, 256, 0, stream>>>(bbw[3], cw3b, 256, 589824);
    wcast_k<<<(65536 + 255) / 256, 256, 0, stream>>>(bbw[4], cw4b, 65536);
    wtrans6_k<<<dim3(4, 4, 12), 256, 0, stream>>>(sa_wq, sa_wk, sa_wv, sa_wo, valw, outw,
                                                  qkvT, qkvT + 65536, qkvT + 131072, owT, valT, outT);
    wtrans_k<<<dim3(6, 4, 2), 256, 0, stream>>>(offw, offwtT,         256, 384,  147456);
    wtrans_k<<<dim3(3, 4, 2), 256, 0, stream>>>(wtw,  offwtT + 98304, 256, 192,  147456);
    wtrans_k<<<dim3(16, 4, 2), 256, 0, stream>>>(fw1, f1T, 256, 1024, 262144);
    wtrans_k<<<dim3(4, 16, 2), 256, 0, stream>>>(fw2, f2T, 1024, 256, 262144);
    packb_k<<<dim3(3, 2), 256, 0, stream>>>(sa_bq, sa_bk, sa_bv, qkvb, 256, 256, 256);
    packb_k<<<dim3(3, 2), 256, 0, stream>>>(offb, wtb, nullptr, owb, 384, 192, 0);

    // ---- projection of BEV grid ----
    project_k<<<(15000 + 255) / 256, 256, 0, stream>>>(intr, e2c, refp, validb);

    // ---- backbone (cam-batched; bf16-pair activations) ----
    for (int c0 = 0; c0 < 6; c0 += ncb) {
        const float* img = images + (long)c0 * 1075200;
        // conv0 fused MFMA -> pairs + stats
        conv0f_k<<<dim3(1400, 1, ncb), 256, 0, stream>>>(img, cw0b, bbb[0], Bbf0, partsP,
                                                         1075200L, 2867200L);
        gnfin_k<<<dim3(32, ncb), 256, 0, stream>>>(partsP, gnst, 1400, 1.f / 179200.f);
        pairapply_k<<<dim3(2800, 1, ncb), 256, 0, stream>>>(Bbf0, bbg[0], bbbeta[0], gnst, 89600, 2, 2867200L);
        // conv1 (M-tile 128 = all Cout) -> pairs + fused stats
        mconv_k<<<dim3(350, 1, ncb), 256, 0, stream>>>(Bbf0, cw1b, bbb[1], (float*)Bbf1, partsP,
                                                       1, 128, 224, 400, 2, 4, 0, 2867200L, 1433600L);
        gnfin_k<<<dim3(32, ncb), 256, 0, stream>>>(partsP, gnst, 350, 1.f / 89600.f);
        pairapply_k<<<dim3(1400, 1, ncb), 256, 0, stream>>>(Bbf1, bbg[1], bbbeta[1], gnst, 22400, 4, 1433600L);
        // conv2 (2 M-tiles of 128) -> pairs + fused stats
        mconv_k<<<dim3(176, 1, ncb), 256, 0, stream>>>(Bbf1, cw2b, bbb[2], (float*)Bbf0, partsP,
                                                       2, 256, 112, 200, 2, 8, 1, 1433600L, 716800L);
        gnfin_k<<<dim3(32, ncb), 256, 0, stream>>>(partsP, gnst, 88, 1.f / 44800.f);
        pairapply_k<<<dim3(700, 1, ncb), 256, 0, stream>>>(Bbf0, bbg[2], bbbeta[2], gnst, 5600, 8, 716800L);
        // conv3 (2 M-tiles of 128) -> f32 spatial-major feats3[cam]
        mconv_k<<<dim3(44, 1, ncb), 256, 0, stream>>>(Bbf0, cw3b, bbb[3], feats3 + (long)c0 * 358400, nullptr,
                                                      3, 256, 56, 100, 1, 0, 1, 716800L, 358400L);
    }
    // batched conv3-GN (+relu), conv4 as one 8400x256 GEMM, batched conv4-GN
    gn_stats_hwd_k<<<dim3(32, 6), 256, 0, stream>>>(feats3, stats);
    gn_apply_hwd_k<<<dim3(350, 6), 256, 0, stream>>>(feats3, bbg[3], bbbeta[3], stats, 1);
    mgemm(feats3, 256, cw4b, bbb[4], nullptr, feats, 8400, 256, 256, 0);
    gn_stats_hwd_k<<<dim3(32, 6), 256, 0, stream>>>(feats, stats);
    gn_apply_hwd_k<<<dim3(350, 6), 256, 0, stream>>>(feats, bbg[4], bbbeta[4], stats, 0);

    // ---- transformer ----
    qinit_k<<<2500, 256, 0, stream>>>(bevq, bevp, qbuf);

    for (int l = 0; l < 2; l++) {
        long o1 = (long)l * 256;

        // self-attention (fused QKV projection: 2500 x 768)
        ln_k<<<625, 256, 0, stream>>>(qbuf, ln1g + o1, ln1b + o1, xq);
        mgemm(xq, 256, qkvT + l * 196608, qkvb + l * 768, nullptr, bQKV, 2500, 768, 256, 0);
        flash2_k<<<dim3(40, 8, FL_SPLITS), 256, 0, stream>>>(bQKV, bQKV + 256, bQKV + 512, 768, OP, MLp);
        flashmerge_k<<<2500, 256, 0, stream>>>(OP, MLp, bO);
        mgemm(bO, 256, owT + l * 65536, sa_bo + o1, qbuf, qbuf, 2500, 256, 256, 0);

        // spatial cross-attention (fused offsets+logits projection: 2500 x 576)
        ln_k<<<625, 256, 0, stream>>>(qbuf, ln2g + o1, ln2b + o1, xq);
        mgemm(feats, 256, valT + l * 65536, valb + o1, nullptr, valsb, 8400, 256, 256, 0);
        mgemm(xq, 256, offwtT + l * 147456, owb + l * 576, nullptr, bOW, 2500, 576, 256, 0);
        scasoftmax_k<<<2500, 64, 0, stream>>>(bOW + 384, 576, validb);
        sample_k<<<2500, 256, 0, stream>>>(valsb, bOW, 576, bOW + 384, refp, validb, bO);
        mgemm(bO, 256, outT + l * 65536, outb + o1, qbuf, qbuf, 2500, 256, 256, 0);

        // FFN
        ln_k<<<625, 256, 0, stream>>>(qbuf, ln3g + o1, ln3b + o1, xq);
        mgemm(xq, 256, f1T + l * 262144, fb1 + (long)l * 1024, nullptr, bH, 2500, 1024, 256, 2);
        mgemm(bH, 1024, f2T + l * 262144, fb2 + o1, qbuf,
              (l == 1) ? (float*)d_out : qbuf, 2500, 256, 1024, 0);
    }
}